// Round 1
// baseline (5164.380 us; speedup 1.0000x reference)
//
#include <hip/hip_runtime.h>

#define H 256
#define FIN 58
#define LN_EPS 1e-5f

// ---------------- utilities ----------------

__device__ __forceinline__ float wave_sum(float v) {
#pragma unroll
  for (int off = 1; off < 64; off <<= 1) v += __shfl_xor(v, off, 64);
  return v;
}

__device__ __forceinline__ float block_sum(float v, volatile float* red) {
  const int tid = threadIdx.x;
  v = wave_sum(v);
  __syncthreads();
  if ((tid & 63) == 0) red[tid >> 6] = v;
  __syncthreads();
  return red[0] + red[1] + red[2] + red[3];
}

// ---------------- setup kernels ----------------

__global__ void k_deg(const int* __restrict__ col, int* __restrict__ deg, int E) {
  int e = blockIdx.x * 256 + threadIdx.x;
  if (e < E) atomicAdd(&deg[col[e]], 1);
}

__global__ void k_invsqrt(const int* __restrict__ deg, float* __restrict__ invs, int N) {
  int i = blockIdx.x * 256 + threadIdx.x;
  if (i < N) {
    int d = deg[i];
    invs[i] = (d > 0) ? (1.0f / sqrtf((float)d)) : 0.0f;
  }
}

// single-block exclusive scan of deg -> offs
__global__ void k_scan(const int* __restrict__ deg, int* __restrict__ offs, int N) {
  __shared__ int buf[1024];
  __shared__ int carry;
  const int tid = threadIdx.x;
  if (tid == 0) carry = 0;
  __syncthreads();
  for (int base = 0; base < N; base += 1024) {
    int v = (base + tid < N) ? deg[base + tid] : 0;
    buf[tid] = v;
    __syncthreads();
    for (int off = 1; off < 1024; off <<= 1) {
      int x = (tid >= off) ? buf[tid - off] : 0;
      __syncthreads();
      buf[tid] += x;
      __syncthreads();
    }
    int incl = buf[tid];
    int c = carry;
    if (base + tid < N) offs[base + tid] = c + incl - v;
    __syncthreads();
    if (tid == 1023) carry = c + buf[1023];
    __syncthreads();
  }
}

__global__ void k_scatter(const int* __restrict__ row, const int* __restrict__ col,
                          const float* __restrict__ invs, const int* __restrict__ offs,
                          int* __restrict__ cursor, int* __restrict__ erow,
                          float* __restrict__ ew, int E) {
  int e = blockIdx.x * 256 + threadIdx.x;
  if (e < E) {
    int r = row[e], c = col[e];
    int pos = offs[c] + atomicAdd(&cursor[c], 1);
    erow[pos] = r;
    ew[pos] = invs[c] * invs[r];
  }
}

// iteration-independent weight products:
// P = Wq*Wk^T, Q = Wq*Wq^T, K2 = Wk*Wk^T, pb=Wq*bk, qb=Wq*bq, wb=Wk*bq, kb=Wk*bk,
// sconst = {bq.bk, |bq|^2, |bk|^2}
__global__ void k_prep(const float* __restrict__ Wq, const float* __restrict__ Wk,
                       const float* __restrict__ bq, const float* __restrict__ bk,
                       float* __restrict__ P, float* __restrict__ Q, float* __restrict__ K2,
                       float* __restrict__ pb, float* __restrict__ qb,
                       float* __restrict__ wb, float* __restrict__ kb,
                       float* __restrict__ sconst) {
  __shared__ float red[4];
  const int b = blockIdx.x, tid = threadIdx.x;
  if (b < 768) {
    const int f = b & 255, which = b >> 8;
    const float* A = (which == 2) ? Wk : Wq;
    const float* Bm = (which == 1) ? Wq : Wk;
    float acc = 0.0f;
    for (int m = 0; m < H; m++) acc = fmaf(A[f * H + m], Bm[tid * H + m], acc);
    float* D = (which == 0) ? P : ((which == 1) ? Q : K2);
    D[f * H + tid] = acc;
  } else {
    float a1 = 0, a2 = 0, a3 = 0, a4 = 0;
    for (int m = 0; m < H; m++) {
      float wqv = Wq[tid * H + m], wkv = Wk[tid * H + m];
      a1 = fmaf(wqv, bk[m], a1);
      a2 = fmaf(wqv, bq[m], a2);
      a3 = fmaf(wkv, bq[m], a3);
      a4 = fmaf(wkv, bk[m], a4);
    }
    pb[tid] = a1; qb[tid] = a2; wb[tid] = a3; kb[tid] = a4;
    float c0 = block_sum(bq[tid] * bk[tid], red);
    float c1 = block_sum(bq[tid] * bq[tid], red);
    float c2 = block_sum(bk[tid] * bk[tid], red);
    if (tid == 0) { sconst[0] = c0; sconst[1] = c1; sconst[2] = c2; }
  }
}

// R0 = relu(x@W1 + b1), plus layer-0 readout: out[n] = wgt0*(R0[n].Wr0 + br0)
__global__ void k_fc1(const float* __restrict__ x, const float* __restrict__ W1,
                      const float* __restrict__ b1, const float* __restrict__ Wr,
                      const float* __restrict__ br, const float* __restrict__ wgt,
                      float* __restrict__ R0, float* __restrict__ out, int N) {
  __shared__ __align__(16) float lx[16 * FIN];
  __shared__ float red[4];
  const int tid = threadIdx.x;
  const int n0 = blockIdx.x * 16;
  for (int idx = tid; idx < 16 * FIN / 4; idx += 256)
    ((float4*)lx)[idx] = ((const float4*)(x + (size_t)n0 * FIN))[idx];
  __syncthreads();
  float acc[16];
  const float bias = b1[tid];
#pragma unroll
  for (int r = 0; r < 16; r++) acc[r] = bias;
  for (int f = 0; f < FIN; f++) {
    float wv = W1[f * H + tid];
#pragma unroll
    for (int r = 0; r < 16; r++) acc[r] = fmaf(lx[r * FIN + f], wv, acc[r]);
  }
  const float wr0 = Wr[tid];
#pragma unroll
  for (int r = 0; r < 16; r++) {
    acc[r] = fmaxf(acc[r], 0.0f);
    int n = n0 + r;
    if (n < N) R0[(size_t)n * H + tid] = acc[r];
  }
  const float w0 = wgt[0], b0 = br[0];
  for (int r = 0; r < 16; r++) {
    float s = block_sum(acc[r] * wr0, red);
    int n = n0 + r;
    if (tid == 0 && n < N) out[n] = w0 * (s + b0);
  }
}

// G += R^T R (atomic over super-chunks); mt==0 blocks also accumulate vsum
__global__ void k_G(const float* __restrict__ R, float* __restrict__ G,
                    float* __restrict__ vsum, int N) {
  __shared__ __align__(16) float lr[64 * H];  // 64 KB
  const int tid = threadIdx.x;
  const int mt = blockIdx.x & 3, sc = blockIdx.x >> 2;
  const int mbase = mt * 64 + (tid & 15) * 4;
  const int dbase = (tid >> 4) * 16;
  float acc[4][16];
#pragma unroll
  for (int a = 0; a < 4; a++)
#pragma unroll
    for (int j = 0; j < 16; j++) acc[a][j] = 0.0f;
  float vs = 0.0f;
  for (int sub = 0; sub < 16; sub++) {
    const int n0 = sc * 1024 + sub * 64;
    __syncthreads();
    for (int idx = tid; idx < 64 * (H / 4); idx += 256) {
      int n = n0 + (idx >> 6);
      ((float4*)lr)[idx] = (n < N) ? ((const float4*)R)[(size_t)n * (H / 4) + (idx & 63)]
                                   : make_float4(0, 0, 0, 0);
    }
    __syncthreads();
    for (int nn = 0; nn < 64; nn++) {
      const float* rowp = &lr[nn * H];
      const float4 kv = *(const float4*)&rowp[mbase];
      const float4 d0v = *(const float4*)&rowp[dbase + 0];
      const float4 d1v = *(const float4*)&rowp[dbase + 4];
      const float4 d2v = *(const float4*)&rowp[dbase + 8];
      const float4 d3v = *(const float4*)&rowp[dbase + 12];
      const float kk[4] = {kv.x, kv.y, kv.z, kv.w};
      const float dd[16] = {d0v.x, d0v.y, d0v.z, d0v.w, d1v.x, d1v.y, d1v.z, d1v.w,
                            d2v.x, d2v.y, d2v.z, d2v.w, d3v.x, d3v.y, d3v.z, d3v.w};
#pragma unroll
      for (int a = 0; a < 4; a++)
#pragma unroll
        for (int j = 0; j < 16; j++) acc[a][j] = fmaf(kk[a], dd[j], acc[a][j]);
    }
    if (mt == 0) {
      float s = 0.0f;
      for (int nn = 0; nn < 64; nn++) s += lr[nn * H + tid];
      vs += s;
    }
  }
#pragma unroll
  for (int a = 0; a < 4; a++)
#pragma unroll
    for (int j = 0; j < 16; j++) atomicAdd(&G[(mbase + a) * H + dbase + j], acc[a][j]);
  if (mt == 0) atomicAdd(&vsum[tid], vs);
}

// per-iteration small products from (G, vsum)
__global__ void k_small(const float* __restrict__ G, const float* __restrict__ vsum,
                        const float* __restrict__ P, const float* __restrict__ pb,
                        const float* __restrict__ wb, const float* __restrict__ sconst,
                        const float* __restrict__ Q, const float* __restrict__ K2,
                        float* __restrict__ M, float* __restrict__ cvec,
                        float* __restrict__ dvec, float* __restrict__ scal, int N) {
  __shared__ float red[4];
  const int b = blockIdx.x, tid = threadIdx.x;
  if (b < 256) {  // M[b,:] = sum_m P[b,m] G[m,:] + pb[b]*vsum
    float acc = 0.0f;
    for (int m = 0; m < H; m++) acc = fmaf(P[b * H + m], G[m * H + tid], acc);
    M[b * H + tid] = acc + pb[b] * vsum[tid];
  } else if (b == 256) {  // cvec = wb^T G + (bq.bk) vsum
    float acc = 0.0f;
    for (int f = 0; f < H; f++) acc = fmaf(wb[f], G[f * H + tid], acc);
    cvec[tid] = acc + sconst[0] * vsum[tid];
  } else if (b == 257) {  // dvec = P*vsum + N*pb
    float acc = 0.0f;
    for (int m = 0; m < H; m++) acc = fmaf(P[tid * H + m], vsum[m], acc);
    dvec[tid] = acc + (float)N * pb[tid];
  } else if (b < 274) {  // <G,Q> partial -> scal[0]
    int base = (b - 258) * 4096 + tid;
    float a = 0.0f;
    for (int j = 0; j < 16; j++) a = fmaf(G[base + j * 256], Q[base + j * 256], a);
    a = block_sum(a, red);
    if (tid == 0) atomicAdd(&scal[0], a);
  } else {  // 274..289: <G,K2> partial -> scal[1]
    int base = (b - 274) * 4096 + tid;
    float a = 0.0f;
    for (int j = 0; j < 16; j++) a = fmaf(G[base + j * 256], K2[base + j * 256], a);
    a = block_sum(a, red);
    if (tid == 0) atomicAdd(&scal[1], a);
  }
}

// finalize norms: scal[2] = 1/(|q| |k|), scal[3] = den const
__global__ void k_final(const float* __restrict__ vsum, const float* __restrict__ qb,
                        const float* __restrict__ kb, const float* __restrict__ wb,
                        const float* __restrict__ sconst, float* __restrict__ scal, int N) {
  __shared__ float red[4];
  const int tid = threadIdx.x;
  float s1 = block_sum(qb[tid] * vsum[tid], red);
  float s2 = block_sum(kb[tid] * vsum[tid], red);
  float s3 = block_sum(wb[tid] * vsum[tid], red);
  if (tid == 0) {
    float sq = scal[0] + 2.0f * s1 + (float)N * sconst[1];
    float sk = scal[1] + 2.0f * s2 + (float)N * sconst[2];
    scal[2] = 1.0f / (sqrtf(sq) * sqrtf(sk));
    scal[3] = s3 + (float)N * sconst[0];
  }
}

// fused: num = R*M, den, gcn gather, residual blend, layernorm, write Rnext, readout
__global__ __launch_bounds__(256) void k_C(
    const float* __restrict__ Rcur, float* __restrict__ Rnext,
    const float* __restrict__ Mm, const float* __restrict__ cvec,
    const float* __restrict__ dvec, const float* __restrict__ vsum,
    const float* __restrict__ scal, const int* __restrict__ offs,
    const int* __restrict__ deg, const int* __restrict__ erow,
    const float* __restrict__ ew, const float* __restrict__ alphap,
    const float* __restrict__ gamma, const float* __restrict__ beta,
    const float* __restrict__ Wr, const float* __restrict__ br,
    const float* __restrict__ wgt, float* __restrict__ out,
    int N, int layer, int last) {
  __shared__ __align__(16) float lR[16 * H];  // 16 KB
  __shared__ __align__(16) float lM[32 * H];  // 32 KB
  const int tid = threadIdx.x, lane = tid & 63, wv = tid >> 6;
  const int wv4 = wv * 4;
  const int d0 = lane * 4;
  const int n0 = blockIdx.x * 16;

  for (int idx = tid; idx < 16 * (H / 4); idx += 256) {
    int n = n0 + (idx >> 6);
    ((float4*)lR)[idx] = (n < N) ? ((const float4*)Rcur)[(size_t)n * (H / 4) + (idx & 63)]
                                 : make_float4(0, 0, 0, 0);
  }
  __syncthreads();

  float accn[4][4];
#pragma unroll
  for (int r = 0; r < 4; r++)
#pragma unroll
    for (int j = 0; j < 4; j++) accn[r][j] = 0.0f;

  for (int ch = 0; ch < 8; ch++) {
    __syncthreads();
    for (int idx = tid; idx < 32 * (H / 4); idx += 256)
      ((float4*)lM)[idx] = ((const float4*)(Mm + (size_t)ch * 32 * H))[idx];
    __syncthreads();
#pragma unroll
    for (int f4 = 0; f4 < 8; f4++) {
      const int fb = f4 * 4;
      const float4 m0 = *(const float4*)&lM[(fb + 0) * H + d0];
      const float4 m1 = *(const float4*)&lM[(fb + 1) * H + d0];
      const float4 m2 = *(const float4*)&lM[(fb + 2) * H + d0];
      const float4 m3 = *(const float4*)&lM[(fb + 3) * H + d0];
#pragma unroll
      for (int r = 0; r < 4; r++) {
        const float4 rv = *(const float4*)&lR[(wv4 + r) * H + ch * 32 + fb];
        accn[r][0] = fmaf(rv.x, m0.x, fmaf(rv.y, m1.x, fmaf(rv.z, m2.x, fmaf(rv.w, m3.x, accn[r][0]))));
        accn[r][1] = fmaf(rv.x, m0.y, fmaf(rv.y, m1.y, fmaf(rv.z, m2.y, fmaf(rv.w, m3.y, accn[r][1]))));
        accn[r][2] = fmaf(rv.x, m0.z, fmaf(rv.y, m1.z, fmaf(rv.z, m2.z, fmaf(rv.w, m3.z, accn[r][2]))));
        accn[r][3] = fmaf(rv.x, m0.w, fmaf(rv.y, m1.w, fmaf(rv.z, m2.w, fmaf(rv.w, m3.w, accn[r][3]))));
      }
    }
  }

  const float invn = scal[2], denc = scal[3];
  const float al = alphap[0], om = 1.0f - al;
  const float4 dv = *(const float4*)&dvec[d0];

  float den[4];
#pragma unroll
  for (int r = 0; r < 4; r++) {
    const float* Rr = &lR[(wv4 + r) * H + d0];
    float p = Rr[0] * dv.x + Rr[1] * dv.y + Rr[2] * dv.z + Rr[3] * dv.w;
    p = wave_sum(p);
    den[r] = (p + denc) * invn + (float)N;
  }

  float accg[4][4];
#pragma unroll
  for (int r = 0; r < 4; r++)
#pragma unroll
    for (int j = 0; j < 4; j++) accg[r][j] = 0.0f;
#pragma unroll
  for (int r = 0; r < 4; r++) {
    int n = n0 + wv4 + r;
    if (n < N) {
      int st = offs[n], cnt = deg[n];
      for (int j = 0; j < cnt; j++) {
        int src = erow[st + j];
        float w = ew[st + j];
        const float4 v = *(const float4*)&Rcur[(size_t)src * H + d0];
        accg[r][0] = fmaf(w, v.x, accg[r][0]);
        accg[r][1] = fmaf(w, v.y, accg[r][1]);
        accg[r][2] = fmaf(w, v.z, accg[r][2]);
        accg[r][3] = fmaf(w, v.w, accg[r][3]);
      }
    }
  }

  const float4 cv = *(const float4*)&cvec[d0];
  const float4 vs = *(const float4*)&vsum[d0];
  const float4 gm = *(const float4*)&gamma[d0];
  const float4 bt = *(const float4*)&beta[d0];
  const float4 wr = *(const float4*)&Wr[layer * H + d0];
  const float wl = wgt[layer], bl = br[layer];

#pragma unroll
  for (int r = 0; r < 4; r++) {
    const int n = n0 + wv4 + r;
    const float rden = 1.0f / den[r];
    const float4 old4 = *(const float4*)&lR[(wv4 + r) * H + d0];
    float hv[4];
    hv[0] = al * (((accn[r][0] + cv.x) * invn + vs.x) * rden + accg[r][0]) + om * old4.x;
    hv[1] = al * (((accn[r][1] + cv.y) * invn + vs.y) * rden + accg[r][1]) + om * old4.y;
    hv[2] = al * (((accn[r][2] + cv.z) * invn + vs.z) * rden + accg[r][2]) + om * old4.z;
    hv[3] = al * (((accn[r][3] + cv.w) * invn + vs.w) * rden + accg[r][3]) + om * old4.w;
    float s = wave_sum(hv[0] + hv[1] + hv[2] + hv[3]);
    float mu = s * (1.0f / H);
    float s2 = wave_sum(hv[0] * hv[0] + hv[1] * hv[1] + hv[2] * hv[2] + hv[3] * hv[3]);
    float var = s2 * (1.0f / H) - mu * mu;
    float rs = rsqrtf(var + LN_EPS);
    float y0 = (hv[0] - mu) * rs * gm.x + bt.x;
    float y1 = (hv[1] - mu) * rs * gm.y + bt.y;
    float y2 = (hv[2] - mu) * rs * gm.z + bt.z;
    float y3 = (hv[3] - mu) * rs * gm.w + bt.w;
    if (!last && n < N)
      *(float4*)&Rnext[(size_t)n * H + d0] = make_float4(y0, y1, y2, y3);
    float rp = wave_sum(y0 * wr.x + y1 * wr.y + y2 * wr.z + y3 * wr.w);
    if (lane == 0 && n < N) out[n] += wl * (rp + bl);
  }
}

// ---------------- host ----------------

extern "C" void kernel_launch(void* const* d_in, const int* in_sizes, int n_in,
                              void* d_out, int out_size, void* d_ws, size_t ws_size,
                              hipStream_t stream) {
  const float* x = (const float*)d_in[0];
  const int* ei = (const int*)d_in[1];
  const float* W1 = (const float*)d_in[2];
  const float* b1 = (const float*)d_in[3];
  const float* Wq = (const float*)d_in[4];
  const float* bq = (const float*)d_in[5];
  const float* Wk = (const float*)d_in[6];
  const float* bk = (const float*)d_in[7];
  const float* gamma = (const float*)d_in[8];
  const float* beta = (const float*)d_in[9];
  const float* alphap = (const float*)d_in[10];
  const float* Wr = (const float*)d_in[11];
  const float* br = (const float*)d_in[12];
  const float* wgt = (const float*)d_in[13];
  float* out = (float*)d_out;

  const int N = in_sizes[0] / FIN;
  const int E = in_sizes[1] / 2;
  const int* row = ei;
  const int* col = ei + E;

  char* w = (char*)d_ws;
  auto alloc = [&](size_t bytes) -> char* {
    char* p = w;
    w += (bytes + 255) & ~(size_t)255;
    return p;
  };
  const size_t SB = (size_t)N * H * sizeof(float);
  float* B0 = (float*)alloc(SB);
  float* B1 = (float*)alloc(SB);
  // zero-region (contiguous): G, vsum, scal
  float* G = (float*)alloc(H * H * sizeof(float));  // 262144
  float* vsum = (float*)alloc(1024);
  float* scal = (float*)alloc(256);
  const size_t zero_bytes = H * H * sizeof(float) + 1024 + 256;
  float* Mbuf = (float*)alloc(H * H * sizeof(float));
  float* cvec = (float*)alloc(1024);
  float* dvec = (float*)alloc(1024);
  float* P = (float*)alloc(H * H * sizeof(float));
  float* Q = (float*)alloc(H * H * sizeof(float));
  float* K2 = (float*)alloc(H * H * sizeof(float));
  float* pb = (float*)alloc(1024);
  float* qb = (float*)alloc(1024);
  float* wb = (float*)alloc(1024);
  float* kb = (float*)alloc(1024);
  float* sconst = (float*)alloc(256);
  int* deg = (int*)alloc((size_t)N * 4);
  int* cursor = (int*)alloc((size_t)N * 4);
  float* invs = (float*)alloc((size_t)N * 4);
  int* offs = (int*)alloc((size_t)(N + 1) * 4);
  int* erow = (int*)alloc((size_t)E * 4);
  float* ew = (float*)alloc((size_t)E * 4);

  hipMemsetAsync(deg, 0, (size_t)N * 4, stream);
  hipMemsetAsync(cursor, 0, (size_t)N * 4, stream);

  const int gE = (E + 255) / 256, gN = (N + 255) / 256;
  k_deg<<<gE, 256, 0, stream>>>(col, deg, E);
  k_invsqrt<<<gN, 256, 0, stream>>>(deg, invs, N);
  k_scan<<<1, 1024, 0, stream>>>(deg, offs, N);
  k_scatter<<<gE, 256, 0, stream>>>(row, col, invs, offs, cursor, erow, ew, E);
  k_prep<<<769, 256, 0, stream>>>(Wq, Wk, bq, bk, P, Q, K2, pb, qb, wb, kb, sconst);
  const int gRows = (N + 15) / 16;
  k_fc1<<<gRows, 256, 0, stream>>>(x, W1, b1, Wr, br, wgt, B0, out, N);

  float* Rc = B0;
  float* Rn = B1;
  const int nsc = (N + 1023) / 1024;
  for (int it = 1; it <= 3; ++it) {
    hipMemsetAsync(G, 0, zero_bytes, stream);
    k_G<<<nsc * 4, 256, 0, stream>>>(Rc, G, vsum, N);
    k_small<<<290, 256, 0, stream>>>(G, vsum, P, pb, wb, sconst, Q, K2, Mbuf, cvec, dvec, scal, N);
    k_final<<<1, 256, 0, stream>>>(vsum, qb, kb, wb, sconst, scal, N);
    k_C<<<gRows, 256, 0, stream>>>(Rc, Rn, Mbuf, cvec, dvec, vsum, scal, offs, deg, erow, ew,
                                   alphap, gamma, beta, Wr, br, wgt, out, N, it, (it == 3) ? 1 : 0);
    float* t = Rc; Rc = Rn; Rn = t;
  }
}

// Round 3
// 3835.472 us; speedup vs baseline: 1.3465x; 1.3465x over previous
//
#include <hip/hip_runtime.h>

#define H 256
#define FIN 58
#define LN_EPS 1e-5f

// ---------------- utilities ----------------

__device__ __forceinline__ float wave_sum(float v) {
#pragma unroll
  for (int off = 1; off < 64; off <<= 1) v += __shfl_xor(v, off, 64);
  return v;
}

__device__ __forceinline__ float block_sum(float v, volatile float* red) {
  const int tid = threadIdx.x;
  v = wave_sum(v);
  __syncthreads();
  if ((tid & 63) == 0) red[tid >> 6] = v;
  __syncthreads();
  return red[0] + red[1] + red[2] + red[3];
}

__device__ __forceinline__ ushort f2bf(float f) {
  unsigned u = __float_as_uint(f);
  unsigned r = (u + 0x7FFFu + ((u >> 16) & 1u)) >> 16;
  return (ushort)r;
}

__device__ __forceinline__ void add4(float* a, ushort4 g) {
  a[0] += __uint_as_float((unsigned)g.x << 16);
  a[1] += __uint_as_float((unsigned)g.y << 16);
  a[2] += __uint_as_float((unsigned)g.z << 16);
  a[3] += __uint_as_float((unsigned)g.w << 16);
}

// ---------------- setup kernels ----------------

__global__ void k_deg(const int* __restrict__ col, int* __restrict__ deg, int E) {
  int e = blockIdx.x * 256 + threadIdx.x;
  if (e < E) atomicAdd(&deg[col[e]], 1);
}

__global__ void k_invsqrt(const int* __restrict__ deg, float* __restrict__ invs, int N) {
  int i = blockIdx.x * 256 + threadIdx.x;
  if (i < N) {
    int d = deg[i];
    invs[i] = (d > 0) ? (1.0f / sqrtf((float)d)) : 0.0f;
  }
}

// single-block exclusive scan of padded degree ((deg+7)&~7) -> offs8
__global__ void k_scan(const int* __restrict__ deg, int* __restrict__ offs8, int N) {
  __shared__ int buf[1024];
  __shared__ int carry;
  const int tid = threadIdx.x;
  if (tid == 0) carry = 0;
  __syncthreads();
  for (int base = 0; base < N; base += 1024) {
    int v = (base + tid < N) ? ((deg[base + tid] + 7) & ~7) : 0;
    buf[tid] = v;
    __syncthreads();
    for (int off = 1; off < 1024; off <<= 1) {
      int x = (tid >= off) ? buf[tid - off] : 0;
      __syncthreads();
      buf[tid] += x;
      __syncthreads();
    }
    int incl = buf[tid];
    int c = carry;
    if (base + tid < N) offs8[base + tid] = c + incl - v;
    __syncthreads();
    if (tid == 1023) carry = c + buf[1023];
    __syncthreads();
  }
}

// fill edge buffer with sentinel row index N (points at the zero row of Rbf)
__global__ void k_fill(int* __restrict__ eb, int val, int total4) {
  int4 v = make_int4(val, val, val, val);
  for (int i = blockIdx.x * 256 + threadIdx.x; i < total4; i += gridDim.x * 256)
    ((int4*)eb)[i] = v;
}

// scatter edges into padded CSR of src indices
__global__ void k_scatter(const int* __restrict__ row, const int* __restrict__ col,
                          const int* __restrict__ offs8, int* __restrict__ cursor,
                          int* __restrict__ eb, int E) {
  int e = blockIdx.x * 256 + threadIdx.x;
  if (e < E) {
    int c = col[e];
    int pos = offs8[c] + atomicAdd(&cursor[c], 1);
    eb[pos] = row[e];
  }
}

// fp32 -> bf16 copy of R scaled by invs[row] (gather source)
__global__ void k_tobf(const float* __restrict__ R, const float* __restrict__ invs,
                       ushort* __restrict__ Rbf, int total4) {
  for (int i = blockIdx.x * 256 + threadIdx.x; i < total4; i += gridDim.x * 256) {
    float s = invs[i >> 6];
    float4 v = ((const float4*)R)[i];
    ushort4 o;
    o.x = f2bf(v.x * s); o.y = f2bf(v.y * s); o.z = f2bf(v.z * s); o.w = f2bf(v.w * s);
    ((ushort4*)Rbf)[i] = o;
  }
}

// iteration-independent weight products:
// P = Wq*Wk^T, Q = Wq*Wq^T, K2 = Wk*Wk^T, pb=Wq*bk, qb=Wq*bq, wb=Wk*bq, kb=Wk*bk,
// sconst = {bq.bk, |bq|^2, |bk|^2}
__global__ void k_prep(const float* __restrict__ Wq, const float* __restrict__ Wk,
                       const float* __restrict__ bq, const float* __restrict__ bk,
                       float* __restrict__ P, float* __restrict__ Q, float* __restrict__ K2,
                       float* __restrict__ pb, float* __restrict__ qb,
                       float* __restrict__ wb, float* __restrict__ kb,
                       float* __restrict__ sconst) {
  __shared__ float red[4];
  const int b = blockIdx.x, tid = threadIdx.x;
  if (b < 768) {
    const int f = b & 255, which = b >> 8;
    const float* A = (which == 2) ? Wk : Wq;
    const float* Bm = (which == 1) ? Wq : Wk;
    float acc = 0.0f;
    for (int m = 0; m < H; m++) acc = fmaf(A[f * H + m], Bm[tid * H + m], acc);
    float* D = (which == 0) ? P : ((which == 1) ? Q : K2);
    D[f * H + tid] = acc;
  } else {
    float a1 = 0, a2 = 0, a3 = 0, a4 = 0;
    for (int m = 0; m < H; m++) {
      float wqv = Wq[tid * H + m], wkv = Wk[tid * H + m];
      a1 = fmaf(wqv, bk[m], a1);
      a2 = fmaf(wqv, bq[m], a2);
      a3 = fmaf(wkv, bq[m], a3);
      a4 = fmaf(wkv, bk[m], a4);
    }
    pb[tid] = a1; qb[tid] = a2; wb[tid] = a3; kb[tid] = a4;
    float c0 = block_sum(bq[tid] * bk[tid], red);
    float c1 = block_sum(bq[tid] * bq[tid], red);
    float c2 = block_sum(bk[tid] * bk[tid], red);
    if (tid == 0) { sconst[0] = c0; sconst[1] = c1; sconst[2] = c2; }
  }
}

// R0 = relu(x@W1 + b1), plus layer-0 readout: out[n] = wgt0*(R0[n].Wr0 + br0)
__global__ void k_fc1(const float* __restrict__ x, const float* __restrict__ W1,
                      const float* __restrict__ b1, const float* __restrict__ Wr,
                      const float* __restrict__ br, const float* __restrict__ wgt,
                      float* __restrict__ R0, float* __restrict__ out, int N) {
  __shared__ __align__(16) float lx[16 * FIN];
  __shared__ float red[4];
  const int tid = threadIdx.x;
  const int n0 = blockIdx.x * 16;
  for (int idx = tid; idx < 16 * FIN / 4; idx += 256)
    ((float4*)lx)[idx] = ((const float4*)(x + (size_t)n0 * FIN))[idx];
  __syncthreads();
  float acc[16];
  const float bias = b1[tid];
#pragma unroll
  for (int r = 0; r < 16; r++) acc[r] = bias;
  for (int f = 0; f < FIN; f++) {
    float wv = W1[f * H + tid];
#pragma unroll
    for (int r = 0; r < 16; r++) acc[r] = fmaf(lx[r * FIN + f], wv, acc[r]);
  }
  const float wr0 = Wr[tid];
#pragma unroll
  for (int r = 0; r < 16; r++) {
    acc[r] = fmaxf(acc[r], 0.0f);
    int n = n0 + r;
    if (n < N) R0[(size_t)n * H + tid] = acc[r];
  }
  const float w0 = wgt[0], b0 = br[0];
  for (int r = 0; r < 16; r++) {
    float s = block_sum(acc[r] * wr0, red);
    int n = n0 + r;
    if (tid == 0 && n < N) out[n] = w0 * (s + b0);
  }
}

// G += R^T R (atomic over super-chunks); mt==0 blocks also accumulate vsum
__global__ void k_G(const float* __restrict__ R, float* __restrict__ G,
                    float* __restrict__ vsum, int N) {
  __shared__ __align__(16) float lr[64 * H];  // 64 KB
  const int tid = threadIdx.x;
  const int mt = blockIdx.x & 3, sc = blockIdx.x >> 2;
  const int mbase = mt * 64 + (tid & 15) * 4;
  const int dbase = (tid >> 4) * 16;
  float acc[4][16];
#pragma unroll
  for (int a = 0; a < 4; a++)
#pragma unroll
    for (int j = 0; j < 16; j++) acc[a][j] = 0.0f;
  float vs = 0.0f;
  for (int sub = 0; sub < 16; sub++) {
    const int n0 = sc * 1024 + sub * 64;
    __syncthreads();
    for (int idx = tid; idx < 64 * (H / 4); idx += 256) {
      int n = n0 + (idx >> 6);
      ((float4*)lr)[idx] = (n < N) ? ((const float4*)R)[(size_t)n * (H / 4) + (idx & 63)]
                                   : make_float4(0, 0, 0, 0);
    }
    __syncthreads();
    for (int nn = 0; nn < 64; nn++) {
      const float* rowp = &lr[nn * H];
      const float4 kv = *(const float4*)&rowp[mbase];
      const float4 d0v = *(const float4*)&rowp[dbase + 0];
      const float4 d1v = *(const float4*)&rowp[dbase + 4];
      const float4 d2v = *(const float4*)&rowp[dbase + 8];
      const float4 d3v = *(const float4*)&rowp[dbase + 12];
      const float kk[4] = {kv.x, kv.y, kv.z, kv.w};
      const float dd[16] = {d0v.x, d0v.y, d0v.z, d0v.w, d1v.x, d1v.y, d1v.z, d1v.w,
                            d2v.x, d2v.y, d2v.z, d2v.w, d3v.x, d3v.y, d3v.z, d3v.w};
#pragma unroll
      for (int a = 0; a < 4; a++)
#pragma unroll
        for (int j = 0; j < 16; j++) acc[a][j] = fmaf(kk[a], dd[j], acc[a][j]);
    }
    if (mt == 0) {
      float s = 0.0f;
      for (int nn = 0; nn < 64; nn++) s += lr[nn * H + tid];
      vs += s;
    }
  }
#pragma unroll
  for (int a = 0; a < 4; a++)
#pragma unroll
    for (int j = 0; j < 16; j++) atomicAdd(&G[(mbase + a) * H + dbase + j], acc[a][j]);
  if (mt == 0) atomicAdd(&vsum[tid], vs);
}

// per-iteration small products from (G, vsum)
__global__ void k_small(const float* __restrict__ G, const float* __restrict__ vsum,
                        const float* __restrict__ P, const float* __restrict__ pb,
                        const float* __restrict__ wb, const float* __restrict__ sconst,
                        const float* __restrict__ Q, const float* __restrict__ K2,
                        float* __restrict__ M, float* __restrict__ cvec,
                        float* __restrict__ dvec, float* __restrict__ scal, int N) {
  __shared__ float red[4];
  const int b = blockIdx.x, tid = threadIdx.x;
  if (b < 256) {  // M[b,:] = sum_m P[b,m] G[m,:] + pb[b]*vsum
    float acc = 0.0f;
    for (int m = 0; m < H; m++) acc = fmaf(P[b * H + m], G[m * H + tid], acc);
    M[b * H + tid] = acc + pb[b] * vsum[tid];
  } else if (b == 256) {  // cvec = wb^T G + (bq.bk) vsum
    float acc = 0.0f;
    for (int f = 0; f < H; f++) acc = fmaf(wb[f], G[f * H + tid], acc);
    cvec[tid] = acc + sconst[0] * vsum[tid];
  } else if (b == 257) {  // dvec = P*vsum + N*pb
    float acc = 0.0f;
    for (int m = 0; m < H; m++) acc = fmaf(P[tid * H + m], vsum[m], acc);
    dvec[tid] = acc + (float)N * pb[tid];
  } else if (b < 274) {  // <G,Q> partial -> scal[0]
    int base = (b - 258) * 4096 + tid;
    float a = 0.0f;
    for (int j = 0; j < 16; j++) a = fmaf(G[base + j * 256], Q[base + j * 256], a);
    a = block_sum(a, red);
    if (tid == 0) atomicAdd(&scal[0], a);
  } else {  // 274..289: <G,K2> partial -> scal[1]
    int base = (b - 274) * 4096 + tid;
    float a = 0.0f;
    for (int j = 0; j < 16; j++) a = fmaf(G[base + j * 256], K2[base + j * 256], a);
    a = block_sum(a, red);
    if (tid == 0) atomicAdd(&scal[1], a);
  }
}

// finalize norms: scal[2] = 1/(|q| |k|), scal[3] = den const
__global__ void k_final(const float* __restrict__ vsum, const float* __restrict__ qb,
                        const float* __restrict__ kb, const float* __restrict__ wb,
                        const float* __restrict__ sconst, float* __restrict__ scal, int N) {
  __shared__ float red[4];
  const int tid = threadIdx.x;
  float s1 = block_sum(qb[tid] * vsum[tid], red);
  float s2 = block_sum(kb[tid] * vsum[tid], red);
  float s3 = block_sum(wb[tid] * vsum[tid], red);
  if (tid == 0) {
    float sq = scal[0] + 2.0f * s1 + (float)N * sconst[1];
    float sk = scal[1] + 2.0f * s2 + (float)N * sconst[2];
    scal[2] = 1.0f / (sqrtf(sq) * sqrtf(sk));
    scal[3] = s3 + (float)N * sconst[0];
  }
}

// fused: num = R*M, den, gcn gather (pre-scaled bf16, 8-deep), residual blend,
// layernorm, write R in place, readout. In-place is safe: fp32 R rows are read
// only by their owning block (gathers use the bf16 snapshot Rbf).
__global__ __launch_bounds__(256) void k_C(
    float* __restrict__ Rcur, const ushort* __restrict__ Rbf,
    const int* __restrict__ eb, const float* __restrict__ invs,
    const float* __restrict__ Mm, const float* __restrict__ cvec,
    const float* __restrict__ dvec, const float* __restrict__ vsum,
    const float* __restrict__ scal, const int* __restrict__ offs8,
    const int* __restrict__ deg, const float* __restrict__ alphap,
    const float* __restrict__ gamma, const float* __restrict__ beta,
    const float* __restrict__ Wr, const float* __restrict__ br,
    const float* __restrict__ wgt, float* __restrict__ out,
    int N, int layer, int last) {
  __shared__ __align__(16) float lR[16 * H];  // 16 KB
  __shared__ __align__(16) float lM[32 * H];  // 32 KB
  const int tid = threadIdx.x, lane = tid & 63, wv = tid >> 6;
  const int wv4 = wv * 4;
  const int d0 = lane * 4;
  const int n0 = blockIdx.x * 16;

  for (int idx = tid; idx < 16 * (H / 4); idx += 256) {
    int n = n0 + (idx >> 6);
    ((float4*)lR)[idx] = (n < N) ? ((const float4*)Rcur)[(size_t)n * (H / 4) + (idx & 63)]
                                 : make_float4(0, 0, 0, 0);
  }
  __syncthreads();

  float accn[4][4];
#pragma unroll
  for (int r = 0; r < 4; r++)
#pragma unroll
    for (int j = 0; j < 4; j++) accn[r][j] = 0.0f;

  for (int ch = 0; ch < 8; ch++) {
    __syncthreads();
    for (int idx = tid; idx < 32 * (H / 4); idx += 256)
      ((float4*)lM)[idx] = ((const float4*)(Mm + (size_t)ch * 32 * H))[idx];
    __syncthreads();
#pragma unroll
    for (int f4 = 0; f4 < 8; f4++) {
      const int fb = f4 * 4;
      const float4 m0 = *(const float4*)&lM[(fb + 0) * H + d0];
      const float4 m1 = *(const float4*)&lM[(fb + 1) * H + d0];
      const float4 m2 = *(const float4*)&lM[(fb + 2) * H + d0];
      const float4 m3 = *(const float4*)&lM[(fb + 3) * H + d0];
#pragma unroll
      for (int r = 0; r < 4; r++) {
        const float4 rv = *(const float4*)&lR[(wv4 + r) * H + ch * 32 + fb];
        accn[r][0] = fmaf(rv.x, m0.x, fmaf(rv.y, m1.x, fmaf(rv.z, m2.x, fmaf(rv.w, m3.x, accn[r][0]))));
        accn[r][1] = fmaf(rv.x, m0.y, fmaf(rv.y, m1.y, fmaf(rv.z, m2.y, fmaf(rv.w, m3.y, accn[r][1]))));
        accn[r][2] = fmaf(rv.x, m0.z, fmaf(rv.y, m1.z, fmaf(rv.z, m2.z, fmaf(rv.w, m3.z, accn[r][2]))));
        accn[r][3] = fmaf(rv.x, m0.w, fmaf(rv.y, m1.w, fmaf(rv.z, m2.w, fmaf(rv.w, m3.w, accn[r][3]))));
      }
    }
  }

  const float invn = scal[2], denc = scal[3];
  const float al = alphap[0], om = 1.0f - al;
  const float4 dv = *(const float4*)&dvec[d0];

  float den[4];
#pragma unroll
  for (int r = 0; r < 4; r++) {
    const float* Rr = &lR[(wv4 + r) * H + d0];
    float p = Rr[0] * dv.x + Rr[1] * dv.y + Rr[2] * dv.z + Rr[3] * dv.w;
    p = wave_sum(p);
    den[r] = (p + denc) * invn + (float)N;
  }

  // GCN gather: pre-scaled bf16 rows, 8 edges in flight per batch
  float accg[4][4];
#pragma unroll
  for (int r = 0; r < 4; r++)
#pragma unroll
    for (int j = 0; j < 4; j++) accg[r][j] = 0.0f;
#pragma unroll
  for (int r = 0; r < 4; r++) {
    int n = n0 + wv4 + r;
    if (n < N) {
      const int st = offs8[n];            // multiple of 8
      const int nb = (deg[n] + 7) >> 3;
      const int4* p = (const int4*)(eb + st);
      for (int b = 0; b < nb; b++, p += 2) {
        const int4 iA = p[0];
        const int4 iB = p[1];
        const ushort4 g0 = *(const ushort4*)&Rbf[((size_t)iA.x << 8) + d0];
        const ushort4 g1 = *(const ushort4*)&Rbf[((size_t)iA.y << 8) + d0];
        const ushort4 g2 = *(const ushort4*)&Rbf[((size_t)iA.z << 8) + d0];
        const ushort4 g3 = *(const ushort4*)&Rbf[((size_t)iA.w << 8) + d0];
        const ushort4 g4 = *(const ushort4*)&Rbf[((size_t)iB.x << 8) + d0];
        const ushort4 g5 = *(const ushort4*)&Rbf[((size_t)iB.y << 8) + d0];
        const ushort4 g6 = *(const ushort4*)&Rbf[((size_t)iB.z << 8) + d0];
        const ushort4 g7 = *(const ushort4*)&Rbf[((size_t)iB.w << 8) + d0];
        add4(accg[r], g0); add4(accg[r], g1); add4(accg[r], g2); add4(accg[r], g3);
        add4(accg[r], g4); add4(accg[r], g5); add4(accg[r], g6); add4(accg[r], g7);
      }
      const float sn = invs[n];
      accg[r][0] *= sn; accg[r][1] *= sn; accg[r][2] *= sn; accg[r][3] *= sn;
    }
  }

  const float4 cv = *(const float4*)&cvec[d0];
  const float4 vs = *(const float4*)&vsum[d0];
  const float4 gm = *(const float4*)&gamma[d0];
  const float4 bt = *(const float4*)&beta[d0];
  const float4 wr = *(const float4*)&Wr[layer * H + d0];
  const float wl = wgt[layer], bl = br[layer];

#pragma unroll
  for (int r = 0; r < 4; r++) {
    const int n = n0 + wv4 + r;
    const float rden = 1.0f / den[r];
    const float4 old4 = *(const float4*)&lR[(wv4 + r) * H + d0];
    float hv[4];
    hv[0] = al * (((accn[r][0] + cv.x) * invn + vs.x) * rden + accg[r][0]) + om * old4.x;
    hv[1] = al * (((accn[r][1] + cv.y) * invn + vs.y) * rden + accg[r][1]) + om * old4.y;
    hv[2] = al * (((accn[r][2] + cv.z) * invn + vs.z) * rden + accg[r][2]) + om * old4.z;
    hv[3] = al * (((accn[r][3] + cv.w) * invn + vs.w) * rden + accg[r][3]) + om * old4.w;
    float s = wave_sum(hv[0] + hv[1] + hv[2] + hv[3]);
    float mu = s * (1.0f / H);
    float s2 = wave_sum(hv[0] * hv[0] + hv[1] * hv[1] + hv[2] * hv[2] + hv[3] * hv[3]);
    float var = s2 * (1.0f / H) - mu * mu;
    float rs = rsqrtf(var + LN_EPS);
    float y0 = (hv[0] - mu) * rs * gm.x + bt.x;
    float y1 = (hv[1] - mu) * rs * gm.y + bt.y;
    float y2 = (hv[2] - mu) * rs * gm.z + bt.z;
    float y3 = (hv[3] - mu) * rs * gm.w + bt.w;
    if (!last && n < N)
      *(float4*)&Rcur[(size_t)n * H + d0] = make_float4(y0, y1, y2, y3);
    float rp = wave_sum(y0 * wr.x + y1 * wr.y + y2 * wr.z + y3 * wr.w);
    if (lane == 0 && n < N) out[n] += wl * (rp + bl);
  }
}

// ---------------- host ----------------

extern "C" void kernel_launch(void* const* d_in, const int* in_sizes, int n_in,
                              void* d_out, int out_size, void* d_ws, size_t ws_size,
                              hipStream_t stream) {
  const float* x = (const float*)d_in[0];
  const int* ei = (const int*)d_in[1];
  const float* W1 = (const float*)d_in[2];
  const float* b1 = (const float*)d_in[3];
  const float* Wq = (const float*)d_in[4];
  const float* bq = (const float*)d_in[5];
  const float* Wk = (const float*)d_in[6];
  const float* bk = (const float*)d_in[7];
  const float* gamma = (const float*)d_in[8];
  const float* beta = (const float*)d_in[9];
  const float* alphap = (const float*)d_in[10];
  const float* Wr = (const float*)d_in[11];
  const float* br = (const float*)d_in[12];
  const float* wgt = (const float*)d_in[13];
  float* out = (float*)d_out;

  const int N = in_sizes[0] / FIN;
  const int E = in_sizes[1] / 2;
  const int* row = ei;
  const int* col = ei + E;

  char* w = (char*)d_ws;
  auto alloc = [&](size_t bytes) -> char* {
    char* p = w;
    w += (bytes + 255) & ~(size_t)255;
    return p;
  };
  const size_t SB = (size_t)N * H * sizeof(float);
  float* B0 = (float*)alloc(SB);
  ushort* Rbf = (ushort*)alloc((size_t)(N + 1) * H * sizeof(ushort));  // +1 zero row
  // zero-region (contiguous): G, vsum, scal
  float* G = (float*)alloc(H * H * sizeof(float));  // 262144
  float* vsum = (float*)alloc(1024);
  float* scal = (float*)alloc(256);
  const size_t zero_bytes = H * H * sizeof(float) + 1024 + 256;
  float* Mbuf = (float*)alloc(H * H * sizeof(float));
  float* cvec = (float*)alloc(1024);
  float* dvec = (float*)alloc(1024);
  float* P = (float*)alloc(H * H * sizeof(float));
  float* Q = (float*)alloc(H * H * sizeof(float));
  float* K2 = (float*)alloc(H * H * sizeof(float));
  float* pb = (float*)alloc(1024);
  float* qb = (float*)alloc(1024);
  float* wb = (float*)alloc(1024);
  float* kb = (float*)alloc(1024);
  float* sconst = (float*)alloc(256);
  int* deg = (int*)alloc((size_t)N * 4);
  int* cursor = (int*)alloc((size_t)N * 4);
  float* invs = (float*)alloc((size_t)N * 4);
  int* offs8 = (int*)alloc((size_t)(N + 1) * 4);
  size_t EPAD = (size_t)E + 8 * (size_t)N;
  EPAD = (EPAD + 3) & ~(size_t)3;
  int* eb = (int*)alloc(EPAD * sizeof(int));

  hipMemsetAsync(deg, 0, (size_t)N * 4, stream);
  hipMemsetAsync(cursor, 0, (size_t)N * 4, stream);
  hipMemsetAsync(Rbf + (size_t)N * H, 0, H * sizeof(ushort), stream);

  const int gE = (E + 255) / 256, gN = (N + 255) / 256;
  k_deg<<<gE, 256, 0, stream>>>(col, deg, E);
  k_invsqrt<<<gN, 256, 0, stream>>>(deg, invs, N);
  k_scan<<<1, 1024, 0, stream>>>(deg, offs8, N);
  k_fill<<<2048, 256, 0, stream>>>(eb, N, (int)(EPAD / 4));
  k_scatter<<<gE, 256, 0, stream>>>(row, col, offs8, cursor, eb, E);
  k_prep<<<769, 256, 0, stream>>>(Wq, Wk, bq, bk, P, Q, K2, pb, qb, wb, kb, sconst);
  const int gRows = (N + 15) / 16;
  k_fc1<<<gRows, 256, 0, stream>>>(x, W1, b1, Wr, br, wgt, B0, out, N);

  const int nsc = (N + 1023) / 1024;
  const int total4 = N * (H / 4);
  for (int it = 1; it <= 3; ++it) {
    hipMemsetAsync(G, 0, zero_bytes, stream);
    k_G<<<nsc * 4, 256, 0, stream>>>(B0, G, vsum, N);
    k_small<<<290, 256, 0, stream>>>(G, vsum, P, pb, wb, sconst, Q, K2, Mbuf, cvec, dvec, scal, N);
    k_final<<<1, 256, 0, stream>>>(vsum, qb, kb, wb, sconst, scal, N);
    k_tobf<<<2048, 256, 0, stream>>>(B0, invs, Rbf, total4);
    k_C<<<gRows, 256, 0, stream>>>(B0, Rbf, eb, invs, Mbuf, cvec, dvec, vsum, scal, offs8, deg,
                                   alphap, gamma, beta, Wr, br, wgt, out, N, it, (it == 3) ? 1 : 0);
  }
}

// Round 4
// 2296.994 us; speedup vs baseline: 2.2483x; 1.6698x over previous
//
#include <hip/hip_runtime.h>

#define H 256
#define FIN 58
#define LN_EPS 1e-5f
#define ROWS_PB 416  // k_Gm rows per block (13 chunks of 32)

typedef __bf16 bf16x8 __attribute__((ext_vector_type(8)));
typedef float f32x16 __attribute__((ext_vector_type(16)));

union FragU {
  ushort u[8];
  bf16x8 v;
};

// ---------------- utilities ----------------

__device__ __forceinline__ float wave_sum(float v) {
#pragma unroll
  for (int off = 1; off < 64; off <<= 1) v += __shfl_xor(v, off, 64);
  return v;
}

__device__ __forceinline__ float block_sum(float v, volatile float* red) {
  const int tid = threadIdx.x;
  v = wave_sum(v);
  __syncthreads();
  if ((tid & 63) == 0) red[tid >> 6] = v;
  __syncthreads();
  return red[0] + red[1] + red[2] + red[3];
}

__device__ __forceinline__ ushort f2bf(float f) {
  unsigned u = __float_as_uint(f);
  unsigned r = (u + 0x7FFFu + ((u >> 16) & 1u)) >> 16;
  return (ushort)r;
}

__device__ __forceinline__ void add4(float* a, ushort4 g) {
  a[0] += __uint_as_float((unsigned)g.x << 16);
  a[1] += __uint_as_float((unsigned)g.y << 16);
  a[2] += __uint_as_float((unsigned)g.z << 16);
  a[3] += __uint_as_float((unsigned)g.w << 16);
}

// ---------------- setup kernels ----------------

__global__ void k_deg(const int* __restrict__ col, int* __restrict__ deg, int E) {
  int e = blockIdx.x * 256 + threadIdx.x;
  if (e < E) atomicAdd(&deg[col[e]], 1);
}

__global__ void k_invsqrt(const int* __restrict__ deg, float* __restrict__ invs, int N) {
  int i = blockIdx.x * 256 + threadIdx.x;
  if (i < N) {
    int d = deg[i];
    invs[i] = (d > 0) ? (1.0f / sqrtf((float)d)) : 0.0f;
  }
}

// single-block exclusive scan of padded degree ((deg+7)&~7) -> offs8
__global__ void k_scan(const int* __restrict__ deg, int* __restrict__ offs8, int N) {
  __shared__ int buf[1024];
  __shared__ int carry;
  const int tid = threadIdx.x;
  if (tid == 0) carry = 0;
  __syncthreads();
  for (int base = 0; base < N; base += 1024) {
    int v = (base + tid < N) ? ((deg[base + tid] + 7) & ~7) : 0;
    buf[tid] = v;
    __syncthreads();
    for (int off = 1; off < 1024; off <<= 1) {
      int x = (tid >= off) ? buf[tid - off] : 0;
      __syncthreads();
      buf[tid] += x;
      __syncthreads();
    }
    int incl = buf[tid];
    int c = carry;
    if (base + tid < N) offs8[base + tid] = c + incl - v;
    __syncthreads();
    if (tid == 1023) carry = c + buf[1023];
    __syncthreads();
  }
}

// fill edge buffer with sentinel row index N (points at the zero row of Rbf)
__global__ void k_fill(int* __restrict__ eb, int val, int total4) {
  int4 v = make_int4(val, val, val, val);
  for (int i = blockIdx.x * 256 + threadIdx.x; i < total4; i += gridDim.x * 256)
    ((int4*)eb)[i] = v;
}

// scatter edges into padded CSR of src indices
__global__ void k_scatter(const int* __restrict__ row, const int* __restrict__ col,
                          const int* __restrict__ offs8, int* __restrict__ cursor,
                          int* __restrict__ eb, int E) {
  int e = blockIdx.x * 256 + threadIdx.x;
  if (e < E) {
    int c = col[e];
    int pos = offs8[c] + atomicAdd(&cursor[c], 1);
    eb[pos] = row[e];
  }
}

// fp32 -> bf16 copy of R scaled by invs[row] (gather source)
__global__ void k_tobf(const float* __restrict__ R, const float* __restrict__ invs,
                       ushort* __restrict__ Rbf, int total4) {
  for (int i = blockIdx.x * 256 + threadIdx.x; i < total4; i += gridDim.x * 256) {
    float s = invs[i >> 6];
    float4 v = ((const float4*)R)[i];
    ushort4 o;
    o.x = f2bf(v.x * s); o.y = f2bf(v.y * s); o.z = f2bf(v.z * s); o.w = f2bf(v.w * s);
    ((ushort4*)Rbf)[i] = o;
  }
}

// iteration-independent weight products
__global__ void k_prep(const float* __restrict__ Wq, const float* __restrict__ Wk,
                       const float* __restrict__ bq, const float* __restrict__ bk,
                       float* __restrict__ P, float* __restrict__ Q, float* __restrict__ K2,
                       float* __restrict__ pb, float* __restrict__ qb,
                       float* __restrict__ wb, float* __restrict__ kb,
                       float* __restrict__ sconst) {
  __shared__ float red[4];
  const int b = blockIdx.x, tid = threadIdx.x;
  if (b < 768) {
    const int f = b & 255, which = b >> 8;
    const float* A = (which == 2) ? Wk : Wq;
    const float* Bm = (which == 1) ? Wq : Wk;
    float acc = 0.0f;
    for (int m = 0; m < H; m++) acc = fmaf(A[f * H + m], Bm[tid * H + m], acc);
    float* D = (which == 0) ? P : ((which == 1) ? Q : K2);
    D[f * H + tid] = acc;
  } else {
    float a1 = 0, a2 = 0, a3 = 0, a4 = 0;
    for (int m = 0; m < H; m++) {
      float wqv = Wq[tid * H + m], wkv = Wk[tid * H + m];
      a1 = fmaf(wqv, bk[m], a1);
      a2 = fmaf(wqv, bq[m], a2);
      a3 = fmaf(wkv, bq[m], a3);
      a4 = fmaf(wkv, bk[m], a4);
    }
    pb[tid] = a1; qb[tid] = a2; wb[tid] = a3; kb[tid] = a4;
    float c0 = block_sum(bq[tid] * bk[tid], red);
    float c1 = block_sum(bq[tid] * bq[tid], red);
    float c2 = block_sum(bk[tid] * bk[tid], red);
    if (tid == 0) { sconst[0] = c0; sconst[1] = c1; sconst[2] = c2; }
  }
}

// R0 = relu(x@W1 + b1), plus layer-0 readout
__global__ void k_fc1(const float* __restrict__ x, const float* __restrict__ W1,
                      const float* __restrict__ b1, const float* __restrict__ Wr,
                      const float* __restrict__ br, const float* __restrict__ wgt,
                      float* __restrict__ R0, float* __restrict__ out, int N) {
  __shared__ __align__(16) float lx[16 * FIN];
  __shared__ float red[4];
  const int tid = threadIdx.x;
  const int n0 = blockIdx.x * 16;
  for (int idx = tid; idx < 16 * FIN / 4; idx += 256)
    ((float4*)lx)[idx] = ((const float4*)(x + (size_t)n0 * FIN))[idx];
  __syncthreads();
  float acc[16];
  const float bias = b1[tid];
#pragma unroll
  for (int r = 0; r < 16; r++) acc[r] = bias;
  for (int f = 0; f < FIN; f++) {
    float wv = W1[f * H + tid];
#pragma unroll
    for (int r = 0; r < 16; r++) acc[r] = fmaf(lx[r * FIN + f], wv, acc[r]);
  }
  const float wr0 = Wr[tid];
#pragma unroll
  for (int r = 0; r < 16; r++) {
    acc[r] = fmaxf(acc[r], 0.0f);
    int n = n0 + r;
    if (n < N) R0[(size_t)n * H + tid] = acc[r];
  }
  const float w0 = wgt[0], b0 = br[0];
  for (int r = 0; r < 16; r++) {
    float s = block_sum(acc[r] * wr0, red);
    int n = n0 + r;
    if (tid == 0 && n < N) out[n] = w0 * (s + b0);
  }
}

// ---------------- MFMA G = R^T R (+ vsum) ----------------
// 512 thr = 8 waves; wave owns 128x64 of the 256x256 output (8 tiles 32x32).
// K sliced: block handles up to 416 rows in 13 chunks of 32, double-buffered
// bf16 LDS with XOR swizzle. atomicAdd partial G; vsum via LDS reduce.
__global__ __launch_bounds__(512, 2) void k_Gm(const float* __restrict__ R,
                                               float* __restrict__ G,
                                               float* __restrict__ vsum, int N) {
  __shared__ ushort sb[2][32 * 256];  // 32 KB
  const int tid = threadIdx.x;
  const int lane = tid & 63;
  const int wid = tid >> 6;
  const int wrow = (wid & 1) * 128;
  const int wcol = (wid >> 1) * 64;
  const int l31 = lane & 31;
  const int lhi = lane >> 5;

  const int rowbase = blockIdx.x * ROWS_PB;
  const int nrows = min(ROWS_PB, N - rowbase);
  const int nch = (nrows + 31) >> 5;

  const int sk = tid >> 4;        // staging row 0..31
  const int sc = (tid & 15) * 4;  // staging col base (cols sc + 64*i + cc)

  f32x16 acc[4][2];
#pragma unroll
  for (int s = 0; s < 4; s++)
#pragma unroll
    for (int t = 0; t < 2; t++)
#pragma unroll
      for (int e = 0; e < 16; e++) acc[s][t][e] = 0.0f;

  float csum[16];
#pragma unroll
  for (int i = 0; i < 16; i++) csum[i] = 0.0f;

  float4 ld[4];

  auto load_chunk = [&](int ch) {
    int g = rowbase + ch * 32 + sk;
    const float4* src = (const float4*)(R + (size_t)g * H);
#pragma unroll
    for (int i = 0; i < 4; i++)
      ld[i] = (g < N) ? src[(sc >> 2) + 16 * i] : make_float4(0, 0, 0, 0);
  };

  auto write_chunk = [&](int buf) {
    const int swz = (sk & 3) << 4;
#pragma unroll
    for (int i = 0; i < 4; i++) {
      float4 v = ld[i];
      csum[i * 4 + 0] += v.x; csum[i * 4 + 1] += v.y;
      csum[i * 4 + 2] += v.z; csum[i * 4 + 3] += v.w;
      ushort4 o;
      o.x = f2bf(v.x); o.y = f2bf(v.y); o.z = f2bf(v.z); o.w = f2bf(v.w);
      int c = sc + 64 * i;
      *(ushort4*)&sb[buf][sk * 256 + (c ^ swz)] = o;
    }
  };

  auto compute = [&](int buf) {
#pragma unroll
    for (int ks = 0; ks < 2; ks++) {
      const int kb = ks * 16 + lhi * 8;
      FragU fr[6];
#pragma unroll
      for (int s = 0; s < 6; s++) {
        const int cbase = (s < 4) ? (wrow + 32 * s + l31) : (wcol + 32 * (s - 4) + l31);
#pragma unroll
        for (int j = 0; j < 8; j++)
          fr[s].u[j] = sb[buf][(kb + j) * 256 + (cbase ^ ((j & 3) << 4))];
      }
#pragma unroll
      for (int s = 0; s < 4; s++)
#pragma unroll
        for (int t = 0; t < 2; t++)
          acc[s][t] = __builtin_amdgcn_mfma_f32_32x32x16_bf16(fr[s].v, fr[4 + t].v,
                                                              acc[s][t], 0, 0, 0);
    }
  };

  load_chunk(0);
  write_chunk(0);
  __syncthreads();
  int cur = 0;
  for (int c = 0; c < nch; c++) {
    if (c + 1 < nch) load_chunk(c + 1);
    compute(cur);
    if (c + 1 < nch) write_chunk(cur ^ 1);
    __syncthreads();
    cur ^= 1;
  }

  // G partial accumulate (C/D layout: col=lane&31, row=(r&3)+8*(r>>2)+4*(lane>>5))
#pragma unroll
  for (int s = 0; s < 4; s++)
#pragma unroll
    for (int t = 0; t < 2; t++) {
      const int n0 = wcol + 32 * t + l31;
#pragma unroll
      for (int r = 0; r < 16; r++) {
        const int row = wrow + 32 * s + (r & 3) + 8 * (r >> 2) + 4 * lhi;
        atomicAdd(&G[row * 256 + n0], acc[s][t][r]);
      }
    }

  // vsum: LDS-reduce the per-thread column partials (reuse sb as float[32][256])
  float* fl = (float*)sb;
#pragma unroll
  for (int i = 0; i < 4; i++) {
#pragma unroll
    for (int cc = 0; cc < 4; cc++)
      fl[sk * 256 + sc + 64 * i + cc] = csum[i * 4 + cc];
  }
  __syncthreads();
  if (tid < 256) {
    float s = 0.0f;
    for (int r = 0; r < 32; r++) s += fl[r * 256 + tid];
    atomicAdd(&vsum[tid], s);
  }
}

// per-iteration small products from (G, vsum)
__global__ void k_small(const float* __restrict__ G, const float* __restrict__ vsum,
                        const float* __restrict__ P, const float* __restrict__ pb,
                        const float* __restrict__ wb, const float* __restrict__ sconst,
                        const float* __restrict__ Q, const float* __restrict__ K2,
                        float* __restrict__ M, float* __restrict__ cvec,
                        float* __restrict__ dvec, float* __restrict__ scal, int N) {
  __shared__ float red[4];
  const int b = blockIdx.x, tid = threadIdx.x;
  if (b < 256) {
    float acc = 0.0f;
    for (int m = 0; m < H; m++) acc = fmaf(P[b * H + m], G[m * H + tid], acc);
    M[b * H + tid] = acc + pb[b] * vsum[tid];
  } else if (b == 256) {
    float acc = 0.0f;
    for (int f = 0; f < H; f++) acc = fmaf(wb[f], G[f * H + tid], acc);
    cvec[tid] = acc + sconst[0] * vsum[tid];
  } else if (b == 257) {
    float acc = 0.0f;
    for (int m = 0; m < H; m++) acc = fmaf(P[tid * H + m], vsum[m], acc);
    dvec[tid] = acc + (float)N * pb[tid];
  } else if (b < 274) {
    int base = (b - 258) * 4096 + tid;
    float a = 0.0f;
    for (int j = 0; j < 16; j++) a = fmaf(G[base + j * 256], Q[base + j * 256], a);
    a = block_sum(a, red);
    if (tid == 0) atomicAdd(&scal[0], a);
  } else {
    int base = (b - 274) * 4096 + tid;
    float a = 0.0f;
    for (int j = 0; j < 16; j++) a = fmaf(G[base + j * 256], K2[base + j * 256], a);
    a = block_sum(a, red);
    if (tid == 0) atomicAdd(&scal[1], a);
  }
}

// finalize norms
__global__ void k_final(const float* __restrict__ vsum, const float* __restrict__ qb,
                        const float* __restrict__ kb, const float* __restrict__ wb,
                        const float* __restrict__ sconst, float* __restrict__ scal, int N) {
  __shared__ float red[4];
  const int tid = threadIdx.x;
  float s1 = block_sum(qb[tid] * vsum[tid], red);
  float s2 = block_sum(kb[tid] * vsum[tid], red);
  float s3 = block_sum(wb[tid] * vsum[tid], red);
  if (tid == 0) {
    float sq = scal[0] + 2.0f * s1 + (float)N * sconst[1];
    float sk = scal[1] + 2.0f * s2 + (float)N * sconst[2];
    scal[2] = 1.0f / (sqrtf(sq) * sqrtf(sk));
    scal[3] = s3 + (float)N * sconst[0];
  }
}

// fused: num = R*M, den, gcn gather (pre-scaled bf16, 8-deep), residual blend,
// layernorm, write R in place, readout
__global__ __launch_bounds__(256) void k_C(
    float* __restrict__ Rcur, const ushort* __restrict__ Rbf,
    const int* __restrict__ eb, const float* __restrict__ invs,
    const float* __restrict__ Mm, const float* __restrict__ cvec,
    const float* __restrict__ dvec, const float* __restrict__ vsum,
    const float* __restrict__ scal, const int* __restrict__ offs8,
    const int* __restrict__ deg, const float* __restrict__ alphap,
    const float* __restrict__ gamma, const float* __restrict__ beta,
    const float* __restrict__ Wr, const float* __restrict__ br,
    const float* __restrict__ wgt, float* __restrict__ out,
    int N, int layer, int last) {
  __shared__ __align__(16) float lR[16 * H];
  __shared__ __align__(16) float lM[32 * H];
  const int tid = threadIdx.x, lane = tid & 63, wv = tid >> 6;
  const int wv4 = wv * 4;
  const int d0 = lane * 4;
  const int n0 = blockIdx.x * 16;

  for (int idx = tid; idx < 16 * (H / 4); idx += 256) {
    int n = n0 + (idx >> 6);
    ((float4*)lR)[idx] = (n < N) ? ((const float4*)Rcur)[(size_t)n * (H / 4) + (idx & 63)]
                                 : make_float4(0, 0, 0, 0);
  }
  __syncthreads();

  float accn[4][4];
#pragma unroll
  for (int r = 0; r < 4; r++)
#pragma unroll
    for (int j = 0; j < 4; j++) accn[r][j] = 0.0f;

  for (int ch = 0; ch < 8; ch++) {
    __syncthreads();
    for (int idx = tid; idx < 32 * (H / 4); idx += 256)
      ((float4*)lM)[idx] = ((const float4*)(Mm + (size_t)ch * 32 * H))[idx];
    __syncthreads();
#pragma unroll
    for (int f4 = 0; f4 < 8; f4++) {
      const int fb = f4 * 4;
      const float4 m0 = *(const float4*)&lM[(fb + 0) * H + d0];
      const float4 m1 = *(const float4*)&lM[(fb + 1) * H + d0];
      const float4 m2 = *(const float4*)&lM[(fb + 2) * H + d0];
      const float4 m3 = *(const float4*)&lM[(fb + 3) * H + d0];
#pragma unroll
      for (int r = 0; r < 4; r++) {
        const float4 rv = *(const float4*)&lR[(wv4 + r) * H + ch * 32 + fb];
        accn[r][0] = fmaf(rv.x, m0.x, fmaf(rv.y, m1.x, fmaf(rv.z, m2.x, fmaf(rv.w, m3.x, accn[r][0]))));
        accn[r][1] = fmaf(rv.x, m0.y, fmaf(rv.y, m1.y, fmaf(rv.z, m2.y, fmaf(rv.w, m3.y, accn[r][1]))));
        accn[r][2] = fmaf(rv.x, m0.z, fmaf(rv.y, m1.z, fmaf(rv.z, m2.z, fmaf(rv.w, m3.z, accn[r][2]))));
        accn[r][3] = fmaf(rv.x, m0.w, fmaf(rv.y, m1.w, fmaf(rv.z, m2.w, fmaf(rv.w, m3.w, accn[r][3]))));
      }
    }
  }

  const float invn = scal[2], denc = scal[3];
  const float al = alphap[0], om = 1.0f - al;
  const float4 dv = *(const float4*)&dvec[d0];

  float den[4];
#pragma unroll
  for (int r = 0; r < 4; r++) {
    const float* Rr = &lR[(wv4 + r) * H + d0];
    float p = Rr[0] * dv.x + Rr[1] * dv.y + Rr[2] * dv.z + Rr[3] * dv.w;
    p = wave_sum(p);
    den[r] = (p + denc) * invn + (float)N;
  }

  float accg[4][4];
#pragma unroll
  for (int r = 0; r < 4; r++)
#pragma unroll
    for (int j = 0; j < 4; j++) accg[r][j] = 0.0f;
#pragma unroll
  for (int r = 0; r < 4; r++) {
    int n = n0 + wv4 + r;
    if (n < N) {
      const int st = offs8[n];
      const int nb = (deg[n] + 7) >> 3;
      const int4* p = (const int4*)(eb + st);
      for (int b = 0; b < nb; b++, p += 2) {
        const int4 iA = p[0];
        const int4 iB = p[1];
        const ushort4 g0 = *(const ushort4*)&Rbf[((size_t)iA.x << 8) + d0];
        const ushort4 g1 = *(const ushort4*)&Rbf[((size_t)iA.y << 8) + d0];
        const ushort4 g2 = *(const ushort4*)&Rbf[((size_t)iA.z << 8) + d0];
        const ushort4 g3 = *(const ushort4*)&Rbf[((size_t)iA.w << 8) + d0];
        const ushort4 g4 = *(const ushort4*)&Rbf[((size_t)iB.x << 8) + d0];
        const ushort4 g5 = *(const ushort4*)&Rbf[((size_t)iB.y << 8) + d0];
        const ushort4 g6 = *(const ushort4*)&Rbf[((size_t)iB.z << 8) + d0];
        const ushort4 g7 = *(const ushort4*)&Rbf[((size_t)iB.w << 8) + d0];
        add4(accg[r], g0); add4(accg[r], g1); add4(accg[r], g2); add4(accg[r], g3);
        add4(accg[r], g4); add4(accg[r], g5); add4(accg[r], g6); add4(accg[r], g7);
      }
      const float sn = invs[n];
      accg[r][0] *= sn; accg[r][1] *= sn; accg[r][2] *= sn; accg[r][3] *= sn;
    }
  }

  const float4 cv = *(const float4*)&cvec[d0];
  const float4 vs = *(const float4*)&vsum[d0];
  const float4 gm = *(const float4*)&gamma[d0];
  const float4 bt = *(const float4*)&beta[d0];
  const float4 wr = *(const float4*)&Wr[layer * H + d0];
  const float wl = wgt[layer], bl = br[layer];

#pragma unroll
  for (int r = 0; r < 4; r++) {
    const int n = n0 + wv4 + r;
    const float rden = 1.0f / den[r];
    const float4 old4 = *(const float4*)&lR[(wv4 + r) * H + d0];
    float hv[4];
    hv[0] = al * (((accn[r][0] + cv.x) * invn + vs.x) * rden + accg[r][0]) + om * old4.x;
    hv[1] = al * (((accn[r][1] + cv.y) * invn + vs.y) * rden + accg[r][1]) + om * old4.y;
    hv[2] = al * (((accn[r][2] + cv.z) * invn + vs.z) * rden + accg[r][2]) + om * old4.z;
    hv[3] = al * (((accn[r][3] + cv.w) * invn + vs.w) * rden + accg[r][3]) + om * old4.w;
    float s = wave_sum(hv[0] + hv[1] + hv[2] + hv[3]);
    float mu = s * (1.0f / H);
    float s2 = wave_sum(hv[0] * hv[0] + hv[1] * hv[1] + hv[2] * hv[2] + hv[3] * hv[3]);
    float var = s2 * (1.0f / H) - mu * mu;
    float rs = rsqrtf(var + LN_EPS);
    float y0 = (hv[0] - mu) * rs * gm.x + bt.x;
    float y1 = (hv[1] - mu) * rs * gm.y + bt.y;
    float y2 = (hv[2] - mu) * rs * gm.z + bt.z;
    float y3 = (hv[3] - mu) * rs * gm.w + bt.w;
    if (!last && n < N)
      *(float4*)&Rcur[(size_t)n * H + d0] = make_float4(y0, y1, y2, y3);
    float rp = wave_sum(y0 * wr.x + y1 * wr.y + y2 * wr.z + y3 * wr.w);
    if (lane == 0 && n < N) out[n] += wl * (rp + bl);
  }
}

// ---------------- host ----------------

extern "C" void kernel_launch(void* const* d_in, const int* in_sizes, int n_in,
                              void* d_out, int out_size, void* d_ws, size_t ws_size,
                              hipStream_t stream) {
  const float* x = (const float*)d_in[0];
  const int* ei = (const int*)d_in[1];
  const float* W1 = (const float*)d_in[2];
  const float* b1 = (const float*)d_in[3];
  const float* Wq = (const float*)d_in[4];
  const float* bq = (const float*)d_in[5];
  const float* Wk = (const float*)d_in[6];
  const float* bk = (const float*)d_in[7];
  const float* gamma = (const float*)d_in[8];
  const float* beta = (const float*)d_in[9];
  const float* alphap = (const float*)d_in[10];
  const float* Wr = (const float*)d_in[11];
  const float* br = (const float*)d_in[12];
  const float* wgt = (const float*)d_in[13];
  float* out = (float*)d_out;

  const int N = in_sizes[0] / FIN;
  const int E = in_sizes[1] / 2;
  const int* row = ei;
  const int* col = ei + E;

  char* w = (char*)d_ws;
  auto alloc = [&](size_t bytes) -> char* {
    char* p = w;
    w += (bytes + 255) & ~(size_t)255;
    return p;
  };
  const size_t SB = (size_t)N * H * sizeof(float);
  float* B0 = (float*)alloc(SB);
  ushort* Rbf = (ushort*)alloc((size_t)(N + 1) * H * sizeof(ushort));  // +1 zero row
  float* G = (float*)alloc(H * H * sizeof(float));
  float* vsum = (float*)alloc(1024);
  float* scal = (float*)alloc(256);
  const size_t zero_bytes = H * H * sizeof(float) + 1024 + 256;
  float* Mbuf = (float*)alloc(H * H * sizeof(float));
  float* cvec = (float*)alloc(1024);
  float* dvec = (float*)alloc(1024);
  float* P = (float*)alloc(H * H * sizeof(float));
  float* Q = (float*)alloc(H * H * sizeof(float));
  float* K2 = (float*)alloc(H * H * sizeof(float));
  float* pb = (float*)alloc(1024);
  float* qb = (float*)alloc(1024);
  float* wb = (float*)alloc(1024);
  float* kb = (float*)alloc(1024);
  float* sconst = (float*)alloc(256);
  int* deg = (int*)alloc((size_t)N * 4);
  int* cursor = (int*)alloc((size_t)N * 4);
  float* invs = (float*)alloc((size_t)N * 4);
  int* offs8 = (int*)alloc((size_t)(N + 1) * 4);
  size_t EPAD = (size_t)E + 8 * (size_t)N;
  EPAD = (EPAD + 3) & ~(size_t)3;
  int* eb = (int*)alloc(EPAD * sizeof(int));

  hipMemsetAsync(deg, 0, (size_t)N * 4, stream);
  hipMemsetAsync(cursor, 0, (size_t)N * 4, stream);
  hipMemsetAsync(Rbf + (size_t)N * H, 0, H * sizeof(ushort), stream);

  const int gE = (E + 255) / 256, gN = (N + 255) / 256;
  k_deg<<<gE, 256, 0, stream>>>(col, deg, E);
  k_invsqrt<<<gN, 256, 0, stream>>>(deg, invs, N);
  k_scan<<<1, 1024, 0, stream>>>(deg, offs8, N);
  k_fill<<<2048, 256, 0, stream>>>(eb, N, (int)(EPAD / 4));
  k_scatter<<<gE, 256, 0, stream>>>(row, col, offs8, cursor, eb, E);
  k_prep<<<769, 256, 0, stream>>>(Wq, Wk, bq, bk, P, Q, K2, pb, qb, wb, kb, sconst);
  const int gRows = (N + 15) / 16;
  k_fc1<<<gRows, 256, 0, stream>>>(x, W1, b1, Wr, br, wgt, B0, out, N);

  const int nbG = (N + ROWS_PB - 1) / ROWS_PB;
  const int total4 = N * (H / 4);
  for (int it = 1; it <= 3; ++it) {
    hipMemsetAsync(G, 0, zero_bytes, stream);
    k_Gm<<<nbG, 512, 0, stream>>>(B0, G, vsum, N);
    k_small<<<290, 256, 0, stream>>>(G, vsum, P, pb, wb, sconst, Q, K2, Mbuf, cvec, dvec, scal, N);
    k_final<<<1, 256, 0, stream>>>(vsum, qb, kb, wb, sconst, scal, N);
    k_tobf<<<2048, 256, 0, stream>>>(B0, invs, Rbf, total4);
    k_C<<<gRows, 256, 0, stream>>>(B0, Rbf, eb, invs, Mbuf, cvec, dvec, vsum, scal, offs8, deg,
                                   alphap, gamma, beta, Wr, br, wgt, out, N, it, (it == 3) ? 1 : 0);
  }
}

// Round 5
// 2250.562 us; speedup vs baseline: 2.2947x; 1.0206x over previous
//
#include <hip/hip_runtime.h>

#define H 256
#define FIN 58
#define LN_EPS 1e-5f
#define ROWS_PB 416  // k_Gm rows per block (13 chunks of 32)

typedef __bf16 bf16x8 __attribute__((ext_vector_type(8)));
typedef float f32x16 __attribute__((ext_vector_type(16)));

union FragU {
  ushort u[8];
  bf16x8 v;
};

// ---------------- utilities ----------------

__device__ __forceinline__ float wave_sum(float v) {
#pragma unroll
  for (int off = 1; off < 64; off <<= 1) v += __shfl_xor(v, off, 64);
  return v;
}

__device__ __forceinline__ float block_sum(float v, volatile float* red) {
  const int tid = threadIdx.x;
  v = wave_sum(v);
  __syncthreads();
  if ((tid & 63) == 0) red[tid >> 6] = v;
  __syncthreads();
  return red[0] + red[1] + red[2] + red[3];
}

__device__ __forceinline__ ushort f2bf(float f) {
  unsigned u = __float_as_uint(f);
  unsigned r = (u + 0x7FFFu + ((u >> 16) & 1u)) >> 16;
  return (ushort)r;
}

__device__ __forceinline__ void add4(float* a, ushort4 g) {
  a[0] += __uint_as_float((unsigned)g.x << 16);
  a[1] += __uint_as_float((unsigned)g.y << 16);
  a[2] += __uint_as_float((unsigned)g.z << 16);
  a[3] += __uint_as_float((unsigned)g.w << 16);
}

// ---------------- setup kernels ----------------

__global__ void k_deg(const int* __restrict__ col, int* __restrict__ deg, int E) {
  int e = blockIdx.x * 256 + threadIdx.x;
  if (e < E) atomicAdd(&deg[col[e]], 1);
}

__global__ void k_invsqrt(const int* __restrict__ deg, float* __restrict__ invs, int N) {
  int i = blockIdx.x * 256 + threadIdx.x;
  if (i < N) {
    int d = deg[i];
    invs[i] = (d > 0) ? (1.0f / sqrtf((float)d)) : 0.0f;
  }
}

// two-level exclusive scan of padded degree ((deg+15)&~15) -> offs16
__global__ __launch_bounds__(1024) void k_scan1(const int* __restrict__ deg,
                                                int* __restrict__ offs16,
                                                int* __restrict__ bsum, int N) {
  __shared__ int buf[1024];
  const int tid = threadIdx.x;
  const int gid = blockIdx.x * 1024 + tid;
  int v = (gid < N) ? ((deg[gid] + 15) & ~15) : 0;
  buf[tid] = v;
  __syncthreads();
  for (int off = 1; off < 1024; off <<= 1) {
    int x = (tid >= off) ? buf[tid - off] : 0;
    __syncthreads();
    buf[tid] += x;
    __syncthreads();
  }
  if (gid < N) offs16[gid] = buf[tid] - v;
  if (tid == 1023) bsum[blockIdx.x] = buf[1023];
}

__global__ __launch_bounds__(1024) void k_scan2(int* __restrict__ bsum, int nb) {
  __shared__ int buf[1024];
  const int tid = threadIdx.x;
  int v = (tid < nb) ? bsum[tid] : 0;
  buf[tid] = v;
  __syncthreads();
  for (int off = 1; off < 1024; off <<= 1) {
    int x = (tid >= off) ? buf[tid - off] : 0;
    __syncthreads();
    buf[tid] += x;
    __syncthreads();
  }
  if (tid < nb) bsum[tid] = buf[tid] - v;
}

__global__ void k_scan3(int* __restrict__ offs16, const int* __restrict__ bsum, int N) {
  int i = blockIdx.x * 256 + threadIdx.x;
  if (i < N) offs16[i] += bsum[i >> 10];
}

// fill edge buffer with sentinel row index N (points at the zero row of Rbf)
__global__ void k_fill(int* __restrict__ eb, int val, int total4) {
  int4 v = make_int4(val, val, val, val);
  for (int i = blockIdx.x * 256 + threadIdx.x; i < total4; i += gridDim.x * 256)
    ((int4*)eb)[i] = v;
}

// scatter edges into padded CSR of src indices
__global__ void k_scatter(const int* __restrict__ row, const int* __restrict__ col,
                          const int* __restrict__ offs16, int* __restrict__ cursor,
                          int* __restrict__ eb, int E) {
  int e = blockIdx.x * 256 + threadIdx.x;
  if (e < E) {
    int c = col[e];
    int pos = offs16[c] + atomicAdd(&cursor[c], 1);
    eb[pos] = row[e];
  }
}

// fp32 -> bf16 copy of R scaled by invs[row] (gather source)
__global__ void k_tobf(const float* __restrict__ R, const float* __restrict__ invs,
                       ushort* __restrict__ Rbf, int total4) {
  for (int i = blockIdx.x * 256 + threadIdx.x; i < total4; i += gridDim.x * 256) {
    float s = invs[i >> 6];
    float4 v = ((const float4*)R)[i];
    ushort4 o;
    o.x = f2bf(v.x * s); o.y = f2bf(v.y * s); o.z = f2bf(v.z * s); o.w = f2bf(v.w * s);
    ((ushort4*)Rbf)[i] = o;
  }
}

// iteration-independent weight products
__global__ void k_prep(const float* __restrict__ Wq, const float* __restrict__ Wk,
                       const float* __restrict__ bq, const float* __restrict__ bk,
                       float* __restrict__ P, float* __restrict__ Q, float* __restrict__ K2,
                       float* __restrict__ pb, float* __restrict__ qb,
                       float* __restrict__ wb, float* __restrict__ kb,
                       float* __restrict__ sconst) {
  __shared__ float red[4];
  const int b = blockIdx.x, tid = threadIdx.x;
  if (b < 768) {
    const int f = b & 255, which = b >> 8;
    const float* A = (which == 2) ? Wk : Wq;
    const float* Bm = (which == 1) ? Wq : Wk;
    float acc = 0.0f;
    for (int m = 0; m < H; m++) acc = fmaf(A[f * H + m], Bm[tid * H + m], acc);
    float* D = (which == 0) ? P : ((which == 1) ? Q : K2);
    D[f * H + tid] = acc;
  } else {
    float a1 = 0, a2 = 0, a3 = 0, a4 = 0;
    for (int m = 0; m < H; m++) {
      float wqv = Wq[tid * H + m], wkv = Wk[tid * H + m];
      a1 = fmaf(wqv, bk[m], a1);
      a2 = fmaf(wqv, bq[m], a2);
      a3 = fmaf(wkv, bq[m], a3);
      a4 = fmaf(wkv, bk[m], a4);
    }
    pb[tid] = a1; qb[tid] = a2; wb[tid] = a3; kb[tid] = a4;
    float c0 = block_sum(bq[tid] * bk[tid], red);
    float c1 = block_sum(bq[tid] * bq[tid], red);
    float c2 = block_sum(bk[tid] * bk[tid], red);
    if (tid == 0) { sconst[0] = c0; sconst[1] = c1; sconst[2] = c2; }
  }
}

// R0 = relu(x@W1 + b1), plus layer-0 readout
__global__ void k_fc1(const float* __restrict__ x, const float* __restrict__ W1,
                      const float* __restrict__ b1, const float* __restrict__ Wr,
                      const float* __restrict__ br, const float* __restrict__ wgt,
                      float* __restrict__ R0, float* __restrict__ out, int N) {
  __shared__ __align__(16) float lx[16 * FIN];
  __shared__ float red2[4][16];
  const int tid = threadIdx.x;
  const int n0 = blockIdx.x * 16;
  for (int idx = tid; idx < 16 * FIN / 4; idx += 256)
    ((float4*)lx)[idx] = ((const float4*)(x + (size_t)n0 * FIN))[idx];
  __syncthreads();
  float acc[16];
  const float bias = b1[tid];
#pragma unroll
  for (int r = 0; r < 16; r++) acc[r] = bias;
  for (int f = 0; f < FIN; f++) {
    float wv = W1[f * H + tid];
#pragma unroll
    for (int r = 0; r < 16; r++) acc[r] = fmaf(lx[r * FIN + f], wv, acc[r]);
  }
  const float wr0 = Wr[tid];
#pragma unroll
  for (int r = 0; r < 16; r++) {
    acc[r] = fmaxf(acc[r], 0.0f);
    int n = n0 + r;
    if (n < N) R0[(size_t)n * H + tid] = acc[r];
  }
#pragma unroll
  for (int r = 0; r < 16; r++) {
    float s = wave_sum(acc[r] * wr0);
    if ((tid & 63) == 0) red2[tid >> 6][r] = s;
  }
  __syncthreads();
  if (tid < 16) {
    int n = n0 + tid;
    if (n < N)
      out[n] = wgt[0] * (red2[0][tid] + red2[1][tid] + red2[2][tid] + red2[3][tid] + br[0]);
  }
}

// ---------------- MFMA G = R^T R (+ vsum) ----------------
__global__ __launch_bounds__(512, 2) void k_Gm(const float* __restrict__ R,
                                               float* __restrict__ G,
                                               float* __restrict__ vsum, int N) {
  __shared__ ushort sb[2][32 * 256];  // 32 KB
  const int tid = threadIdx.x;
  const int lane = tid & 63;
  const int wid = tid >> 6;
  const int wrow = (wid & 1) * 128;
  const int wcol = (wid >> 1) * 64;
  const int l31 = lane & 31;
  const int lhi = lane >> 5;

  const int rowbase = blockIdx.x * ROWS_PB;
  const int nrows = min(ROWS_PB, N - rowbase);
  const int nch = (nrows + 31) >> 5;

  const int sk = tid >> 4;
  const int sc = (tid & 15) * 4;

  f32x16 acc[4][2];
#pragma unroll
  for (int s = 0; s < 4; s++)
#pragma unroll
    for (int t = 0; t < 2; t++)
#pragma unroll
      for (int e = 0; e < 16; e++) acc[s][t][e] = 0.0f;

  float csum[16];
#pragma unroll
  for (int i = 0; i < 16; i++) csum[i] = 0.0f;

  float4 ld[4];

  auto load_chunk = [&](int ch) {
    int g = rowbase + ch * 32 + sk;
    const float4* src = (const float4*)(R + (size_t)g * H);
#pragma unroll
    for (int i = 0; i < 4; i++)
      ld[i] = (g < N) ? src[(sc >> 2) + 16 * i] : make_float4(0, 0, 0, 0);
  };

  auto write_chunk = [&](int buf) {
    const int swz = (sk & 3) << 4;
#pragma unroll
    for (int i = 0; i < 4; i++) {
      float4 v = ld[i];
      csum[i * 4 + 0] += v.x; csum[i * 4 + 1] += v.y;
      csum[i * 4 + 2] += v.z; csum[i * 4 + 3] += v.w;
      ushort4 o;
      o.x = f2bf(v.x); o.y = f2bf(v.y); o.z = f2bf(v.z); o.w = f2bf(v.w);
      int c = sc + 64 * i;
      *(ushort4*)&sb[buf][sk * 256 + (c ^ swz)] = o;
    }
  };

  auto compute = [&](int buf) {
#pragma unroll
    for (int ks = 0; ks < 2; ks++) {
      const int kb = ks * 16 + lhi * 8;
      FragU fr[6];
#pragma unroll
      for (int s = 0; s < 6; s++) {
        const int cbase = (s < 4) ? (wrow + 32 * s + l31) : (wcol + 32 * (s - 4) + l31);
#pragma unroll
        for (int j = 0; j < 8; j++)
          fr[s].u[j] = sb[buf][(kb + j) * 256 + (cbase ^ ((j & 3) << 4))];
      }
#pragma unroll
      for (int s = 0; s < 4; s++)
#pragma unroll
        for (int t = 0; t < 2; t++)
          acc[s][t] = __builtin_amdgcn_mfma_f32_32x32x16_bf16(fr[s].v, fr[4 + t].v,
                                                              acc[s][t], 0, 0, 0);
    }
  };

  load_chunk(0);
  write_chunk(0);
  __syncthreads();
  int cur = 0;
  for (int c = 0; c < nch; c++) {
    if (c + 1 < nch) load_chunk(c + 1);
    compute(cur);
    if (c + 1 < nch) write_chunk(cur ^ 1);
    __syncthreads();
    cur ^= 1;
  }

#pragma unroll
  for (int s = 0; s < 4; s++)
#pragma unroll
    for (int t = 0; t < 2; t++) {
      const int n0 = wcol + 32 * t + l31;
#pragma unroll
      for (int r = 0; r < 16; r++) {
        const int row = wrow + 32 * s + (r & 3) + 8 * (r >> 2) + 4 * lhi;
        atomicAdd(&G[row * 256 + n0], acc[s][t][r]);
      }
    }

  float* fl = (float*)sb;
#pragma unroll
  for (int i = 0; i < 4; i++) {
#pragma unroll
    for (int cc = 0; cc < 4; cc++)
      fl[sk * 256 + sc + 64 * i + cc] = csum[i * 4 + cc];
  }
  __syncthreads();
  if (tid < 256) {
    float s = 0.0f;
    for (int r = 0; r < 32; r++) s += fl[r * 256 + tid];
    atomicAdd(&vsum[tid], s);
  }
}

// per-iteration small products from (G, vsum)
__global__ void k_small(const float* __restrict__ G, const float* __restrict__ vsum,
                        const float* __restrict__ P, const float* __restrict__ pb,
                        const float* __restrict__ wb, const float* __restrict__ sconst,
                        const float* __restrict__ Q, const float* __restrict__ K2,
                        float* __restrict__ M, float* __restrict__ cvec,
                        float* __restrict__ dvec, float* __restrict__ scal, int N) {
  __shared__ float red[4];
  const int b = blockIdx.x, tid = threadIdx.x;
  if (b < 256) {
    float acc = 0.0f;
    for (int m = 0; m < H; m++) acc = fmaf(P[b * H + m], G[m * H + tid], acc);
    M[b * H + tid] = acc + pb[b] * vsum[tid];
  } else if (b == 256) {
    float acc = 0.0f;
    for (int f = 0; f < H; f++) acc = fmaf(wb[f], G[f * H + tid], acc);
    cvec[tid] = acc + sconst[0] * vsum[tid];
  } else if (b == 257) {
    float acc = 0.0f;
    for (int m = 0; m < H; m++) acc = fmaf(P[tid * H + m], vsum[m], acc);
    dvec[tid] = acc + (float)N * pb[tid];
  } else if (b < 274) {
    int base = (b - 258) * 4096 + tid;
    float a = 0.0f;
    for (int j = 0; j < 16; j++) a = fmaf(G[base + j * 256], Q[base + j * 256], a);
    a = block_sum(a, red);
    if (tid == 0) atomicAdd(&scal[0], a);
  } else {
    int base = (b - 274) * 4096 + tid;
    float a = 0.0f;
    for (int j = 0; j < 16; j++) a = fmaf(G[base + j * 256], K2[base + j * 256], a);
    a = block_sum(a, red);
    if (tid == 0) atomicAdd(&scal[1], a);
  }
}

// finalize norms
__global__ void k_final(const float* __restrict__ vsum, const float* __restrict__ qb,
                        const float* __restrict__ kb, const float* __restrict__ wb,
                        const float* __restrict__ sconst, float* __restrict__ scal, int N) {
  __shared__ float red[4];
  const int tid = threadIdx.x;
  float s1 = block_sum(qb[tid] * vsum[tid], red);
  float s2 = block_sum(kb[tid] * vsum[tid], red);
  float s3 = block_sum(wb[tid] * vsum[tid], red);
  if (tid == 0) {
    float sq = scal[0] + 2.0f * s1 + (float)N * sconst[1];
    float sk = scal[1] + 2.0f * s2 + (float)N * sconst[2];
    scal[2] = 1.0f / (sqrtf(sq) * sqrtf(sk));
    scal[3] = s3 + (float)N * sconst[0];
  }
}

// fused: num = R*M, den, gcn gather (pre-scaled bf16, 16-deep), residual blend,
// layernorm, write R in place, readout. 32 rows per block, 4 waves x 8 rows.
__global__ __launch_bounds__(256, 2) void k_C(
    float* __restrict__ Rcur, const ushort* __restrict__ Rbf,
    const int* __restrict__ eb, const float* __restrict__ invs,
    const float* __restrict__ Mm, const float* __restrict__ cvec,
    const float* __restrict__ dvec, const float* __restrict__ vsum,
    const float* __restrict__ scal, const int* __restrict__ offs16,
    const int* __restrict__ deg, const float* __restrict__ alphap,
    const float* __restrict__ gamma, const float* __restrict__ beta,
    const float* __restrict__ Wr, const float* __restrict__ br,
    const float* __restrict__ wgt, float* __restrict__ out,
    int N, int layer, int last) {
  __shared__ __align__(16) float lR[32 * H];  // 32 KB
  __shared__ __align__(16) float lM[32 * H];  // 32 KB
  const int tid = threadIdx.x, lane = tid & 63, wv = tid >> 6;
  const int wv8 = wv * 8;
  const int d0 = lane * 4;
  const int n0 = blockIdx.x * 32;

  for (int idx = tid; idx < 32 * (H / 4); idx += 256) {
    int n = n0 + (idx >> 6);
    ((float4*)lR)[idx] = (n < N) ? ((const float4*)Rcur)[(size_t)n * (H / 4) + (idx & 63)]
                                 : make_float4(0, 0, 0, 0);
  }
  __syncthreads();

  float accn[8][4];
#pragma unroll
  for (int r = 0; r < 8; r++)
#pragma unroll
    for (int j = 0; j < 4; j++) accn[r][j] = 0.0f;

  for (int ch = 0; ch < 8; ch++) {
    __syncthreads();
    for (int idx = tid; idx < 32 * (H / 4); idx += 256)
      ((float4*)lM)[idx] = ((const float4*)(Mm + (size_t)ch * 32 * H))[idx];
    __syncthreads();
#pragma unroll
    for (int f4 = 0; f4 < 8; f4++) {
      const int fb = f4 * 4;
      const float4 m0 = *(const float4*)&lM[(fb + 0) * H + d0];
      const float4 m1 = *(const float4*)&lM[(fb + 1) * H + d0];
      const float4 m2 = *(const float4*)&lM[(fb + 2) * H + d0];
      const float4 m3 = *(const float4*)&lM[(fb + 3) * H + d0];
#pragma unroll
      for (int r = 0; r < 8; r++) {
        const float4 rv = *(const float4*)&lR[(wv8 + r) * H + ch * 32 + fb];
        accn[r][0] = fmaf(rv.x, m0.x, fmaf(rv.y, m1.x, fmaf(rv.z, m2.x, fmaf(rv.w, m3.x, accn[r][0]))));
        accn[r][1] = fmaf(rv.x, m0.y, fmaf(rv.y, m1.y, fmaf(rv.z, m2.y, fmaf(rv.w, m3.y, accn[r][1]))));
        accn[r][2] = fmaf(rv.x, m0.z, fmaf(rv.y, m1.z, fmaf(rv.z, m2.z, fmaf(rv.w, m3.z, accn[r][2]))));
        accn[r][3] = fmaf(rv.x, m0.w, fmaf(rv.y, m1.w, fmaf(rv.z, m2.w, fmaf(rv.w, m3.w, accn[r][3]))));
      }
    }
  }

  const float invn = scal[2], denc = scal[3];
  const float al = alphap[0], om = 1.0f - al;
  const float4 dv = *(const float4*)&dvec[d0];

  float den[8];
#pragma unroll
  for (int r = 0; r < 8; r++) {
    const float* Rr = &lR[(wv8 + r) * H + d0];
    float p = Rr[0] * dv.x + Rr[1] * dv.y + Rr[2] * dv.z + Rr[3] * dv.w;
    p = wave_sum(p);
    den[r] = (p + denc) * invn + (float)N;
  }

  // GCN gather: pre-scaled bf16 rows, 16 edges in flight per batch
  float accg[8][4];
#pragma unroll
  for (int r = 0; r < 8; r++)
#pragma unroll
    for (int j = 0; j < 4; j++) accg[r][j] = 0.0f;
#pragma unroll
  for (int r = 0; r < 8; r++) {
    int n = n0 + wv8 + r;
    if (n < N) {
      const int st = offs16[n];  // multiple of 16
      const int nb = (deg[n] + 15) >> 4;
      const int4* p = (const int4*)(eb + st);
      for (int b = 0; b < nb; b++, p += 4) {
        const int4 iA = p[0];
        const int4 iB = p[1];
        const int4 iC = p[2];
        const int4 iD = p[3];
        const ushort4 g0 = *(const ushort4*)&Rbf[((size_t)iA.x << 8) + d0];
        const ushort4 g1 = *(const ushort4*)&Rbf[((size_t)iA.y << 8) + d0];
        const ushort4 g2 = *(const ushort4*)&Rbf[((size_t)iA.z << 8) + d0];
        const ushort4 g3 = *(const ushort4*)&Rbf[((size_t)iA.w << 8) + d0];
        const ushort4 g4 = *(const ushort4*)&Rbf[((size_t)iB.x << 8) + d0];
        const ushort4 g5 = *(const ushort4*)&Rbf[((size_t)iB.y << 8) + d0];
        const ushort4 g6 = *(const ushort4*)&Rbf[((size_t)iB.z << 8) + d0];
        const ushort4 g7 = *(const ushort4*)&Rbf[((size_t)iB.w << 8) + d0];
        const ushort4 g8 = *(const ushort4*)&Rbf[((size_t)iC.x << 8) + d0];
        const ushort4 g9 = *(const ushort4*)&Rbf[((size_t)iC.y << 8) + d0];
        const ushort4 gA = *(const ushort4*)&Rbf[((size_t)iC.z << 8) + d0];
        const ushort4 gB = *(const ushort4*)&Rbf[((size_t)iC.w << 8) + d0];
        const ushort4 gC = *(const ushort4*)&Rbf[((size_t)iD.x << 8) + d0];
        const ushort4 gD = *(const ushort4*)&Rbf[((size_t)iD.y << 8) + d0];
        const ushort4 gE = *(const ushort4*)&Rbf[((size_t)iD.z << 8) + d0];
        const ushort4 gF = *(const ushort4*)&Rbf[((size_t)iD.w << 8) + d0];
        add4(accg[r], g0); add4(accg[r], g1); add4(accg[r], g2); add4(accg[r], g3);
        add4(accg[r], g4); add4(accg[r], g5); add4(accg[r], g6); add4(accg[r], g7);
        add4(accg[r], g8); add4(accg[r], g9); add4(accg[r], gA); add4(accg[r], gB);
        add4(accg[r], gC); add4(accg[r], gD); add4(accg[r], gE); add4(accg[r], gF);
      }
      const float sn = invs[n];
      accg[r][0] *= sn; accg[r][1] *= sn; accg[r][2] *= sn; accg[r][3] *= sn;
    }
  }

  const float4 cv = *(const float4*)&cvec[d0];
  const float4 vs = *(const float4*)&vsum[d0];
  const float4 gm = *(const float4*)&gamma[d0];
  const float4 bt = *(const float4*)&beta[d0];
  const float4 wr = *(const float4*)&Wr[layer * H + d0];
  const float wl = wgt[layer], bl = br[layer];

#pragma unroll
  for (int r = 0; r < 8; r++) {
    const int n = n0 + wv8 + r;
    const float rden = 1.0f / den[r];
    const float4 old4 = *(const float4*)&lR[(wv8 + r) * H + d0];
    float hv[4];
    hv[0] = al * (((accn[r][0] + cv.x) * invn + vs.x) * rden + accg[r][0]) + om * old4.x;
    hv[1] = al * (((accn[r][1] + cv.y) * invn + vs.y) * rden + accg[r][1]) + om * old4.y;
    hv[2] = al * (((accn[r][2] + cv.z) * invn + vs.z) * rden + accg[r][2]) + om * old4.z;
    hv[3] = al * (((accn[r][3] + cv.w) * invn + vs.w) * rden + accg[r][3]) + om * old4.w;
    float s = wave_sum(hv[0] + hv[1] + hv[2] + hv[3]);
    float mu = s * (1.0f / H);
    float s2 = wave_sum(hv[0] * hv[0] + hv[1] * hv[1] + hv[2] * hv[2] + hv[3] * hv[3]);
    float var = s2 * (1.0f / H) - mu * mu;
    float rs = rsqrtf(var + LN_EPS);
    float y0 = (hv[0] - mu) * rs * gm.x + bt.x;
    float y1 = (hv[1] - mu) * rs * gm.y + bt.y;
    float y2 = (hv[2] - mu) * rs * gm.z + bt.z;
    float y3 = (hv[3] - mu) * rs * gm.w + bt.w;
    if (!last && n < N)
      *(float4*)&Rcur[(size_t)n * H + d0] = make_float4(y0, y1, y2, y3);
    float rp = wave_sum(y0 * wr.x + y1 * wr.y + y2 * wr.z + y3 * wr.w);
    if (lane == 0 && n < N) out[n] += wl * (rp + bl);
  }
}

// ---------------- host ----------------

extern "C" void kernel_launch(void* const* d_in, const int* in_sizes, int n_in,
                              void* d_out, int out_size, void* d_ws, size_t ws_size,
                              hipStream_t stream) {
  const float* x = (const float*)d_in[0];
  const int* ei = (const int*)d_in[1];
  const float* W1 = (const float*)d_in[2];
  const float* b1 = (const float*)d_in[3];
  const float* Wq = (const float*)d_in[4];
  const float* bq = (const float*)d_in[5];
  const float* Wk = (const float*)d_in[6];
  const float* bk = (const float*)d_in[7];
  const float* gamma = (const float*)d_in[8];
  const float* beta = (const float*)d_in[9];
  const float* alphap = (const float*)d_in[10];
  const float* Wr = (const float*)d_in[11];
  const float* br = (const float*)d_in[12];
  const float* wgt = (const float*)d_in[13];
  float* out = (float*)d_out;

  const int N = in_sizes[0] / FIN;
  const int E = in_sizes[1] / 2;
  const int* row = ei;
  const int* col = ei + E;

  char* w = (char*)d_ws;
  auto alloc = [&](size_t bytes) -> char* {
    char* p = w;
    w += (bytes + 255) & ~(size_t)255;
    return p;
  };
  const size_t SB = (size_t)N * H * sizeof(float);
  float* B0 = (float*)alloc(SB);
  ushort* Rbf = (ushort*)alloc((size_t)(N + 1) * H * sizeof(ushort));  // +1 zero row
  float* G = (float*)alloc(H * H * sizeof(float));
  float* vsum = (float*)alloc(1024);
  float* scal = (float*)alloc(256);
  const size_t zero_bytes = H * H * sizeof(float) + 1024 + 256;
  float* Mbuf = (float*)alloc(H * H * sizeof(float));
  float* cvec = (float*)alloc(1024);
  float* dvec = (float*)alloc(1024);
  float* P = (float*)alloc(H * H * sizeof(float));
  float* Q = (float*)alloc(H * H * sizeof(float));
  float* K2 = (float*)alloc(H * H * sizeof(float));
  float* pb = (float*)alloc(1024);
  float* qb = (float*)alloc(1024);
  float* wb = (float*)alloc(1024);
  float* kb = (float*)alloc(1024);
  float* sconst = (float*)alloc(256);
  int* deg = (int*)alloc((size_t)N * 4);
  int* cursor = (int*)alloc((size_t)N * 4);
  float* invs = (float*)alloc((size_t)N * 4);
  int* offs16 = (int*)alloc((size_t)(N + 1) * 4);
  int* bsum = (int*)alloc(1024 * 4);
  size_t EPAD = (size_t)E + 16 * (size_t)N;
  EPAD = (EPAD + 3) & ~(size_t)3;
  int* eb = (int*)alloc(EPAD * sizeof(int));

  hipMemsetAsync(deg, 0, (size_t)N * 4, stream);
  hipMemsetAsync(cursor, 0, (size_t)N * 4, stream);
  hipMemsetAsync(Rbf + (size_t)N * H, 0, H * sizeof(ushort), stream);

  const int gE = (E + 255) / 256, gN = (N + 255) / 256;
  const int nblk = (N + 1023) / 1024;
  k_deg<<<gE, 256, 0, stream>>>(col, deg, E);
  k_invsqrt<<<gN, 256, 0, stream>>>(deg, invs, N);
  k_scan1<<<nblk, 1024, 0, stream>>>(deg, offs16, bsum, N);
  k_scan2<<<1, 1024, 0, stream>>>(bsum, nblk);
  k_scan3<<<gN, 256, 0, stream>>>(offs16, bsum, N);
  k_fill<<<2048, 256, 0, stream>>>(eb, N, (int)(EPAD / 4));
  k_scatter<<<gE, 256, 0, stream>>>(row, col, offs16, cursor, eb, E);
  k_prep<<<769, 256, 0, stream>>>(Wq, Wk, bq, bk, P, Q, K2, pb, qb, wb, kb, sconst);
  const int gRows16 = (N + 15) / 16;
  k_fc1<<<gRows16, 256, 0, stream>>>(x, W1, b1, Wr, br, wgt, B0, out, N);

  const int nbG = (N + ROWS_PB - 1) / ROWS_PB;
  const int total4 = N * (H / 4);
  const int gRows32 = (N + 31) / 32;
  for (int it = 1; it <= 3; ++it) {
    hipMemsetAsync(G, 0, zero_bytes, stream);
    k_Gm<<<nbG, 512, 0, stream>>>(B0, G, vsum, N);
    k_small<<<290, 256, 0, stream>>>(G, vsum, P, pb, wb, sconst, Q, K2, Mbuf, cvec, dvec, scal, N);
    k_final<<<1, 256, 0, stream>>>(vsum, qb, kb, wb, sconst, scal, N);
    k_tobf<<<2048, 256, 0, stream>>>(B0, invs, Rbf, total4);
    k_C<<<gRows32, 256, 0, stream>>>(B0, Rbf, eb, invs, Mbuf, cvec, dvec, vsum, scal, offs16, deg,
                                     alphap, gamma, beta, Wr, br, wgt, out, N, it, (it == 3) ? 1 : 0);
  }
}

// Round 6
// 1773.413 us; speedup vs baseline: 2.9121x; 1.2691x over previous
//
#include <hip/hip_runtime.h>

#define H 256
#define FIN 58
#define LN_EPS 1e-5f
#define ROWS_PB 416  // k_Gm rows per block (13 chunks of 32)

typedef __bf16 bf16x8 __attribute__((ext_vector_type(8)));
typedef float f32x16 __attribute__((ext_vector_type(16)));

union FragU {
  ushort u[8];
  bf16x8 v;
};

// ---------------- utilities ----------------

__device__ __forceinline__ float wave_sum(float v) {
#pragma unroll
  for (int off = 1; off < 64; off <<= 1) v += __shfl_xor(v, off, 64);
  return v;
}

__device__ __forceinline__ float block_sum(float v, volatile float* red) {
  const int tid = threadIdx.x;
  v = wave_sum(v);
  __syncthreads();
  if ((tid & 63) == 0) red[tid >> 6] = v;
  __syncthreads();
  return red[0] + red[1] + red[2] + red[3];
}

__device__ __forceinline__ ushort f2bf(float f) {
  unsigned u = __float_as_uint(f);
  unsigned r = (u + 0x7FFFu + ((u >> 16) & 1u)) >> 16;
  return (ushort)r;
}

__device__ __forceinline__ float bf2f(ushort u) {
  return __uint_as_float((unsigned)u << 16);
}

// ---------------- setup kernels ----------------

__global__ void k_deg(const int* __restrict__ col, int* __restrict__ deg, int E) {
  int e = blockIdx.x * 256 + threadIdx.x;
  if (e < E) atomicAdd(&deg[col[e]], 1);
}

__global__ void k_invsqrt(const int* __restrict__ deg, float* __restrict__ invs, int N) {
  int i = blockIdx.x * 256 + threadIdx.x;
  if (i < N) {
    int d = deg[i];
    invs[i] = (d > 0) ? (1.0f / sqrtf((float)d)) : 0.0f;
  }
}

// two-level exclusive scan of padded degree ((deg+15)&~15) -> offs16
__global__ __launch_bounds__(1024) void k_scan1(const int* __restrict__ deg,
                                                int* __restrict__ offs16,
                                                int* __restrict__ bsum, int N) {
  __shared__ int buf[1024];
  const int tid = threadIdx.x;
  const int gid = blockIdx.x * 1024 + tid;
  int v = (gid < N) ? ((deg[gid] + 15) & ~15) : 0;
  buf[tid] = v;
  __syncthreads();
  for (int off = 1; off < 1024; off <<= 1) {
    int x = (tid >= off) ? buf[tid - off] : 0;
    __syncthreads();
    buf[tid] += x;
    __syncthreads();
  }
  if (gid < N) offs16[gid] = buf[tid] - v;
  if (tid == 1023) bsum[blockIdx.x] = buf[1023];
}

__global__ __launch_bounds__(1024) void k_scan2(int* __restrict__ bsum, int nb) {
  __shared__ int buf[1024];
  const int tid = threadIdx.x;
  int v = (tid < nb) ? bsum[tid] : 0;
  buf[tid] = v;
  __syncthreads();
  for (int off = 1; off < 1024; off <<= 1) {
    int x = (tid >= off) ? buf[tid - off] : 0;
    __syncthreads();
    buf[tid] += x;
    __syncthreads();
  }
  if (tid < nb) bsum[tid] = buf[tid] - v;
}

__global__ void k_scan3(int* __restrict__ offs16, const int* __restrict__ bsum, int N) {
  int i = blockIdx.x * 256 + threadIdx.x;
  if (i < N) offs16[i] += bsum[i >> 10];
}

// scatter edges into padded CSR of {src, weight} records (pad slots are {0,0})
__global__ void k_scatter(const int* __restrict__ row, const int* __restrict__ col,
                          const float* __restrict__ invs, const int* __restrict__ offs16,
                          int* __restrict__ cursor, int2* __restrict__ eb, int E) {
  int e = blockIdx.x * 256 + threadIdx.x;
  if (e < E) {
    int r = row[e], c = col[e];
    int pos = offs16[c] + atomicAdd(&cursor[c], 1);
    eb[pos] = make_int2(r, __float_as_int(invs[c] * invs[r]));
  }
}

// iteration-independent weight products
__global__ void k_prep(const float* __restrict__ Wq, const float* __restrict__ Wk,
                       const float* __restrict__ bq, const float* __restrict__ bk,
                       float* __restrict__ P, float* __restrict__ Q, float* __restrict__ K2,
                       float* __restrict__ pb, float* __restrict__ qb,
                       float* __restrict__ wb, float* __restrict__ kb,
                       float* __restrict__ sconst) {
  __shared__ float red[4];
  const int b = blockIdx.x, tid = threadIdx.x;
  if (b < 768) {
    const int f = b & 255, which = b >> 8;
    const float* A = (which == 2) ? Wk : Wq;
    const float* Bm = (which == 1) ? Wq : Wk;
    float acc = 0.0f;
    for (int m = 0; m < H; m++) acc = fmaf(A[f * H + m], Bm[tid * H + m], acc);
    float* D = (which == 0) ? P : ((which == 1) ? Q : K2);
    D[f * H + tid] = acc;
  } else {
    float a1 = 0, a2 = 0, a3 = 0, a4 = 0;
    for (int m = 0; m < H; m++) {
      float wqv = Wq[tid * H + m], wkv = Wk[tid * H + m];
      a1 = fmaf(wqv, bk[m], a1);
      a2 = fmaf(wqv, bq[m], a2);
      a3 = fmaf(wkv, bq[m], a3);
      a4 = fmaf(wkv, bk[m], a4);
    }
    pb[tid] = a1; qb[tid] = a2; wb[tid] = a3; kb[tid] = a4;
    float c0 = block_sum(bq[tid] * bk[tid], red);
    float c1 = block_sum(bq[tid] * bq[tid], red);
    float c2 = block_sum(bk[tid] * bk[tid], red);
    if (tid == 0) { sconst[0] = c0; sconst[1] = c1; sconst[2] = c2; }
  }
}

// R0 = relu(x@W1 + b1) -> bf16, plus layer-0 readout
__global__ void k_fc1(const float* __restrict__ x, const float* __restrict__ W1,
                      const float* __restrict__ b1, const float* __restrict__ Wr,
                      const float* __restrict__ br, const float* __restrict__ wgt,
                      ushort* __restrict__ R0, float* __restrict__ out, int N) {
  __shared__ __align__(16) float lx[16 * FIN];
  __shared__ float red2[4][16];
  const int tid = threadIdx.x;
  const int n0 = blockIdx.x * 16;
  for (int idx = tid; idx < 16 * FIN / 4; idx += 256)
    ((float4*)lx)[idx] = ((const float4*)(x + (size_t)n0 * FIN))[idx];
  __syncthreads();
  float acc[16];
  const float bias = b1[tid];
#pragma unroll
  for (int r = 0; r < 16; r++) acc[r] = bias;
  for (int f = 0; f < FIN; f++) {
    float wv = W1[f * H + tid];
#pragma unroll
    for (int r = 0; r < 16; r++) acc[r] = fmaf(lx[r * FIN + f], wv, acc[r]);
  }
  const float wr0 = Wr[tid];
#pragma unroll
  for (int r = 0; r < 16; r++) {
    acc[r] = fmaxf(acc[r], 0.0f);
    int n = n0 + r;
    if (n < N) R0[(size_t)n * H + tid] = f2bf(acc[r]);
  }
#pragma unroll
  for (int r = 0; r < 16; r++) {
    float s = wave_sum(acc[r] * wr0);
    if ((tid & 63) == 0) red2[tid >> 6][r] = s;
  }
  __syncthreads();
  if (tid < 16) {
    int n = n0 + tid;
    if (n < N)
      out[n] = wgt[0] * (red2[0][tid] + red2[1][tid] + red2[2][tid] + red2[3][tid] + br[0]);
  }
}

// ---------------- MFMA G = R^T R (+ vsum), bf16 input ----------------
__global__ __launch_bounds__(512, 2) void k_Gm(const ushort* __restrict__ Rb,
                                               float* __restrict__ G,
                                               float* __restrict__ vsum, int N) {
  __shared__ ushort sb[2][32 * 256];  // 32 KB
  const int tid = threadIdx.x;
  const int lane = tid & 63;
  const int wid = tid >> 6;
  const int wrow = (wid & 1) * 128;
  const int wcol = (wid >> 1) * 64;
  const int l31 = lane & 31;
  const int lhi = lane >> 5;

  const int rowbase = blockIdx.x * ROWS_PB;
  const int nrows = min(ROWS_PB, N - rowbase);
  const int nch = (nrows + 31) >> 5;

  const int sk = tid >> 4;        // staging row 0..31
  const int c0 = (tid & 15) * 16; // 16 contiguous bf16 per thread

  f32x16 acc[4][2];
#pragma unroll
  for (int s = 0; s < 4; s++)
#pragma unroll
    for (int t = 0; t < 2; t++)
#pragma unroll
      for (int e = 0; e < 16; e++) acc[s][t][e] = 0.0f;

  float csum[16];
#pragma unroll
  for (int i = 0; i < 16; i++) csum[i] = 0.0f;

  int4 ld[2];

  auto load_chunk = [&](int ch) {
    int g = rowbase + ch * 32 + sk;
    const int4* src = (const int4*)(Rb + (size_t)g * H + c0);
    ld[0] = (g < N) ? src[0] : make_int4(0, 0, 0, 0);
    ld[1] = (g < N) ? src[1] : make_int4(0, 0, 0, 0);
  };

  auto write_chunk = [&](int buf) {
    const int swz = (sk & 3) << 4;
#pragma unroll
    for (int i = 0; i < 2; i++) {
      *(int4*)&sb[buf][sk * 256 + ((c0 + 8 * i) ^ swz)] = ld[i];
      const ushort* pu = (const ushort*)&ld[i];
#pragma unroll
      for (int j = 0; j < 8; j++) csum[8 * i + j] += bf2f(pu[j]);
    }
  };

  auto compute = [&](int buf) {
#pragma unroll
    for (int ks = 0; ks < 2; ks++) {
      const int kb = ks * 16 + lhi * 8;
      FragU fr[6];
#pragma unroll
      for (int s = 0; s < 6; s++) {
        const int cbase = (s < 4) ? (wrow + 32 * s + l31) : (wcol + 32 * (s - 4) + l31);
#pragma unroll
        for (int j = 0; j < 8; j++)
          fr[s].u[j] = sb[buf][(kb + j) * 256 + (cbase ^ ((j & 3) << 4))];
      }
#pragma unroll
      for (int s = 0; s < 4; s++)
#pragma unroll
        for (int t = 0; t < 2; t++)
          acc[s][t] = __builtin_amdgcn_mfma_f32_32x32x16_bf16(fr[s].v, fr[4 + t].v,
                                                              acc[s][t], 0, 0, 0);
    }
  };

  load_chunk(0);
  write_chunk(0);
  __syncthreads();
  int cur = 0;
  for (int c = 0; c < nch; c++) {
    if (c + 1 < nch) load_chunk(c + 1);
    compute(cur);
    if (c + 1 < nch) write_chunk(cur ^ 1);
    __syncthreads();
    cur ^= 1;
  }

#pragma unroll
  for (int s = 0; s < 4; s++)
#pragma unroll
    for (int t = 0; t < 2; t++) {
      const int n0 = wcol + 32 * t + l31;
#pragma unroll
      for (int r = 0; r < 16; r++) {
        const int row = wrow + 32 * s + (r & 3) + 8 * (r >> 2) + 4 * lhi;
        atomicAdd(&G[row * 256 + n0], acc[s][t][r]);
      }
    }

  float* fl = (float*)sb;
#pragma unroll
  for (int j = 0; j < 16; j++) fl[sk * 256 + c0 + j] = csum[j];
  __syncthreads();
  if (tid < 256) {
    float s = 0.0f;
    for (int r = 0; r < 32; r++) s += fl[r * 256 + tid];
    atomicAdd(&vsum[tid], s);
  }
}

// per-iteration small products from (G, vsum); writes transposed bf16 Mt[n][k]
__global__ void k_small(const float* __restrict__ G, const float* __restrict__ vsum,
                        const float* __restrict__ P, const float* __restrict__ pb,
                        const float* __restrict__ wb, const float* __restrict__ sconst,
                        const float* __restrict__ Q, const float* __restrict__ K2,
                        ushort* __restrict__ Mt, float* __restrict__ cvec,
                        float* __restrict__ dvec, float* __restrict__ scal, int N) {
  __shared__ float red[4];
  const int b = blockIdx.x, tid = threadIdx.x;
  if (b < 256) {  // M[b][n] for n=tid -> Mt[n][b]
    float acc = 0.0f;
    for (int m = 0; m < H; m++) acc = fmaf(P[b * H + m], G[m * H + tid], acc);
    Mt[(size_t)tid * H + b] = f2bf(acc + pb[b] * vsum[tid]);
  } else if (b == 256) {
    float acc = 0.0f;
    for (int f = 0; f < H; f++) acc = fmaf(wb[f], G[f * H + tid], acc);
    cvec[tid] = acc + sconst[0] * vsum[tid];
  } else if (b == 257) {
    float acc = 0.0f;
    for (int m = 0; m < H; m++) acc = fmaf(P[tid * H + m], vsum[m], acc);
    dvec[tid] = acc + (float)N * pb[tid];
  } else if (b < 274) {
    int base = (b - 258) * 4096 + tid;
    float a = 0.0f;
    for (int j = 0; j < 16; j++) a = fmaf(G[base + j * 256], Q[base + j * 256], a);
    a = block_sum(a, red);
    if (tid == 0) atomicAdd(&scal[0], a);
  } else {
    int base = (b - 274) * 4096 + tid;
    float a = 0.0f;
    for (int j = 0; j < 16; j++) a = fmaf(G[base + j * 256], K2[base + j * 256], a);
    a = block_sum(a, red);
    if (tid == 0) atomicAdd(&scal[1], a);
  }
}

// finalize norms
__global__ void k_final(const float* __restrict__ vsum, const float* __restrict__ qb,
                        const float* __restrict__ kb, const float* __restrict__ wb,
                        const float* __restrict__ sconst, float* __restrict__ scal, int N) {
  __shared__ float red[4];
  const int tid = threadIdx.x;
  float s1 = block_sum(qb[tid] * vsum[tid], red);
  float s2 = block_sum(kb[tid] * vsum[tid], red);
  float s3 = block_sum(wb[tid] * vsum[tid], red);
  if (tid == 0) {
    float sq = scal[0] + 2.0f * s1 + (float)N * sconst[1];
    float sk = scal[1] + 2.0f * s2 + (float)N * sconst[2];
    scal[2] = 1.0f / (sqrtf(sq) * sqrtf(sk));
    scal[3] = s3 + (float)N * sconst[0];
  }
}

// ---------------- MFMA num = R * M (bf16 in, bf16 out) ----------------
// 512 thr / 8 waves; block = 128 rows x 256 cols; wave = 32 rows x 128 cols
// (4 tiles 32x32). No LDS: A-frags from Rb rows, B-frags from Mt (L2-hot).
__global__ __launch_bounds__(512) void k_N(const ushort* __restrict__ Rb,
                                           const ushort* __restrict__ Mt,
                                           ushort* __restrict__ numb, int N) {
  const int tid = threadIdx.x;
  const int lane = tid & 63;
  const int wid = tid >> 6;
  const int l31 = lane & 31;
  const int lhi = lane >> 5;
  const int wrow = (wid & 3) * 32;
  const int wcol = (wid >> 2) * 128;
  const int rowbase = blockIdx.x * 128;

  f32x16 acc[4];
#pragma unroll
  for (int t = 0; t < 4; t++)
#pragma unroll
    for (int e = 0; e < 16; e++) acc[t][e] = 0.0f;

  const ushort* aptr = Rb + (size_t)(rowbase + wrow + l31) * H;

  for (int kc = 0; kc < 16; kc++) {
    const int kb = kc * 16 + lhi * 8;
    FragU fa;
    *(int4*)fa.u = *(const int4*)(aptr + kb);
    FragU fb0, fb1, fb2, fb3;
    *(int4*)fb0.u = *(const int4*)(Mt + (size_t)(wcol + 0 + l31) * H + kb);
    *(int4*)fb1.u = *(const int4*)(Mt + (size_t)(wcol + 32 + l31) * H + kb);
    *(int4*)fb2.u = *(const int4*)(Mt + (size_t)(wcol + 64 + l31) * H + kb);
    *(int4*)fb3.u = *(const int4*)(Mt + (size_t)(wcol + 96 + l31) * H + kb);
    acc[0] = __builtin_amdgcn_mfma_f32_32x32x16_bf16(fa.v, fb0.v, acc[0], 0, 0, 0);
    acc[1] = __builtin_amdgcn_mfma_f32_32x32x16_bf16(fa.v, fb1.v, acc[1], 0, 0, 0);
    acc[2] = __builtin_amdgcn_mfma_f32_32x32x16_bf16(fa.v, fb2.v, acc[2], 0, 0, 0);
    acc[3] = __builtin_amdgcn_mfma_f32_32x32x16_bf16(fa.v, fb3.v, acc[3], 0, 0, 0);
  }

#pragma unroll
  for (int t = 0; t < 4; t++) {
    const int col = wcol + 32 * t + l31;
#pragma unroll
    for (int r = 0; r < 16; r++) {
      const int row = rowbase + wrow + (r & 3) + 8 * (r >> 2) + 4 * lhi;
      if (row < N) numb[(size_t)row * H + col] = f2bf(acc[t][r]);
    }
  }
}

// slim fused: den, gcn gather (bf16 rows x per-edge weight, 16-deep), attn from
// numb, residual blend, layernorm, write bf16 Rnext, readout. No LDS.
__global__ __launch_bounds__(256) void k_C(
    const ushort* __restrict__ Rb, ushort* __restrict__ Rnext,
    const ushort* __restrict__ numb, const int2* __restrict__ eb,
    const float* __restrict__ cvec, const float* __restrict__ dvec,
    const float* __restrict__ vsum, const float* __restrict__ scal,
    const int* __restrict__ offs16, const int* __restrict__ deg,
    const float* __restrict__ alphap, const float* __restrict__ gamma,
    const float* __restrict__ beta, const float* __restrict__ Wr,
    const float* __restrict__ br, const float* __restrict__ wgt,
    float* __restrict__ out, int N, int layer, int last) {
  const int tid = threadIdx.x, lane = tid & 63, wv = tid >> 6;
  const int d0 = lane * 4;
  const int n0 = blockIdx.x * 32 + wv * 8;

  const float invn = scal[2], denc = scal[3];
  const float al = alphap[0], om = 1.0f - al;
  const float4 dv = *(const float4*)&dvec[d0];
  const float4 cv = *(const float4*)&cvec[d0];
  const float4 vs = *(const float4*)&vsum[d0];
  const float4 gm = *(const float4*)&gamma[d0];
  const float4 bt = *(const float4*)&beta[d0];
  const float4 wr = *(const float4*)&Wr[layer * H + d0];
  const float wl = wgt[layer], bl = br[layer];

  for (int r = 0; r < 8; r++) {
    const int n = n0 + r;
    if (n >= N) break;  // uniform across the wave
    const ushort4 ro = *(const ushort4*)&Rb[(size_t)n * H + d0];
    const ushort4 no = *(const ushort4*)&numb[(size_t)n * H + d0];
    const float old0 = bf2f(ro.x), old1 = bf2f(ro.y), old2 = bf2f(ro.z), old3 = bf2f(ro.w);

    float p = old0 * dv.x + old1 * dv.y + old2 * dv.z + old3 * dv.w;
    p = wave_sum(p);
    const float rden = 1.0f / ((p + denc) * invn + (float)N);

    float a0 = 0.0f, a1 = 0.0f, a2 = 0.0f, a3 = 0.0f;
    const int st = offs16[n];
    const int nb = (deg[n] + 15) >> 4;
    const int4* pe = (const int4*)(eb + st);
    for (int b = 0; b < nb; b++, pe += 8) {
      int4 q[8];
#pragma unroll
      for (int i = 0; i < 8; i++) q[i] = pe[i];
      ushort4 g[16];
      float w[16];
#pragma unroll
      for (int i = 0; i < 8; i++) {
        g[2 * i] = *(const ushort4*)&Rb[((size_t)q[i].x << 8) + d0];
        w[2 * i] = __int_as_float(q[i].y);
        g[2 * i + 1] = *(const ushort4*)&Rb[((size_t)q[i].z << 8) + d0];
        w[2 * i + 1] = __int_as_float(q[i].w);
      }
#pragma unroll
      for (int i = 0; i < 16; i++) {
        a0 = fmaf(w[i], bf2f(g[i].x), a0);
        a1 = fmaf(w[i], bf2f(g[i].y), a1);
        a2 = fmaf(w[i], bf2f(g[i].z), a2);
        a3 = fmaf(w[i], bf2f(g[i].w), a3);
      }
    }

    float hv0 = al * (((bf2f(no.x) + cv.x) * invn + vs.x) * rden + a0) + om * old0;
    float hv1 = al * (((bf2f(no.y) + cv.y) * invn + vs.y) * rden + a1) + om * old1;
    float hv2 = al * (((bf2f(no.z) + cv.z) * invn + vs.z) * rden + a2) + om * old2;
    float hv3 = al * (((bf2f(no.w) + cv.w) * invn + vs.w) * rden + a3) + om * old3;

    float s = wave_sum(hv0 + hv1 + hv2 + hv3);
    float mu = s * (1.0f / H);
    float s2 = wave_sum(hv0 * hv0 + hv1 * hv1 + hv2 * hv2 + hv3 * hv3);
    float var = s2 * (1.0f / H) - mu * mu;
    float rs = rsqrtf(var + LN_EPS);
    float y0 = (hv0 - mu) * rs * gm.x + bt.x;
    float y1 = (hv1 - mu) * rs * gm.y + bt.y;
    float y2 = (hv2 - mu) * rs * gm.z + bt.z;
    float y3 = (hv3 - mu) * rs * gm.w + bt.w;
    if (!last) {
      ushort4 o;
      o.x = f2bf(y0); o.y = f2bf(y1); o.z = f2bf(y2); o.w = f2bf(y3);
      *(ushort4*)&Rnext[(size_t)n * H + d0] = o;
    }
    float rp = wave_sum(y0 * wr.x + y1 * wr.y + y2 * wr.z + y3 * wr.w);
    if (lane == 0) out[n] += wl * (rp + bl);
  }
}

// ---------------- host ----------------

extern "C" void kernel_launch(void* const* d_in, const int* in_sizes, int n_in,
                              void* d_out, int out_size, void* d_ws, size_t ws_size,
                              hipStream_t stream) {
  const float* x = (const float*)d_in[0];
  const int* ei = (const int*)d_in[1];
  const float* W1 = (const float*)d_in[2];
  const float* b1 = (const float*)d_in[3];
  const float* Wq = (const float*)d_in[4];
  const float* bq = (const float*)d_in[5];
  const float* Wk = (const float*)d_in[6];
  const float* bk = (const float*)d_in[7];
  const float* gamma = (const float*)d_in[8];
  const float* beta = (const float*)d_in[9];
  const float* alphap = (const float*)d_in[10];
  const float* Wr = (const float*)d_in[11];
  const float* br = (const float*)d_in[12];
  const float* wgt = (const float*)d_in[13];
  float* out = (float*)d_out;

  const int N = in_sizes[0] / FIN;
  const int E = in_sizes[1] / 2;
  const int* row = ei;
  const int* col = ei + E;

  char* w = (char*)d_ws;
  auto alloc = [&](size_t bytes) -> char* {
    char* p = w;
    w += (bytes + 255) & ~(size_t)255;
    return p;
  };
  const size_t RB = (size_t)(N + 128) * H * sizeof(ushort);
  ushort* Rb0 = (ushort*)alloc(RB);
  ushort* Rb1 = (ushort*)alloc(RB);
  ushort* numb = (ushort*)alloc(RB);
  ushort* Mt = (ushort*)alloc(H * H * sizeof(ushort));
  // zero-region (contiguous): G, vsum, scal
  float* G = (float*)alloc(H * H * sizeof(float));
  float* vsum = (float*)alloc(1024);
  float* scal = (float*)alloc(256);
  const size_t zero_bytes = H * H * sizeof(float) + 1024 + 256;
  float* cvec = (float*)alloc(1024);
  float* dvec = (float*)alloc(1024);
  float* P = (float*)alloc(H * H * sizeof(float));
  float* Q = (float*)alloc(H * H * sizeof(float));
  float* K2 = (float*)alloc(H * H * sizeof(float));
  float* pb = (float*)alloc(1024);
  float* qb = (float*)alloc(1024);
  float* wb = (float*)alloc(1024);
  float* kb = (float*)alloc(1024);
  float* sconst = (float*)alloc(256);
  int* deg = (int*)alloc((size_t)N * 4);
  int* cursor = (int*)alloc((size_t)N * 4);
  float* invs = (float*)alloc((size_t)N * 4);
  int* offs16 = (int*)alloc((size_t)(N + 1) * 4);
  int* bsum = (int*)alloc(1024 * 4);
  size_t EPAD = (size_t)E + 16 * (size_t)N;
  int2* eb = (int2*)alloc(EPAD * sizeof(int2));

  hipMemsetAsync(deg, 0, (size_t)N * 4, stream);
  hipMemsetAsync(cursor, 0, (size_t)N * 4, stream);
  hipMemsetAsync(eb, 0, EPAD * sizeof(int2), stream);

  const int gE = (E + 255) / 256, gN = (N + 255) / 256;
  const int nblk = (N + 1023) / 1024;
  k_deg<<<gE, 256, 0, stream>>>(col, deg, E);
  k_invsqrt<<<gN, 256, 0, stream>>>(deg, invs, N);
  k_scan1<<<nblk, 1024, 0, stream>>>(deg, offs16, bsum, N);
  k_scan2<<<1, 1024, 0, stream>>>(bsum, nblk);
  k_scan3<<<gN, 256, 0, stream>>>(offs16, bsum, N);
  k_scatter<<<gE, 256, 0, stream>>>(row, col, invs, offs16, cursor, eb, E);
  k_prep<<<769, 256, 0, stream>>>(Wq, Wk, bq, bk, P, Q, K2, pb, qb, wb, kb, sconst);
  const int gRows16 = (N + 15) / 16;
  k_fc1<<<gRows16, 256, 0, stream>>>(x, W1, b1, Wr, br, wgt, Rb0, out, N);

  const int nbG = (N + ROWS_PB - 1) / ROWS_PB;
  const int nbN = (N + 127) / 128;
  const int gRows32 = (N + 31) / 32;
  ushort* Rc = Rb0;
  ushort* Rn = Rb1;
  for (int it = 1; it <= 3; ++it) {
    hipMemsetAsync(G, 0, zero_bytes, stream);
    k_Gm<<<nbG, 512, 0, stream>>>(Rc, G, vsum, N);
    k_small<<<290, 256, 0, stream>>>(G, vsum, P, pb, wb, sconst, Q, K2, Mt, cvec, dvec, scal, N);
    k_final<<<1, 256, 0, stream>>>(vsum, qb, kb, wb, sconst, scal, N);
    k_N<<<nbN, 512, 0, stream>>>(Rc, Mt, numb, N);
    k_C<<<gRows32, 256, 0, stream>>>(Rc, Rn, numb, eb, cvec, dvec, vsum, scal, offs16, deg,
                                     alphap, gamma, beta, Wr, br, wgt, out, N, it, (it == 3) ? 1 : 0);
    ushort* t = Rc; Rc = Rn; Rn = t;
  }
}

// Round 7
// 1593.976 us; speedup vs baseline: 3.2399x; 1.1126x over previous
//
#include <hip/hip_runtime.h>

#define H 256
#define FIN 58
#define LN_EPS 1e-5f
#define ROWS_PB 416  // k_Gm rows per block (13 chunks of 32)

typedef __bf16 bf16x8 __attribute__((ext_vector_type(8)));
typedef float f32x16 __attribute__((ext_vector_type(16)));
typedef float f32x2 __attribute__((ext_vector_type(2)));

union FragU {
  ushort u[8];
  bf16x8 v;
};

// ---------------- utilities ----------------

__device__ __forceinline__ float wave_sum(float v) {
#pragma unroll
  for (int off = 1; off < 64; off <<= 1) v += __shfl_xor(v, off, 64);
  return v;
}

__device__ __forceinline__ float block_sum(float v, volatile float* red) {
  const int tid = threadIdx.x;
  v = wave_sum(v);
  __syncthreads();
  if ((tid & 63) == 0) red[tid >> 6] = v;
  __syncthreads();
  return red[0] + red[1] + red[2] + red[3];
}

__device__ __forceinline__ ushort f2bf(float f) {
  unsigned u = __float_as_uint(f);
  unsigned r = (u + 0x7FFFu + ((u >> 16) & 1u)) >> 16;
  return (ushort)r;
}

__device__ __forceinline__ float bf2f(ushort u) {
  return __uint_as_float((unsigned)u << 16);
}

// ---- fp8 e4m3 pack/unpack (HW path on gfx950, manual fallback) ----
#if __has_builtin(__builtin_amdgcn_cvt_pk_fp8_f32) && __has_builtin(__builtin_amdgcn_cvt_pk_f32_fp8)
__device__ __forceinline__ unsigned pack_fp8x4(float a, float b, float c, float d) {
  int v = 0;
  v = __builtin_amdgcn_cvt_pk_fp8_f32(a, b, v, false);
  v = __builtin_amdgcn_cvt_pk_fp8_f32(c, d, v, true);
  return (unsigned)v;
}
__device__ __forceinline__ void unpack_fp8x4_acc(float* acc, unsigned v) {
  f32x2 lo = __builtin_amdgcn_cvt_pk_f32_fp8((int)v, false);
  f32x2 hi = __builtin_amdgcn_cvt_pk_f32_fp8((int)v, true);
  acc[0] += lo[0]; acc[1] += lo[1]; acc[2] += hi[0]; acc[3] += hi[1];
}
#else
__device__ __forceinline__ unsigned char f2e4m3_1(float f) {
  unsigned u = __float_as_uint(f);
  unsigned s = (u >> 31) << 7;
  float a = fabsf(f);
  if (a >= 448.0f) return (unsigned char)(s | 0x7E);
  if (a < 0.0009765625f) return (unsigned char)s;
  int e;
  float m = frexpf(a, &e);  // a = m*2^e, m in [0.5,1)
  int E = e - 1 + 7;
  if (E >= 1) {
    int mm = (int)rintf((m * 2.0f - 1.0f) * 8.0f);
    if (mm == 8) { mm = 0; E++; }
    return (unsigned char)(s | (E << 3) | mm);
  }
  int mm = (int)rintf(a * 512.0f);
  if (mm > 7) return (unsigned char)(s | (1 << 3));
  return (unsigned char)(s | mm);
}
__device__ __forceinline__ unsigned pack_fp8x4(float a, float b, float c, float d) {
  return (unsigned)f2e4m3_1(a) | ((unsigned)f2e4m3_1(b) << 8) |
         ((unsigned)f2e4m3_1(c) << 16) | ((unsigned)f2e4m3_1(d) << 24);
}
__device__ __forceinline__ float e4m3f_1(unsigned v) {
  int s = (v >> 7) & 1, E = (v >> 3) & 15, m = v & 7;
  float mag = E ? ldexpf(1.0f + m * 0.125f, E - 7) : ldexpf((float)m, -9);
  return s ? -mag : mag;
}
__device__ __forceinline__ void unpack_fp8x4_acc(float* acc, unsigned v) {
  acc[0] += e4m3f_1(v & 255);
  acc[1] += e4m3f_1((v >> 8) & 255);
  acc[2] += e4m3f_1((v >> 16) & 255);
  acc[3] += e4m3f_1(v >> 24);
}
#endif

// ---------------- setup kernels ----------------

__global__ void k_deg(const int* __restrict__ col, int* __restrict__ deg, int E) {
  int e = blockIdx.x * 256 + threadIdx.x;
  if (e < E) atomicAdd(&deg[col[e]], 1);
}

__global__ void k_invsqrt(const int* __restrict__ deg, float* __restrict__ invs, int N) {
  int i = blockIdx.x * 256 + threadIdx.x;
  if (i < N) {
    int d = deg[i];
    invs[i] = (d > 0) ? (1.0f / sqrtf((float)d)) : 0.0f;
  }
}

// two-level exclusive scan of padded degree ((deg+15)&~15) -> offs16
__global__ __launch_bounds__(1024) void k_scan1(const int* __restrict__ deg,
                                                int* __restrict__ offs16,
                                                int* __restrict__ bsum, int N) {
  __shared__ int buf[1024];
  const int tid = threadIdx.x;
  const int gid = blockIdx.x * 1024 + tid;
  int v = (gid < N) ? ((deg[gid] + 15) & ~15) : 0;
  buf[tid] = v;
  __syncthreads();
  for (int off = 1; off < 1024; off <<= 1) {
    int x = (tid >= off) ? buf[tid - off] : 0;
    __syncthreads();
    buf[tid] += x;
    __syncthreads();
  }
  if (gid < N) offs16[gid] = buf[tid] - v;
  if (tid == 1023) bsum[blockIdx.x] = buf[1023];
}

__global__ __launch_bounds__(1024) void k_scan2(int* __restrict__ bsum, int nb) {
  __shared__ int buf[1024];
  const int tid = threadIdx.x;
  int v = (tid < nb) ? bsum[tid] : 0;
  buf[tid] = v;
  __syncthreads();
  for (int off = 1; off < 1024; off <<= 1) {
    int x = (tid >= off) ? buf[tid - off] : 0;
    __syncthreads();
    buf[tid] += x;
    __syncthreads();
  }
  if (tid < nb) bsum[tid] = buf[tid] - v;
}

__global__ void k_scan3(int* __restrict__ offs16, const int* __restrict__ bsum, int N) {
  int i = blockIdx.x * 256 + threadIdx.x;
  if (i < N) offs16[i] += bsum[i >> 10];
}

// fill edge buffer with sentinel row index N (points at the zero row of Rf8)
__global__ void k_fill(int* __restrict__ eb, int val, int total4) {
  int4 v = make_int4(val, val, val, val);
  for (int i = blockIdx.x * 256 + threadIdx.x; i < total4; i += gridDim.x * 256)
    ((int4*)eb)[i] = v;
}

// scatter edges into padded CSR of src indices
__global__ void k_scatter(const int* __restrict__ row, const int* __restrict__ col,
                          const int* __restrict__ offs16, int* __restrict__ cursor,
                          int* __restrict__ eb, int E) {
  int e = blockIdx.x * 256 + threadIdx.x;
  if (e < E) {
    int c = col[e];
    int pos = offs16[c] + atomicAdd(&cursor[c], 1);
    eb[pos] = row[e];
  }
}

// bf16 R -> fp8 e4m3 copy scaled by invs[row] (gather source); 8 elems/thread
__global__ void k_tofp8(const ushort* __restrict__ Rb, const float* __restrict__ invs,
                        unsigned* __restrict__ Rf8, int total8) {
  for (int i = blockIdx.x * 256 + threadIdx.x; i < total8; i += gridDim.x * 256) {
    float s = invs[i >> 5];
    int4 v = ((const int4*)Rb)[i];
    const ushort* pu = (const ushort*)&v;
    unsigned lo = pack_fp8x4(bf2f(pu[0]) * s, bf2f(pu[1]) * s, bf2f(pu[2]) * s, bf2f(pu[3]) * s);
    unsigned hi = pack_fp8x4(bf2f(pu[4]) * s, bf2f(pu[5]) * s, bf2f(pu[6]) * s, bf2f(pu[7]) * s);
    ((uint2*)Rf8)[i] = make_uint2(lo, hi);
  }
}

// iteration-independent weight products
__global__ void k_prep(const float* __restrict__ Wq, const float* __restrict__ Wk,
                       const float* __restrict__ bq, const float* __restrict__ bk,
                       float* __restrict__ P, float* __restrict__ Q, float* __restrict__ K2,
                       float* __restrict__ pb, float* __restrict__ qb,
                       float* __restrict__ wb, float* __restrict__ kb,
                       float* __restrict__ sconst) {
  __shared__ float red[4];
  const int b = blockIdx.x, tid = threadIdx.x;
  if (b < 768) {
    const int f = b & 255, which = b >> 8;
    const float* A = (which == 2) ? Wk : Wq;
    const float* Bm = (which == 1) ? Wq : Wk;
    float acc = 0.0f;
    for (int m = 0; m < H; m++) acc = fmaf(A[f * H + m], Bm[tid * H + m], acc);
    float* D = (which == 0) ? P : ((which == 1) ? Q : K2);
    D[f * H + tid] = acc;
  } else {
    float a1 = 0, a2 = 0, a3 = 0, a4 = 0;
    for (int m = 0; m < H; m++) {
      float wqv = Wq[tid * H + m], wkv = Wk[tid * H + m];
      a1 = fmaf(wqv, bk[m], a1);
      a2 = fmaf(wqv, bq[m], a2);
      a3 = fmaf(wkv, bq[m], a3);
      a4 = fmaf(wkv, bk[m], a4);
    }
    pb[tid] = a1; qb[tid] = a2; wb[tid] = a3; kb[tid] = a4;
    float c0 = block_sum(bq[tid] * bk[tid], red);
    float c1 = block_sum(bq[tid] * bq[tid], red);
    float c2 = block_sum(bk[tid] * bk[tid], red);
    if (tid == 0) { sconst[0] = c0; sconst[1] = c1; sconst[2] = c2; }
  }
}

// R0 = relu(x@W1 + b1) -> bf16, plus layer-0 readout
__global__ void k_fc1(const float* __restrict__ x, const float* __restrict__ W1,
                      const float* __restrict__ b1, const float* __restrict__ Wr,
                      const float* __restrict__ br, const float* __restrict__ wgt,
                      ushort* __restrict__ R0, float* __restrict__ out, int N) {
  __shared__ __align__(16) float lx[16 * FIN];
  __shared__ float red2[4][16];
  const int tid = threadIdx.x;
  const int n0 = blockIdx.x * 16;
  for (int idx = tid; idx < 16 * FIN / 4; idx += 256)
    ((float4*)lx)[idx] = ((const float4*)(x + (size_t)n0 * FIN))[idx];
  __syncthreads();
  float acc[16];
  const float bias = b1[tid];
#pragma unroll
  for (int r = 0; r < 16; r++) acc[r] = bias;
  for (int f = 0; f < FIN; f++) {
    float wv = W1[f * H + tid];
#pragma unroll
    for (int r = 0; r < 16; r++) acc[r] = fmaf(lx[r * FIN + f], wv, acc[r]);
  }
  const float wr0 = Wr[tid];
#pragma unroll
  for (int r = 0; r < 16; r++) {
    acc[r] = fmaxf(acc[r], 0.0f);
    int n = n0 + r;
    if (n < N) R0[(size_t)n * H + tid] = f2bf(acc[r]);
  }
#pragma unroll
  for (int r = 0; r < 16; r++) {
    float s = wave_sum(acc[r] * wr0);
    if ((tid & 63) == 0) red2[tid >> 6][r] = s;
  }
  __syncthreads();
  if (tid < 16) {
    int n = n0 + tid;
    if (n < N)
      out[n] = wgt[0] * (red2[0][tid] + red2[1][tid] + red2[2][tid] + red2[3][tid] + br[0]);
  }
}

// ---------------- MFMA G = R^T R (+ vsum), bf16 input ----------------
__global__ __launch_bounds__(512, 2) void k_Gm(const ushort* __restrict__ Rb,
                                               float* __restrict__ G,
                                               float* __restrict__ vsum, int N) {
  __shared__ ushort sb[2][32 * 256];  // 32 KB
  const int tid = threadIdx.x;
  const int lane = tid & 63;
  const int wid = tid >> 6;
  const int wrow = (wid & 1) * 128;
  const int wcol = (wid >> 1) * 64;
  const int l31 = lane & 31;
  const int lhi = lane >> 5;

  const int rowbase = blockIdx.x * ROWS_PB;
  const int nrows = min(ROWS_PB, N - rowbase);
  const int nch = (nrows + 31) >> 5;

  const int sk = tid >> 4;        // staging row 0..31
  const int c0 = (tid & 15) * 16; // 16 contiguous bf16 per thread

  f32x16 acc[4][2];
#pragma unroll
  for (int s = 0; s < 4; s++)
#pragma unroll
    for (int t = 0; t < 2; t++)
#pragma unroll
      for (int e = 0; e < 16; e++) acc[s][t][e] = 0.0f;

  float csum[16];
#pragma unroll
  for (int i = 0; i < 16; i++) csum[i] = 0.0f;

  int4 ld[2];

  auto load_chunk = [&](int ch) {
    int g = rowbase + ch * 32 + sk;
    const int4* src = (const int4*)(Rb + (size_t)g * H + c0);
    ld[0] = (g < N) ? src[0] : make_int4(0, 0, 0, 0);
    ld[1] = (g < N) ? src[1] : make_int4(0, 0, 0, 0);
  };

  auto write_chunk = [&](int buf) {
    const int swz = (sk & 3) << 4;
#pragma unroll
    for (int i = 0; i < 2; i++) {
      *(int4*)&sb[buf][sk * 256 + ((c0 + 8 * i) ^ swz)] = ld[i];
      const ushort* pu = (const ushort*)&ld[i];
#pragma unroll
      for (int j = 0; j < 8; j++) csum[8 * i + j] += bf2f(pu[j]);
    }
  };

  auto compute = [&](int buf) {
#pragma unroll
    for (int ks = 0; ks < 2; ks++) {
      const int kb = ks * 16 + lhi * 8;
      FragU fr[6];
#pragma unroll
      for (int s = 0; s < 6; s++) {
        const int cbase = (s < 4) ? (wrow + 32 * s + l31) : (wcol + 32 * (s - 4) + l31);
#pragma unroll
        for (int j = 0; j < 8; j++)
          fr[s].u[j] = sb[buf][(kb + j) * 256 + (cbase ^ ((j & 3) << 4))];
      }
#pragma unroll
      for (int s = 0; s < 4; s++)
#pragma unroll
        for (int t = 0; t < 2; t++)
          acc[s][t] = __builtin_amdgcn_mfma_f32_32x32x16_bf16(fr[s].v, fr[4 + t].v,
                                                              acc[s][t], 0, 0, 0);
    }
  };

  load_chunk(0);
  write_chunk(0);
  __syncthreads();
  int cur = 0;
  for (int c = 0; c < nch; c++) {
    if (c + 1 < nch) load_chunk(c + 1);
    compute(cur);
    if (c + 1 < nch) write_chunk(cur ^ 1);
    __syncthreads();
    cur ^= 1;
  }

#pragma unroll
  for (int s = 0; s < 4; s++)
#pragma unroll
    for (int t = 0; t < 2; t++) {
      const int n0 = wcol + 32 * t + l31;
#pragma unroll
      for (int r = 0; r < 16; r++) {
        const int row = wrow + 32 * s + (r & 3) + 8 * (r >> 2) + 4 * lhi;
        atomicAdd(&G[row * 256 + n0], acc[s][t][r]);
      }
    }

  float* fl = (float*)sb;
#pragma unroll
  for (int j = 0; j < 16; j++) fl[sk * 256 + c0 + j] = csum[j];
  __syncthreads();
  if (tid < 256) {
    float s = 0.0f;
    for (int r = 0; r < 32; r++) s += fl[r * 256 + tid];
    atomicAdd(&vsum[tid], s);
  }
}

// per-iteration small products from (G, vsum); writes transposed bf16 Mt[n][k]
__global__ void k_small(const float* __restrict__ G, const float* __restrict__ vsum,
                        const float* __restrict__ P, const float* __restrict__ pb,
                        const float* __restrict__ wb, const float* __restrict__ sconst,
                        const float* __restrict__ Q, const float* __restrict__ K2,
                        ushort* __restrict__ Mt, float* __restrict__ cvec,
                        float* __restrict__ dvec, float* __restrict__ scal, int N) {
  __shared__ float red[4];
  const int b = blockIdx.x, tid = threadIdx.x;
  if (b < 256) {  // M[b][n] for n=tid -> Mt[n][b]
    float acc = 0.0f;
    for (int m = 0; m < H; m++) acc = fmaf(P[b * H + m], G[m * H + tid], acc);
    Mt[(size_t)tid * H + b] = f2bf(acc + pb[b] * vsum[tid]);
  } else if (b == 256) {
    float acc = 0.0f;
    for (int f = 0; f < H; f++) acc = fmaf(wb[f], G[f * H + tid], acc);
    cvec[tid] = acc + sconst[0] * vsum[tid];
  } else if (b == 257) {
    float acc = 0.0f;
    for (int m = 0; m < H; m++) acc = fmaf(P[tid * H + m], vsum[m], acc);
    dvec[tid] = acc + (float)N * pb[tid];
  } else if (b < 274) {
    int base = (b - 258) * 4096 + tid;
    float a = 0.0f;
    for (int j = 0; j < 16; j++) a = fmaf(G[base + j * 256], Q[base + j * 256], a);
    a = block_sum(a, red);
    if (tid == 0) atomicAdd(&scal[0], a);
  } else {
    int base = (b - 274) * 4096 + tid;
    float a = 0.0f;
    for (int j = 0; j < 16; j++) a = fmaf(G[base + j * 256], K2[base + j * 256], a);
    a = block_sum(a, red);
    if (tid == 0) atomicAdd(&scal[1], a);
  }
}

// finalize norms
__global__ void k_final(const float* __restrict__ vsum, const float* __restrict__ qb,
                        const float* __restrict__ kb, const float* __restrict__ wb,
                        const float* __restrict__ sconst, float* __restrict__ scal, int N) {
  __shared__ float red[4];
  const int tid = threadIdx.x;
  float s1 = block_sum(qb[tid] * vsum[tid], red);
  float s2 = block_sum(kb[tid] * vsum[tid], red);
  float s3 = block_sum(wb[tid] * vsum[tid], red);
  if (tid == 0) {
    float sq = scal[0] + 2.0f * s1 + (float)N * sconst[1];
    float sk = scal[1] + 2.0f * s2 + (float)N * sconst[2];
    scal[2] = 1.0f / (sqrtf(sq) * sqrtf(sk));
    scal[3] = s3 + (float)N * sconst[0];
  }
}

// ---------------- MFMA num = R * M (bf16 in, bf16 out) ----------------
__global__ __launch_bounds__(512) void k_N(const ushort* __restrict__ Rb,
                                           const ushort* __restrict__ Mt,
                                           ushort* __restrict__ numb, int N) {
  const int tid = threadIdx.x;
  const int lane = tid & 63;
  const int wid = tid >> 6;
  const int l31 = lane & 31;
  const int lhi = lane >> 5;
  const int wrow = (wid & 3) * 32;
  const int wcol = (wid >> 2) * 128;
  const int rowbase = blockIdx.x * 128;

  f32x16 acc[4];
#pragma unroll
  for (int t = 0; t < 4; t++)
#pragma unroll
    for (int e = 0; e < 16; e++) acc[t][e] = 0.0f;

  const ushort* aptr = Rb + (size_t)(rowbase + wrow + l31) * H;

  for (int kc = 0; kc < 16; kc++) {
    const int kb = kc * 16 + lhi * 8;
    FragU fa;
    *(int4*)fa.u = *(const int4*)(aptr + kb);
    FragU fb0, fb1, fb2, fb3;
    *(int4*)fb0.u = *(const int4*)(Mt + (size_t)(wcol + 0 + l31) * H + kb);
    *(int4*)fb1.u = *(const int4*)(Mt + (size_t)(wcol + 32 + l31) * H + kb);
    *(int4*)fb2.u = *(const int4*)(Mt + (size_t)(wcol + 64 + l31) * H + kb);
    *(int4*)fb3.u = *(const int4*)(Mt + (size_t)(wcol + 96 + l31) * H + kb);
    acc[0] = __builtin_amdgcn_mfma_f32_32x32x16_bf16(fa.v, fb0.v, acc[0], 0, 0, 0);
    acc[1] = __builtin_amdgcn_mfma_f32_32x32x16_bf16(fa.v, fb1.v, acc[1], 0, 0, 0);
    acc[2] = __builtin_amdgcn_mfma_f32_32x32x16_bf16(fa.v, fb2.v, acc[2], 0, 0, 0);
    acc[3] = __builtin_amdgcn_mfma_f32_32x32x16_bf16(fa.v, fb3.v, acc[3], 0, 0, 0);
  }

#pragma unroll
  for (int t = 0; t < 4; t++) {
    const int col = wcol + 32 * t + l31;
#pragma unroll
    for (int r = 0; r < 16; r++) {
      const int row = rowbase + wrow + (r & 3) + 8 * (r >> 2) + 4 * lhi;
      if (row < N) numb[(size_t)row * H + col] = f2bf(acc[t][r]);
    }
  }
}

// slim fused: den, gcn gather (pre-scaled fp8 rows, 16-deep), attn from numb,
// residual blend, layernorm, write bf16 Rnext, readout. No LDS.
__global__ __launch_bounds__(256) void k_C(
    const ushort* __restrict__ Rb, ushort* __restrict__ Rnext,
    const ushort* __restrict__ numb, const unsigned* __restrict__ Rf8,
    const int* __restrict__ eb, const float* __restrict__ invs,
    const float* __restrict__ cvec, const float* __restrict__ dvec,
    const float* __restrict__ vsum, const float* __restrict__ scal,
    const int* __restrict__ offs16, const int* __restrict__ deg,
    const float* __restrict__ alphap, const float* __restrict__ gamma,
    const float* __restrict__ beta, const float* __restrict__ Wr,
    const float* __restrict__ br, const float* __restrict__ wgt,
    float* __restrict__ out, int N, int layer, int last) {
  const int tid = threadIdx.x, lane = tid & 63, wv = tid >> 6;
  const int d0 = lane * 4;
  const int n0 = blockIdx.x * 32 + wv * 8;

  const float invn = scal[2], denc = scal[3];
  const float al = alphap[0], om = 1.0f - al;
  const float4 dv = *(const float4*)&dvec[d0];
  const float4 cv = *(const float4*)&cvec[d0];
  const float4 vs = *(const float4*)&vsum[d0];
  const float4 gm = *(const float4*)&gamma[d0];
  const float4 bt = *(const float4*)&beta[d0];
  const float4 wr = *(const float4*)&Wr[layer * H + d0];
  const float wl = wgt[layer], bl = br[layer];

  for (int r = 0; r < 8; r++) {
    const int n = n0 + r;
    if (n >= N) break;  // uniform across the wave
    const ushort4 ro = *(const ushort4*)&Rb[(size_t)n * H + d0];
    const ushort4 no = *(const ushort4*)&numb[(size_t)n * H + d0];
    const float old0 = bf2f(ro.x), old1 = bf2f(ro.y), old2 = bf2f(ro.z), old3 = bf2f(ro.w);

    float p = old0 * dv.x + old1 * dv.y + old2 * dv.z + old3 * dv.w;
    p = wave_sum(p);
    const float rden = 1.0f / ((p + denc) * invn + (float)N);

    float a[4] = {0.0f, 0.0f, 0.0f, 0.0f};
    const int st = offs16[n];
    const int nb = (deg[n] + 15) >> 4;
    const int4* pe = (const int4*)(eb + st);
    for (int b = 0; b < nb; b++, pe += 4) {
      int4 q0 = pe[0], q1 = pe[1], q2 = pe[2], q3 = pe[3];
      unsigned g[16];
      g[0] = Rf8[((size_t)q0.x << 6) + lane];
      g[1] = Rf8[((size_t)q0.y << 6) + lane];
      g[2] = Rf8[((size_t)q0.z << 6) + lane];
      g[3] = Rf8[((size_t)q0.w << 6) + lane];
      g[4] = Rf8[((size_t)q1.x << 6) + lane];
      g[5] = Rf8[((size_t)q1.y << 6) + lane];
      g[6] = Rf8[((size_t)q1.z << 6) + lane];
      g[7] = Rf8[((size_t)q1.w << 6) + lane];
      g[8] = Rf8[((size_t)q2.x << 6) + lane];
      g[9] = Rf8[((size_t)q2.y << 6) + lane];
      g[10] = Rf8[((size_t)q2.z << 6) + lane];
      g[11] = Rf8[((size_t)q2.w << 6) + lane];
      g[12] = Rf8[((size_t)q3.x << 6) + lane];
      g[13] = Rf8[((size_t)q3.y << 6) + lane];
      g[14] = Rf8[((size_t)q3.z << 6) + lane];
      g[15] = Rf8[((size_t)q3.w << 6) + lane];
#pragma unroll
      for (int i = 0; i < 16; i++) unpack_fp8x4_acc(a, g[i]);
    }
    const float sn = invs[n];

    float hv0 = al * (((bf2f(no.x) + cv.x) * invn + vs.x) * rden + a[0] * sn) + om * old0;
    float hv1 = al * (((bf2f(no.y) + cv.y) * invn + vs.y) * rden + a[1] * sn) + om * old1;
    float hv2 = al * (((bf2f(no.z) + cv.z) * invn + vs.z) * rden + a[2] * sn) + om * old2;
    float hv3 = al * (((bf2f(no.w) + cv.w) * invn + vs.w) * rden + a[3] * sn) + om * old3;

    float s = wave_sum(hv0 + hv1 + hv2 + hv3);
    float mu = s * (1.0f / H);
    float s2 = wave_sum(hv0 * hv0 + hv1 * hv1 + hv2 * hv2 + hv3 * hv3);
    float var = s2 * (1.0f / H) - mu * mu;
    float rs = rsqrtf(var + LN_EPS);
    float y0 = (hv0 - mu) * rs * gm.x + bt.x;
    float y1 = (hv1 - mu) * rs * gm.y + bt.y;
    float y2 = (hv2 - mu) * rs * gm.z + bt.z;
    float y3 = (hv3 - mu) * rs * gm.w + bt.w;
    if (!last) {
      ushort4 o;
      o.x = f2bf(y0); o.y = f2bf(y1); o.z = f2bf(y2); o.w = f2bf(y3);
      *(ushort4*)&Rnext[(size_t)n * H + d0] = o;
    }
    float rp = wave_sum(y0 * wr.x + y1 * wr.y + y2 * wr.z + y3 * wr.w);
    if (lane == 0) out[n] += wl * (rp + bl);
  }
}

// ---------------- host ----------------

extern "C" void kernel_launch(void* const* d_in, const int* in_sizes, int n_in,
                              void* d_out, int out_size, void* d_ws, size_t ws_size,
                              hipStream_t stream) {
  const float* x = (const float*)d_in[0];
  const int* ei = (const int*)d_in[1];
  const float* W1 = (const float*)d_in[2];
  const float* b1 = (const float*)d_in[3];
  const float* Wq = (const float*)d_in[4];
  const float* bq = (const float*)d_in[5];
  const float* Wk = (const float*)d_in[6];
  const float* bk = (const float*)d_in[7];
  const float* gamma = (const float*)d_in[8];
  const float* beta = (const float*)d_in[9];
  const float* alphap = (const float*)d_in[10];
  const float* Wr = (const float*)d_in[11];
  const float* br = (const float*)d_in[12];
  const float* wgt = (const float*)d_in[13];
  float* out = (float*)d_out;

  const int N = in_sizes[0] / FIN;
  const int E = in_sizes[1] / 2;
  const int* row = ei;
  const int* col = ei + E;

  char* w = (char*)d_ws;
  auto alloc = [&](size_t bytes) -> char* {
    char* p = w;
    w += (bytes + 255) & ~(size_t)255;
    return p;
  };
  const size_t RB = (size_t)(N + 128) * H * sizeof(ushort);
  ushort* Rb0 = (ushort*)alloc(RB);
  ushort* Rb1 = (ushort*)alloc(RB);
  ushort* numb = (ushort*)alloc(RB);
  unsigned* Rf8 = (unsigned*)alloc((size_t)(N + 1) * 64 * sizeof(unsigned));  // +1 zero row
  ushort* Mt = (ushort*)alloc(H * H * sizeof(ushort));
  // zero-region (contiguous): G, vsum, scal
  float* G = (float*)alloc(H * H * sizeof(float));
  float* vsum = (float*)alloc(1024);
  float* scal = (float*)alloc(256);
  const size_t zero_bytes = H * H * sizeof(float) + 1024 + 256;
  float* cvec = (float*)alloc(1024);
  float* dvec = (float*)alloc(1024);
  float* P = (float*)alloc(H * H * sizeof(float));
  float* Q = (float*)alloc(H * H * sizeof(float));
  float* K2 = (float*)alloc(H * H * sizeof(float));
  float* pb = (float*)alloc(1024);
  float* qb = (float*)alloc(1024);
  float* wb = (float*)alloc(1024);
  float* kb = (float*)alloc(1024);
  float* sconst = (float*)alloc(256);
  int* deg = (int*)alloc((size_t)N * 4);
  int* cursor = (int*)alloc((size_t)N * 4);
  float* invs = (float*)alloc((size_t)N * 4);
  int* offs16 = (int*)alloc((size_t)(N + 1) * 4);
  int* bsum = (int*)alloc(1024 * 4);
  size_t EPAD = (size_t)E + 16 * (size_t)N;
  EPAD = (EPAD + 3) & ~(size_t)3;
  int* eb = (int*)alloc(EPAD * sizeof(int));

  hipMemsetAsync(deg, 0, (size_t)N * 4, stream);
  hipMemsetAsync(cursor, 0, (size_t)N * 4, stream);
  hipMemsetAsync(Rf8 + (size_t)N * 64, 0, 64 * sizeof(unsigned), stream);

  const int gE = (E + 255) / 256, gN = (N + 255) / 256;
  const int nblk = (N + 1023) / 1024;
  k_deg<<<gE, 256, 0, stream>>>(col, deg, E);
  k_invsqrt<<<gN, 256, 0, stream>>>(deg, invs, N);
  k_scan1<<<nblk, 1024, 0, stream>>>(deg, offs16, bsum, N);
  k_scan2<<<1, 1024, 0, stream>>>(bsum, nblk);
  k_scan3<<<gN, 256, 0, stream>>>(offs16, bsum, N);
  k_fill<<<2048, 256, 0, stream>>>(eb, N, (int)(EPAD / 4));
  k_scatter<<<gE, 256, 0, stream>>>(row, col, offs16, cursor, eb, E);
  k_prep<<<769, 256, 0, stream>>>(Wq, Wk, bq, bk, P, Q, K2, pb, qb, wb, kb, sconst);
  const int gRows16 = (N + 15) / 16;
  k_fc1<<<gRows16, 256, 0, stream>>>(x, W1, b1, Wr, br, wgt, Rb0, out, N);

  const int nbG = (N + ROWS_PB - 1) / ROWS_PB;
  const int nbN = (N + 127) / 128;
  const int gRows32 = (N + 31) / 32;
  const int total8 = N * (H / 8);
  ushort* Rc = Rb0;
  ushort* Rn = Rb1;
  for (int it = 1; it <= 3; ++it) {
    hipMemsetAsync(G, 0, zero_bytes, stream);
    k_Gm<<<nbG, 512, 0, stream>>>(Rc, G, vsum, N);
    k_small<<<290, 256, 0, stream>>>(G, vsum, P, pb, wb, sconst, Q, K2, Mt, cvec, dvec, scal, N);
    k_final<<<1, 256, 0, stream>>>(vsum, qb, kb, wb, sconst, scal, N);
    k_tofp8<<<2048, 256, 0, stream>>>(Rc, invs, Rf8, total8);
    k_N<<<nbN, 512, 0, stream>>>(Rc, Mt, numb, N);
    k_C<<<gRows32, 256, 0, stream>>>(Rc, Rn, numb, Rf8, eb, invs, cvec, dvec, vsum, scal,
                                     offs16, deg, alphap, gamma, beta, Wr, br, wgt, out,
                                     N, it, (it == 3) ? 1 : 0);
    ushort* t = Rc; Rc = Rn; Rn = t;
  }
}

// Round 8
// 1330.874 us; speedup vs baseline: 3.8804x; 1.1977x over previous
//
#include <hip/hip_runtime.h>

#define H 256
#define FIN 58
#define LN_EPS 1e-5f
#define ROWS_PB 544  // k_Gm rows per block (17 chunks of 32)
#define BCAP 8192    // bucket capacity (mean 4096 for E/N=32, 64-sigma headroom)

typedef __bf16 bf16x8 __attribute__((ext_vector_type(8)));
typedef float f32x16 __attribute__((ext_vector_type(16)));
typedef float f32x2 __attribute__((ext_vector_type(2)));

union FragU {
  ushort u[8];
  bf16x8 v;
};

// ---------------- utilities ----------------

__device__ __forceinline__ float wave_sum(float v) {
#pragma unroll
  for (int off = 1; off < 64; off <<= 1) v += __shfl_xor(v, off, 64);
  return v;
}

__device__ __forceinline__ float block_sum(float v, volatile float* red) {
  const int tid = threadIdx.x;
  v = wave_sum(v);
  __syncthreads();
  if ((tid & 63) == 0) red[tid >> 6] = v;
  __syncthreads();
  return red[0] + red[1] + red[2] + red[3];
}

__device__ __forceinline__ ushort f2bf(float f) {
  unsigned u = __float_as_uint(f);
  unsigned r = (u + 0x7FFFu + ((u >> 16) & 1u)) >> 16;
  return (ushort)r;
}

__device__ __forceinline__ float bf2f(ushort u) {
  return __uint_as_float((unsigned)u << 16);
}

// ---- fp8 e4m3 pack/unpack (HW path on gfx950, manual fallback) ----
#if __has_builtin(__builtin_amdgcn_cvt_pk_fp8_f32) && __has_builtin(__builtin_amdgcn_cvt_pk_f32_fp8)
__device__ __forceinline__ unsigned pack_fp8x4(float a, float b, float c, float d) {
  int v = 0;
  v = __builtin_amdgcn_cvt_pk_fp8_f32(a, b, v, false);
  v = __builtin_amdgcn_cvt_pk_fp8_f32(c, d, v, true);
  return (unsigned)v;
}
__device__ __forceinline__ void unpack_fp8x4_acc(float* acc, unsigned v) {
  f32x2 lo = __builtin_amdgcn_cvt_pk_f32_fp8((int)v, false);
  f32x2 hi = __builtin_amdgcn_cvt_pk_f32_fp8((int)v, true);
  acc[0] += lo[0]; acc[1] += lo[1]; acc[2] += hi[0]; acc[3] += hi[1];
}
#else
__device__ __forceinline__ unsigned char f2e4m3_1(float f) {
  unsigned u = __float_as_uint(f);
  unsigned s = (u >> 31) << 7;
  float a = fabsf(f);
  if (a >= 448.0f) return (unsigned char)(s | 0x7E);
  if (a < 0.0009765625f) return (unsigned char)s;
  int e;
  float m = frexpf(a, &e);
  int E = e - 1 + 7;
  if (E >= 1) {
    int mm = (int)rintf((m * 2.0f - 1.0f) * 8.0f);
    if (mm == 8) { mm = 0; E++; }
    return (unsigned char)(s | (E << 3) | mm);
  }
  int mm = (int)rintf(a * 512.0f);
  if (mm > 7) return (unsigned char)(s | (1 << 3));
  return (unsigned char)(s | mm);
}
__device__ __forceinline__ unsigned pack_fp8x4(float a, float b, float c, float d) {
  return (unsigned)f2e4m3_1(a) | ((unsigned)f2e4m3_1(b) << 8) |
         ((unsigned)f2e4m3_1(c) << 16) | ((unsigned)f2e4m3_1(d) << 24);
}
__device__ __forceinline__ float e4m3f_1(unsigned v) {
  int s = (v >> 7) & 1, E = (v >> 3) & 15, m = v & 7;
  float mag = E ? ldexpf(1.0f + m * 0.125f, E - 7) : ldexpf((float)m, -9);
  return s ? -mag : mag;
}
__device__ __forceinline__ void unpack_fp8x4_acc(float* acc, unsigned v) {
  acc[0] += e4m3f_1(v & 255);
  acc[1] += e4m3f_1((v >> 8) & 255);
  acc[2] += e4m3f_1((v >> 16) & 255);
  acc[3] += e4m3f_1(v >> 24);
}
#endif

// ---------------- setup: bucketed CSR build ----------------

// phase A: scatter {row,col} into coarse buckets of 128 destinations
__global__ void k_bucket(const int* __restrict__ row, const int* __restrict__ col,
                         int2* __restrict__ bbuf, int* __restrict__ bcnt, int E) {
  int e = blockIdx.x * 256 + threadIdx.x;
  if (e < E) {
    int c = col[e];
    int b = c >> 7;
    int pos = atomicAdd(&bcnt[b * 16], 1);  // counters padded to 64B lines
    if (pos < BCAP) bbuf[(size_t)b * BCAP + pos] = make_int2(row[e], c);
  }
}

// per-bucket degree count via LDS (replaces global atomic k_deg)
__global__ void k_degB(const int2* __restrict__ bbuf, const int* __restrict__ bcnt,
                       int* __restrict__ deg, int N) {
  __shared__ int lcnt[128];
  const int b = blockIdx.x, tid = threadIdx.x, base = b << 7;
  if (tid < 128) lcnt[tid] = 0;
  __syncthreads();
  const int cnt = min(bcnt[b * 16], BCAP);
  const int2* bp = bbuf + (size_t)b * BCAP;
  for (int i = tid; i < cnt; i += 256) atomicAdd(&lcnt[bp[i].y - base], 1);
  __syncthreads();
  if (tid < 128) {
    int d = base + tid;
    if (d < N) deg[d] = lcnt[tid];
  }
}

// phase B: place edges into final CSR (bucket window is contiguous in eb),
// then write sentinel (row N -> zero fp8 row) into the padding slots
__global__ void k_place(const int2* __restrict__ bbuf, const int* __restrict__ bcnt,
                        const int* __restrict__ offs16, int* __restrict__ eb, int N) {
  __shared__ int lcnt[128];
  const int b = blockIdx.x, tid = threadIdx.x, base = b << 7;
  if (tid < 128) lcnt[tid] = 0;
  __syncthreads();
  const int cnt = min(bcnt[b * 16], BCAP);
  const int2* bp = bbuf + (size_t)b * BCAP;
  for (int i = tid; i < cnt; i += 256) {
    int2 e = bp[i];
    int slot = atomicAdd(&lcnt[e.y - base], 1);
    eb[offs16[e.y] + slot] = e.x;
  }
  __syncthreads();
  if (tid < 128) {
    int d = base + tid;
    if (d < N) {
      int c = lcnt[tid];
      int pad = (c + 15) & ~15;
      int o = offs16[d];
      for (int j = c; j < pad; j++) eb[o + j] = N;
    }
  }
}

__global__ void k_invsqrt(const int* __restrict__ deg, float* __restrict__ invs, int N) {
  int i = blockIdx.x * 256 + threadIdx.x;
  if (i < N) {
    int d = deg[i];
    invs[i] = (d > 0) ? (1.0f / sqrtf((float)d)) : 0.0f;
  }
}

// two-level exclusive scan of padded degree ((deg+15)&~15) -> offs16
__global__ __launch_bounds__(1024) void k_scan1(const int* __restrict__ deg,
                                                int* __restrict__ offs16,
                                                int* __restrict__ bsum, int N) {
  __shared__ int buf[1024];
  const int tid = threadIdx.x;
  const int gid = blockIdx.x * 1024 + tid;
  int v = (gid < N) ? ((deg[gid] + 15) & ~15) : 0;
  buf[tid] = v;
  __syncthreads();
  for (int off = 1; off < 1024; off <<= 1) {
    int x = (tid >= off) ? buf[tid - off] : 0;
    __syncthreads();
    buf[tid] += x;
    __syncthreads();
  }
  if (gid < N) offs16[gid] = buf[tid] - v;
  if (tid == 1023) bsum[blockIdx.x] = buf[1023];
}

__global__ __launch_bounds__(1024) void k_scan2(int* __restrict__ bsum, int nb) {
  __shared__ int buf[1024];
  const int tid = threadIdx.x;
  int v = (tid < nb) ? bsum[tid] : 0;
  buf[tid] = v;
  __syncthreads();
  for (int off = 1; off < 1024; off <<= 1) {
    int x = (tid >= off) ? buf[tid - off] : 0;
    __syncthreads();
    buf[tid] += x;
    __syncthreads();
  }
  if (tid < nb) bsum[tid] = buf[tid] - v;
}

__global__ void k_scan3(int* __restrict__ offs16, const int* __restrict__ bsum, int N) {
  int i = blockIdx.x * 256 + threadIdx.x;
  if (i < N) offs16[i] += bsum[i >> 10];
}

// bf16 R -> fp8 e4m3 copy scaled by invs[row] (gather source); 8 elems/thread
__global__ void k_tofp8(const ushort* __restrict__ Rb, const float* __restrict__ invs,
                        unsigned* __restrict__ Rf8, int total8) {
  for (int i = blockIdx.x * 256 + threadIdx.x; i < total8; i += gridDim.x * 256) {
    float s = invs[i >> 5];
    int4 v = ((const int4*)Rb)[i];
    const ushort* pu = (const ushort*)&v;
    unsigned lo = pack_fp8x4(bf2f(pu[0]) * s, bf2f(pu[1]) * s, bf2f(pu[2]) * s, bf2f(pu[3]) * s);
    unsigned hi = pack_fp8x4(bf2f(pu[4]) * s, bf2f(pu[5]) * s, bf2f(pu[6]) * s, bf2f(pu[7]) * s);
    ((uint2*)Rf8)[i] = make_uint2(lo, hi);
  }
}

// iteration-independent weight products
__global__ void k_prep(const float* __restrict__ Wq, const float* __restrict__ Wk,
                       const float* __restrict__ bq, const float* __restrict__ bk,
                       float* __restrict__ P, float* __restrict__ Q, float* __restrict__ K2,
                       float* __restrict__ pb, float* __restrict__ qb,
                       float* __restrict__ wb, float* __restrict__ kb,
                       float* __restrict__ sconst) {
  __shared__ float red[4];
  const int b = blockIdx.x, tid = threadIdx.x;
  if (b < 768) {
    const int f = b & 255, which = b >> 8;
    const float* A = (which == 2) ? Wk : Wq;
    const float* Bm = (which == 1) ? Wq : Wk;
    float acc = 0.0f;
    for (int m = 0; m < H; m++) acc = fmaf(A[f * H + m], Bm[tid * H + m], acc);
    float* D = (which == 0) ? P : ((which == 1) ? Q : K2);
    D[f * H + tid] = acc;
  } else {
    float a1 = 0, a2 = 0, a3 = 0, a4 = 0;
    for (int m = 0; m < H; m++) {
      float wqv = Wq[tid * H + m], wkv = Wk[tid * H + m];
      a1 = fmaf(wqv, bk[m], a1);
      a2 = fmaf(wqv, bq[m], a2);
      a3 = fmaf(wkv, bq[m], a3);
      a4 = fmaf(wkv, bk[m], a4);
    }
    pb[tid] = a1; qb[tid] = a2; wb[tid] = a3; kb[tid] = a4;
    float c0 = block_sum(bq[tid] * bk[tid], red);
    float c1 = block_sum(bq[tid] * bq[tid], red);
    float c2 = block_sum(bk[tid] * bk[tid], red);
    if (tid == 0) { sconst[0] = c0; sconst[1] = c1; sconst[2] = c2; }
  }
}

// R0 = relu(x@W1 + b1) -> bf16, plus layer-0 readout
__global__ void k_fc1(const float* __restrict__ x, const float* __restrict__ W1,
                      const float* __restrict__ b1, const float* __restrict__ Wr,
                      const float* __restrict__ br, const float* __restrict__ wgt,
                      ushort* __restrict__ R0, float* __restrict__ out, int N) {
  __shared__ __align__(16) float lx[16 * FIN];
  __shared__ float red2[4][16];
  const int tid = threadIdx.x;
  const int n0 = blockIdx.x * 16;
  for (int idx = tid; idx < 16 * FIN / 4; idx += 256)
    ((float4*)lx)[idx] = ((const float4*)(x + (size_t)n0 * FIN))[idx];
  __syncthreads();
  float acc[16];
  const float bias = b1[tid];
#pragma unroll
  for (int r = 0; r < 16; r++) acc[r] = bias;
  for (int f = 0; f < FIN; f++) {
    float wv = W1[f * H + tid];
#pragma unroll
    for (int r = 0; r < 16; r++) acc[r] = fmaf(lx[r * FIN + f], wv, acc[r]);
  }
  const float wr0 = Wr[tid];
#pragma unroll
  for (int r = 0; r < 16; r++) {
    acc[r] = fmaxf(acc[r], 0.0f);
    int n = n0 + r;
    if (n < N) R0[(size_t)n * H + tid] = f2bf(acc[r]);
  }
#pragma unroll
  for (int r = 0; r < 16; r++) {
    float s = wave_sum(acc[r] * wr0);
    if ((tid & 63) == 0) red2[tid >> 6][r] = s;
  }
  __syncthreads();
  if (tid < 16) {
    int n = n0 + tid;
    if (n < N)
      out[n] = wgt[0] * (red2[0][tid] + red2[1][tid] + red2[2][tid] + red2[3][tid] + br[0]);
  }
}

// ---------------- MFMA G = R^T R (+ vsum), bf16 input, slab partials ----------------
__global__ __launch_bounds__(512, 2) void k_Gm(const ushort* __restrict__ Rb,
                                               float* __restrict__ Gslab,
                                               float* __restrict__ vsum, int N) {
  __shared__ ushort sb[2][32 * 256];  // 32 KB
  const int tid = threadIdx.x;
  const int lane = tid & 63;
  const int wid = tid >> 6;
  const int wrow = (wid & 1) * 128;
  const int wcol = (wid >> 1) * 64;
  const int l31 = lane & 31;
  const int lhi = lane >> 5;

  const int rowbase = blockIdx.x * ROWS_PB;
  const int nrows = min(ROWS_PB, N - rowbase);
  const int nch = (nrows + 31) >> 5;

  const int sk = tid >> 4;
  const int c0 = (tid & 15) * 16;

  f32x16 acc[4][2];
#pragma unroll
  for (int s = 0; s < 4; s++)
#pragma unroll
    for (int t = 0; t < 2; t++)
#pragma unroll
      for (int e = 0; e < 16; e++) acc[s][t][e] = 0.0f;

  float csum[16];
#pragma unroll
  for (int i = 0; i < 16; i++) csum[i] = 0.0f;

  int4 ld[2];

  auto load_chunk = [&](int ch) {
    int g = rowbase + ch * 32 + sk;
    const int4* src = (const int4*)(Rb + (size_t)g * H + c0);
    ld[0] = (g < N) ? src[0] : make_int4(0, 0, 0, 0);
    ld[1] = (g < N) ? src[1] : make_int4(0, 0, 0, 0);
  };

  auto write_chunk = [&](int buf) {
    const int swz = (sk & 3) << 4;
#pragma unroll
    for (int i = 0; i < 2; i++) {
      *(int4*)&sb[buf][sk * 256 + ((c0 + 8 * i) ^ swz)] = ld[i];
      const ushort* pu = (const ushort*)&ld[i];
#pragma unroll
      for (int j = 0; j < 8; j++) csum[8 * i + j] += bf2f(pu[j]);
    }
  };

  auto compute = [&](int buf) {
#pragma unroll
    for (int ks = 0; ks < 2; ks++) {
      const int kb = ks * 16 + lhi * 8;
      FragU fr[6];
#pragma unroll
      for (int s = 0; s < 6; s++) {
        const int cbase = (s < 4) ? (wrow + 32 * s + l31) : (wcol + 32 * (s - 4) + l31);
#pragma unroll
        for (int j = 0; j < 8; j++)
          fr[s].u[j] = sb[buf][(kb + j) * 256 + (cbase ^ ((j & 3) << 4))];
      }
#pragma unroll
      for (int s = 0; s < 4; s++)
#pragma unroll
        for (int t = 0; t < 2; t++)
          acc[s][t] = __builtin_amdgcn_mfma_f32_32x32x16_bf16(fr[s].v, fr[4 + t].v,
                                                              acc[s][t], 0, 0, 0);
    }
  };

  if (nch > 0) {
    load_chunk(0);
    write_chunk(0);
    __syncthreads();
    int cur = 0;
    for (int c = 0; c < nch; c++) {
      if (c + 1 < nch) load_chunk(c + 1);
      compute(cur);
      if (c + 1 < nch) write_chunk(cur ^ 1);
      __syncthreads();
      cur ^= 1;
    }
  }

  // non-atomic partial-G slab write (k_Gr reduces the slabs)
  float* Gs = Gslab + (size_t)blockIdx.x * 65536;
#pragma unroll
  for (int s = 0; s < 4; s++)
#pragma unroll
    for (int t = 0; t < 2; t++) {
      const int n0 = wcol + 32 * t + l31;
#pragma unroll
      for (int r = 0; r < 16; r++) {
        const int row = wrow + 32 * s + (r & 3) + 8 * (r >> 2) + 4 * lhi;
        Gs[row * 256 + n0] = acc[s][t][r];
      }
    }

  float* fl = (float*)sb;
#pragma unroll
  for (int j = 0; j < 16; j++) fl[sk * 256 + c0 + j] = csum[j];
  __syncthreads();
  if (tid < 256) {
    float s = 0.0f;
    for (int r = 0; r < 32; r++) s += fl[r * 256 + tid];
    atomicAdd(&vsum[tid], s);
  }
}

// reduce slabs -> G
__global__ void k_Gr(const float* __restrict__ Gslab, float* __restrict__ G, int nslab) {
  const int i = blockIdx.x * 256 + threadIdx.x;
  float s0 = 0, s1 = 0, s2 = 0, s3 = 0;
  int b = 0;
  for (; b + 3 < nslab; b += 4) {
    s0 += Gslab[(size_t)b * 65536 + i];
    s1 += Gslab[(size_t)(b + 1) * 65536 + i];
    s2 += Gslab[(size_t)(b + 2) * 65536 + i];
    s3 += Gslab[(size_t)(b + 3) * 65536 + i];
  }
  float s = s0 + s1 + s2 + s3;
  for (; b < nslab; b++) s += Gslab[(size_t)b * 65536 + i];
  G[i] = s;
}

// per-iteration small products from (G, vsum); writes transposed bf16 Mt[n][k]
__global__ void k_small(const float* __restrict__ G, const float* __restrict__ vsum,
                        const float* __restrict__ P, const float* __restrict__ pb,
                        const float* __restrict__ wb, const float* __restrict__ sconst,
                        const float* __restrict__ Q, const float* __restrict__ K2,
                        ushort* __restrict__ Mt, float* __restrict__ cvec,
                        float* __restrict__ dvec, float* __restrict__ scal, int N) {
  __shared__ float red[4];
  const int b = blockIdx.x, tid = threadIdx.x;
  if (b < 256) {
    float acc = 0.0f;
    for (int m = 0; m < H; m++) acc = fmaf(P[b * H + m], G[m * H + tid], acc);
    Mt[(size_t)tid * H + b] = f2bf(acc + pb[b] * vsum[tid]);
  } else if (b == 256) {
    float acc = 0.0f;
    for (int f = 0; f < H; f++) acc = fmaf(wb[f], G[f * H + tid], acc);
    cvec[tid] = acc + sconst[0] * vsum[tid];
  } else if (b == 257) {
    float acc = 0.0f;
    for (int m = 0; m < H; m++) acc = fmaf(P[tid * H + m], vsum[m], acc);
    dvec[tid] = acc + (float)N * pb[tid];
  } else if (b < 274) {
    int base = (b - 258) * 4096 + tid;
    float a = 0.0f;
    for (int j = 0; j < 16; j++) a = fmaf(G[base + j * 256], Q[base + j * 256], a);
    a = block_sum(a, red);
    if (tid == 0) atomicAdd(&scal[0], a);
  } else {
    int base = (b - 274) * 4096 + tid;
    float a = 0.0f;
    for (int j = 0; j < 16; j++) a = fmaf(G[base + j * 256], K2[base + j * 256], a);
    a = block_sum(a, red);
    if (tid == 0) atomicAdd(&scal[1], a);
  }
}

// finalize norms
__global__ void k_final(const float* __restrict__ vsum, const float* __restrict__ qb,
                        const float* __restrict__ kb, const float* __restrict__ wb,
                        const float* __restrict__ sconst, float* __restrict__ scal, int N) {
  __shared__ float red[4];
  const int tid = threadIdx.x;
  float s1 = block_sum(qb[tid] * vsum[tid], red);
  float s2 = block_sum(kb[tid] * vsum[tid], red);
  float s3 = block_sum(wb[tid] * vsum[tid], red);
  if (tid == 0) {
    float sq = scal[0] + 2.0f * s1 + (float)N * sconst[1];
    float sk = scal[1] + 2.0f * s2 + (float)N * sconst[2];
    scal[2] = 1.0f / (sqrtf(sq) * sqrtf(sk));
    scal[3] = s3 + (float)N * sconst[0];
  }
}

// ---------------- MFMA num = R * M (bf16 in, bf16 out) ----------------
__global__ __launch_bounds__(512) void k_N(const ushort* __restrict__ Rb,
                                           const ushort* __restrict__ Mt,
                                           ushort* __restrict__ numb, int N) {
  const int tid = threadIdx.x;
  const int lane = tid & 63;
  const int wid = tid >> 6;
  const int l31 = lane & 31;
  const int lhi = lane >> 5;
  const int wrow = (wid & 3) * 32;
  const int wcol = (wid >> 2) * 128;
  const int rowbase = blockIdx.x * 128;

  f32x16 acc[4];
#pragma unroll
  for (int t = 0; t < 4; t++)
#pragma unroll
    for (int e = 0; e < 16; e++) acc[t][e] = 0.0f;

  const ushort* aptr = Rb + (size_t)(rowbase + wrow + l31) * H;

  for (int kc = 0; kc < 16; kc++) {
    const int kb = kc * 16 + lhi * 8;
    FragU fa;
    *(int4*)fa.u = *(const int4*)(aptr + kb);
    FragU fb0, fb1, fb2, fb3;
    *(int4*)fb0.u = *(const int4*)(Mt + (size_t)(wcol + 0 + l31) * H + kb);
    *(int4*)fb1.u = *(const int4*)(Mt + (size_t)(wcol + 32 + l31) * H + kb);
    *(int4*)fb2.u = *(const int4*)(Mt + (size_t)(wcol + 64 + l31) * H + kb);
    *(int4*)fb3.u = *(const int4*)(Mt + (size_t)(wcol + 96 + l31) * H + kb);
    acc[0] = __builtin_amdgcn_mfma_f32_32x32x16_bf16(fa.v, fb0.v, acc[0], 0, 0, 0);
    acc[1] = __builtin_amdgcn_mfma_f32_32x32x16_bf16(fa.v, fb1.v, acc[1], 0, 0, 0);
    acc[2] = __builtin_amdgcn_mfma_f32_32x32x16_bf16(fa.v, fb2.v, acc[2], 0, 0, 0);
    acc[3] = __builtin_amdgcn_mfma_f32_32x32x16_bf16(fa.v, fb3.v, acc[3], 0, 0, 0);
  }

#pragma unroll
  for (int t = 0; t < 4; t++) {
    const int col = wcol + 32 * t + l31;
#pragma unroll
    for (int r = 0; r < 16; r++) {
      const int row = rowbase + wrow + (r & 3) + 8 * (r >> 2) + 4 * lhi;
      if (row < N) numb[(size_t)row * H + col] = f2bf(acc[t][r]);
    }
  }
}

// slim fused: den, gcn gather (pre-scaled fp8 rows, 16-deep), attn from numb,
// residual blend, layernorm, write bf16 Rnext, readout. No LDS.
__global__ __launch_bounds__(256) void k_C(
    const ushort* __restrict__ Rb, ushort* __restrict__ Rnext,
    const ushort* __restrict__ numb, const unsigned* __restrict__ Rf8,
    const int* __restrict__ eb, const float* __restrict__ invs,
    const float* __restrict__ cvec, const float* __restrict__ dvec,
    const float* __restrict__ vsum, const float* __restrict__ scal,
    const int* __restrict__ offs16, const int* __restrict__ deg,
    const float* __restrict__ alphap, const float* __restrict__ gamma,
    const float* __restrict__ beta, const float* __restrict__ Wr,
    const float* __restrict__ br, const float* __restrict__ wgt,
    float* __restrict__ out, int N, int layer, int last) {
  const int tid = threadIdx.x, lane = tid & 63, wv = tid >> 6;
  const int d0 = lane * 4;
  const int n0 = blockIdx.x * 32 + wv * 8;

  const float invn = scal[2], denc = scal[3];
  const float al = alphap[0], om = 1.0f - al;
  const float4 dv = *(const float4*)&dvec[d0];
  const float4 cv = *(const float4*)&cvec[d0];
  const float4 vs = *(const float4*)&vsum[d0];
  const float4 gm = *(const float4*)&gamma[d0];
  const float4 bt = *(const float4*)&beta[d0];
  const float4 wr = *(const float4*)&Wr[layer * H + d0];
  const float wl = wgt[layer], bl = br[layer];

  for (int r = 0; r < 8; r++) {
    const int n = n0 + r;
    if (n >= N) break;  // uniform across the wave
    const ushort4 ro = *(const ushort4*)&Rb[(size_t)n * H + d0];
    const ushort4 no = *(const ushort4*)&numb[(size_t)n * H + d0];
    const float old0 = bf2f(ro.x), old1 = bf2f(ro.y), old2 = bf2f(ro.z), old3 = bf2f(ro.w);

    float p = old0 * dv.x + old1 * dv.y + old2 * dv.z + old3 * dv.w;
    p = wave_sum(p);
    const float rden = 1.0f / ((p + denc) * invn + (float)N);

    float a[4] = {0.0f, 0.0f, 0.0f, 0.0f};
    const int st = offs16[n];
    const int nb = (deg[n] + 15) >> 4;
    const int4* pe = (const int4*)(eb + st);
    for (int b = 0; b < nb; b++, pe += 4) {
      int4 q0 = pe[0], q1 = pe[1], q2 = pe[2], q3 = pe[3];
      unsigned g[16];
      g[0] = Rf8[((size_t)q0.x << 6) + lane];
      g[1] = Rf8[((size_t)q0.y << 6) + lane];
      g[2] = Rf8[((size_t)q0.z << 6) + lane];
      g[3] = Rf8[((size_t)q0.w << 6) + lane];
      g[4] = Rf8[((size_t)q1.x << 6) + lane];
      g[5] = Rf8[((size_t)q1.y << 6) + lane];
      g[6] = Rf8[((size_t)q1.z << 6) + lane];
      g[7] = Rf8[((size_t)q1.w << 6) + lane];
      g[8] = Rf8[((size_t)q2.x << 6) + lane];
      g[9] = Rf8[((size_t)q2.y << 6) + lane];
      g[10] = Rf8[((size_t)q2.z << 6) + lane];
      g[11] = Rf8[((size_t)q2.w << 6) + lane];
      g[12] = Rf8[((size_t)q3.x << 6) + lane];
      g[13] = Rf8[((size_t)q3.y << 6) + lane];
      g[14] = Rf8[((size_t)q3.z << 6) + lane];
      g[15] = Rf8[((size_t)q3.w << 6) + lane];
#pragma unroll
      for (int i = 0; i < 16; i++) unpack_fp8x4_acc(a, g[i]);
    }
    const float sn = invs[n];

    float hv0 = al * (((bf2f(no.x) + cv.x) * invn + vs.x) * rden + a[0] * sn) + om * old0;
    float hv1 = al * (((bf2f(no.y) + cv.y) * invn + vs.y) * rden + a[1] * sn) + om * old1;
    float hv2 = al * (((bf2f(no.z) + cv.z) * invn + vs.z) * rden + a[2] * sn) + om * old2;
    float hv3 = al * (((bf2f(no.w) + cv.w) * invn + vs.w) * rden + a[3] * sn) + om * old3;

    float s = wave_sum(hv0 + hv1 + hv2 + hv3);
    float mu = s * (1.0f / H);
    float s2 = wave_sum(hv0 * hv0 + hv1 * hv1 + hv2 * hv2 + hv3 * hv3);
    float var = s2 * (1.0f / H) - mu * mu;
    float rs = rsqrtf(var + LN_EPS);
    float y0 = (hv0 - mu) * rs * gm.x + bt.x;
    float y1 = (hv1 - mu) * rs * gm.y + bt.y;
    float y2 = (hv2 - mu) * rs * gm.z + bt.z;
    float y3 = (hv3 - mu) * rs * gm.w + bt.w;
    if (!last) {
      ushort4 o;
      o.x = f2bf(y0); o.y = f2bf(y1); o.z = f2bf(y2); o.w = f2bf(y3);
      *(ushort4*)&Rnext[(size_t)n * H + d0] = o;
    }
    float rp = wave_sum(y0 * wr.x + y1 * wr.y + y2 * wr.z + y3 * wr.w);
    if (lane == 0) out[n] += wl * (rp + bl);
  }
}

// ---------------- host ----------------

extern "C" void kernel_launch(void* const* d_in, const int* in_sizes, int n_in,
                              void* d_out, int out_size, void* d_ws, size_t ws_size,
                              hipStream_t stream) {
  const float* x = (const float*)d_in[0];
  const int* ei = (const int*)d_in[1];
  const float* W1 = (const float*)d_in[2];
  const float* b1 = (const float*)d_in[3];
  const float* Wq = (const float*)d_in[4];
  const float* bq = (const float*)d_in[5];
  const float* Wk = (const float*)d_in[6];
  const float* bk = (const float*)d_in[7];
  const float* gamma = (const float*)d_in[8];
  const float* beta = (const float*)d_in[9];
  const float* alphap = (const float*)d_in[10];
  const float* Wr = (const float*)d_in[11];
  const float* br = (const float*)d_in[12];
  const float* wgt = (const float*)d_in[13];
  float* out = (float*)d_out;

  const int N = in_sizes[0] / FIN;
  const int E = in_sizes[1] / 2;
  const int* row = ei;
  const int* col = ei + E;

  char* w = (char*)d_ws;
  auto alloc = [&](size_t bytes) -> char* {
    char* p = w;
    w += (bytes + 255) & ~(size_t)255;
    return p;
  };
  const size_t RB = (size_t)(N + 128) * H * sizeof(ushort);
  ushort* Rb0 = (ushort*)alloc(RB);
  ushort* Rb1 = (ushort*)alloc(RB);   // also aliased as bucket scratch during setup
  ushort* numb = (ushort*)alloc(RB);  // also aliased as G-slab scratch per iter
  unsigned* Rf8 = (unsigned*)alloc((size_t)(N + 1) * 64 * sizeof(unsigned));  // +1 zero row
  ushort* Mt = (ushort*)alloc(H * H * sizeof(ushort));
  float* G = (float*)alloc(H * H * sizeof(float));
  // zero-region (contiguous): vsum, scal
  float* vsum = (float*)alloc(1024);
  float* scal = (float*)alloc(256);
  float* cvec = (float*)alloc(1024);
  float* dvec = (float*)alloc(1024);
  float* P = (float*)alloc(H * H * sizeof(float));
  float* Q = (float*)alloc(H * H * sizeof(float));
  float* K2 = (float*)alloc(H * H * sizeof(float));
  float* pb = (float*)alloc(1024);
  float* qb = (float*)alloc(1024);
  float* wb = (float*)alloc(1024);
  float* kb = (float*)alloc(1024);
  float* sconst = (float*)alloc(256);
  int* deg = (int*)alloc((size_t)N * 4);
  float* invs = (float*)alloc((size_t)N * 4);
  int* offs16 = (int*)alloc((size_t)(N + 1) * 4);
  int* bsum = (int*)alloc(1024 * 4);
  const int NB = (N + 127) >> 7;  // buckets of 128 destinations
  int* bcnt = (int*)alloc((size_t)NB * 16 * 4);
  size_t EPAD = (size_t)E + 16 * (size_t)N;
  EPAD = (EPAD + 3) & ~(size_t)3;
  int* eb = (int*)alloc(EPAD * sizeof(int));

  int2* bbuf = (int2*)Rb1;        // NB*BCAP*8 <= RB (512N vs 512N+64KB)
  float* Gslab = (float*)numb;    // nbG*256KB <= RB

  hipMemsetAsync(bcnt, 0, (size_t)NB * 16 * 4, stream);
  hipMemsetAsync(Rf8 + (size_t)N * 64, 0, 64 * sizeof(unsigned), stream);

  const int gE = (E + 255) / 256, gN = (N + 255) / 256;
  const int nblk = (N + 1023) / 1024;
  k_bucket<<<gE, 256, 0, stream>>>(row, col, bbuf, bcnt, E);
  k_degB<<<NB, 256, 0, stream>>>(bbuf, bcnt, deg, N);
  k_invsqrt<<<gN, 256, 0, stream>>>(deg, invs, N);
  k_scan1<<<nblk, 1024, 0, stream>>>(deg, offs16, bsum, N);
  k_scan2<<<1, 1024, 0, stream>>>(bsum, nblk);
  k_scan3<<<gN, 256, 0, stream>>>(offs16, bsum, N);
  k_place<<<NB, 256, 0, stream>>>(bbuf, bcnt, offs16, eb, N);
  k_prep<<<769, 256, 0, stream>>>(Wq, Wk, bq, bk, P, Q, K2, pb, qb, wb, kb, sconst);
  const int gRows16 = (N + 15) / 16;
  k_fc1<<<gRows16, 256, 0, stream>>>(x, W1, b1, Wr, br, wgt, Rb0, out, N);

  const int nbG = (N + ROWS_PB - 1) / ROWS_PB;
  const int nbN = (N + 127) / 128;
  const int gRows32 = (N + 31) / 32;
  const int total8 = N * (H / 8);
  ushort* Rc = Rb0;
  ushort* Rn = Rb1;
  for (int it = 1; it <= 3; ++it) {
    hipMemsetAsync(vsum, 0, 1024 + 256, stream);
    k_Gm<<<nbG, 512, 0, stream>>>(Rc, Gslab, vsum, N);
    k_Gr<<<256, 256, 0, stream>>>(Gslab, G, nbG);
    k_small<<<290, 256, 0, stream>>>(G, vsum, P, pb, wb, sconst, Q, K2, Mt, cvec, dvec, scal, N);
    k_final<<<1, 256, 0, stream>>>(vsum, qb, kb, wb, sconst, scal, N);
    k_tofp8<<<2048, 256, 0, stream>>>(Rc, invs, Rf8, total8);
    k_N<<<nbN, 512, 0, stream>>>(Rc, Mt, numb, N);
    k_C<<<gRows32, 256, 0, stream>>>(Rc, Rn, numb, Rf8, eb, invs, cvec, dvec, vsum, scal,
                                     offs16, deg, alphap, gamma, beta, Wr, br, wgt, out,
                                     N, it, (it == 3) ? 1 : 0);
    ushort* t = Rc; Rc = Rn; Rn = t;
  }
}

// Round 9
// 1247.822 us; speedup vs baseline: 4.1387x; 1.0666x over previous
//
#include <hip/hip_runtime.h>

#define H 256
#define FIN 58
#define LN_EPS 1e-5f
#define ROWS_PB 544  // k_Gm rows per block (17 chunks of 32)
#define EPB 8192     // k_b1 edges per block
#define SBW 11       // super-bin width: 2048 dests

typedef __bf16 bf16x8 __attribute__((ext_vector_type(8)));
typedef float f32x16 __attribute__((ext_vector_type(16)));
typedef float f32x2 __attribute__((ext_vector_type(2)));

union FragU {
  ushort u[8];
  bf16x8 v;
};

// ---------------- utilities ----------------

__device__ __forceinline__ float wave_sum(float v) {
#pragma unroll
  for (int off = 1; off < 64; off <<= 1) v += __shfl_xor(v, off, 64);
  return v;
}

__device__ __forceinline__ float block_sum(float v, volatile float* red) {
  const int tid = threadIdx.x;
  v = wave_sum(v);
  __syncthreads();
  if ((tid & 63) == 0) red[tid >> 6] = v;
  __syncthreads();
  return red[0] + red[1] + red[2] + red[3];
}

__device__ __forceinline__ ushort f2bf(float f) {
  unsigned u = __float_as_uint(f);
  unsigned r = (u + 0x7FFFu + ((u >> 16) & 1u)) >> 16;
  return (ushort)r;
}

__device__ __forceinline__ float bf2f(ushort u) {
  return __uint_as_float((unsigned)u << 16);
}

// ---- fp8 e4m3 pack/unpack (HW path on gfx950, manual fallback) ----
#if __has_builtin(__builtin_amdgcn_cvt_pk_fp8_f32) && __has_builtin(__builtin_amdgcn_cvt_pk_f32_fp8)
__device__ __forceinline__ unsigned pack_fp8x4(float a, float b, float c, float d) {
  int v = 0;
  v = __builtin_amdgcn_cvt_pk_fp8_f32(a, b, v, false);
  v = __builtin_amdgcn_cvt_pk_fp8_f32(c, d, v, true);
  return (unsigned)v;
}
__device__ __forceinline__ void unpack_fp8x4_acc(float* acc, unsigned v) {
  f32x2 lo = __builtin_amdgcn_cvt_pk_f32_fp8((int)v, false);
  f32x2 hi = __builtin_amdgcn_cvt_pk_f32_fp8((int)v, true);
  acc[0] += lo[0]; acc[1] += lo[1]; acc[2] += hi[0]; acc[3] += hi[1];
}
#else
__device__ __forceinline__ unsigned char f2e4m3_1(float f) {
  unsigned u = __float_as_uint(f);
  unsigned s = (u >> 31) << 7;
  float a = fabsf(f);
  if (a >= 448.0f) return (unsigned char)(s | 0x7E);
  if (a < 0.0009765625f) return (unsigned char)s;
  int e;
  float m = frexpf(a, &e);
  int E = e - 1 + 7;
  if (E >= 1) {
    int mm = (int)rintf((m * 2.0f - 1.0f) * 8.0f);
    if (mm == 8) { mm = 0; E++; }
    return (unsigned char)(s | (E << 3) | mm);
  }
  int mm = (int)rintf(a * 512.0f);
  if (mm > 7) return (unsigned char)(s | (1 << 3));
  return (unsigned char)(s | mm);
}
__device__ __forceinline__ unsigned pack_fp8x4(float a, float b, float c, float d) {
  return (unsigned)f2e4m3_1(a) | ((unsigned)f2e4m3_1(b) << 8) |
         ((unsigned)f2e4m3_1(c) << 16) | ((unsigned)f2e4m3_1(d) << 24);
}
__device__ __forceinline__ float e4m3f_1(unsigned v) {
  int s = (v >> 7) & 1, E = (v >> 3) & 15, m = v & 7;
  float mag = E ? ldexpf(1.0f + m * 0.125f, E - 7) : ldexpf((float)m, -9);
  return s ? -mag : mag;
}
__device__ __forceinline__ void unpack_fp8x4_acc(float* acc, unsigned v) {
  acc[0] += e4m3f_1(v & 255);
  acc[1] += e4m3f_1((v >> 8) & 255);
  acc[2] += e4m3f_1((v >> 16) & 255);
  acc[3] += e4m3f_1(v >> 24);
}
#endif

// ---------------- setup: radix-style CSR build ----------------

// level 1: LDS-reordered scatter into <=64 super-bin regions (coalesced writes)
__global__ __launch_bounds__(512) void k_b1(const int* __restrict__ row,
                                            const int* __restrict__ col,
                                            unsigned* __restrict__ breg,
                                            int* __restrict__ gcnt,
                                            int cap2, int E, int nsb) {
  __shared__ unsigned stage[EPB];  // 32 KB
  __shared__ int lh[65], lbase[65], lcur[64], gclaim[64];
  const int tid = threadIdx.x;
  const int e0 = blockIdx.x * EPB;
  const int cnt = min(EPB, E - e0);
  if (tid < 64) lh[tid] = 0;
  __syncthreads();
  // pass 1: histogram of super-bin
  for (int i = tid; i < cnt; i += 512) atomicAdd(&lh[col[e0 + i] >> SBW], 1);
  __syncthreads();
  if (tid == 0) {
    int acc = 0;
    for (int b = 0; b < nsb; b++) { lbase[b] = acc; acc += lh[b]; }
    lbase[nsb] = acc;
  }
  __syncthreads();
  if (tid < nsb) {
    gclaim[tid] = atomicAdd(&gcnt[tid], lh[tid]);
    lcur[tid] = lbase[tid];
  }
  __syncthreads();
  // pass 2: place packed records into LDS staging, bin-sorted
  for (int i = tid; i < cnt; i += 512) {
    int c = col[e0 + i];
    int b = c >> SBW;
    int s = atomicAdd(&lcur[b], 1);
    stage[s] = ((unsigned)row[e0 + i] << SBW) | (unsigned)(c & ((1 << SBW) - 1));
  }
  __syncthreads();
  // pass 3: linear LDS -> global (coalesced per bin segment)
  for (int i = tid; i < cnt; i += 512) {
    int lo = 0, hi = nsb;  // find b: lbase[b] <= i < lbase[b+1]
    while (hi - lo > 1) {
      int mid = (lo + hi) >> 1;
      if (lbase[mid] <= i) lo = mid; else hi = mid;
    }
    int off = gclaim[lo] + (i - lbase[lo]);
    if (off < cap2) breg[(size_t)lo * cap2 + off] = stage[i];
  }
}

// per-super-bin degree count (2048 LDS counters)
__global__ __launch_bounds__(512) void k_degB2(const unsigned* __restrict__ breg,
                                               const int* __restrict__ gcnt, int cap2,
                                               int* __restrict__ deg, int N) {
  __shared__ int lcnt[1 << SBW];
  const int b = blockIdx.x, tid = threadIdx.x, base = b << SBW;
  for (int i = tid; i < (1 << SBW); i += 512) lcnt[i] = 0;
  __syncthreads();
  const int cnt = min(gcnt[b], cap2);
  const unsigned* p = breg + (size_t)b * cap2;
  for (int i = tid; i < cnt; i += 512) atomicAdd(&lcnt[p[i] & ((1 << SBW) - 1)], 1);
  __syncthreads();
  for (int i = tid; i < (1 << SBW); i += 512) {
    int d = base + i;
    if (d < N) deg[d] = lcnt[i];
  }
}

// level 2: place into final CSR (offs16 window cached in LDS) + sentinel fill
__global__ __launch_bounds__(512) void k_b2(const unsigned* __restrict__ breg,
                                            const int* __restrict__ gcnt, int cap2,
                                            const int* __restrict__ offs16,
                                            int* __restrict__ eb, int N) {
  __shared__ int loffs[1 << SBW];
  __shared__ int lcur[1 << SBW];
  const int b = blockIdx.x, tid = threadIdx.x, base = b << SBW;
  for (int i = tid; i < (1 << SBW); i += 512) {
    int d = base + i;
    loffs[i] = (d < N) ? offs16[d] : 0;
    lcur[i] = 0;
  }
  __syncthreads();
  const int cnt = min(gcnt[b], cap2);
  const unsigned* p = breg + (size_t)b * cap2;
  for (int i = tid; i < cnt; i += 512) {
    unsigned rc = p[i];
    int lc = rc & ((1 << SBW) - 1);
    int slot = atomicAdd(&lcur[lc], 1);
    eb[loffs[lc] + slot] = (int)(rc >> SBW);
  }
  __syncthreads();
  for (int i = tid; i < (1 << SBW); i += 512) {
    int d = base + i;
    if (d < N) {
      int c = lcur[i];
      int pad = (c + 15) & ~15;
      int o = loffs[i];
      for (int j = c; j < pad; j++) eb[o + j] = N;
    }
  }
}

__global__ void k_invsqrt(const int* __restrict__ deg, float* __restrict__ invs, int N) {
  int i = blockIdx.x * 256 + threadIdx.x;
  if (i < N) {
    int d = deg[i];
    invs[i] = (d > 0) ? (1.0f / sqrtf((float)d)) : 0.0f;
  }
}

// two-level exclusive scan of padded degree ((deg+15)&~15) -> offs16
__global__ __launch_bounds__(1024) void k_scan1(const int* __restrict__ deg,
                                                int* __restrict__ offs16,
                                                int* __restrict__ bsum, int N) {
  __shared__ int buf[1024];
  const int tid = threadIdx.x;
  const int gid = blockIdx.x * 1024 + tid;
  int v = (gid < N) ? ((deg[gid] + 15) & ~15) : 0;
  buf[tid] = v;
  __syncthreads();
  for (int off = 1; off < 1024; off <<= 1) {
    int x = (tid >= off) ? buf[tid - off] : 0;
    __syncthreads();
    buf[tid] += x;
    __syncthreads();
  }
  if (gid < N) offs16[gid] = buf[tid] - v;
  if (tid == 1023) bsum[blockIdx.x] = buf[1023];
}

__global__ __launch_bounds__(1024) void k_scan2(int* __restrict__ bsum, int nb) {
  __shared__ int buf[1024];
  const int tid = threadIdx.x;
  int v = (tid < nb) ? bsum[tid] : 0;
  buf[tid] = v;
  __syncthreads();
  for (int off = 1; off < 1024; off <<= 1) {
    int x = (tid >= off) ? buf[tid - off] : 0;
    __syncthreads();
    buf[tid] += x;
    __syncthreads();
  }
  if (tid < nb) bsum[tid] = buf[tid] - v;
}

__global__ void k_scan3(int* __restrict__ offs16, const int* __restrict__ bsum, int N) {
  int i = blockIdx.x * 256 + threadIdx.x;
  if (i < N) offs16[i] += bsum[i >> 10];
}

// bf16 R -> fp8 e4m3 copy scaled by invs[row] (gather source); 8 elems/thread
__global__ void k_tofp8(const ushort* __restrict__ Rb, const float* __restrict__ invs,
                        unsigned* __restrict__ Rf8, int total8) {
  for (int i = blockIdx.x * 256 + threadIdx.x; i < total8; i += gridDim.x * 256) {
    float s = invs[i >> 5];
    int4 v = ((const int4*)Rb)[i];
    const ushort* pu = (const ushort*)&v;
    unsigned lo = pack_fp8x4(bf2f(pu[0]) * s, bf2f(pu[1]) * s, bf2f(pu[2]) * s, bf2f(pu[3]) * s);
    unsigned hi = pack_fp8x4(bf2f(pu[4]) * s, bf2f(pu[5]) * s, bf2f(pu[6]) * s, bf2f(pu[7]) * s);
    ((uint2*)Rf8)[i] = make_uint2(lo, hi);
  }
}

// iteration-independent weight products
__global__ void k_prep(const float* __restrict__ Wq, const float* __restrict__ Wk,
                       const float* __restrict__ bq, const float* __restrict__ bk,
                       float* __restrict__ P, float* __restrict__ Q, float* __restrict__ K2,
                       float* __restrict__ pb, float* __restrict__ qb,
                       float* __restrict__ wb, float* __restrict__ kb,
                       float* __restrict__ sconst) {
  __shared__ float red[4];
  const int b = blockIdx.x, tid = threadIdx.x;
  if (b < 768) {
    const int f = b & 255, which = b >> 8;
    const float* A = (which == 2) ? Wk : Wq;
    const float* Bm = (which == 1) ? Wq : Wk;
    float acc = 0.0f;
    for (int m = 0; m < H; m++) acc = fmaf(A[f * H + m], Bm[tid * H + m], acc);
    float* D = (which == 0) ? P : ((which == 1) ? Q : K2);
    D[f * H + tid] = acc;
  } else {
    float a1 = 0, a2 = 0, a3 = 0, a4 = 0;
    for (int m = 0; m < H; m++) {
      float wqv = Wq[tid * H + m], wkv = Wk[tid * H + m];
      a1 = fmaf(wqv, bk[m], a1);
      a2 = fmaf(wqv, bq[m], a2);
      a3 = fmaf(wkv, bq[m], a3);
      a4 = fmaf(wkv, bk[m], a4);
    }
    pb[tid] = a1; qb[tid] = a2; wb[tid] = a3; kb[tid] = a4;
    float c0 = block_sum(bq[tid] * bk[tid], red);
    float c1 = block_sum(bq[tid] * bq[tid], red);
    float c2 = block_sum(bk[tid] * bk[tid], red);
    if (tid == 0) { sconst[0] = c0; sconst[1] = c1; sconst[2] = c2; }
  }
}

// R0 = relu(x@W1 + b1) -> bf16, plus layer-0 readout
__global__ void k_fc1(const float* __restrict__ x, const float* __restrict__ W1,
                      const float* __restrict__ b1, const float* __restrict__ Wr,
                      const float* __restrict__ br, const float* __restrict__ wgt,
                      ushort* __restrict__ R0, float* __restrict__ out, int N) {
  __shared__ __align__(16) float lx[16 * FIN];
  __shared__ float red2[4][16];
  const int tid = threadIdx.x;
  const int n0 = blockIdx.x * 16;
  for (int idx = tid; idx < 16 * FIN / 4; idx += 256)
    ((float4*)lx)[idx] = ((const float4*)(x + (size_t)n0 * FIN))[idx];
  __syncthreads();
  float acc[16];
  const float bias = b1[tid];
#pragma unroll
  for (int r = 0; r < 16; r++) acc[r] = bias;
  for (int f = 0; f < FIN; f++) {
    float wv = W1[f * H + tid];
#pragma unroll
    for (int r = 0; r < 16; r++) acc[r] = fmaf(lx[r * FIN + f], wv, acc[r]);
  }
  const float wr0 = Wr[tid];
#pragma unroll
  for (int r = 0; r < 16; r++) {
    acc[r] = fmaxf(acc[r], 0.0f);
    int n = n0 + r;
    if (n < N) R0[(size_t)n * H + tid] = f2bf(acc[r]);
  }
#pragma unroll
  for (int r = 0; r < 16; r++) {
    float s = wave_sum(acc[r] * wr0);
    if ((tid & 63) == 0) red2[tid >> 6][r] = s;
  }
  __syncthreads();
  if (tid < 16) {
    int n = n0 + tid;
    if (n < N)
      out[n] = wgt[0] * (red2[0][tid] + red2[1][tid] + red2[2][tid] + red2[3][tid] + br[0]);
  }
}

// ---------------- MFMA G = R^T R (+ vsum), bf16 input, slab partials ----------------
__global__ __launch_bounds__(512, 2) void k_Gm(const ushort* __restrict__ Rb,
                                               float* __restrict__ Gslab,
                                               float* __restrict__ vsum, int N) {
  __shared__ ushort sb[2][32 * 256];  // 32 KB
  const int tid = threadIdx.x;
  const int lane = tid & 63;
  const int wid = tid >> 6;
  const int wrow = (wid & 1) * 128;
  const int wcol = (wid >> 1) * 64;
  const int l31 = lane & 31;
  const int lhi = lane >> 5;

  const int rowbase = blockIdx.x * ROWS_PB;
  const int nrows = min(ROWS_PB, N - rowbase);
  const int nch = (nrows + 31) >> 5;

  const int sk = tid >> 4;
  const int c0 = (tid & 15) * 16;

  f32x16 acc[4][2];
#pragma unroll
  for (int s = 0; s < 4; s++)
#pragma unroll
    for (int t = 0; t < 2; t++)
#pragma unroll
      for (int e = 0; e < 16; e++) acc[s][t][e] = 0.0f;

  float csum[16];
#pragma unroll
  for (int i = 0; i < 16; i++) csum[i] = 0.0f;

  int4 ld[2];

  auto load_chunk = [&](int ch) {
    int g = rowbase + ch * 32 + sk;
    const int4* src = (const int4*)(Rb + (size_t)g * H + c0);
    ld[0] = (g < N) ? src[0] : make_int4(0, 0, 0, 0);
    ld[1] = (g < N) ? src[1] : make_int4(0, 0, 0, 0);
  };

  auto write_chunk = [&](int buf) {
    const int swz = (sk & 3) << 4;
#pragma unroll
    for (int i = 0; i < 2; i++) {
      *(int4*)&sb[buf][sk * 256 + ((c0 + 8 * i) ^ swz)] = ld[i];
      const ushort* pu = (const ushort*)&ld[i];
#pragma unroll
      for (int j = 0; j < 8; j++) csum[8 * i + j] += bf2f(pu[j]);
    }
  };

  auto compute = [&](int buf) {
#pragma unroll
    for (int ks = 0; ks < 2; ks++) {
      const int kb = ks * 16 + lhi * 8;
      FragU fr[6];
#pragma unroll
      for (int s = 0; s < 6; s++) {
        const int cbase = (s < 4) ? (wrow + 32 * s + l31) : (wcol + 32 * (s - 4) + l31);
#pragma unroll
        for (int j = 0; j < 8; j++)
          fr[s].u[j] = sb[buf][(kb + j) * 256 + (cbase ^ ((j & 3) << 4))];
      }
#pragma unroll
      for (int s = 0; s < 4; s++)
#pragma unroll
        for (int t = 0; t < 2; t++)
          acc[s][t] = __builtin_amdgcn_mfma_f32_32x32x16_bf16(fr[s].v, fr[4 + t].v,
                                                              acc[s][t], 0, 0, 0);
    }
  };

  if (nch > 0) {
    load_chunk(0);
    write_chunk(0);
    __syncthreads();
    int cur = 0;
    for (int c = 0; c < nch; c++) {
      if (c + 1 < nch) load_chunk(c + 1);
      compute(cur);
      if (c + 1 < nch) write_chunk(cur ^ 1);
      __syncthreads();
      cur ^= 1;
    }
  }

  // non-atomic partial-G slab write (k_Gr reduces the slabs)
  float* Gs = Gslab + (size_t)blockIdx.x * 65536;
#pragma unroll
  for (int s = 0; s < 4; s++)
#pragma unroll
    for (int t = 0; t < 2; t++) {
      const int n0 = wcol + 32 * t + l31;
#pragma unroll
      for (int r = 0; r < 16; r++) {
        const int row = wrow + 32 * s + (r & 3) + 8 * (r >> 2) + 4 * lhi;
        Gs[row * 256 + n0] = acc[s][t][r];
      }
    }

  float* fl = (float*)sb;
#pragma unroll
  for (int j = 0; j < 16; j++) fl[sk * 256 + c0 + j] = csum[j];
  __syncthreads();
  if (tid < 256) {
    float s = 0.0f;
    for (int r = 0; r < 32; r++) s += fl[r * 256 + tid];
    atomicAdd(&vsum[tid], s);
  }
}

// reduce slabs -> G
__global__ void k_Gr(const float* __restrict__ Gslab, float* __restrict__ G, int nslab) {
  const int i = blockIdx.x * 256 + threadIdx.x;
  float s0 = 0, s1 = 0, s2 = 0, s3 = 0;
  int b = 0;
  for (; b + 3 < nslab; b += 4) {
    s0 += Gslab[(size_t)b * 65536 + i];
    s1 += Gslab[(size_t)(b + 1) * 65536 + i];
    s2 += Gslab[(size_t)(b + 2) * 65536 + i];
    s3 += Gslab[(size_t)(b + 3) * 65536 + i];
  }
  float s = s0 + s1 + s2 + s3;
  for (; b < nslab; b++) s += Gslab[(size_t)b * 65536 + i];
  G[i] = s;
}

// per-iteration small products from (G, vsum); writes transposed bf16 Mt[n][k]
__global__ void k_small(const float* __restrict__ G, const float* __restrict__ vsum,
                        const float* __restrict__ P, const float* __restrict__ pb,
                        const float* __restrict__ wb, const float* __restrict__ sconst,
                        const float* __restrict__ Q, const float* __restrict__ K2,
                        ushort* __restrict__ Mt, float* __restrict__ cvec,
                        float* __restrict__ dvec, float* __restrict__ scal, int N) {
  __shared__ float red[4];
  const int b = blockIdx.x, tid = threadIdx.x;
  if (b < 256) {
    float acc = 0.0f;
    for (int m = 0; m < H; m++) acc = fmaf(P[b * H + m], G[m * H + tid], acc);
    Mt[(size_t)tid * H + b] = f2bf(acc + pb[b] * vsum[tid]);
  } else if (b == 256) {
    float acc = 0.0f;
    for (int f = 0; f < H; f++) acc = fmaf(wb[f], G[f * H + tid], acc);
    cvec[tid] = acc + sconst[0] * vsum[tid];
  } else if (b == 257) {
    float acc = 0.0f;
    for (int m = 0; m < H; m++) acc = fmaf(P[tid * H + m], vsum[m], acc);
    dvec[tid] = acc + (float)N * pb[tid];
  } else if (b < 274) {
    int base = (b - 258) * 4096 + tid;
    float a = 0.0f;
    for (int j = 0; j < 16; j++) a = fmaf(G[base + j * 256], Q[base + j * 256], a);
    a = block_sum(a, red);
    if (tid == 0) atomicAdd(&scal[0], a);
  } else {
    int base = (b - 274) * 4096 + tid;
    float a = 0.0f;
    for (int j = 0; j < 16; j++) a = fmaf(G[base + j * 256], K2[base + j * 256], a);
    a = block_sum(a, red);
    if (tid == 0) atomicAdd(&scal[1], a);
  }
}

// finalize norms
__global__ void k_final(const float* __restrict__ vsum, const float* __restrict__ qb,
                        const float* __restrict__ kb, const float* __restrict__ wb,
                        const float* __restrict__ sconst, float* __restrict__ scal, int N) {
  __shared__ float red[4];
  const int tid = threadIdx.x;
  float s1 = block_sum(qb[tid] * vsum[tid], red);
  float s2 = block_sum(kb[tid] * vsum[tid], red);
  float s3 = block_sum(wb[tid] * vsum[tid], red);
  if (tid == 0) {
    float sq = scal[0] + 2.0f * s1 + (float)N * sconst[1];
    float sk = scal[1] + 2.0f * s2 + (float)N * sconst[2];
    scal[2] = 1.0f / (sqrtf(sq) * sqrtf(sk));
    scal[3] = s3 + (float)N * sconst[0];
  }
}

// ---------------- MFMA num = R * M (bf16 in, bf16 out) ----------------
__global__ __launch_bounds__(512) void k_N(const ushort* __restrict__ Rb,
                                           const ushort* __restrict__ Mt,
                                           ushort* __restrict__ numb, int N) {
  const int tid = threadIdx.x;
  const int lane = tid & 63;
  const int wid = tid >> 6;
  const int l31 = lane & 31;
  const int lhi = lane >> 5;
  const int wrow = (wid & 3) * 32;
  const int wcol = (wid >> 2) * 128;
  const int rowbase = blockIdx.x * 128;

  f32x16 acc[4];
#pragma unroll
  for (int t = 0; t < 4; t++)
#pragma unroll
    for (int e = 0; e < 16; e++) acc[t][e] = 0.0f;

  const ushort* aptr = Rb + (size_t)(rowbase + wrow + l31) * H;

  for (int kc = 0; kc < 16; kc++) {
    const int kb = kc * 16 + lhi * 8;
    FragU fa;
    *(int4*)fa.u = *(const int4*)(aptr + kb);
    FragU fb0, fb1, fb2, fb3;
    *(int4*)fb0.u = *(const int4*)(Mt + (size_t)(wcol + 0 + l31) * H + kb);
    *(int4*)fb1.u = *(const int4*)(Mt + (size_t)(wcol + 32 + l31) * H + kb);
    *(int4*)fb2.u = *(const int4*)(Mt + (size_t)(wcol + 64 + l31) * H + kb);
    *(int4*)fb3.u = *(const int4*)(Mt + (size_t)(wcol + 96 + l31) * H + kb);
    acc[0] = __builtin_amdgcn_mfma_f32_32x32x16_bf16(fa.v, fb0.v, acc[0], 0, 0, 0);
    acc[1] = __builtin_amdgcn_mfma_f32_32x32x16_bf16(fa.v, fb1.v, acc[1], 0, 0, 0);
    acc[2] = __builtin_amdgcn_mfma_f32_32x32x16_bf16(fa.v, fb2.v, acc[2], 0, 0, 0);
    acc[3] = __builtin_amdgcn_mfma_f32_32x32x16_bf16(fa.v, fb3.v, acc[3], 0, 0, 0);
  }

#pragma unroll
  for (int t = 0; t < 4; t++) {
    const int col = wcol + 32 * t + l31;
#pragma unroll
    for (int r = 0; r < 16; r++) {
      const int row = rowbase + wrow + (r & 3) + 8 * (r >> 2) + 4 * lhi;
      if (row < N) numb[(size_t)row * H + col] = f2bf(acc[t][r]);
    }
  }
}

// slim fused: den, gcn gather (pre-scaled fp8 rows, 16-deep), attn from numb,
// residual blend, layernorm, write bf16 Rnext, readout. No LDS.
__global__ __launch_bounds__(256) void k_C(
    const ushort* __restrict__ Rb, ushort* __restrict__ Rnext,
    const ushort* __restrict__ numb, const unsigned* __restrict__ Rf8,
    const int* __restrict__ eb, const float* __restrict__ invs,
    const float* __restrict__ cvec, const float* __restrict__ dvec,
    const float* __restrict__ vsum, const float* __restrict__ scal,
    const int* __restrict__ offs16, const int* __restrict__ deg,
    const float* __restrict__ alphap, const float* __restrict__ gamma,
    const float* __restrict__ beta, const float* __restrict__ Wr,
    const float* __restrict__ br, const float* __restrict__ wgt,
    float* __restrict__ out, int N, int layer, int last) {
  const int tid = threadIdx.x, lane = tid & 63, wv = tid >> 6;
  const int d0 = lane * 4;
  const int n0 = blockIdx.x * 32 + wv * 8;

  const float invn = scal[2], denc = scal[3];
  const float al = alphap[0], om = 1.0f - al;
  const float4 dv = *(const float4*)&dvec[d0];
  const float4 cv = *(const float4*)&cvec[d0];
  const float4 vs = *(const float4*)&vsum[d0];
  const float4 gm = *(const float4*)&gamma[d0];
  const float4 bt = *(const float4*)&beta[d0];
  const float4 wr = *(const float4*)&Wr[layer * H + d0];
  const float wl = wgt[layer], bl = br[layer];

  for (int r = 0; r < 8; r++) {
    const int n = n0 + r;
    if (n >= N) break;  // uniform across the wave
    const ushort4 ro = *(const ushort4*)&Rb[(size_t)n * H + d0];
    const ushort4 no = *(const ushort4*)&numb[(size_t)n * H + d0];
    const float old0 = bf2f(ro.x), old1 = bf2f(ro.y), old2 = bf2f(ro.z), old3 = bf2f(ro.w);

    float p = old0 * dv.x + old1 * dv.y + old2 * dv.z + old3 * dv.w;
    p = wave_sum(p);
    const float rden = 1.0f / ((p + denc) * invn + (float)N);

    float a[4] = {0.0f, 0.0f, 0.0f, 0.0f};
    const int st = offs16[n];
    const int nb = (deg[n] + 15) >> 4;
    const int4* pe = (const int4*)(eb + st);
    for (int b = 0; b < nb; b++, pe += 4) {
      int4 q0 = pe[0], q1 = pe[1], q2 = pe[2], q3 = pe[3];
      unsigned g[16];
      g[0] = Rf8[((size_t)q0.x << 6) + lane];
      g[1] = Rf8[((size_t)q0.y << 6) + lane];
      g[2] = Rf8[((size_t)q0.z << 6) + lane];
      g[3] = Rf8[((size_t)q0.w << 6) + lane];
      g[4] = Rf8[((size_t)q1.x << 6) + lane];
      g[5] = Rf8[((size_t)q1.y << 6) + lane];
      g[6] = Rf8[((size_t)q1.z << 6) + lane];
      g[7] = Rf8[((size_t)q1.w << 6) + lane];
      g[8] = Rf8[((size_t)q2.x << 6) + lane];
      g[9] = Rf8[((size_t)q2.y << 6) + lane];
      g[10] = Rf8[((size_t)q2.z << 6) + lane];
      g[11] = Rf8[((size_t)q2.w << 6) + lane];
      g[12] = Rf8[((size_t)q3.x << 6) + lane];
      g[13] = Rf8[((size_t)q3.y << 6) + lane];
      g[14] = Rf8[((size_t)q3.z << 6) + lane];
      g[15] = Rf8[((size_t)q3.w << 6) + lane];
#pragma unroll
      for (int i = 0; i < 16; i++) unpack_fp8x4_acc(a, g[i]);
    }
    const float sn = invs[n];

    float hv0 = al * (((bf2f(no.x) + cv.x) * invn + vs.x) * rden + a[0] * sn) + om * old0;
    float hv1 = al * (((bf2f(no.y) + cv.y) * invn + vs.y) * rden + a[1] * sn) + om * old1;
    float hv2 = al * (((bf2f(no.z) + cv.z) * invn + vs.z) * rden + a[2] * sn) + om * old2;
    float hv3 = al * (((bf2f(no.w) + cv.w) * invn + vs.w) * rden + a[3] * sn) + om * old3;

    float s = wave_sum(hv0 + hv1 + hv2 + hv3);
    float mu = s * (1.0f / H);
    float s2 = wave_sum(hv0 * hv0 + hv1 * hv1 + hv2 * hv2 + hv3 * hv3);
    float var = s2 * (1.0f / H) - mu * mu;
    float rs = rsqrtf(var + LN_EPS);
    float y0 = (hv0 - mu) * rs * gm.x + bt.x;
    float y1 = (hv1 - mu) * rs * gm.y + bt.y;
    float y2 = (hv2 - mu) * rs * gm.z + bt.z;
    float y3 = (hv3 - mu) * rs * gm.w + bt.w;
    if (!last) {
      ushort4 o;
      o.x = f2bf(y0); o.y = f2bf(y1); o.z = f2bf(y2); o.w = f2bf(y3);
      *(ushort4*)&Rnext[(size_t)n * H + d0] = o;
    }
    float rp = wave_sum(y0 * wr.x + y1 * wr.y + y2 * wr.z + y3 * wr.w);
    if (lane == 0) out[n] += wl * (rp + bl);
  }
}

// ---------------- host ----------------

extern "C" void kernel_launch(void* const* d_in, const int* in_sizes, int n_in,
                              void* d_out, int out_size, void* d_ws, size_t ws_size,
                              hipStream_t stream) {
  const float* x = (const float*)d_in[0];
  const int* ei = (const int*)d_in[1];
  const float* W1 = (const float*)d_in[2];
  const float* b1 = (const float*)d_in[3];
  const float* Wq = (const float*)d_in[4];
  const float* bq = (const float*)d_in[5];
  const float* Wk = (const float*)d_in[6];
  const float* bk = (const float*)d_in[7];
  const float* gamma = (const float*)d_in[8];
  const float* beta = (const float*)d_in[9];
  const float* alphap = (const float*)d_in[10];
  const float* Wr = (const float*)d_in[11];
  const float* br = (const float*)d_in[12];
  const float* wgt = (const float*)d_in[13];
  float* out = (float*)d_out;

  const int N = in_sizes[0] / FIN;
  const int E = in_sizes[1] / 2;
  const int* row = ei;
  const int* col = ei + E;

  char* w = (char*)d_ws;
  auto alloc = [&](size_t bytes) -> char* {
    char* p = w;
    w += (bytes + 255) & ~(size_t)255;
    return p;
  };
  const size_t RB = (size_t)(N + 128) * H * sizeof(ushort);
  ushort* Rb0 = (ushort*)alloc(RB);
  ushort* Rb1 = (ushort*)alloc(RB);   // aliased as super-bin record scratch in setup
  ushort* numb = (ushort*)alloc(RB);  // aliased as G-slab scratch per iter
  unsigned* Rf8 = (unsigned*)alloc((size_t)(N + 1) * 64 * sizeof(unsigned));  // +1 zero row
  ushort* Mt = (ushort*)alloc(H * H * sizeof(ushort));
  float* G = (float*)alloc(H * H * sizeof(float));
  float* vsum = (float*)alloc(1024);
  float* scal = (float*)alloc(256);
  float* cvec = (float*)alloc(1024);
  float* dvec = (float*)alloc(1024);
  float* P = (float*)alloc(H * H * sizeof(float));
  float* Q = (float*)alloc(H * H * sizeof(float));
  float* K2 = (float*)alloc(H * H * sizeof(float));
  float* pb = (float*)alloc(1024);
  float* qb = (float*)alloc(1024);
  float* wb = (float*)alloc(1024);
  float* kb = (float*)alloc(1024);
  float* sconst = (float*)alloc(256);
  int* deg = (int*)alloc((size_t)N * 4);
  float* invs = (float*)alloc((size_t)N * 4);
  int* offs16 = (int*)alloc((size_t)(N + 1) * 4);
  int* bsum = (int*)alloc(1024 * 4);
  int* gcnt = (int*)alloc(64 * 4);
  size_t EPAD = (size_t)E + 16 * (size_t)N;
  EPAD = (EPAD + 3) & ~(size_t)3;
  int* eb = (int*)alloc(EPAD * sizeof(int));

  const int NSB = (N + (1 << SBW) - 1) >> SBW;  // super-bins (<=64 for N<=131072)
  int cap2 = (E / (NSB > 0 ? NSB : 1)) * 2 + 4096;
  cap2 = (cap2 + 3) & ~3;
  unsigned* breg = (unsigned*)Rb1;  // NSB*cap2*4B <= RB
  float* Gslab = (float*)numb;      // nbG*256KB <= RB

  hipMemsetAsync(gcnt, 0, 64 * 4, stream);
  hipMemsetAsync(Rf8 + (size_t)N * 64, 0, 64 * sizeof(unsigned), stream);

  const int gN = (N + 255) / 256;
  const int nblk = (N + 1023) / 1024;
  const int nbB1 = (E + EPB - 1) / EPB;
  k_b1<<<nbB1, 512, 0, stream>>>(row, col, breg, gcnt, cap2, E, NSB);
  k_degB2<<<NSB, 512, 0, stream>>>(breg, gcnt, cap2, deg, N);
  k_invsqrt<<<gN, 256, 0, stream>>>(deg, invs, N);
  k_scan1<<<nblk, 1024, 0, stream>>>(deg, offs16, bsum, N);
  k_scan2<<<1, 1024, 0, stream>>>(bsum, nblk);
  k_scan3<<<gN, 256, 0, stream>>>(offs16, bsum, N);
  k_b2<<<NSB, 512, 0, stream>>>(breg, gcnt, cap2, offs16, eb, N);
  k_prep<<<769, 256, 0, stream>>>(Wq, Wk, bq, bk, P, Q, K2, pb, qb, wb, kb, sconst);
  const int gRows16 = (N + 15) / 16;
  k_fc1<<<gRows16, 256, 0, stream>>>(x, W1, b1, Wr, br, wgt, Rb0, out, N);

  const int nbG = (N + ROWS_PB - 1) / ROWS_PB;
  const int nbN = (N + 127) / 128;
  const int gRows32 = (N + 31) / 32;
  const int total8 = N * (H / 8);
  ushort* Rc = Rb0;
  ushort* Rn = Rb1;
  for (int it = 1; it <= 3; ++it) {
    hipMemsetAsync(vsum, 0, 1024 + 256, stream);
    k_Gm<<<nbG, 512, 0, stream>>>(Rc, Gslab, vsum, N);
    k_Gr<<<256, 256, 0, stream>>>(Gslab, G, nbG);
    k_small<<<290, 256, 0, stream>>>(G, vsum, P, pb, wb, sconst, Q, K2, Mt, cvec, dvec, scal, N);
    k_final<<<1, 256, 0, stream>>>(vsum, qb, kb, wb, sconst, scal, N);
    k_tofp8<<<2048, 256, 0, stream>>>(Rc, invs, Rf8, total8);
    k_N<<<nbN, 512, 0, stream>>>(Rc, Mt, numb, N);
    k_C<<<gRows32, 256, 0, stream>>>(Rc, Rn, numb, Rf8, eb, invs, cvec, dvec, vsum, scal,
                                     offs16, deg, alphap, gamma, beta, Wr, br, wgt, out,
                                     N, it, (it == 3) ? 1 : 0);
    ushort* t = Rc; Rc = Rn; Rn = t;
  }
}

// Round 10
// 1212.348 us; speedup vs baseline: 4.2598x; 1.0293x over previous
//
#include <hip/hip_runtime.h>

#define H 256
#define FIN 58
#define LN_EPS 1e-5f
#define ROWS_PB 384  // k_Gm rows per block (12 chunks of 32) -> ~261 blocks
#define EPB 8192     // k_b1 edges per block
#define SBW 11       // super-bin width: 2048 dests

typedef __bf16 bf16x8 __attribute__((ext_vector_type(8)));
typedef float f32x16 __attribute__((ext_vector_type(16)));
typedef float f32x2 __attribute__((ext_vector_type(2)));

union FragU {
  ushort u[8];
  bf16x8 v;
};

// ---------------- utilities ----------------

__device__ __forceinline__ float wave_sum(float v) {
#pragma unroll
  for (int off = 1; off < 64; off <<= 1) v += __shfl_xor(v, off, 64);
  return v;
}

__device__ __forceinline__ float half_sum(float v) {  // width-32 (per half-wave)
#pragma unroll
  for (int off = 1; off < 32; off <<= 1) v += __shfl_xor(v, off, 64);
  return v;
}

__device__ __forceinline__ float block_sum(float v, volatile float* red) {
  const int tid = threadIdx.x;
  v = wave_sum(v);
  __syncthreads();
  if ((tid & 63) == 0) red[tid >> 6] = v;
  __syncthreads();
  return red[0] + red[1] + red[2] + red[3];
}

__device__ __forceinline__ ushort f2bf(float f) {
  unsigned u = __float_as_uint(f);
  unsigned r = (u + 0x7FFFu + ((u >> 16) & 1u)) >> 16;
  return (ushort)r;
}

__device__ __forceinline__ float bf2f(ushort u) {
  return __uint_as_float((unsigned)u << 16);
}

// ---- fp8 e4m3 pack/unpack (HW path on gfx950, manual fallback) ----
#if __has_builtin(__builtin_amdgcn_cvt_pk_fp8_f32) && __has_builtin(__builtin_amdgcn_cvt_pk_f32_fp8)
__device__ __forceinline__ unsigned pack_fp8x4(float a, float b, float c, float d) {
  int v = 0;
  v = __builtin_amdgcn_cvt_pk_fp8_f32(a, b, v, false);
  v = __builtin_amdgcn_cvt_pk_fp8_f32(c, d, v, true);
  return (unsigned)v;
}
__device__ __forceinline__ void unpack_fp8x2_acc(f32x2& lo, f32x2& hi, unsigned v) {
  lo += __builtin_amdgcn_cvt_pk_f32_fp8((int)v, false);
  hi += __builtin_amdgcn_cvt_pk_f32_fp8((int)v, true);
}
#else
__device__ __forceinline__ unsigned char f2e4m3_1(float f) {
  unsigned u = __float_as_uint(f);
  unsigned s = (u >> 31) << 7;
  float a = fabsf(f);
  if (a >= 448.0f) return (unsigned char)(s | 0x7E);
  if (a < 0.0009765625f) return (unsigned char)s;
  int e;
  float m = frexpf(a, &e);
  int E = e - 1 + 7;
  if (E >= 1) {
    int mm = (int)rintf((m * 2.0f - 1.0f) * 8.0f);
    if (mm == 8) { mm = 0; E++; }
    return (unsigned char)(s | (E << 3) | mm);
  }
  int mm = (int)rintf(a * 512.0f);
  if (mm > 7) return (unsigned char)(s | (1 << 3));
  return (unsigned char)(s | mm);
}
__device__ __forceinline__ unsigned pack_fp8x4(float a, float b, float c, float d) {
  return (unsigned)f2e4m3_1(a) | ((unsigned)f2e4m3_1(b) << 8) |
         ((unsigned)f2e4m3_1(c) << 16) | ((unsigned)f2e4m3_1(d) << 24);
}
__device__ __forceinline__ float e4m3f_1(unsigned v) {
  int s = (v >> 7) & 1, E = (v >> 3) & 15, m = v & 7;
  float mag = E ? ldexpf(1.0f + m * 0.125f, E - 7) : ldexpf((float)m, -9);
  return s ? -mag : mag;
}
__device__ __forceinline__ void unpack_fp8x2_acc(f32x2& lo, f32x2& hi, unsigned v) {
  lo[0] += e4m3f_1(v & 255);
  lo[1] += e4m3f_1((v >> 8) & 255);
  hi[0] += e4m3f_1((v >> 16) & 255);
  hi[1] += e4m3f_1(v >> 24);
}
#endif

// ---------------- setup: radix-style CSR build ----------------

__global__ __launch_bounds__(512) void k_b1(const int* __restrict__ row,
                                            const int* __restrict__ col,
                                            unsigned* __restrict__ breg,
                                            int* __restrict__ gcnt,
                                            int cap2, int E, int nsb) {
  __shared__ unsigned stage[EPB];  // 32 KB
  __shared__ int lh[65], lbase[65], lcur[64], gclaim[64];
  const int tid = threadIdx.x;
  const int e0 = blockIdx.x * EPB;
  const int cnt = min(EPB, E - e0);
  if (tid < 64) lh[tid] = 0;
  __syncthreads();
  for (int i = tid; i < cnt; i += 512) atomicAdd(&lh[col[e0 + i] >> SBW], 1);
  __syncthreads();
  if (tid == 0) {
    int acc = 0;
    for (int b = 0; b < nsb; b++) { lbase[b] = acc; acc += lh[b]; }
    lbase[nsb] = acc;
  }
  __syncthreads();
  if (tid < nsb) {
    gclaim[tid] = atomicAdd(&gcnt[tid], lh[tid]);
    lcur[tid] = lbase[tid];
  }
  __syncthreads();
  for (int i = tid; i < cnt; i += 512) {
    int c = col[e0 + i];
    int b = c >> SBW;
    int s = atomicAdd(&lcur[b], 1);
    stage[s] = ((unsigned)row[e0 + i] << SBW) | (unsigned)(c & ((1 << SBW) - 1));
  }
  __syncthreads();
  for (int i = tid; i < cnt; i += 512) {
    int lo = 0, hi = nsb;
    while (hi - lo > 1) {
      int mid = (lo + hi) >> 1;
      if (lbase[mid] <= i) lo = mid; else hi = mid;
    }
    int off = gclaim[lo] + (i - lbase[lo]);
    if (off < cap2) breg[(size_t)lo * cap2 + off] = stage[i];
  }
}

__global__ __launch_bounds__(512) void k_degB2(const unsigned* __restrict__ breg,
                                               const int* __restrict__ gcnt, int cap2,
                                               int* __restrict__ deg, int N) {
  __shared__ int lcnt[1 << SBW];
  const int b = blockIdx.x, tid = threadIdx.x, base = b << SBW;
  for (int i = tid; i < (1 << SBW); i += 512) lcnt[i] = 0;
  __syncthreads();
  const int cnt = min(gcnt[b], cap2);
  const unsigned* p = breg + (size_t)b * cap2;
  for (int i = tid; i < cnt; i += 512) atomicAdd(&lcnt[p[i] & ((1 << SBW) - 1)], 1);
  __syncthreads();
  for (int i = tid; i < (1 << SBW); i += 512) {
    int d = base + i;
    if (d < N) deg[d] = lcnt[i];
  }
}

__global__ __launch_bounds__(512) void k_b2(const unsigned* __restrict__ breg,
                                            const int* __restrict__ gcnt, int cap2,
                                            const int* __restrict__ offs16,
                                            int* __restrict__ eb, int N) {
  __shared__ int loffs[1 << SBW];
  __shared__ int lcur[1 << SBW];
  const int b = blockIdx.x, tid = threadIdx.x, base = b << SBW;
  for (int i = tid; i < (1 << SBW); i += 512) {
    int d = base + i;
    loffs[i] = (d < N) ? offs16[d] : 0;
    lcur[i] = 0;
  }
  __syncthreads();
  const int cnt = min(gcnt[b], cap2);
  const unsigned* p = breg + (size_t)b * cap2;
  for (int i = tid; i < cnt; i += 512) {
    unsigned rc = p[i];
    int lc = rc & ((1 << SBW) - 1);
    int slot = atomicAdd(&lcur[lc], 1);
    eb[loffs[lc] + slot] = (int)(rc >> SBW);
  }
  __syncthreads();
  for (int i = tid; i < (1 << SBW); i += 512) {
    int d = base + i;
    if (d < N) {
      int c = lcur[i];
      int pad = (c + 15) & ~15;
      int o = loffs[i];
      for (int j = c; j < pad; j++) eb[o + j] = N;
    }
  }
}

__global__ void k_invsqrt(const int* __restrict__ deg, float* __restrict__ invs, int N) {
  int i = blockIdx.x * 256 + threadIdx.x;
  if (i < N) {
    int d = deg[i];
    invs[i] = (d > 0) ? (1.0f / sqrtf((float)d)) : 0.0f;
  }
}

__global__ __launch_bounds__(1024) void k_scan1(const int* __restrict__ deg,
                                                int* __restrict__ offs16,
                                                int* __restrict__ bsum, int N) {
  __shared__ int buf[1024];
  const int tid = threadIdx.x;
  const int gid = blockIdx.x * 1024 + tid;
  int v = (gid < N) ? ((deg[gid] + 15) & ~15) : 0;
  buf[tid] = v;
  __syncthreads();
  for (int off = 1; off < 1024; off <<= 1) {
    int x = (tid >= off) ? buf[tid - off] : 0;
    __syncthreads();
    buf[tid] += x;
    __syncthreads();
  }
  if (gid < N) offs16[gid] = buf[tid] - v;
  if (tid == 1023) bsum[blockIdx.x] = buf[1023];
}

__global__ __launch_bounds__(1024) void k_scan2(int* __restrict__ bsum, int nb) {
  __shared__ int buf[1024];
  const int tid = threadIdx.x;
  int v = (tid < nb) ? bsum[tid] : 0;
  buf[tid] = v;
  __syncthreads();
  for (int off = 1; off < 1024; off <<= 1) {
    int x = (tid >= off) ? buf[tid - off] : 0;
    __syncthreads();
    buf[tid] += x;
    __syncthreads();
  }
  if (tid < nb) bsum[tid] = buf[tid] - v;
}

__global__ void k_scan3(int* __restrict__ offs16, const int* __restrict__ bsum, int N) {
  int i = blockIdx.x * 256 + threadIdx.x;
  if (i < N) offs16[i] += bsum[i >> 10];
}

// iteration-independent weight products
__global__ void k_prep(const float* __restrict__ Wq, const float* __restrict__ Wk,
                       const float* __restrict__ bq, const float* __restrict__ bk,
                       float* __restrict__ P, float* __restrict__ Q, float* __restrict__ K2,
                       float* __restrict__ pb, float* __restrict__ qb,
                       float* __restrict__ wb, float* __restrict__ kb,
                       float* __restrict__ sconst) {
  __shared__ float red[4];
  const int b = blockIdx.x, tid = threadIdx.x;
  if (b < 768) {
    const int f = b & 255, which = b >> 8;
    const float* A = (which == 2) ? Wk : Wq;
    const float* Bm = (which == 1) ? Wq : Wk;
    float acc = 0.0f;
    for (int m = 0; m < H; m++) acc = fmaf(A[f * H + m], Bm[tid * H + m], acc);
    float* D = (which == 0) ? P : ((which == 1) ? Q : K2);
    D[f * H + tid] = acc;
  } else {
    float a1 = 0, a2 = 0, a3 = 0, a4 = 0;
    for (int m = 0; m < H; m++) {
      float wqv = Wq[tid * H + m], wkv = Wk[tid * H + m];
      a1 = fmaf(wqv, bk[m], a1);
      a2 = fmaf(wqv, bq[m], a2);
      a3 = fmaf(wkv, bq[m], a3);
      a4 = fmaf(wkv, bk[m], a4);
    }
    pb[tid] = a1; qb[tid] = a2; wb[tid] = a3; kb[tid] = a4;
    float c0 = block_sum(bq[tid] * bk[tid], red);
    float c1 = block_sum(bq[tid] * bq[tid], red);
    float c2 = block_sum(bk[tid] * bk[tid], red);
    if (tid == 0) { sconst[0] = c0; sconst[1] = c1; sconst[2] = c2; }
  }
}

// R0 = relu(x@W1 + b1) -> bf16, plus layer-0 readout
__global__ void k_fc1(const float* __restrict__ x, const float* __restrict__ W1,
                      const float* __restrict__ b1, const float* __restrict__ Wr,
                      const float* __restrict__ br, const float* __restrict__ wgt,
                      ushort* __restrict__ R0, float* __restrict__ out, int N) {
  __shared__ __align__(16) float lx[16 * FIN];
  __shared__ float red2[4][16];
  const int tid = threadIdx.x;
  const int n0 = blockIdx.x * 16;
  for (int idx = tid; idx < 16 * FIN / 4; idx += 256)
    ((float4*)lx)[idx] = ((const float4*)(x + (size_t)n0 * FIN))[idx];
  __syncthreads();
  float acc[16];
  const float bias = b1[tid];
#pragma unroll
  for (int r = 0; r < 16; r++) acc[r] = bias;
  for (int f = 0; f < FIN; f++) {
    float wv = W1[f * H + tid];
#pragma unroll
    for (int r = 0; r < 16; r++) acc[r] = fmaf(lx[r * FIN + f], wv, acc[r]);
  }
  const float wr0 = Wr[tid];
#pragma unroll
  for (int r = 0; r < 16; r++) {
    acc[r] = fmaxf(acc[r], 0.0f);
    int n = n0 + r;
    if (n < N) R0[(size_t)n * H + tid] = f2bf(acc[r]);
  }
#pragma unroll
  for (int r = 0; r < 16; r++) {
    float s = wave_sum(acc[r] * wr0);
    if ((tid & 63) == 0) red2[tid >> 6][r] = s;
  }
  __syncthreads();
  if (tid < 16) {
    int n = n0 + tid;
    if (n < N)
      out[n] = wgt[0] * (red2[0][tid] + red2[1][tid] + red2[2][tid] + red2[3][tid] + br[0]);
  }
}

// ---------------- MFMA G = R^T R (+ vsum + fused fp8 production) ----------------
// bf16 slabs (non-atomic), 261 blocks cover all CUs; Rf8 written during staging.
__global__ __launch_bounds__(512, 2) void k_Gm(const ushort* __restrict__ Rb,
                                               const float* __restrict__ invs,
                                               ushort* __restrict__ Gslab,
                                               unsigned* __restrict__ Rf8,
                                               float* __restrict__ vsum, int N) {
  __shared__ ushort sb[2][32 * 256];  // 32 KB
  const int tid = threadIdx.x;
  const int lane = tid & 63;
  const int wid = tid >> 6;
  const int wrow = (wid & 1) * 128;
  const int wcol = (wid >> 1) * 64;
  const int l31 = lane & 31;
  const int lhi = lane >> 5;

  const int rowbase = blockIdx.x * ROWS_PB;
  const int nrows = min(ROWS_PB, N - rowbase);
  const int nch = (nrows + 31) >> 5;

  const int sk = tid >> 4;
  const int c0 = (tid & 15) * 16;

  f32x16 acc[4][2];
#pragma unroll
  for (int s = 0; s < 4; s++)
#pragma unroll
    for (int t = 0; t < 2; t++)
#pragma unroll
      for (int e = 0; e < 16; e++) acc[s][t][e] = 0.0f;

  float csum[16];
#pragma unroll
  for (int i = 0; i < 16; i++) csum[i] = 0.0f;

  int4 ld[2];

  auto load_chunk = [&](int ch) {
    int g = rowbase + ch * 32 + sk;
    const int4* src = (const int4*)(Rb + (size_t)g * H + c0);
    ld[0] = (g < N) ? src[0] : make_int4(0, 0, 0, 0);
    ld[1] = (g < N) ? src[1] : make_int4(0, 0, 0, 0);
  };

  auto write_chunk = [&](int ch, int buf) {
    int g = rowbase + ch * 32 + sk;
    const int swz = (sk & 3) << 4;
    const float sc = (g < N) ? invs[g] : 0.0f;
    unsigned w8[4];
#pragma unroll
    for (int i = 0; i < 2; i++) {
      *(int4*)&sb[buf][sk * 256 + ((c0 + 8 * i) ^ swz)] = ld[i];
      const ushort* pu = (const ushort*)&ld[i];
#pragma unroll
      for (int j = 0; j < 8; j++) csum[8 * i + j] += bf2f(pu[j]);
      w8[2 * i] = pack_fp8x4(bf2f(pu[0]) * sc, bf2f(pu[1]) * sc,
                             bf2f(pu[2]) * sc, bf2f(pu[3]) * sc);
      w8[2 * i + 1] = pack_fp8x4(bf2f(pu[4]) * sc, bf2f(pu[5]) * sc,
                                 bf2f(pu[6]) * sc, bf2f(pu[7]) * sc);
    }
    if (g < N)
      *(uint4*)&Rf8[(size_t)g * 64 + (c0 >> 2)] = make_uint4(w8[0], w8[1], w8[2], w8[3]);
  };

  auto compute = [&](int buf) {
#pragma unroll
    for (int ks = 0; ks < 2; ks++) {
      const int kb = ks * 16 + lhi * 8;
      FragU fr[6];
#pragma unroll
      for (int s = 0; s < 6; s++) {
        const int cbase = (s < 4) ? (wrow + 32 * s + l31) : (wcol + 32 * (s - 4) + l31);
#pragma unroll
        for (int j = 0; j < 8; j++)
          fr[s].u[j] = sb[buf][(kb + j) * 256 + (cbase ^ ((j & 3) << 4))];
      }
#pragma unroll
      for (int s = 0; s < 4; s++)
#pragma unroll
        for (int t = 0; t < 2; t++)
          acc[s][t] = __builtin_amdgcn_mfma_f32_32x32x16_bf16(fr[s].v, fr[4 + t].v,
                                                              acc[s][t], 0, 0, 0);
    }
  };

  if (nch > 0) {
    load_chunk(0);
    write_chunk(0, 0);
    __syncthreads();
    int cur = 0;
    for (int c = 0; c < nch; c++) {
      if (c + 1 < nch) load_chunk(c + 1);
      compute(cur);
      if (c + 1 < nch) write_chunk(c + 1, cur ^ 1);
      __syncthreads();
      cur ^= 1;
    }
  }

  // non-atomic bf16 partial-G slab write (k_Gr reduces the slabs)
  ushort* Gs = Gslab + (size_t)blockIdx.x * 65536;
#pragma unroll
  for (int s = 0; s < 4; s++)
#pragma unroll
    for (int t = 0; t < 2; t++) {
      const int n0c = wcol + 32 * t + l31;
#pragma unroll
      for (int r = 0; r < 16; r++) {
        const int row = wrow + 32 * s + (r & 3) + 8 * (r >> 2) + 4 * lhi;
        Gs[row * 256 + n0c] = f2bf(acc[s][t][r]);
      }
    }

  float* fl = (float*)sb;
#pragma unroll
  for (int j = 0; j < 16; j++) fl[sk * 256 + c0 + j] = csum[j];
  __syncthreads();
  if (tid < 256) {
    float s = 0.0f;
    for (int r = 0; r < 32; r++) s += fl[r * 256 + tid];
    atomicAdd(&vsum[tid], s);
  }
}

// reduce bf16 slabs -> fp32 G
__global__ void k_Gr(const ushort* __restrict__ Gslab, float* __restrict__ G, int nslab) {
  const int i = blockIdx.x * 256 + threadIdx.x;
  float s0 = 0, s1 = 0, s2 = 0, s3 = 0;
  int b = 0;
  for (; b + 3 < nslab; b += 4) {
    s0 += bf2f(Gslab[(size_t)b * 65536 + i]);
    s1 += bf2f(Gslab[(size_t)(b + 1) * 65536 + i]);
    s2 += bf2f(Gslab[(size_t)(b + 2) * 65536 + i]);
    s3 += bf2f(Gslab[(size_t)(b + 3) * 65536 + i]);
  }
  float s = s0 + s1 + s2 + s3;
  for (; b < nslab; b++) s += bf2f(Gslab[(size_t)b * 65536 + i]);
  G[i] = s;
}

// per-iteration small products from (G, vsum); writes transposed bf16 Mt[n][k]
__global__ void k_small(const float* __restrict__ G, const float* __restrict__ vsum,
                        const float* __restrict__ P, const float* __restrict__ pb,
                        const float* __restrict__ wb, const float* __restrict__ sconst,
                        const float* __restrict__ Q, const float* __restrict__ K2,
                        ushort* __restrict__ Mt, float* __restrict__ cvec,
                        float* __restrict__ dvec, float* __restrict__ scal, int N) {
  __shared__ float red[4];
  const int b = blockIdx.x, tid = threadIdx.x;
  if (b < 256) {
    float acc = 0.0f;
    for (int m = 0; m < H; m++) acc = fmaf(P[b * H + m], G[m * H + tid], acc);
    Mt[(size_t)tid * H + b] = f2bf(acc + pb[b] * vsum[tid]);
  } else if (b == 256) {
    float acc = 0.0f;
    for (int f = 0; f < H; f++) acc = fmaf(wb[f], G[f * H + tid], acc);
    cvec[tid] = acc + sconst[0] * vsum[tid];
  } else if (b == 257) {
    float acc = 0.0f;
    for (int m = 0; m < H; m++) acc = fmaf(P[tid * H + m], vsum[m], acc);
    dvec[tid] = acc + (float)N * pb[tid];
  } else if (b < 274) {
    int base = (b - 258) * 4096 + tid;
    float a = 0.0f;
    for (int j = 0; j < 16; j++) a = fmaf(G[base + j * 256], Q[base + j * 256], a);
    a = block_sum(a, red);
    if (tid == 0) atomicAdd(&scal[0], a);
  } else {
    int base = (b - 274) * 4096 + tid;
    float a = 0.0f;
    for (int j = 0; j < 16; j++) a = fmaf(G[base + j * 256], K2[base + j * 256], a);
    a = block_sum(a, red);
    if (tid == 0) atomicAdd(&scal[1], a);
  }
}

// finalize norms
__global__ void k_final(const float* __restrict__ vsum, const float* __restrict__ qb,
                        const float* __restrict__ kb, const float* __restrict__ wb,
                        const float* __restrict__ sconst, float* __restrict__ scal, int N) {
  __shared__ float red[4];
  const int tid = threadIdx.x;
  float s1 = block_sum(qb[tid] * vsum[tid], red);
  float s2 = block_sum(kb[tid] * vsum[tid], red);
  float s3 = block_sum(wb[tid] * vsum[tid], red);
  if (tid == 0) {
    float sq = scal[0] + 2.0f * s1 + (float)N * sconst[1];
    float sk = scal[1] + 2.0f * s2 + (float)N * sconst[2];
    scal[2] = 1.0f / (sqrtf(sq) * sqrtf(sk));
    scal[3] = s3 + (float)N * sconst[0];
  }
}

// ---------------- MFMA num = R * M (bf16 in, bf16 out) ----------------
__global__ __launch_bounds__(512) void k_N(const ushort* __restrict__ Rb,
                                           const ushort* __restrict__ Mt,
                                           ushort* __restrict__ numb, int N) {
  const int tid = threadIdx.x;
  const int lane = tid & 63;
  const int wid = tid >> 6;
  const int l31 = lane & 31;
  const int lhi = lane >> 5;
  const int wrow = (wid & 3) * 32;
  const int wcol = (wid >> 2) * 128;
  const int rowbase = blockIdx.x * 128;

  f32x16 acc[4];
#pragma unroll
  for (int t = 0; t < 4; t++)
#pragma unroll
    for (int e = 0; e < 16; e++) acc[t][e] = 0.0f;

  const ushort* aptr = Rb + (size_t)(rowbase + wrow + l31) * H;

  for (int kc = 0; kc < 16; kc++) {
    const int kb = kc * 16 + lhi * 8;
    FragU fa;
    *(int4*)fa.u = *(const int4*)(aptr + kb);
    FragU fb0, fb1, fb2, fb3;
    *(int4*)fb0.u = *(const int4*)(Mt + (size_t)(wcol + 0 + l31) * H + kb);
    *(int4*)fb1.u = *(const int4*)(Mt + (size_t)(wcol + 32 + l31) * H + kb);
    *(int4*)fb2.u = *(const int4*)(Mt + (size_t)(wcol + 64 + l31) * H + kb);
    *(int4*)fb3.u = *(const int4*)(Mt + (size_t)(wcol + 96 + l31) * H + kb);
    acc[0] = __builtin_amdgcn_mfma_f32_32x32x16_bf16(fa.v, fb0.v, acc[0], 0, 0, 0);
    acc[1] = __builtin_amdgcn_mfma_f32_32x32x16_bf16(fa.v, fb1.v, acc[1], 0, 0, 0);
    acc[2] = __builtin_amdgcn_mfma_f32_32x32x16_bf16(fa.v, fb2.v, acc[2], 0, 0, 0);
    acc[3] = __builtin_amdgcn_mfma_f32_32x32x16_bf16(fa.v, fb3.v, acc[3], 0, 0, 0);
  }

#pragma unroll
  for (int t = 0; t < 4; t++) {
    const int col = wcol + 32 * t + l31;
#pragma unroll
    for (int r = 0; r < 16; r++) {
      const int row = rowbase + wrow + (r & 3) + 8 * (r >> 2) + 4 * lhi;
      if (row < N) numb[(size_t)row * H + col] = f2bf(acc[t][r]);
    }
  }
}

// slim fused: half-wave per row (8 dims/lane), gather 2 rows per load (uint2
// fp8), packed f32x2 accumulate, den/LN via width-32 reductions. No LDS.
__global__ __launch_bounds__(256) void k_C(
    const ushort* __restrict__ Rb, ushort* __restrict__ Rnext,
    const ushort* __restrict__ numb, const unsigned* __restrict__ Rf8,
    const int* __restrict__ eb, const float* __restrict__ invs,
    const float* __restrict__ cvec, const float* __restrict__ dvec,
    const float* __restrict__ vsum, const float* __restrict__ scal,
    const int* __restrict__ offs16, const int* __restrict__ deg,
    const float* __restrict__ alphap, const float* __restrict__ gamma,
    const float* __restrict__ beta, const float* __restrict__ Wr,
    const float* __restrict__ br, const float* __restrict__ wgt,
    float* __restrict__ out, int N, int layer, int last) {
  const int tid = threadIdx.x, lane = tid & 63, wv = tid >> 6;
  const int half = lane >> 5, hl = lane & 31;
  const int d0 = hl * 8;
  const int n0 = blockIdx.x * 32 + wv * 8;

  const float invn = scal[2], denc = scal[3];
  const float al = alphap[0], om = 1.0f - al;
  const float4 dvA = *(const float4*)&dvec[d0];
  const float4 dvB = *(const float4*)&dvec[d0 + 4];
  const float4 cvA = *(const float4*)&cvec[d0];
  const float4 cvB = *(const float4*)&cvec[d0 + 4];
  const float4 vsA = *(const float4*)&vsum[d0];
  const float4 vsB = *(const float4*)&vsum[d0 + 4];
  const float4 gmA = *(const float4*)&gamma[d0];
  const float4 gmB = *(const float4*)&gamma[d0 + 4];
  const float4 btA = *(const float4*)&beta[d0];
  const float4 btB = *(const float4*)&beta[d0 + 4];
  const float4 wrA = *(const float4*)&Wr[layer * H + d0];
  const float4 wrB = *(const float4*)&Wr[layer * H + d0 + 4];
  const float wl = wgt[layer], bl = br[layer];

  for (int r = 0; r < 4; r++) {
    const int n = n0 + r * 2 + half;
    const bool valid = n < N;
    const int ns = valid ? n : 0;

    const int4 rv = *(const int4*)&Rb[(size_t)ns * H + d0];
    const int4 nv = *(const int4*)&numb[(size_t)ns * H + d0];
    const ushort* rp = (const ushort*)&rv;
    const ushort* np = (const ushort*)&nv;
    float old[8], num[8];
#pragma unroll
    for (int j = 0; j < 8; j++) { old[j] = bf2f(rp[j]); num[j] = bf2f(np[j]); }

    float p = old[0] * dvA.x + old[1] * dvA.y + old[2] * dvA.z + old[3] * dvA.w +
              old[4] * dvB.x + old[5] * dvB.y + old[6] * dvB.z + old[7] * dvB.w;
    p = half_sum(p);
    const float rden = 1.0f / ((p + denc) * invn + (float)N);

    f32x2 a01 = {0.f, 0.f}, a23 = {0.f, 0.f}, a45 = {0.f, 0.f}, a67 = {0.f, 0.f};
    const int st = offs16[ns];
    const int nbch = valid ? ((deg[ns] + 15) >> 4) : 0;
    const int4* pe = (const int4*)(eb + st);
    const int woff = hl * 2;
    for (int b = 0; b < nbch; b++, pe += 4) {
      int4 q0 = pe[0], q1 = pe[1], q2 = pe[2], q3 = pe[3];
      const int srcs[16] = {q0.x, q0.y, q0.z, q0.w, q1.x, q1.y, q1.z, q1.w,
                            q2.x, q2.y, q2.z, q2.w, q3.x, q3.y, q3.z, q3.w};
      uint2 g[16];
#pragma unroll
      for (int i = 0; i < 16; i++)
        g[i] = *(const uint2*)&Rf8[((size_t)srcs[i] << 6) + woff];
#pragma unroll
      for (int i = 0; i < 16; i++) {
        unpack_fp8x2_acc(a01, a23, g[i].x);
        unpack_fp8x2_acc(a45, a67, g[i].y);
      }
    }
    const float sn = invs[ns];
    float ag[8] = {a01[0] * sn, a01[1] * sn, a23[0] * sn, a23[1] * sn,
                   a45[0] * sn, a45[1] * sn, a67[0] * sn, a67[1] * sn};

    const float cva[8] = {cvA.x, cvA.y, cvA.z, cvA.w, cvB.x, cvB.y, cvB.z, cvB.w};
    const float vsa[8] = {vsA.x, vsA.y, vsA.z, vsA.w, vsB.x, vsB.y, vsB.z, vsB.w};
    float hv[8];
#pragma unroll
    for (int j = 0; j < 8; j++)
      hv[j] = al * (((num[j] + cva[j]) * invn + vsa[j]) * rden + ag[j]) + om * old[j];

    float s = 0.0f, s2 = 0.0f;
#pragma unroll
    for (int j = 0; j < 8; j++) { s += hv[j]; s2 += hv[j] * hv[j]; }
    s = half_sum(s);
    s2 = half_sum(s2);
    const float mu = s * (1.0f / H);
    const float var = s2 * (1.0f / H) - mu * mu;
    const float rs = rsqrtf(var + LN_EPS);

    const float gma[8] = {gmA.x, gmA.y, gmA.z, gmA.w, gmB.x, gmB.y, gmB.z, gmB.w};
    const float bta[8] = {btA.x, btA.y, btA.z, btA.w, btB.x, btB.y, btB.z, btB.w};
    const float wra[8] = {wrA.x, wrA.y, wrA.z, wrA.w, wrB.x, wrB.y, wrB.z, wrB.w};
    float y[8], rp2 = 0.0f;
    ushort yo[8];
#pragma unroll
    for (int j = 0; j < 8; j++) {
      y[j] = (hv[j] - mu) * rs * gma[j] + bta[j];
      yo[j] = f2bf(y[j]);
      rp2 += y[j] * wra[j];
    }
    if (!last && valid) *(int4*)&Rnext[(size_t)n * H + d0] = *(int4*)yo;
    rp2 = half_sum(rp2);
    if (hl == 0 && valid) out[n] += wl * (rp2 + bl);
  }
}

// ---------------- host ----------------

extern "C" void kernel_launch(void* const* d_in, const int* in_sizes, int n_in,
                              void* d_out, int out_size, void* d_ws, size_t ws_size,
                              hipStream_t stream) {
  const float* x = (const float*)d_in[0];
  const int* ei = (const int*)d_in[1];
  const float* W1 = (const float*)d_in[2];
  const float* b1 = (const float*)d_in[3];
  const float* Wq = (const float*)d_in[4];
  const float* bq = (const float*)d_in[5];
  const float* Wk = (const float*)d_in[6];
  const float* bk = (const float*)d_in[7];
  const float* gamma = (const float*)d_in[8];
  const float* beta = (const float*)d_in[9];
  const float* alphap = (const float*)d_in[10];
  const float* Wr = (const float*)d_in[11];
  const float* br = (const float*)d_in[12];
  const float* wgt = (const float*)d_in[13];
  float* out = (float*)d_out;

  const int N = in_sizes[0] / FIN;
  const int E = in_sizes[1] / 2;
  const int* row = ei;
  const int* col = ei + E;

  char* w = (char*)d_ws;
  auto alloc = [&](size_t bytes) -> char* {
    char* p = w;
    w += (bytes + 255) & ~(size_t)255;
    return p;
  };
  const size_t RB = (size_t)(N + 128) * H * sizeof(ushort);
  ushort* Rb0 = (ushort*)alloc(RB);
  ushort* Rb1 = (ushort*)alloc(RB);   // aliased as super-bin record scratch in setup
  ushort* numb = (ushort*)alloc(RB);  // aliased as bf16 G-slab scratch per iter
  unsigned* Rf8 = (unsigned*)alloc((size_t)(N + 1) * 64 * sizeof(unsigned));  // +1 zero row
  ushort* Mt = (ushort*)alloc(H * H * sizeof(ushort));
  float* G = (float*)alloc(H * H * sizeof(float));
  float* vsum = (float*)alloc(1024);
  float* scal = (float*)alloc(256);
  float* cvec = (float*)alloc(1024);
  float* dvec = (float*)alloc(1024);
  float* P = (float*)alloc(H * H * sizeof(float));
  float* Q = (float*)alloc(H * H * sizeof(float));
  float* K2 = (float*)alloc(H * H * sizeof(float));
  float* pb = (float*)alloc(1024);
  float* qb = (float*)alloc(1024);
  float* wb = (float*)alloc(1024);
  float* kb = (float*)alloc(1024);
  float* sconst = (float*)alloc(256);
  int* deg = (int*)alloc((size_t)N * 4);
  float* invs = (float*)alloc((size_t)N * 4);
  int* offs16 = (int*)alloc((size_t)(N + 1) * 4);
  int* bsum = (int*)alloc(1024 * 4);
  int* gcnt = (int*)alloc(64 * 4);
  size_t EPAD = (size_t)E + 16 * (size_t)N;
  EPAD = (EPAD + 3) & ~(size_t)3;
  int* eb = (int*)alloc(EPAD * sizeof(int));

  const int NSB = (N + (1 << SBW) - 1) >> SBW;  // super-bins (<=64 for N<=131072)
  int cap2 = (E / (NSB > 0 ? NSB : 1)) * 2 + 4096;
  cap2 = (cap2 + 3) & ~3;
  unsigned* breg = (unsigned*)Rb1;  // NSB*cap2*4B <= RB
  ushort* Gslab = (ushort*)numb;    // nbG*128KB <= RB

  hipMemsetAsync(gcnt, 0, 64 * 4, stream);
  hipMemsetAsync(Rf8 + (size_t)N * 64, 0, 64 * sizeof(unsigned), stream);

  const int gN = (N + 255) / 256;
  const int nblk = (N + 1023) / 1024;
  const int nbB1 = (E + EPB - 1) / EPB;
  k_b1<<<nbB1, 512, 0, stream>>>(row, col, breg, gcnt, cap2, E, NSB);
  k_degB2<<<NSB, 512, 0, stream>>>(breg, gcnt, cap2, deg, N);
  k_invsqrt<<<gN, 256, 0, stream>>>(deg, invs, N);
  k_scan1<<<nblk, 1024, 0, stream>>>(deg, offs16, bsum, N);
  k_scan2<<<1, 1024, 0, stream>>>(bsum, nblk);
  k_scan3<<<gN, 256, 0, stream>>>(offs16, bsum, N);
  k_b2<<<NSB, 512, 0, stream>>>(breg, gcnt, cap2, offs16, eb, N);
  k_prep<<<769, 256, 0, stream>>>(Wq, Wk, bq, bk, P, Q, K2, pb, qb, wb, kb, sconst);
  const int gRows16 = (N + 15) / 16;
  k_fc1<<<gRows16, 256, 0, stream>>>(x, W1, b1, Wr, br, wgt, Rb0, out, N);

  const int nbG = (N + ROWS_PB - 1) / ROWS_PB;
  const int nbN = (N + 127) / 128;
  const int gRows32 = (N + 31) / 32;
  ushort* Rc = Rb0;
  ushort* Rn = Rb1;
  for (int it = 1; it <= 3; ++it) {
    hipMemsetAsync(vsum, 0, 1024 + 256, stream);
    k_Gm<<<nbG, 512, 0, stream>>>(Rc, invs, Gslab, Rf8, vsum, N);
    k_Gr<<<256, 256, 0, stream>>>(Gslab, G, nbG);
    k_small<<<290, 256, 0, stream>>>(G, vsum, P, pb, wb, sconst, Q, K2, Mt, cvec, dvec, scal, N);
    k_final<<<1, 256, 0, stream>>>(vsum, qb, kb, wb, sconst, scal, N);
    k_N<<<nbN, 512, 0, stream>>>(Rc, Mt, numb, N);
    k_C<<<gRows32, 256, 0, stream>>>(Rc, Rn, numb, Rf8, eb, invs, cvec, dvec, vsum, scal,
                                     offs16, deg, alphap, gamma, beta, Wr, br, wgt, out,
                                     N, it, (it == 3) ? 1 : 0);
    ushort* t = Rc; Rc = Rn; Rn = t;
  }
}

// Round 11
// 1163.191 us; speedup vs baseline: 4.4398x; 1.0423x over previous
//
#include <hip/hip_runtime.h>

#define H 256
#define FIN 58
#define LN_EPS 1e-5f
#define ROWS_PB 384  // k_Gm rows per block (12 chunks of 32) -> 261 blocks
#define EPB 8192     // k_b1 edges per block
#define SBW 11       // super-bin width: 2048 dests

typedef __bf16 bf16x8 __attribute__((ext_vector_type(8)));
typedef float f32x16 __attribute__((ext_vector_type(16)));
typedef float f32x2 __attribute__((ext_vector_type(2)));

union FragU {
  ushort u[8];
  bf16x8 v;
};

// ---------------- utilities ----------------

__device__ __forceinline__ float wave_sum(float v) {
#pragma unroll
  for (int off = 1; off < 64; off <<= 1) v += __shfl_xor(v, off, 64);
  return v;
}

__device__ __forceinline__ float half_sum(float v) {
#pragma unroll
  for (int off = 1; off < 32; off <<= 1) v += __shfl_xor(v, off, 64);
  return v;
}

__device__ __forceinline__ float block_sum(float v, volatile float* red) {
  const int tid = threadIdx.x;
  v = wave_sum(v);
  __syncthreads();
  if ((tid & 63) == 0) red[tid >> 6] = v;
  __syncthreads();
  return red[0] + red[1] + red[2] + red[3];
}

__device__ __forceinline__ ushort f2bf(float f) {
  unsigned u = __float_as_uint(f);
  unsigned r = (u + 0x7FFFu + ((u >> 16) & 1u)) >> 16;
  return (ushort)r;
}

__device__ __forceinline__ float bf2f(ushort u) {
  return __uint_as_float((unsigned)u << 16);
}

// ---- fp8 e4m3 pack/unpack (HW path on gfx950, manual fallback) ----
#if __has_builtin(__builtin_amdgcn_cvt_pk_fp8_f32) && __has_builtin(__builtin_amdgcn_cvt_pk_f32_fp8)
__device__ __forceinline__ unsigned pack_fp8x4(float a, float b, float c, float d) {
  int v = 0;
  v = __builtin_amdgcn_cvt_pk_fp8_f32(a, b, v, false);
  v = __builtin_amdgcn_cvt_pk_fp8_f32(c, d, v, true);
  return (unsigned)v;
}
__device__ __forceinline__ void unpack_fp8x2_acc(f32x2& lo, f32x2& hi, unsigned v) {
  lo += __builtin_amdgcn_cvt_pk_f32_fp8((int)v, false);
  hi += __builtin_amdgcn_cvt_pk_f32_fp8((int)v, true);
}
#else
__device__ __forceinline__ unsigned char f2e4m3_1(float f) {
  unsigned u = __float_as_uint(f);
  unsigned s = (u >> 31) << 7;
  float a = fabsf(f);
  if (a >= 448.0f) return (unsigned char)(s | 0x7E);
  if (a < 0.0009765625f) return (unsigned char)s;
  int e;
  float m = frexpf(a, &e);
  int E = e - 1 + 7;
  if (E >= 1) {
    int mm = (int)rintf((m * 2.0f - 1.0f) * 8.0f);
    if (mm == 8) { mm = 0; E++; }
    return (unsigned char)(s | (E << 3) | mm);
  }
  int mm = (int)rintf(a * 512.0f);
  if (mm > 7) return (unsigned char)(s | (1 << 3));
  return (unsigned char)(s | mm);
}
__device__ __forceinline__ unsigned pack_fp8x4(float a, float b, float c, float d) {
  return (unsigned)f2e4m3_1(a) | ((unsigned)f2e4m3_1(b) << 8) |
         ((unsigned)f2e4m3_1(c) << 16) | ((unsigned)f2e4m3_1(d) << 24);
}
__device__ __forceinline__ float e4m3f_1(unsigned v) {
  int s = (v >> 7) & 1, E = (v >> 3) & 15, m = v & 7;
  float mag = E ? ldexpf(1.0f + m * 0.125f, E - 7) : ldexpf((float)m, -9);
  return s ? -mag : mag;
}
__device__ __forceinline__ void unpack_fp8x2_acc(f32x2& lo, f32x2& hi, unsigned v) {
  lo[0] += e4m3f_1(v & 255);
  lo[1] += e4m3f_1((v >> 8) & 255);
  hi[0] += e4m3f_1((v >> 16) & 255);
  hi[1] += e4m3f_1(v >> 24);
}
#endif

// ---------------- setup: radix-style CSR build ----------------

__global__ __launch_bounds__(512) void k_b1(const int* __restrict__ row,
                                            const int* __restrict__ col,
                                            unsigned* __restrict__ breg,
                                            int* __restrict__ gcnt,
                                            int cap2, int E, int nsb) {
  __shared__ unsigned stage[EPB];  // 32 KB
  __shared__ int lh[65], lbase[65], lcur[64], gclaim[64];
  const int tid = threadIdx.x;
  const int e0 = blockIdx.x * EPB;
  const int cnt = min(EPB, E - e0);
  if (tid < 64) lh[tid] = 0;
  __syncthreads();
  for (int i = tid; i < cnt; i += 512) atomicAdd(&lh[col[e0 + i] >> SBW], 1);
  __syncthreads();
  if (tid == 0) {
    int acc = 0;
    for (int b = 0; b < nsb; b++) { lbase[b] = acc; acc += lh[b]; }
    lbase[nsb] = acc;
  }
  __syncthreads();
  if (tid < nsb) {
    gclaim[tid] = atomicAdd(&gcnt[tid], lh[tid]);
    lcur[tid] = lbase[tid];
  }
  __syncthreads();
  for (int i = tid; i < cnt; i += 512) {
    int c = col[e0 + i];
    int b = c >> SBW;
    int s = atomicAdd(&lcur[b], 1);
    stage[s] = ((unsigned)row[e0 + i] << SBW) | (unsigned)(c & ((1 << SBW) - 1));
  }
  __syncthreads();
  for (int i = tid; i < cnt; i += 512) {
    int lo = 0, hi = nsb;
    while (hi - lo > 1) {
      int mid = (lo + hi) >> 1;
      if (lbase[mid] <= i) lo = mid; else hi = mid;
    }
    int off = gclaim[lo] + (i - lbase[lo]);
    if (off < cap2) breg[(size_t)lo * cap2 + off] = stage[i];
  }
}

// per-super-bin degree count + invs (fused)
__global__ __launch_bounds__(512) void k_degB2(const unsigned* __restrict__ breg,
                                               const int* __restrict__ gcnt, int cap2,
                                               int* __restrict__ deg,
                                               float* __restrict__ invs, int N) {
  __shared__ int lcnt[1 << SBW];
  const int b = blockIdx.x, tid = threadIdx.x, base = b << SBW;
  for (int i = tid; i < (1 << SBW); i += 512) lcnt[i] = 0;
  __syncthreads();
  const int cnt = min(gcnt[b], cap2);
  const unsigned* p = breg + (size_t)b * cap2;
  for (int i = tid; i < cnt; i += 512) atomicAdd(&lcnt[p[i] & ((1 << SBW) - 1)], 1);
  __syncthreads();
  for (int i = tid; i < (1 << SBW); i += 512) {
    int d = base + i;
    if (d < N) {
      int c = lcnt[i];
      deg[d] = c;
      invs[d] = (c > 0) ? (1.0f / sqrtf((float)c)) : 0.0f;
    }
  }
}

// level 2: place into final CSR; applies bsum fix-up and writes final offs16 back
__global__ __launch_bounds__(512) void k_b2(const unsigned* __restrict__ breg,
                                            const int* __restrict__ gcnt, int cap2,
                                            int* __restrict__ offs16,
                                            const int* __restrict__ bsum,
                                            int* __restrict__ eb, int N) {
  __shared__ int loffs[1 << SBW];
  __shared__ int lcur[1 << SBW];
  const int b = blockIdx.x, tid = threadIdx.x, base = b << SBW;
  for (int i = tid; i < (1 << SBW); i += 512) {
    int d = base + i;
    if (d < N) {
      int o = offs16[d] + bsum[d >> 10];
      loffs[i] = o;
      offs16[d] = o;  // final value for k_C
    } else {
      loffs[i] = 0;
    }
    lcur[i] = 0;
  }
  __syncthreads();
  const int cnt = min(gcnt[b], cap2);
  const unsigned* p = breg + (size_t)b * cap2;
  for (int i = tid; i < cnt; i += 512) {
    unsigned rc = p[i];
    int lc = rc & ((1 << SBW) - 1);
    int slot = atomicAdd(&lcur[lc], 1);
    eb[loffs[lc] + slot] = (int)(rc >> SBW);
  }
  __syncthreads();
  for (int i = tid; i < (1 << SBW); i += 512) {
    int d = base + i;
    if (d < N) {
      int c = lcur[i];
      int pad = (c + 15) & ~15;
      int o = loffs[i];
      for (int j = c; j < pad; j++) eb[o + j] = N;
    }
  }
}

__global__ __launch_bounds__(1024) void k_scan1(const int* __restrict__ deg,
                                                int* __restrict__ offs16,
                                                int* __restrict__ bsum, int N) {
  __shared__ int buf[1024];
  const int tid = threadIdx.x;
  const int gid = blockIdx.x * 1024 + tid;
  int v = (gid < N) ? ((deg[gid] + 15) & ~15) : 0;
  buf[tid] = v;
  __syncthreads();
  for (int off = 1; off < 1024; off <<= 1) {
    int x = (tid >= off) ? buf[tid - off] : 0;
    __syncthreads();
    buf[tid] += x;
    __syncthreads();
  }
  if (gid < N) offs16[gid] = buf[tid] - v;
  if (tid == 1023) bsum[blockIdx.x] = buf[1023];
}

__global__ __launch_bounds__(1024) void k_scan2(int* __restrict__ bsum, int nb) {
  __shared__ int buf[1024];
  const int tid = threadIdx.x;
  int v = (tid < nb) ? bsum[tid] : 0;
  buf[tid] = v;
  __syncthreads();
  for (int off = 1; off < 1024; off <<= 1) {
    int x = (tid >= off) ? buf[tid - off] : 0;
    __syncthreads();
    buf[tid] += x;
    __syncthreads();
  }
  if (tid < nb) bsum[tid] = buf[tid] - v;
}

// iteration-independent weight products
__global__ void k_prep(const float* __restrict__ Wq, const float* __restrict__ Wk,
                       const float* __restrict__ bq, const float* __restrict__ bk,
                       float* __restrict__ P, float* __restrict__ Q, float* __restrict__ K2,
                       float* __restrict__ pb, float* __restrict__ qb,
                       float* __restrict__ wb, float* __restrict__ kb,
                       float* __restrict__ sconst) {
  __shared__ float red[4];
  const int b = blockIdx.x, tid = threadIdx.x;
  if (b < 768) {
    const int f = b & 255, which = b >> 8;
    const float* A = (which == 2) ? Wk : Wq;
    const float* Bm = (which == 1) ? Wq : Wk;
    float acc = 0.0f;
    for (int m = 0; m < H; m++) acc = fmaf(A[f * H + m], Bm[tid * H + m], acc);
    float* D = (which == 0) ? P : ((which == 1) ? Q : K2);
    D[f * H + tid] = acc;
  } else {
    float a1 = 0, a2 = 0, a3 = 0, a4 = 0;
    for (int m = 0; m < H; m++) {
      float wqv = Wq[tid * H + m], wkv = Wk[tid * H + m];
      a1 = fmaf(wqv, bk[m], a1);
      a2 = fmaf(wqv, bq[m], a2);
      a3 = fmaf(wkv, bq[m], a3);
      a4 = fmaf(wkv, bk[m], a4);
    }
    pb[tid] = a1; qb[tid] = a2; wb[tid] = a3; kb[tid] = a4;
    float c0 = block_sum(bq[tid] * bk[tid], red);
    float c1 = block_sum(bq[tid] * bq[tid], red);
    float c2 = block_sum(bk[tid] * bk[tid], red);
    if (tid == 0) { sconst[0] = c0; sconst[1] = c1; sconst[2] = c2; }
  }
}

// R0 = relu(x@W1 + b1) -> bf16, plus layer-0 readout
__global__ void k_fc1(const float* __restrict__ x, const float* __restrict__ W1,
                      const float* __restrict__ b1, const float* __restrict__ Wr,
                      const float* __restrict__ br, const float* __restrict__ wgt,
                      ushort* __restrict__ R0, float* __restrict__ out, int N) {
  __shared__ __align__(16) float lx[16 * FIN];
  __shared__ float red2[4][16];
  const int tid = threadIdx.x;
  const int n0 = blockIdx.x * 16;
  for (int idx = tid; idx < 16 * FIN / 4; idx += 256)
    ((float4*)lx)[idx] = ((const float4*)(x + (size_t)n0 * FIN))[idx];
  __syncthreads();
  float acc[16];
  const float bias = b1[tid];
#pragma unroll
  for (int r = 0; r < 16; r++) acc[r] = bias;
  for (int f = 0; f < FIN; f++) {
    float wv = W1[f * H + tid];
#pragma unroll
    for (int r = 0; r < 16; r++) acc[r] = fmaf(lx[r * FIN + f], wv, acc[r]);
  }
  const float wr0 = Wr[tid];
#pragma unroll
  for (int r = 0; r < 16; r++) {
    acc[r] = fmaxf(acc[r], 0.0f);
    int n = n0 + r;
    if (n < N) R0[(size_t)n * H + tid] = f2bf(acc[r]);
  }
#pragma unroll
  for (int r = 0; r < 16; r++) {
    float s = wave_sum(acc[r] * wr0);
    if ((tid & 63) == 0) red2[tid >> 6][r] = s;
  }
  __syncthreads();
  if (tid < 16) {
    int n = n0 + tid;
    if (n < N)
      out[n] = wgt[0] * (red2[0][tid] + red2[1][tid] + red2[2][tid] + red2[3][tid] + br[0]);
  }
}

// ---------------- MFMA G = R^T R (transposed-LDS, b128 frags) ----------------
// LDS: sbT[buf][f][32 k-slots] u16, k-block XOR swizzle. Fragment = 1 b128 read.
// Also produces Rf8 (fp8 gather source) and per-block column-sum slab (csl).
__global__ __launch_bounds__(512, 2) void k_Gm(const ushort* __restrict__ Rb,
                                               const float* __restrict__ invs,
                                               ushort* __restrict__ Gslab,
                                               unsigned* __restrict__ Rf8,
                                               float* __restrict__ csl, int N) {
  __shared__ ushort sbT[2][256 * 32];  // 2 x 16 KB
  const int tid = threadIdx.x;
  const int lane = tid & 63;
  const int wid = tid >> 6;
  const int wrow = (wid & 1) * 128;
  const int wcol = (wid >> 1) * 64;
  const int l31 = lane & 31;
  const int lhi = lane >> 5;

  const int rowbase = blockIdx.x * ROWS_PB;
  const int nrows = min(ROWS_PB, N - rowbase);
  const int nch = (nrows + 31) >> 5;

  const int rp = tid >> 5;   // node pair (nodes 2rp, 2rp+1)
  const int fg = tid & 31;   // feature group (feats fg*8..fg*8+7)
  const int k2 = rp * 2;

  f32x16 acc[4][2];
#pragma unroll
  for (int s = 0; s < 4; s++)
#pragma unroll
    for (int t = 0; t < 2; t++)
#pragma unroll
      for (int e = 0; e < 16; e++) acc[s][t][e] = 0.0f;

  float cs[8];
#pragma unroll
  for (int i = 0; i < 8; i++) cs[i] = 0.0f;

  int4 la, lb;
  float sc0, sc1;

  auto load_chunk = [&](int ch) {
    int g0 = rowbase + ch * 32 + k2;
    const int4* s0 = (const int4*)(Rb + (size_t)g0 * H + fg * 8);
    const int4* s1 = (const int4*)(Rb + (size_t)(g0 + 1) * H + fg * 8);
    la = (g0 < N) ? s0[0] : make_int4(0, 0, 0, 0);
    lb = (g0 + 1 < N) ? s1[0] : make_int4(0, 0, 0, 0);
    sc0 = (g0 < N) ? invs[g0] : 0.0f;
    sc1 = (g0 + 1 < N) ? invs[g0 + 1] : 0.0f;
  };

  auto write_chunk = [&](int ch, int buf) {
    int g0 = rowbase + ch * 32 + k2;
    const ushort* pa = (const ushort*)&la;
    const ushort* pbu = (const ushort*)&lb;
    // transposed LDS write: u32 = (node k2, node k2+1) at feature f
    const int blk = (k2 & 24) ^ ((fg & 3) << 3);
    uint* dst = (uint*)sbT[buf];
#pragma unroll
    for (int i = 0; i < 8; i++) {
      float av = bf2f(pa[i]), bv = bf2f(pbu[i]);
      cs[i] += av + bv;
      unsigned val = (unsigned)pa[i] | ((unsigned)pbu[i] << 16);
      int f = fg * 8 + i;
      dst[f * 16 + ((blk + (k2 & 7)) >> 1)] = val;
    }
    if (g0 < N) {
      unsigned w0 = pack_fp8x4(bf2f(pa[0]) * sc0, bf2f(pa[1]) * sc0,
                               bf2f(pa[2]) * sc0, bf2f(pa[3]) * sc0);
      unsigned w1 = pack_fp8x4(bf2f(pa[4]) * sc0, bf2f(pa[5]) * sc0,
                               bf2f(pa[6]) * sc0, bf2f(pa[7]) * sc0);
      *(uint2*)&Rf8[(size_t)g0 * 64 + fg * 2] = make_uint2(w0, w1);
    }
    if (g0 + 1 < N) {
      unsigned w0 = pack_fp8x4(bf2f(pbu[0]) * sc1, bf2f(pbu[1]) * sc1,
                               bf2f(pbu[2]) * sc1, bf2f(pbu[3]) * sc1);
      unsigned w1 = pack_fp8x4(bf2f(pbu[4]) * sc1, bf2f(pbu[5]) * sc1,
                               bf2f(pbu[6]) * sc1, bf2f(pbu[7]) * sc1);
      *(uint2*)&Rf8[(size_t)(g0 + 1) * 64 + fg * 2] = make_uint2(w0, w1);
    }
  };

  auto compute = [&](int buf) {
    const ushort* bp = sbT[buf];
#pragma unroll
    for (int ks = 0; ks < 2; ks++) {
      const int kb = ks * 16 + lhi * 8;
      FragU fr[6];
#pragma unroll
      for (int s = 0; s < 6; s++) {
        const int cb = (s < 4) ? (wrow + 32 * s + l31) : (wcol + 32 * (s - 4) + l31);
        const int off = cb * 32 + (kb ^ (((cb >> 3) & 3) << 3));
        *(int4*)fr[s].u = *(const int4*)(bp + off);
      }
#pragma unroll
      for (int s = 0; s < 4; s++)
#pragma unroll
        for (int t = 0; t < 2; t++)
          acc[s][t] = __builtin_amdgcn_mfma_f32_32x32x16_bf16(fr[s].v, fr[4 + t].v,
                                                              acc[s][t], 0, 0, 0);
    }
  };

  if (nch > 0) {
    load_chunk(0);
    write_chunk(0, 0);
    __syncthreads();
    int cur = 0;
    for (int c = 0; c < nch; c++) {
      if (c + 1 < nch) load_chunk(c + 1);
      compute(cur);
      if (c + 1 < nch) write_chunk(c + 1, cur ^ 1);
      __syncthreads();
      cur ^= 1;
    }
  }

  // non-atomic bf16 partial-G slab write
  ushort* Gs = Gslab + (size_t)blockIdx.x * 65536;
#pragma unroll
  for (int s = 0; s < 4; s++)
#pragma unroll
    for (int t = 0; t < 2; t++) {
      const int n0c = wcol + 32 * t + l31;
#pragma unroll
      for (int r = 0; r < 16; r++) {
        const int row = wrow + 32 * s + (r & 3) + 8 * (r >> 2) + 4 * lhi;
        Gs[row * 256 + n0c] = f2bf(acc[s][t][r]);
      }
    }

  // column-sum slab (non-atomic): reduce per-thread cs over node-pairs
  __syncthreads();
  float* fl = (float*)sbT;  // 16 KB scratch
#pragma unroll
  for (int i = 0; i < 8; i++) fl[rp * 256 + fg * 8 + i] = cs[i];
  __syncthreads();
  if (tid < 256) {
    float v = 0.0f;
    for (int j = 0; j < 16; j++) v += fl[j * 256 + tid];
    csl[(size_t)blockIdx.x * 256 + tid] = v;
  }
}

// reduce bf16 slabs -> fp32 G; also vsum and <G,Q>/<G,K2> partials (non-atomic)
__global__ void k_Gr(const ushort* __restrict__ Gslab, const float* __restrict__ csl,
                     const float* __restrict__ Q, const float* __restrict__ K2,
                     float* __restrict__ G, float* __restrict__ vsum,
                     float2* __restrict__ spart, int nslab) {
  __shared__ float red[4];
  const int b = blockIdx.x, t = threadIdx.x;
  const int i = b * 256 + t;
  float s0 = 0, s1 = 0, s2 = 0, s3 = 0;
  int j = 0;
  for (; j + 3 < nslab; j += 4) {
    s0 += bf2f(Gslab[(size_t)j * 65536 + i]);
    s1 += bf2f(Gslab[(size_t)(j + 1) * 65536 + i]);
    s2 += bf2f(Gslab[(size_t)(j + 2) * 65536 + i]);
    s3 += bf2f(Gslab[(size_t)(j + 3) * 65536 + i]);
  }
  float s = s0 + s1 + s2 + s3;
  for (; j < nslab; j++) s += bf2f(Gslab[(size_t)j * 65536 + i]);
  G[i] = s;
  float dq = block_sum(s * Q[i], red);
  float dk = block_sum(s * K2[i], red);
  if (t == 0) spart[b] = make_float2(dq, dk);
  // vsum[b] = sum over slabs of csl[slab][b]
  float v = 0.0f;
  for (int u = t; u < nslab; u += 256) v += csl[(size_t)u * 256 + b];
  v = block_sum(v, red);
  if (t == 0) vsum[b] = v;
}

// per-iteration small products; block 258 finalizes scal (was k_final)
__global__ void k_small(const float* __restrict__ G, const float* __restrict__ vsum,
                        const float* __restrict__ P, const float* __restrict__ pb,
                        const float* __restrict__ wb, const float* __restrict__ sconst,
                        const float* __restrict__ qb, const float* __restrict__ kbv,
                        const float2* __restrict__ spart,
                        ushort* __restrict__ Mt, float* __restrict__ cvec,
                        float* __restrict__ dvec, float* __restrict__ scal, int N) {
  __shared__ float red[4];
  const int b = blockIdx.x, tid = threadIdx.x;
  if (b < 256) {
    float acc = 0.0f;
    for (int m = 0; m < H; m++) acc = fmaf(P[b * H + m], G[m * H + tid], acc);
    Mt[(size_t)tid * H + b] = f2bf(acc + pb[b] * vsum[tid]);
  } else if (b == 256) {
    float acc = 0.0f;
    for (int f = 0; f < H; f++) acc = fmaf(wb[f], G[f * H + tid], acc);
    cvec[tid] = acc + sconst[0] * vsum[tid];
  } else if (b == 257) {
    float acc = 0.0f;
    for (int m = 0; m < H; m++) acc = fmaf(P[tid * H + m], vsum[m], acc);
    dvec[tid] = acc + (float)N * pb[tid];
  } else {
    float2 sp = spart[tid];
    float dq = block_sum(sp.x, red);
    float dk = block_sum(sp.y, red);
    float s1 = block_sum(qb[tid] * vsum[tid], red);
    float s2 = block_sum(kbv[tid] * vsum[tid], red);
    float s3 = block_sum(wb[tid] * vsum[tid], red);
    if (tid == 0) {
      float sq = dq + 2.0f * s1 + (float)N * sconst[1];
      float sk = dk + 2.0f * s2 + (float)N * sconst[2];
      scal[2] = 1.0f / (sqrtf(sq) * sqrtf(sk));
      scal[3] = s3 + (float)N * sconst[0];
    }
  }
}

// ---------------- MFMA num = R * M (bf16 in, bf16 out) ----------------
__global__ __launch_bounds__(512) void k_N(const ushort* __restrict__ Rb,
                                           const ushort* __restrict__ Mt,
                                           ushort* __restrict__ numb, int N) {
  const int tid = threadIdx.x;
  const int lane = tid & 63;
  const int wid = tid >> 6;
  const int l31 = lane & 31;
  const int lhi = lane >> 5;
  const int wrow = (wid & 3) * 32;
  const int wcol = (wid >> 2) * 128;
  const int rowbase = blockIdx.x * 128;

  f32x16 acc[4];
#pragma unroll
  for (int t = 0; t < 4; t++)
#pragma unroll
    for (int e = 0; e < 16; e++) acc[t][e] = 0.0f;

  const ushort* aptr = Rb + (size_t)(rowbase + wrow + l31) * H;

  for (int kc = 0; kc < 16; kc++) {
    const int kb = kc * 16 + lhi * 8;
    FragU fa;
    *(int4*)fa.u = *(const int4*)(aptr + kb);
    FragU fb0, fb1, fb2, fb3;
    *(int4*)fb0.u = *(const int4*)(Mt + (size_t)(wcol + 0 + l31) * H + kb);
    *(int4*)fb1.u = *(const int4*)(Mt + (size_t)(wcol + 32 + l31) * H + kb);
    *(int4*)fb2.u = *(const int4*)(Mt + (size_t)(wcol + 64 + l31) * H + kb);
    *(int4*)fb3.u = *(const int4*)(Mt + (size_t)(wcol + 96 + l31) * H + kb);
    acc[0] = __builtin_amdgcn_mfma_f32_32x32x16_bf16(fa.v, fb0.v, acc[0], 0, 0, 0);
    acc[1] = __builtin_amdgcn_mfma_f32_32x32x16_bf16(fa.v, fb1.v, acc[1], 0, 0, 0);
    acc[2] = __builtin_amdgcn_mfma_f32_32x32x16_bf16(fa.v, fb2.v, acc[2], 0, 0, 0);
    acc[3] = __builtin_amdgcn_mfma_f32_32x32x16_bf16(fa.v, fb3.v, acc[3], 0, 0, 0);
  }

#pragma unroll
  for (int t = 0; t < 4; t++) {
    const int col = wcol + 32 * t + l31;
#pragma unroll
    for (int r = 0; r < 16; r++) {
      const int row = rowbase + wrow + (r & 3) + 8 * (r >> 2) + 4 * lhi;
      if (row < N) numb[(size_t)row * H + col] = f2bf(acc[t][r]);
    }
  }
}

// slim fused: half-wave per row, fp8 gather (uint2 = 2 rows/load), LN, readout
__global__ __launch_bounds__(256) void k_C(
    const ushort* __restrict__ Rb, ushort* __restrict__ Rnext,
    const ushort* __restrict__ numb, const unsigned* __restrict__ Rf8,
    const int* __restrict__ eb, const float* __restrict__ invs,
    const float* __restrict__ cvec, const float* __restrict__ dvec,
    const float* __restrict__ vsum, const float* __restrict__ scal,
    const int* __restrict__ offs16, const int* __restrict__ deg,
    const float* __restrict__ alphap, const float* __restrict__ gamma,
    const float* __restrict__ beta, const float* __restrict__ Wr,
    const float* __restrict__ br, const float* __restrict__ wgt,
    float* __restrict__ out, int N, int layer, int last) {
  const int tid = threadIdx.x, lane = tid & 63, wv = tid >> 6;
  const int half = lane >> 5, hl = lane & 31;
  const int d0 = hl * 8;
  const int n0 = blockIdx.x * 32 + wv * 8;

  const float invn = scal[2], denc = scal[3];
  const float al = alphap[0], om = 1.0f - al;
  const float4 dvA = *(const float4*)&dvec[d0];
  const float4 dvB = *(const float4*)&dvec[d0 + 4];
  const float4 cvA = *(const float4*)&cvec[d0];
  const float4 cvB = *(const float4*)&cvec[d0 + 4];
  const float4 vsA = *(const float4*)&vsum[d0];
  const float4 vsB = *(const float4*)&vsum[d0 + 4];
  const float4 gmA = *(const float4*)&gamma[d0];
  const float4 gmB = *(const float4*)&gamma[d0 + 4];
  const float4 btA = *(const float4*)&beta[d0];
  const float4 btB = *(const float4*)&beta[d0 + 4];
  const float4 wrA = *(const float4*)&Wr[layer * H + d0];
  const float4 wrB = *(const float4*)&Wr[layer * H + d0 + 4];
  const float wl = wgt[layer], bl = br[layer];

  for (int r = 0; r < 4; r++) {
    const int n = n0 + r * 2 + half;
    const bool valid = n < N;
    const int ns = valid ? n : 0;

    const int4 rv = *(const int4*)&Rb[(size_t)ns * H + d0];
    const int4 nv = *(const int4*)&numb[(size_t)ns * H + d0];
    const ushort* rp = (const ushort*)&rv;
    const ushort* np = (const ushort*)&nv;
    float old[8], num[8];
#pragma unroll
    for (int j = 0; j < 8; j++) { old[j] = bf2f(rp[j]); num[j] = bf2f(np[j]); }

    float p = old[0] * dvA.x + old[1] * dvA.y + old[2] * dvA.z + old[3] * dvA.w +
              old[4] * dvB.x + old[5] * dvB.y + old[6] * dvB.z + old[7] * dvB.w;
    p = half_sum(p);
    const float rden = 1.0f / ((p + denc) * invn + (float)N);

    f32x2 a01 = {0.f, 0.f}, a23 = {0.f, 0.f}, a45 = {0.f, 0.f}, a67 = {0.f, 0.f};
    const int st = offs16[ns];
    const int nbch = valid ? ((deg[ns] + 15) >> 4) : 0;
    const int4* pe = (const int4*)(eb + st);
    const int woff = hl * 2;
    for (int b = 0; b < nbch; b++, pe += 4) {
      int4 q0 = pe[0], q1 = pe[1], q2 = pe[2], q3 = pe[3];
      const int srcs[16] = {q0.x, q0.y, q0.z, q0.w, q1.x, q1.y, q1.z, q1.w,
                            q2.x, q2.y, q2.z, q2.w, q3.x, q3.y, q3.z, q3.w};
      uint2 g[16];
#pragma unroll
      for (int i = 0; i < 16; i++)
        g[i] = *(const uint2*)&Rf8[((size_t)srcs[i] << 6) + woff];
#pragma unroll
      for (int i = 0; i < 16; i++) {
        unpack_fp8x2_acc(a01, a23, g[i].x);
        unpack_fp8x2_acc(a45, a67, g[i].y);
      }
    }
    const float sn = invs[ns];
    float ag[8] = {a01[0] * sn, a01[1] * sn, a23[0] * sn, a23[1] * sn,
                   a45[0] * sn, a45[1] * sn, a67[0] * sn, a67[1] * sn};

    const float cva[8] = {cvA.x, cvA.y, cvA.z, cvA.w, cvB.x, cvB.y, cvB.z, cvB.w};
    const float vsa[8] = {vsA.x, vsA.y, vsA.z, vsA.w, vsB.x, vsB.y, vsB.z, vsB.w};
    float hv[8];
#pragma unroll
    for (int j = 0; j < 8; j++)
      hv[j] = al * (((num[j] + cva[j]) * invn + vsa[j]) * rden + ag[j]) + om * old[j];

    float s = 0.0f, s2 = 0.0f;
#pragma unroll
    for (int j = 0; j < 8; j++) { s += hv[j]; s2 += hv[j] * hv[j]; }
    s = half_sum(s);
    s2 = half_sum(s2);
    const float mu = s * (1.0f / H);
    const float var = s2 * (1.0f / H) - mu * mu;
    const float rs = rsqrtf(var + LN_EPS);

    const float gma[8] = {gmA.x, gmA.y, gmA.z, gmA.w, gmB.x, gmB.y, gmB.z, gmB.w};
    const float bta[8] = {btA.x, btA.y, btA.z, btA.w, btB.x, btB.y, btB.z, btB.w};
    const float wra[8] = {wrA.x, wrA.y, wrA.z, wrA.w, wrB.x, wrB.y, wrB.z, wrB.w};
    float y[8], rp2 = 0.0f;
    ushort yo[8];
#pragma unroll
    for (int j = 0; j < 8; j++) {
      y[j] = (hv[j] - mu) * rs * gma[j] + bta[j];
      yo[j] = f2bf(y[j]);
      rp2 += y[j] * wra[j];
    }
    if (!last && valid) *(int4*)&Rnext[(size_t)n * H + d0] = *(int4*)yo;
    rp2 = half_sum(rp2);
    if (hl == 0 && valid) out[n] += wl * (rp2 + bl);
  }
}

// ---------------- host ----------------

extern "C" void kernel_launch(void* const* d_in, const int* in_sizes, int n_in,
                              void* d_out, int out_size, void* d_ws, size_t ws_size,
                              hipStream_t stream) {
  const float* x = (const float*)d_in[0];
  const int* ei = (const int*)d_in[1];
  const float* W1 = (const float*)d_in[2];
  const float* b1 = (const float*)d_in[3];
  const float* Wq = (const float*)d_in[4];
  const float* bq = (const float*)d_in[5];
  const float* Wk = (const float*)d_in[6];
  const float* bk = (const float*)d_in[7];
  const float* gamma = (const float*)d_in[8];
  const float* beta = (const float*)d_in[9];
  const float* alphap = (const float*)d_in[10];
  const float* Wr = (const float*)d_in[11];
  const float* br = (const float*)d_in[12];
  const float* wgt = (const float*)d_in[13];
  float* out = (float*)d_out;

  const int N = in_sizes[0] / FIN;
  const int E = in_sizes[1] / 2;
  const int* row = ei;
  const int* col = ei + E;

  char* w = (char*)d_ws;
  auto alloc = [&](size_t bytes) -> char* {
    char* p = w;
    w += (bytes + 255) & ~(size_t)255;
    return p;
  };
  const size_t RB = (size_t)(N + 128) * H * sizeof(ushort);
  ushort* Rb0 = (ushort*)alloc(RB);
  ushort* Rb1 = (ushort*)alloc(RB);   // aliased as super-bin record scratch in setup
  ushort* numb = (ushort*)alloc(RB);  // aliased as bf16 G-slab scratch per iter
  unsigned* Rf8 = (unsigned*)alloc((size_t)(N + 1) * 64 * sizeof(unsigned));  // +1 zero row
  ushort* Mt = (ushort*)alloc(H * H * sizeof(ushort));
  float* G = (float*)alloc(H * H * sizeof(float));
  float* vsum = (float*)alloc(1024);
  float* scal = (float*)alloc(256);
  float* cvec = (float*)alloc(1024);
  float* dvec = (float*)alloc(1024);
  float* P = (float*)alloc(H * H * sizeof(float));
  float* Q = (float*)alloc(H * H * sizeof(float));
  float* K2 = (float*)alloc(H * H * sizeof(float));
  float* pb = (float*)alloc(1024);
  float* qb = (float*)alloc(1024);
  float* wb = (float*)alloc(1024);
  float* kb = (float*)alloc(1024);
  float* sconst = (float*)alloc(256);
  int* deg = (int*)alloc((size_t)N * 4);
  float* invs = (float*)alloc((size_t)N * 4);
  int* offs16 = (int*)alloc((size_t)(N + 1) * 4);
  int* bsum = (int*)alloc(1024 * 4);
  int* gcnt = (int*)alloc(64 * 4);
  const int nbG = (N + ROWS_PB - 1) / ROWS_PB;
  float* csl = (float*)alloc((size_t)nbG * 256 * sizeof(float));
  float2* spart = (float2*)alloc(256 * sizeof(float2));
  size_t EPAD = (size_t)E + 16 * (size_t)N;
  EPAD = (EPAD + 3) & ~(size_t)3;
  int* eb = (int*)alloc(EPAD * sizeof(int));

  const int NSB = (N + (1 << SBW) - 1) >> SBW;  // super-bins (<=64 for N<=131072)
  int cap2 = (E / (NSB > 0 ? NSB : 1)) * 2 + 4096;
  cap2 = (cap2 + 3) & ~3;
  unsigned* breg = (unsigned*)Rb1;  // NSB*cap2*4B <= RB
  ushort* Gslab = (ushort*)numb;    // nbG*128KB <= RB

  hipMemsetAsync(gcnt, 0, 64 * 4, stream);
  hipMemsetAsync(Rf8 + (size_t)N * 64, 0, 64 * sizeof(unsigned), stream);

  const int nblk = (N + 1023) / 1024;
  const int nbB1 = (E + EPB - 1) / EPB;
  k_b1<<<nbB1, 512, 0, stream>>>(row, col, breg, gcnt, cap2, E, NSB);
  k_degB2<<<NSB, 512, 0, stream>>>(breg, gcnt, cap2, deg, invs, N);
  k_scan1<<<nblk, 1024, 0, stream>>>(deg, offs16, bsum, N);
  k_scan2<<<1, 1024, 0, stream>>>(bsum, nblk);
  k_b2<<<NSB, 512, 0, stream>>>(breg, gcnt, cap2, offs16, bsum, eb, N);
  k_prep<<<769, 256, 0, stream>>>(Wq, Wk, bq, bk, P, Q, K2, pb, qb, wb, kb, sconst);
  const int gRows16 = (N + 15) / 16;
  k_fc1<<<gRows16, 256, 0, stream>>>(x, W1, b1, Wr, br, wgt, Rb0, out, N);

  const int nbN = (N + 127) / 128;
  const int gRows32 = (N + 31) / 32;
  ushort* Rc = Rb0;
  ushort* Rn = Rb1;
  for (int it = 1; it <= 3; ++it) {
    k_Gm<<<nbG, 512, 0, stream>>>(Rc, invs, Gslab, Rf8, csl, N);
    k_Gr<<<256, 256, 0, stream>>>(Gslab, csl, Q, K2, G, vsum, spart, nbG);
    k_small<<<259, 256, 0, stream>>>(G, vsum, P, pb, wb, sconst, qb, kb, spart,
                                     Mt, cvec, dvec, scal, N);
    k_N<<<nbN, 512, 0, stream>>>(Rc, Mt, numb, N);
    k_C<<<gRows32, 256, 0, stream>>>(Rc, Rn, numb, Rf8, eb, invs, cvec, dvec, vsum, scal,
                                     offs16, deg, alphap, gamma, beta, Wr, br, wgt, out,
                                     N, it, (it == 3) ? 1 : 0);
    ushort* t = Rc; Rc = Rn; Rn = t;
  }
}

// Round 12
// 1105.881 us; speedup vs baseline: 4.6699x; 1.0518x over previous
//
#include <hip/hip_runtime.h>

#define H 256
#define FIN 58
#define LN_EPS 1e-5f
#define EPB 8192     // k_b1 edges per block
#define SBW 11       // super-bin width: 2048 dests

typedef __bf16 bf16x8 __attribute__((ext_vector_type(8)));
typedef float f32x16 __attribute__((ext_vector_type(16)));
typedef float f32x2 __attribute__((ext_vector_type(2)));

union FragU {
  ushort u[8];
  bf16x8 v;
};

// ---------------- utilities ----------------

__device__ __forceinline__ float wave_sum(float v) {
#pragma unroll
  for (int off = 1; off < 64; off <<= 1) v += __shfl_xor(v, off, 64);
  return v;
}

__device__ __forceinline__ float half_sum(float v) {
#pragma unroll
  for (int off = 1; off < 32; off <<= 1) v += __shfl_xor(v, off, 64);
  return v;
}

__device__ __forceinline__ float block_sum(float v, volatile float* red) {
  const int tid = threadIdx.x;
  v = wave_sum(v);
  __syncthreads();
  if ((tid & 63) == 0) red[tid >> 6] = v;
  __syncthreads();
  return red[0] + red[1] + red[2] + red[3];
}

__device__ __forceinline__ ushort f2bf(float f) {
  unsigned u = __float_as_uint(f);
  unsigned r = (u + 0x7FFFu + ((u >> 16) & 1u)) >> 16;
  return (ushort)r;
}

__device__ __forceinline__ float bf2f(ushort u) {
  return __uint_as_float((unsigned)u << 16);
}

// ---- fp8 e4m3 pack/unpack (HW path on gfx950, manual fallback) ----
#if __has_builtin(__builtin_amdgcn_cvt_pk_fp8_f32) && __has_builtin(__builtin_amdgcn_cvt_pk_f32_fp8)
__device__ __forceinline__ unsigned pack_fp8x4(float a, float b, float c, float d) {
  int v = 0;
  v = __builtin_amdgcn_cvt_pk_fp8_f32(a, b, v, false);
  v = __builtin_amdgcn_cvt_pk_fp8_f32(c, d, v, true);
  return (unsigned)v;
}
__device__ __forceinline__ void unpack_fp8x2_acc(f32x2& lo, f32x2& hi, unsigned v) {
  lo += __builtin_amdgcn_cvt_pk_f32_fp8((int)v, false);
  hi += __builtin_amdgcn_cvt_pk_f32_fp8((int)v, true);
}
#else
__device__ __forceinline__ unsigned char f2e4m3_1(float f) {
  unsigned u = __float_as_uint(f);
  unsigned s = (u >> 31) << 7;
  float a = fabsf(f);
  if (a >= 448.0f) return (unsigned char)(s | 0x7E);
  if (a < 0.0009765625f) return (unsigned char)s;
  int e;
  float m = frexpf(a, &e);
  int E = e - 1 + 7;
  if (E >= 1) {
    int mm = (int)rintf((m * 2.0f - 1.0f) * 8.0f);
    if (mm == 8) { mm = 0; E++; }
    return (unsigned char)(s | (E << 3) | mm);
  }
  int mm = (int)rintf(a * 512.0f);
  if (mm > 7) return (unsigned char)(s | (1 << 3));
  return (unsigned char)(s | mm);
}
__device__ __forceinline__ unsigned pack_fp8x4(float a, float b, float c, float d) {
  return (unsigned)f2e4m3_1(a) | ((unsigned)f2e4m3_1(b) << 8) |
         ((unsigned)f2e4m3_1(c) << 16) | ((unsigned)f2e4m3_1(d) << 24);
}
__device__ __forceinline__ float e4m3f_1(unsigned v) {
  int s = (v >> 7) & 1, E = (v >> 3) & 15, m = v & 7;
  float mag = E ? ldexpf(1.0f + m * 0.125f, E - 7) : ldexpf((float)m, -9);
  return s ? -mag : mag;
}
__device__ __forceinline__ void unpack_fp8x2_acc(f32x2& lo, f32x2& hi, unsigned v) {
  lo[0] += e4m3f_1(v & 255);
  lo[1] += e4m3f_1((v >> 8) & 255);
  hi[0] += e4m3f_1((v >> 16) & 255);
  hi[1] += e4m3f_1(v >> 24);
}
#endif

// ---------------- setup: radix-style CSR build ----------------

__global__ __launch_bounds__(512) void k_b1(const int* __restrict__ row,
                                            const int* __restrict__ col,
                                            unsigned* __restrict__ breg,
                                            int* __restrict__ gcnt,
                                            int cap2, int E, int nsb) {
  __shared__ unsigned stage[EPB];  // 32 KB
  __shared__ int lh[65], lbase[65], lcur[64], gclaim[64];
  const int tid = threadIdx.x;
  const int e0 = blockIdx.x * EPB;
  const int cnt = min(EPB, E - e0);
  if (tid < 64) lh[tid] = 0;
  __syncthreads();
  for (int i = tid; i < cnt; i += 512) atomicAdd(&lh[col[e0 + i] >> SBW], 1);
  __syncthreads();
  if (tid == 0) {
    int acc = 0;
    for (int b = 0; b < nsb; b++) { lbase[b] = acc; acc += lh[b]; }
    lbase[nsb] = acc;
  }
  __syncthreads();
  if (tid < nsb) {
    gclaim[tid] = atomicAdd(&gcnt[tid], lh[tid]);
    lcur[tid] = lbase[tid];
  }
  __syncthreads();
  for (int i = tid; i < cnt; i += 512) {
    int c = col[e0 + i];
    int b = c >> SBW;
    int s = atomicAdd(&lcur[b], 1);
    stage[s] = ((unsigned)row[e0 + i] << SBW) | (unsigned)(c & ((1 << SBW) - 1));
  }
  __syncthreads();
  for (int i = tid; i < cnt; i += 512) {
    int lo = 0, hi = nsb;
    while (hi - lo > 1) {
      int mid = (lo + hi) >> 1;
      if (lbase[mid] <= i) lo = mid; else hi = mid;
    }
    int off = gclaim[lo] + (i - lbase[lo]);
    if (off < cap2) breg[(size_t)lo * cap2 + off] = stage[i];
  }
}

// per-super-bin degree count + invs (fused)
__global__ __launch_bounds__(512) void k_degB2(const unsigned* __restrict__ breg,
                                               const int* __restrict__ gcnt, int cap2,
                                               int* __restrict__ deg,
                                               float* __restrict__ invs, int N) {
  __shared__ int lcnt[1 << SBW];
  const int b = blockIdx.x, tid = threadIdx.x, base = b << SBW;
  for (int i = tid; i < (1 << SBW); i += 512) lcnt[i] = 0;
  __syncthreads();
  const int cnt = min(gcnt[b], cap2);
  const unsigned* p = breg + (size_t)b * cap2;
  for (int i = tid; i < cnt; i += 512) atomicAdd(&lcnt[p[i] & ((1 << SBW) - 1)], 1);
  __syncthreads();
  for (int i = tid; i < (1 << SBW); i += 512) {
    int d = base + i;
    if (d < N) {
      int c = lcnt[i];
      deg[d] = c;
      invs[d] = (c > 0) ? (1.0f / sqrtf((float)c)) : 0.0f;
    }
  }
}

// level 2: place into final CSR; applies bsum fix-up and writes final offs16 back
__global__ __launch_bounds__(512) void k_b2(const unsigned* __restrict__ breg,
                                            const int* __restrict__ gcnt, int cap2,
                                            int* __restrict__ offs16,
                                            const int* __restrict__ bsum,
                                            int* __restrict__ eb, int N) {
  __shared__ int loffs[1 << SBW];
  __shared__ int lcur[1 << SBW];
  const int b = blockIdx.x, tid = threadIdx.x, base = b << SBW;
  for (int i = tid; i < (1 << SBW); i += 512) {
    int d = base + i;
    if (d < N) {
      int o = offs16[d] + bsum[d >> 10];
      loffs[i] = o;
      offs16[d] = o;  // final value for k_C
    } else {
      loffs[i] = 0;
    }
    lcur[i] = 0;
  }
  __syncthreads();
  const int cnt = min(gcnt[b], cap2);
  const unsigned* p = breg + (size_t)b * cap2;
  for (int i = tid; i < cnt; i += 512) {
    unsigned rc = p[i];
    int lc = rc & ((1 << SBW) - 1);
    int slot = atomicAdd(&lcur[lc], 1);
    eb[loffs[lc] + slot] = (int)(rc >> SBW);
  }
  __syncthreads();
  for (int i = tid; i < (1 << SBW); i += 512) {
    int d = base + i;
    if (d < N) {
      int c = lcur[i];
      int pad = (c + 15) & ~15;
      int o = loffs[i];
      for (int j = c; j < pad; j++) eb[o + j] = N;
    }
  }
}

__global__ __launch_bounds__(1024) void k_scan1(const int* __restrict__ deg,
                                                int* __restrict__ offs16,
                                                int* __restrict__ bsum, int N) {
  __shared__ int buf[1024];
  const int tid = threadIdx.x;
  const int gid = blockIdx.x * 1024 + tid;
  int v = (gid < N) ? ((deg[gid] + 15) & ~15) : 0;
  buf[tid] = v;
  __syncthreads();
  for (int off = 1; off < 1024; off <<= 1) {
    int x = (tid >= off) ? buf[tid - off] : 0;
    __syncthreads();
    buf[tid] += x;
    __syncthreads();
  }
  if (gid < N) offs16[gid] = buf[tid] - v;
  if (tid == 1023) bsum[blockIdx.x] = buf[1023];
}

__global__ __launch_bounds__(1024) void k_scan2(int* __restrict__ bsum, int nb) {
  __shared__ int buf[1024];
  const int tid = threadIdx.x;
  int v = (tid < nb) ? bsum[tid] : 0;
  buf[tid] = v;
  __syncthreads();
  for (int off = 1; off < 1024; off <<= 1) {
    int x = (tid >= off) ? buf[tid - off] : 0;
    __syncthreads();
    buf[tid] += x;
    __syncthreads();
  }
  if (tid < nb) bsum[tid] = buf[tid] - v;
}

// iteration-independent weight products
__global__ void k_prep(const float* __restrict__ Wq, const float* __restrict__ Wk,
                       const float* __restrict__ bq, const float* __restrict__ bk,
                       float* __restrict__ P, float* __restrict__ Q, float* __restrict__ K2,
                       float* __restrict__ pb, float* __restrict__ qb,
                       float* __restrict__ wb, float* __restrict__ kb,
                       float* __restrict__ sconst) {
  __shared__ float red[4];
  const int b = blockIdx.x, tid = threadIdx.x;
  if (b < 768) {
    const int f = b & 255, which = b >> 8;
    const float* A = (which == 2) ? Wk : Wq;
    const float* Bm = (which == 1) ? Wq : Wk;
    float acc = 0.0f;
    for (int m = 0; m < H; m++) acc = fmaf(A[f * H + m], Bm[tid * H + m], acc);
    float* D = (which == 0) ? P : ((which == 1) ? Q : K2);
    D[f * H + tid] = acc;
  } else {
    float a1 = 0, a2 = 0, a3 = 0, a4 = 0;
    for (int m = 0; m < H; m++) {
      float wqv = Wq[tid * H + m], wkv = Wk[tid * H + m];
      a1 = fmaf(wqv, bk[m], a1);
      a2 = fmaf(wqv, bq[m], a2);
      a3 = fmaf(wkv, bq[m], a3);
      a4 = fmaf(wkv, bk[m], a4);
    }
    pb[tid] = a1; qb[tid] = a2; wb[tid] = a3; kb[tid] = a4;
    float c0 = block_sum(bq[tid] * bk[tid], red);
    float c1 = block_sum(bq[tid] * bq[tid], red);
    float c2 = block_sum(bk[tid] * bk[tid], red);
    if (tid == 0) { sconst[0] = c0; sconst[1] = c1; sconst[2] = c2; }
  }
}

// R0 = relu(x@W1 + b1) -> bf16, plus layer-0 readout
__global__ void k_fc1(const float* __restrict__ x, const float* __restrict__ W1,
                      const float* __restrict__ b1, const float* __restrict__ Wr,
                      const float* __restrict__ br, const float* __restrict__ wgt,
                      ushort* __restrict__ R0, float* __restrict__ out, int N) {
  __shared__ __align__(16) float lx[16 * FIN];
  __shared__ float red2[4][16];
  const int tid = threadIdx.x;
  const int n0 = blockIdx.x * 16;
  for (int idx = tid; idx < 16 * FIN / 4; idx += 256)
    ((float4*)lx)[idx] = ((const float4*)(x + (size_t)n0 * FIN))[idx];
  __syncthreads();
  float acc[16];
  const float bias = b1[tid];
#pragma unroll
  for (int r = 0; r < 16; r++) acc[r] = bias;
  for (int f = 0; f < FIN; f++) {
    float wv = W1[f * H + tid];
#pragma unroll
    for (int r = 0; r < 16; r++) acc[r] = fmaf(lx[r * FIN + f], wv, acc[r]);
  }
  const float wr0 = Wr[tid];
#pragma unroll
  for (int r = 0; r < 16; r++) {
    acc[r] = fmaxf(acc[r], 0.0f);
    int n = n0 + r;
    if (n < N) R0[(size_t)n * H + tid] = f2bf(acc[r]);
  }
#pragma unroll
  for (int r = 0; r < 16; r++) {
    float s = wave_sum(acc[r] * wr0);
    if ((tid & 63) == 0) red2[tid >> 6][r] = s;
  }
  __syncthreads();
  if (tid < 16) {
    int n = n0 + tid;
    if (n < N)
      out[n] = wgt[0] * (red2[0][tid] + red2[1][tid] + red2[2][tid] + red2[3][tid] + br[0]);
  }
}

// ---------------- MFMA G = R^T R (transposed-LDS, b128 frags) ----------------
// Even 256-block chunk partition (critical path = ceil(TC/256) chunks).
__global__ __launch_bounds__(512, 2) void k_Gm(const ushort* __restrict__ Rb,
                                               const float* __restrict__ invs,
                                               ushort* __restrict__ Gslab,
                                               unsigned* __restrict__ Rf8,
                                               float* __restrict__ csl, int N) {
  __shared__ ushort sbT[2][256 * 32];  // 2 x 16 KB
  const int tid = threadIdx.x;
  const int lane = tid & 63;
  const int wid = tid >> 6;
  const int wrow = (wid & 1) * 128;
  const int wcol = (wid >> 1) * 64;
  const int l31 = lane & 31;
  const int lhi = lane >> 5;

  const int TC = (N + 31) >> 5;
  const int cbase = TC >> 8;
  const int crem = TC & 255;
  const int b = blockIdx.x;
  const int startc = b * cbase + min(b, crem);
  const int nch = cbase + (b < crem ? 1 : 0);
  const int rowbase = startc * 32;

  const int rp = tid >> 5;   // node pair (nodes 2rp, 2rp+1)
  const int fg = tid & 31;   // feature group (feats fg*8..fg*8+7)
  const int k2 = rp * 2;

  f32x16 acc[4][2];
#pragma unroll
  for (int s = 0; s < 4; s++)
#pragma unroll
    for (int t = 0; t < 2; t++)
#pragma unroll
      for (int e = 0; e < 16; e++) acc[s][t][e] = 0.0f;

  float cs[8];
#pragma unroll
  for (int i = 0; i < 8; i++) cs[i] = 0.0f;

  int4 la, lb;
  float sc0, sc1;

  auto load_chunk = [&](int ch) {
    int g0 = rowbase + ch * 32 + k2;
    const int4* s0 = (const int4*)(Rb + (size_t)g0 * H + fg * 8);
    const int4* s1 = (const int4*)(Rb + (size_t)(g0 + 1) * H + fg * 8);
    la = (g0 < N) ? s0[0] : make_int4(0, 0, 0, 0);
    lb = (g0 + 1 < N) ? s1[0] : make_int4(0, 0, 0, 0);
    sc0 = (g0 < N) ? invs[g0] : 0.0f;
    sc1 = (g0 + 1 < N) ? invs[g0 + 1] : 0.0f;
  };

  auto write_chunk = [&](int ch, int buf) {
    int g0 = rowbase + ch * 32 + k2;
    const ushort* pa = (const ushort*)&la;
    const ushort* pbu = (const ushort*)&lb;
    const int blk = (k2 & 24) ^ ((fg & 3) << 3);
    uint* dst = (uint*)sbT[buf];
#pragma unroll
    for (int i = 0; i < 8; i++) {
      float av = bf2f(pa[i]), bv = bf2f(pbu[i]);
      cs[i] += av + bv;
      unsigned val = (unsigned)pa[i] | ((unsigned)pbu[i] << 16);
      int f = fg * 8 + i;
      dst[f * 16 + ((blk + (k2 & 7)) >> 1)] = val;
    }
    if (g0 < N) {
      unsigned w0 = pack_fp8x4(bf2f(pa[0]) * sc0, bf2f(pa[1]) * sc0,
                               bf2f(pa[2]) * sc0, bf2f(pa[3]) * sc0);
      unsigned w1 = pack_fp8x4(bf2f(pa[4]) * sc0, bf2f(pa[5]) * sc0,
                               bf2f(pa[6]) * sc0, bf2f(pa[7]) * sc0);
      *(uint2*)&Rf8[(size_t)g0 * 64 + fg * 2] = make_uint2(w0, w1);
    }
    if (g0 + 1 < N) {
      unsigned w0 = pack_fp8x4(bf2f(pbu[0]) * sc1, bf2f(pbu[1]) * sc1,
                               bf2f(pbu[2]) * sc1, bf2f(pbu[3]) * sc1);
      unsigned w1 = pack_fp8x4(bf2f(pbu[4]) * sc1, bf2f(pbu[5]) * sc1,
                               bf2f(pbu[6]) * sc1, bf2f(pbu[7]) * sc1);
      *(uint2*)&Rf8[(size_t)(g0 + 1) * 64 + fg * 2] = make_uint2(w0, w1);
    }
  };

  auto compute = [&](int buf) {
    const ushort* bp = sbT[buf];
#pragma unroll
    for (int ks = 0; ks < 2; ks++) {
      const int kb = ks * 16 + lhi * 8;
      FragU fr[6];
#pragma unroll
      for (int s = 0; s < 6; s++) {
        const int cb = (s < 4) ? (wrow + 32 * s + l31) : (wcol + 32 * (s - 4) + l31);
        const int off = cb * 32 + (kb ^ (((cb >> 3) & 3) << 3));
        *(int4*)fr[s].u = *(const int4*)(bp + off);
      }
#pragma unroll
      for (int s = 0; s < 4; s++)
#pragma unroll
        for (int t = 0; t < 2; t++)
          acc[s][t] = __builtin_amdgcn_mfma_f32_32x32x16_bf16(fr[s].v, fr[4 + t].v,
                                                              acc[s][t], 0, 0, 0);
    }
  };

  load_chunk(0);
  write_chunk(0, 0);
  __syncthreads();
  int cur = 0;
  for (int c = 0; c < nch; c++) {
    if (c + 1 < nch) load_chunk(c + 1);
    compute(cur);
    if (c + 1 < nch) write_chunk(c + 1, cur ^ 1);
    __syncthreads();
    cur ^= 1;
  }

  // non-atomic bf16 partial-G slab write
  ushort* Gs = Gslab + (size_t)b * 65536;
#pragma unroll
  for (int s = 0; s < 4; s++)
#pragma unroll
    for (int t = 0; t < 2; t++) {
      const int n0c = wcol + 32 * t + l31;
#pragma unroll
      for (int r = 0; r < 16; r++) {
        const int row = wrow + 32 * s + (r & 3) + 8 * (r >> 2) + 4 * lhi;
        Gs[row * 256 + n0c] = f2bf(acc[s][t][r]);
      }
    }

  // column-sum slab (non-atomic)
  __syncthreads();
  float* fl = (float*)sbT;  // scratch
#pragma unroll
  for (int i = 0; i < 8; i++) fl[rp * 256 + fg * 8 + i] = cs[i];
  __syncthreads();
  if (tid < 256) {
    float v = 0.0f;
    for (int j = 0; j < 16; j++) v += fl[j * 256 + tid];
    csl[(size_t)b * 256 + tid] = v;
  }
}

// reduce bf16 slabs -> fp32 G; also vsum and <G,Q>/<G,K2> partials (non-atomic)
__global__ void k_Gr(const ushort* __restrict__ Gslab, const float* __restrict__ csl,
                     const float* __restrict__ Q, const float* __restrict__ K2,
                     float* __restrict__ G, float* __restrict__ vsum,
                     float2* __restrict__ spart, int nslab) {
  __shared__ float red[4];
  const int b = blockIdx.x, t = threadIdx.x;
  const int i = b * 256 + t;
  float s0 = 0, s1 = 0, s2 = 0, s3 = 0;
  int j = 0;
  for (; j + 3 < nslab; j += 4) {
    s0 += bf2f(Gslab[(size_t)j * 65536 + i]);
    s1 += bf2f(Gslab[(size_t)(j + 1) * 65536 + i]);
    s2 += bf2f(Gslab[(size_t)(j + 2) * 65536 + i]);
    s3 += bf2f(Gslab[(size_t)(j + 3) * 65536 + i]);
  }
  float s = s0 + s1 + s2 + s3;
  for (; j < nslab; j++) s += bf2f(Gslab[(size_t)j * 65536 + i]);
  G[i] = s;
  float dq = block_sum(s * Q[i], red);
  float dk = block_sum(s * K2[i], red);
  if (t == 0) spart[b] = make_float2(dq, dk);
  float v = 0.0f;
  for (int u = t; u < nslab; u += 256) v += csl[(size_t)u * 256 + b];
  v = block_sum(v, red);
  if (t == 0) vsum[b] = v;
}

// per-iteration small products; block 258 finalizes scal
__global__ void k_small(const float* __restrict__ G, const float* __restrict__ vsum,
                        const float* __restrict__ P, const float* __restrict__ pb,
                        const float* __restrict__ wb, const float* __restrict__ sconst,
                        const float* __restrict__ qb, const float* __restrict__ kbv,
                        const float2* __restrict__ spart,
                        ushort* __restrict__ Mt, float* __restrict__ cvec,
                        float* __restrict__ dvec, float* __restrict__ scal, int N) {
  __shared__ float red[4];
  const int b = blockIdx.x, tid = threadIdx.x;
  if (b < 256) {
    float acc = 0.0f;
    for (int m = 0; m < H; m++) acc = fmaf(P[b * H + m], G[m * H + tid], acc);
    Mt[(size_t)tid * H + b] = f2bf(acc + pb[b] * vsum[tid]);
  } else if (b == 256) {
    float acc = 0.0f;
    for (int f = 0; f < H; f++) acc = fmaf(wb[f], G[f * H + tid], acc);
    cvec[tid] = acc + sconst[0] * vsum[tid];
  } else if (b == 257) {
    float acc = 0.0f;
    for (int m = 0; m < H; m++) acc = fmaf(P[tid * H + m], vsum[m], acc);
    dvec[tid] = acc + (float)N * pb[tid];
  } else {
    float2 sp = spart[tid];
    float dq = block_sum(sp.x, red);
    float dk = block_sum(sp.y, red);
    float s1 = block_sum(qb[tid] * vsum[tid], red);
    float s2 = block_sum(kbv[tid] * vsum[tid], red);
    float s3 = block_sum(wb[tid] * vsum[tid], red);
    if (tid == 0) {
      float sq = dq + 2.0f * s1 + (float)N * sconst[1];
      float sk = dk + 2.0f * s2 + (float)N * sconst[2];
      scal[2] = 1.0f / (sqrtf(sq) * sqrtf(sk));
      scal[3] = s3 + (float)N * sconst[0];
    }
  }
}

// ---------------- MFMA num = R * M (bf16 in, bf16 out) ----------------
__global__ __launch_bounds__(512) void k_N(const ushort* __restrict__ Rb,
                                           const ushort* __restrict__ Mt,
                                           ushort* __restrict__ numb, int N) {
  const int tid = threadIdx.x;
  const int lane = tid & 63;
  const int wid = tid >> 6;
  const int l31 = lane & 31;
  const int lhi = lane >> 5;
  const int wrow = (wid & 3) * 32;
  const int wcol = (wid >> 2) * 128;
  const int rowbase = blockIdx.x * 128;

  f32x16 acc[4];
#pragma unroll
  for (int t = 0; t < 4; t++)
#pragma unroll
    for (int e = 0; e < 16; e++) acc[t][e] = 0.0f;

  const ushort* aptr = Rb + (size_t)(rowbase + wrow + l31) * H;

  for (int kc = 0; kc < 16; kc++) {
    const int kb = kc * 16 + lhi * 8;
    FragU fa;
    *(int4*)fa.u = *(const int4*)(aptr + kb);
    FragU fb0, fb1, fb2, fb3;
    *(int4*)fb0.u = *(const int4*)(Mt + (size_t)(wcol + 0 + l31) * H + kb);
    *(int4*)fb1.u = *(const int4*)(Mt + (size_t)(wcol + 32 + l31) * H + kb);
    *(int4*)fb2.u = *(const int4*)(Mt + (size_t)(wcol + 64 + l31) * H + kb);
    *(int4*)fb3.u = *(const int4*)(Mt + (size_t)(wcol + 96 + l31) * H + kb);
    acc[0] = __builtin_amdgcn_mfma_f32_32x32x16_bf16(fa.v, fb0.v, acc[0], 0, 0, 0);
    acc[1] = __builtin_amdgcn_mfma_f32_32x32x16_bf16(fa.v, fb1.v, acc[1], 0, 0, 0);
    acc[2] = __builtin_amdgcn_mfma_f32_32x32x16_bf16(fa.v, fb2.v, acc[2], 0, 0, 0);
    acc[3] = __builtin_amdgcn_mfma_f32_32x32x16_bf16(fa.v, fb3.v, acc[3], 0, 0, 0);
  }

#pragma unroll
  for (int t = 0; t < 4; t++) {
    const int col = wcol + 32 * t + l31;
#pragma unroll
    for (int r = 0; r < 16; r++) {
      const int row = rowbase + wrow + (r & 3) + 8 * (r >> 2) + 4 * lhi;
      if (row < N) numb[(size_t)row * H + col] = f2bf(acc[t][r]);
    }
  }
}

// slim fused: half-wave per row, fp8 gather (uint2 = 2 rows/load), LN, readout
__global__ __launch_bounds__(256) void k_C(
    const ushort* __restrict__ Rb, ushort* __restrict__ Rnext,
    const ushort* __restrict__ numb, const unsigned* __restrict__ Rf8,
    const int* __restrict__ eb, const float* __restrict__ invs,
    const float* __restrict__ cvec, const float* __restrict__ dvec,
    const float* __restrict__ vsum, const float* __restrict__ scal,
    const int* __restrict__ offs16, const int* __restrict__ deg,
    const float* __restrict__ alphap, const float* __restrict__ gamma,
    const float* __restrict__ beta, const float* __restrict__ Wr,
    const float* __restrict__ br, const float* __restrict__ wgt,
    float* __restrict__ out, int N, int layer, int last) {
  const int tid = threadIdx.x, lane = tid & 63, wv = tid >> 6;
  const int half = lane >> 5, hl = lane & 31;
  const int d0 = hl * 8;
  const int n0 = blockIdx.x * 32 + wv * 8;

  const float invn = scal[2], denc = scal[3];
  const float al = alphap[0], om = 1.0f - al;
  const float4 dvA = *(const float4*)&dvec[d0];
  const float4 dvB = *(const float4*)&dvec[d0 + 4];
  const float4 cvA = *(const float4*)&cvec[d0];
  const float4 cvB = *(const float4*)&cvec[d0 + 4];
  const float4 vsA = *(const float4*)&vsum[d0];
  const float4 vsB = *(const float4*)&vsum[d0 + 4];
  const float4 gmA = *(const float4*)&gamma[d0];
  const float4 gmB = *(const float4*)&gamma[d0 + 4];
  const float4 btA = *(const float4*)&beta[d0];
  const float4 btB = *(const float4*)&beta[d0 + 4];
  const float4 wrA = *(const float4*)&Wr[layer * H + d0];
  const float4 wrB = *(const float4*)&Wr[layer * H + d0 + 4];
  const float wl = wgt[layer], bl = br[layer];

  for (int r = 0; r < 4; r++) {
    const int n = n0 + r * 2 + half;
    const bool valid = n < N;
    const int ns = valid ? n : 0;

    const int4 rv = *(const int4*)&Rb[(size_t)ns * H + d0];
    const int4 nv = *(const int4*)&numb[(size_t)ns * H + d0];
    const ushort* rp = (const ushort*)&rv;
    const ushort* np = (const ushort*)&nv;
    float old[8], num[8];
#pragma unroll
    for (int j = 0; j < 8; j++) { old[j] = bf2f(rp[j]); num[j] = bf2f(np[j]); }

    float p = old[0] * dvA.x + old[1] * dvA.y + old[2] * dvA.z + old[3] * dvA.w +
              old[4] * dvB.x + old[5] * dvB.y + old[6] * dvB.z + old[7] * dvB.w;
    p = half_sum(p);
    const float rden = 1.0f / ((p + denc) * invn + (float)N);

    f32x2 a01 = {0.f, 0.f}, a23 = {0.f, 0.f}, a45 = {0.f, 0.f}, a67 = {0.f, 0.f};
    const int st = offs16[ns];
    const int nbch = valid ? ((deg[ns] + 15) >> 4) : 0;
    const int4* pe = (const int4*)(eb + st);
    const int woff = hl * 2;
    for (int b = 0; b < nbch; b++, pe += 4) {
      int4 q0 = pe[0], q1 = pe[1], q2 = pe[2], q3 = pe[3];
      const int srcs[16] = {q0.x, q0.y, q0.z, q0.w, q1.x, q1.y, q1.z, q1.w,
                            q2.x, q2.y, q2.z, q2.w, q3.x, q3.y, q3.z, q3.w};
      uint2 g[16];
#pragma unroll
      for (int i = 0; i < 16; i++)
        g[i] = *(const uint2*)&Rf8[((size_t)srcs[i] << 6) + woff];
#pragma unroll
      for (int i = 0; i < 16; i++) {
        unpack_fp8x2_acc(a01, a23, g[i].x);
        unpack_fp8x2_acc(a45, a67, g[i].y);
      }
    }
    const float sn = invs[ns];
    float ag[8] = {a01[0] * sn, a01[1] * sn, a23[0] * sn, a23[1] * sn,
                   a45[0] * sn, a45[1] * sn, a67[0] * sn, a67[1] * sn};

    const float cva[8] = {cvA.x, cvA.y, cvA.z, cvA.w, cvB.x, cvB.y, cvB.z, cvB.w};
    const float vsa[8] = {vsA.x, vsA.y, vsA.z, vsA.w, vsB.x, vsB.y, vsB.z, vsB.w};
    float hv[8];
#pragma unroll
    for (int j = 0; j < 8; j++)
      hv[j] = al * (((num[j] + cva[j]) * invn + vsa[j]) * rden + ag[j]) + om * old[j];

    float s = 0.0f, s2 = 0.0f;
#pragma unroll
    for (int j = 0; j < 8; j++) { s += hv[j]; s2 += hv[j] * hv[j]; }
    s = half_sum(s);
    s2 = half_sum(s2);
    const float mu = s * (1.0f / H);
    const float var = s2 * (1.0f / H) - mu * mu;
    const float rs = rsqrtf(var + LN_EPS);

    const float gma[8] = {gmA.x, gmA.y, gmA.z, gmA.w, gmB.x, gmB.y, gmB.z, gmB.w};
    const float bta[8] = {btA.x, btA.y, btA.z, btA.w, btB.x, btB.y, btB.z, btB.w};
    const float wra[8] = {wrA.x, wrA.y, wrA.z, wrA.w, wrB.x, wrB.y, wrB.z, wrB.w};
    float y[8], rp2 = 0.0f;
    ushort yo[8];
#pragma unroll
    for (int j = 0; j < 8; j++) {
      y[j] = (hv[j] - mu) * rs * gma[j] + bta[j];
      yo[j] = f2bf(y[j]);
      rp2 += y[j] * wra[j];
    }
    if (!last && valid) *(int4*)&Rnext[(size_t)n * H + d0] = *(int4*)yo;
    rp2 = half_sum(rp2);
    if (hl == 0 && valid) out[n] += wl * (rp2 + bl);
  }
}

// ---------------- host ----------------

extern "C" void kernel_launch(void* const* d_in, const int* in_sizes, int n_in,
                              void* d_out, int out_size, void* d_ws, size_t ws_size,
                              hipStream_t stream) {
  const float* x = (const float*)d_in[0];
  const int* ei = (const int*)d_in[1];
  const float* W1 = (const float*)d_in[2];
  const float* b1 = (const float*)d_in[3];
  const float* Wq = (const float*)d_in[4];
  const float* bq = (const float*)d_in[5];
  const float* Wk = (const float*)d_in[6];
  const float* bk = (const float*)d_in[7];
  const float* gamma = (const float*)d_in[8];
  const float* beta = (const float*)d_in[9];
  const float* alphap = (const float*)d_in[10];
  const float* Wr = (const float*)d_in[11];
  const float* br = (const float*)d_in[12];
  const float* wgt = (const float*)d_in[13];
  float* out = (float*)d_out;

  const int N = in_sizes[0] / FIN;
  const int E = in_sizes[1] / 2;
  const int* row = ei;
  const int* col = ei + E;

  char* w = (char*)d_ws;
  auto alloc = [&](size_t bytes) -> char* {
    char* p = w;
    w += (bytes + 255) & ~(size_t)255;
    return p;
  };
  const size_t RB = (size_t)(N + 128) * H * sizeof(ushort);
  ushort* Rb0 = (ushort*)alloc(RB);
  ushort* Rb1 = (ushort*)alloc(RB);   // aliased as super-bin record scratch in setup
  ushort* numb = (ushort*)alloc(RB);  // aliased as bf16 G-slab scratch per iter
  unsigned* Rf8 = (unsigned*)alloc((size_t)(N + 1) * 64 * sizeof(unsigned));  // +1 zero row
  ushort* Mt = (ushort*)alloc(H * H * sizeof(ushort));
  float* G = (float*)alloc(H * H * sizeof(float));
  float* vsum = (float*)alloc(1024);
  float* scal = (float*)alloc(256);
  float* cvec = (float*)alloc(1024);
  float* dvec = (float*)alloc(1024);
  float* P = (float*)alloc(H * H * sizeof(float));
  float* Q = (float*)alloc(H * H * sizeof(float));
  float* K2 = (float*)alloc(H * H * sizeof(float));
  float* pb = (float*)alloc(1024);
  float* qb = (float*)alloc(1024);
  float* wb = (float*)alloc(1024);
  float* kb = (float*)alloc(1024);
  float* sconst = (float*)alloc(256);
  int* deg = (int*)alloc((size_t)N * 4);
  float* invs = (float*)alloc((size_t)N * 4);
  int* offs16 = (int*)alloc((size_t)(N + 1) * 4);
  int* bsum = (int*)alloc(1024 * 4);
  int* gcnt = (int*)alloc(64 * 4);
  const int nbG = 256;  // even chunk partition
  float* csl = (float*)alloc((size_t)nbG * 256 * sizeof(float));
  float2* spart = (float2*)alloc(256 * sizeof(float2));
  size_t EPAD = (size_t)E + 16 * (size_t)N;
  EPAD = (EPAD + 3) & ~(size_t)3;
  int* eb = (int*)alloc(EPAD * sizeof(int));

  const int NSB = (N + (1 << SBW) - 1) >> SBW;  // super-bins (<=64 for N<=131072)
  int cap2 = (E / (NSB > 0 ? NSB : 1)) * 2 + 4096;
  cap2 = (cap2 + 3) & ~3;
  unsigned* breg = (unsigned*)Rb1;  // NSB*cap2*4B <= RB
  ushort* Gslab = (ushort*)numb;    // 256*128KB = 32MB <= RB

  hipMemsetAsync(gcnt, 0, 64 * 4, stream);
  hipMemsetAsync(Rf8 + (size_t)N * 64, 0, 64 * sizeof(unsigned), stream);

  const int nblk = (N + 1023) / 1024;
  const int nbB1 = (E + EPB - 1) / EPB;
  k_b1<<<nbB1, 512, 0, stream>>>(row, col, breg, gcnt, cap2, E, NSB);
  k_degB2<<<NSB, 512, 0, stream>>>(breg, gcnt, cap2, deg, invs, N);
  k_scan1<<<nblk, 1024, 0, stream>>>(deg, offs16, bsum, N);
  k_scan2<<<1, 1024, 0, stream>>>(bsum, nblk);
  k_b2<<<NSB, 512, 0, stream>>>(breg, gcnt, cap2, offs16, bsum, eb, N);
  k_prep<<<769, 256, 0, stream>>>(Wq, Wk, bq, bk, P, Q, K2, pb, qb, wb, kb, sconst);
  const int gRows16 = (N + 15) / 16;
  k_fc1<<<gRows16, 256, 0, stream>>>(x, W1, b1, Wr, br, wgt, Rb0, out, N);

  const int nbN = (N + 127) / 128;
  const int gRows32 = (N + 31) / 32;
  ushort* Rc = Rb0;
  ushort* Rn = Rb1;
  for (int it = 1; it <= 3; ++it) {
    k_Gm<<<nbG, 512, 0, stream>>>(Rc, invs, Gslab, Rf8, csl, N);
    k_Gr<<<256, 256, 0, stream>>>(Gslab, csl, Q, K2, G, vsum, spart, nbG);
    k_small<<<259, 256, 0, stream>>>(G, vsum, P, pb, wb, sconst, qb, kb, spart,
                                     Mt, cvec, dvec, scal, N);
    k_N<<<nbN, 512, 0, stream>>>(Rc, Mt, numb, N);
    k_C<<<gRows32, 256, 0, stream>>>(Rc, Rn, numb, Rf8, eb, invs, cvec, dvec, vsum, scal,
                                     offs16, deg, alphap, gamma, beta, Wr, br, wgt, out,
                                     N, it, (it == 3) ? 1 : 0);
    ushort* t = Rc; Rc = Rn; Rn = t;
  }
}

// Round 13
// 1058.760 us; speedup vs baseline: 4.8778x; 1.0445x over previous
//
#include <hip/hip_runtime.h>

#define H 256
#define FIN 58
#define LN_EPS 1e-5f
#define EPB 8192     // k_b1 edges per block
#define SBW 11       // super-bin width: 2048 dests

typedef __bf16 bf16x8 __attribute__((ext_vector_type(8)));
typedef float f32x16 __attribute__((ext_vector_type(16)));
typedef float f32x2 __attribute__((ext_vector_type(2)));

union FragU {
  ushort u[8];
  bf16x8 v;
};

// ---------------- utilities ----------------

__device__ __forceinline__ float wave_sum(float v) {
#pragma unroll
  for (int off = 1; off < 64; off <<= 1) v += __shfl_xor(v, off, 64);
  return v;
}

__device__ __forceinline__ float half_sum(float v) {
#pragma unroll
  for (int off = 1; off < 32; off <<= 1) v += __shfl_xor(v, off, 64);
  return v;
}

__device__ __forceinline__ float block_sum(float v, volatile float* red) {
  const int tid = threadIdx.x;
  v = wave_sum(v);
  __syncthreads();
  if ((tid & 63) == 0) red[tid >> 6] = v;
  __syncthreads();
  return red[0] + red[1] + red[2] + red[3];
}

__device__ __forceinline__ ushort f2bf(float f) {
  unsigned u = __float_as_uint(f);
  unsigned r = (u + 0x7FFFu + ((u >> 16) & 1u)) >> 16;
  return (ushort)r;
}

__device__ __forceinline__ float bf2f(ushort u) {
  return __uint_as_float((unsigned)u << 16);
}

// ---- fp8 e4m3 pack/unpack (HW path on gfx950, manual fallback) ----
#if __has_builtin(__builtin_amdgcn_cvt_pk_fp8_f32) && __has_builtin(__builtin_amdgcn_cvt_pk_f32_fp8)
__device__ __forceinline__ unsigned pack_fp8x4(float a, float b, float c, float d) {
  int v = 0;
  v = __builtin_amdgcn_cvt_pk_fp8_f32(a, b, v, false);
  v = __builtin_amdgcn_cvt_pk_fp8_f32(c, d, v, true);
  return (unsigned)v;
}
__device__ __forceinline__ void unpack_fp8x2_acc(f32x2& lo, f32x2& hi, unsigned v) {
  lo += __builtin_amdgcn_cvt_pk_f32_fp8((int)v, false);
  hi += __builtin_amdgcn_cvt_pk_f32_fp8((int)v, true);
}
#else
__device__ __forceinline__ unsigned char f2e4m3_1(float f) {
  unsigned u = __float_as_uint(f);
  unsigned s = (u >> 31) << 7;
  float a = fabsf(f);
  if (a >= 448.0f) return (unsigned char)(s | 0x7E);
  if (a < 0.0009765625f) return (unsigned char)s;
  int e;
  float m = frexpf(a, &e);
  int E = e - 1 + 7;
  if (E >= 1) {
    int mm = (int)rintf((m * 2.0f - 1.0f) * 8.0f);
    if (mm == 8) { mm = 0; E++; }
    return (unsigned char)(s | (E << 3) | mm);
  }
  int mm = (int)rintf(a * 512.0f);
  if (mm > 7) return (unsigned char)(s | (1 << 3));
  return (unsigned char)(s | mm);
}
__device__ __forceinline__ unsigned pack_fp8x4(float a, float b, float c, float d) {
  return (unsigned)f2e4m3_1(a) | ((unsigned)f2e4m3_1(b) << 8) |
         ((unsigned)f2e4m3_1(c) << 16) | ((unsigned)f2e4m3_1(d) << 24);
}
__device__ __forceinline__ float e4m3f_1(unsigned v) {
  int s = (v >> 7) & 1, E = (v >> 3) & 15, m = v & 7;
  float mag = E ? ldexpf(1.0f + m * 0.125f, E - 7) : ldexpf((float)m, -9);
  return s ? -mag : mag;
}
__device__ __forceinline__ void unpack_fp8x2_acc(f32x2& lo, f32x2& hi, unsigned v) {
  lo[0] += e4m3f_1(v & 255);
  lo[1] += e4m3f_1((v >> 8) & 255);
  hi[0] += e4m3f_1((v >> 16) & 255);
  hi[1] += e4m3f_1(v >> 24);
}
#endif

// ---------------- setup: radix-style CSR build ----------------

__global__ __launch_bounds__(512) void k_b1(const int* __restrict__ row,
                                            const int* __restrict__ col,
                                            unsigned* __restrict__ breg,
                                            int* __restrict__ gcnt,
                                            int cap2, int E, int nsb) {
  __shared__ unsigned stage[EPB];  // 32 KB
  __shared__ int lh[65], lbase[65], lcur[64], gclaim[64];
  const int tid = threadIdx.x;
  const int e0 = blockIdx.x * EPB;
  const int cnt = min(EPB, E - e0);
  if (tid < 64) lh[tid] = 0;
  __syncthreads();
  for (int i = tid; i < cnt; i += 512) atomicAdd(&lh[col[e0 + i] >> SBW], 1);
  __syncthreads();
  if (tid == 0) {
    int acc = 0;
    for (int b = 0; b < nsb; b++) { lbase[b] = acc; acc += lh[b]; }
    lbase[nsb] = acc;
  }
  __syncthreads();
  if (tid < nsb) {
    gclaim[tid] = atomicAdd(&gcnt[tid], lh[tid]);
    lcur[tid] = lbase[tid];
  }
  __syncthreads();
  for (int i = tid; i < cnt; i += 512) {
    int c = col[e0 + i];
    int b = c >> SBW;
    int s = atomicAdd(&lcur[b], 1);
    stage[s] = ((unsigned)row[e0 + i] << SBW) | (unsigned)(c & ((1 << SBW) - 1));
  }
  __syncthreads();
  for (int i = tid; i < cnt; i += 512) {
    int lo = 0, hi = nsb;
    while (hi - lo > 1) {
      int mid = (lo + hi) >> 1;
      if (lbase[mid] <= i) lo = mid; else hi = mid;
    }
    int off = gclaim[lo] + (i - lbase[lo]);
    if (off < cap2) breg[(size_t)lo * cap2 + off] = stage[i];
  }
}

// per-super-bin degree count + invs (fused)
__global__ __launch_bounds__(512) void k_degB2(const unsigned* __restrict__ breg,
                                               const int* __restrict__ gcnt, int cap2,
                                               int* __restrict__ deg,
                                               float* __restrict__ invs, int N) {
  __shared__ int lcnt[1 << SBW];
  const int b = blockIdx.x, tid = threadIdx.x, base = b << SBW;
  for (int i = tid; i < (1 << SBW); i += 512) lcnt[i] = 0;
  __syncthreads();
  const int cnt = min(gcnt[b], cap2);
  const unsigned* p = breg + (size_t)b * cap2;
  for (int i = tid; i < cnt; i += 512) atomicAdd(&lcnt[p[i] & ((1 << SBW) - 1)], 1);
  __syncthreads();
  for (int i = tid; i < (1 << SBW); i += 512) {
    int d = base + i;
    if (d < N) {
      int c = lcnt[i];
      deg[d] = c;
      invs[d] = (c > 0) ? (1.0f / sqrtf((float)c)) : 0.0f;
    }
  }
}

// level 2: place into final CSR; applies bsum fix-up and writes final offs16 back
__global__ __launch_bounds__(512) void k_b2(const unsigned* __restrict__ breg,
                                            const int* __restrict__ gcnt, int cap2,
                                            int* __restrict__ offs16,
                                            const int* __restrict__ bsum,
                                            int* __restrict__ eb, int N) {
  __shared__ int loffs[1 << SBW];
  __shared__ int lcur[1 << SBW];
  const int b = blockIdx.x, tid = threadIdx.x, base = b << SBW;
  for (int i = tid; i < (1 << SBW); i += 512) {
    int d = base + i;
    if (d < N) {
      int o = offs16[d] + bsum[d >> 10];
      loffs[i] = o;
      offs16[d] = o;  // final value for k_C
    } else {
      loffs[i] = 0;
    }
    lcur[i] = 0;
  }
  __syncthreads();
  const int cnt = min(gcnt[b], cap2);
  const unsigned* p = breg + (size_t)b * cap2;
  for (int i = tid; i < cnt; i += 512) {
    unsigned rc = p[i];
    int lc = rc & ((1 << SBW) - 1);
    int slot = atomicAdd(&lcur[lc], 1);
    eb[loffs[lc] + slot] = (int)(rc >> SBW);
  }
  __syncthreads();
  for (int i = tid; i < (1 << SBW); i += 512) {
    int d = base + i;
    if (d < N) {
      int c = lcur[i];
      int pad = (c + 15) & ~15;
      int o = loffs[i];
      for (int j = c; j < pad; j++) eb[o + j] = N;
    }
  }
}

__global__ __launch_bounds__(1024) void k_scan1(const int* __restrict__ deg,
                                                int* __restrict__ offs16,
                                                int* __restrict__ bsum, int N) {
  __shared__ int buf[1024];
  const int tid = threadIdx.x;
  const int gid = blockIdx.x * 1024 + tid;
  int v = (gid < N) ? ((deg[gid] + 15) & ~15) : 0;
  buf[tid] = v;
  __syncthreads();
  for (int off = 1; off < 1024; off <<= 1) {
    int x = (tid >= off) ? buf[tid - off] : 0;
    __syncthreads();
    buf[tid] += x;
    __syncthreads();
  }
  if (gid < N) offs16[gid] = buf[tid] - v;
  if (tid == 1023) bsum[blockIdx.x] = buf[1023];
}

__global__ __launch_bounds__(1024) void k_scan2(int* __restrict__ bsum, int nb) {
  __shared__ int buf[1024];
  const int tid = threadIdx.x;
  int v = (tid < nb) ? bsum[tid] : 0;
  buf[tid] = v;
  __syncthreads();
  for (int off = 1; off < 1024; off <<= 1) {
    int x = (tid >= off) ? buf[tid - off] : 0;
    __syncthreads();
    buf[tid] += x;
    __syncthreads();
  }
  if (tid < nb) bsum[tid] = buf[tid] - v;
}

// iteration-independent weight products
__global__ void k_prep(const float* __restrict__ Wq, const float* __restrict__ Wk,
                       const float* __restrict__ bq, const float* __restrict__ bk,
                       float* __restrict__ P, float* __restrict__ Q, float* __restrict__ K2,
                       float* __restrict__ pb, float* __restrict__ qb,
                       float* __restrict__ wb, float* __restrict__ kb,
                       float* __restrict__ sconst) {
  __shared__ float red[4];
  const int b = blockIdx.x, tid = threadIdx.x;
  if (b < 768) {
    const int f = b & 255, which = b >> 8;
    const float* A = (which == 2) ? Wk : Wq;
    const float* Bm = (which == 1) ? Wq : Wk;
    float acc = 0.0f;
    for (int m = 0; m < H; m++) acc = fmaf(A[f * H + m], Bm[tid * H + m], acc);
    float* D = (which == 0) ? P : ((which == 1) ? Q : K2);
    D[f * H + tid] = acc;
  } else {
    float a1 = 0, a2 = 0, a3 = 0, a4 = 0;
    for (int m = 0; m < H; m++) {
      float wqv = Wq[tid * H + m], wkv = Wk[tid * H + m];
      a1 = fmaf(wqv, bk[m], a1);
      a2 = fmaf(wqv, bq[m], a2);
      a3 = fmaf(wkv, bq[m], a3);
      a4 = fmaf(wkv, bk[m], a4);
    }
    pb[tid] = a1; qb[tid] = a2; wb[tid] = a3; kb[tid] = a4;
    float c0 = block_sum(bq[tid] * bk[tid], red);
    float c1 = block_sum(bq[tid] * bq[tid], red);
    float c2 = block_sum(bk[tid] * bk[tid], red);
    if (tid == 0) { sconst[0] = c0; sconst[1] = c1; sconst[2] = c2; }
  }
}

// R0 = relu(x@W1 + b1) -> bf16, plus layer-0 readout
__global__ void k_fc1(const float* __restrict__ x, const float* __restrict__ W1,
                      const float* __restrict__ b1, const float* __restrict__ Wr,
                      const float* __restrict__ br, const float* __restrict__ wgt,
                      ushort* __restrict__ R0, float* __restrict__ out, int N) {
  __shared__ __align__(16) float lx[16 * FIN];
  __shared__ float red2[4][16];
  const int tid = threadIdx.x;
  const int n0 = blockIdx.x * 16;
  for (int idx = tid; idx < 16 * FIN / 4; idx += 256)
    ((float4*)lx)[idx] = ((const float4*)(x + (size_t)n0 * FIN))[idx];
  __syncthreads();
  float acc[16];
  const float bias = b1[tid];
#pragma unroll
  for (int r = 0; r < 16; r++) acc[r] = bias;
  for (int f = 0; f < FIN; f++) {
    float wv = W1[f * H + tid];
#pragma unroll
    for (int r = 0; r < 16; r++) acc[r] = fmaf(lx[r * FIN + f], wv, acc[r]);
  }
  const float wr0 = Wr[tid];
#pragma unroll
  for (int r = 0; r < 16; r++) {
    acc[r] = fmaxf(acc[r], 0.0f);
    int n = n0 + r;
    if (n < N) R0[(size_t)n * H + tid] = f2bf(acc[r]);
  }
#pragma unroll
  for (int r = 0; r < 16; r++) {
    float s = wave_sum(acc[r] * wr0);
    if ((tid & 63) == 0) red2[tid >> 6][r] = s;
  }
  __syncthreads();
  if (tid < 16) {
    int n = n0 + tid;
    if (n < N)
      out[n] = wgt[0] * (red2[0][tid] + red2[1][tid] + red2[2][tid] + red2[3][tid] + br[0]);
  }
}

// ---------------- MFMA G = R^T R (transposed-LDS, b128 frags) ----------------
// Even 256-block chunk partition (critical path = ceil(TC/256) chunks).
__global__ __launch_bounds__(512, 2) void k_Gm(const ushort* __restrict__ Rb,
                                               const float* __restrict__ invs,
                                               ushort* __restrict__ Gslab,
                                               unsigned* __restrict__ Rf8,
                                               float* __restrict__ csl, int N) {
  __shared__ ushort sbT[2][256 * 32];  // 2 x 16 KB
  const int tid = threadIdx.x;
  const int lane = tid & 63;
  const int wid = tid >> 6;
  const int wrow = (wid & 1) * 128;
  const int wcol = (wid >> 1) * 64;
  const int l31 = lane & 31;
  const int lhi = lane >> 5;

  const int TC = (N + 31) >> 5;
  const int cbase = TC >> 8;
  const int crem = TC & 255;
  const int b = blockIdx.x;
  const int startc = b * cbase + min(b, crem);
  const int nch = cbase + (b < crem ? 1 : 0);
  const int rowbase = startc * 32;

  const int rp = tid >> 5;   // node pair (nodes 2rp, 2rp+1)
  const int fg = tid & 31;   // feature group (feats fg*8..fg*8+7)
  const int k2 = rp * 2;

  f32x16 acc[4][2];
#pragma unroll
  for (int s = 0; s < 4; s++)
#pragma unroll
    for (int t = 0; t < 2; t++)
#pragma unroll
      for (int e = 0; e < 16; e++) acc[s][t][e] = 0.0f;

  float cs[8];
#pragma unroll
  for (int i = 0; i < 8; i++) cs[i] = 0.0f;

  int4 la, lb;
  float sc0, sc1;

  auto load_chunk = [&](int ch) {
    int g0 = rowbase + ch * 32 + k2;
    const int4* s0 = (const int4*)(Rb + (size_t)g0 * H + fg * 8);
    const int4* s1 = (const int4*)(Rb + (size_t)(g0 + 1) * H + fg * 8);
    la = (g0 < N) ? s0[0] : make_int4(0, 0, 0, 0);
    lb = (g0 + 1 < N) ? s1[0] : make_int4(0, 0, 0, 0);
    sc0 = (g0 < N) ? invs[g0] : 0.0f;
    sc1 = (g0 + 1 < N) ? invs[g0 + 1] : 0.0f;
  };

  auto write_chunk = [&](int ch, int buf) {
    int g0 = rowbase + ch * 32 + k2;
    const ushort* pa = (const ushort*)&la;
    const ushort* pbu = (const ushort*)&lb;
    const int blk = (k2 & 24) ^ ((fg & 3) << 3);
    uint* dst = (uint*)sbT[buf];
#pragma unroll
    for (int i = 0; i < 8; i++) {
      float av = bf2f(pa[i]), bv = bf2f(pbu[i]);
      cs[i] += av + bv;
      unsigned val = (unsigned)pa[i] | ((unsigned)pbu[i] << 16);
      int f = fg * 8 + i;
      dst[f * 16 + ((blk + (k2 & 7)) >> 1)] = val;
    }
    if (g0 < N) {
      unsigned w0 = pack_fp8x4(bf2f(pa[0]) * sc0, bf2f(pa[1]) * sc0,
                               bf2f(pa[2]) * sc0, bf2f(pa[3]) * sc0);
      unsigned w1 = pack_fp8x4(bf2f(pa[4]) * sc0, bf2f(pa[5]) * sc0,
                               bf2f(pa[6]) * sc0, bf2f(pa[7]) * sc0);
      *(uint2*)&Rf8[(size_t)g0 * 64 + fg * 2] = make_uint2(w0, w1);
    }
    if (g0 + 1 < N) {
      unsigned w0 = pack_fp8x4(bf2f(pbu[0]) * sc1, bf2f(pbu[1]) * sc1,
                               bf2f(pbu[2]) * sc1, bf2f(pbu[3]) * sc1);
      unsigned w1 = pack_fp8x4(bf2f(pbu[4]) * sc1, bf2f(pbu[5]) * sc1,
                               bf2f(pbu[6]) * sc1, bf2f(pbu[7]) * sc1);
      *(uint2*)&Rf8[(size_t)(g0 + 1) * 64 + fg * 2] = make_uint2(w0, w1);
    }
  };

  auto compute = [&](int buf) {
    const ushort* bp = sbT[buf];
#pragma unroll
    for (int ks = 0; ks < 2; ks++) {
      const int kb = ks * 16 + lhi * 8;
      FragU fr[6];
#pragma unroll
      for (int s = 0; s < 6; s++) {
        const int cb = (s < 4) ? (wrow + 32 * s + l31) : (wcol + 32 * (s - 4) + l31);
        const int off = cb * 32 + (kb ^ (((cb >> 3) & 3) << 3));
        *(int4*)fr[s].u = *(const int4*)(bp + off);
      }
#pragma unroll
      for (int s = 0; s < 4; s++)
#pragma unroll
        for (int t = 0; t < 2; t++)
          acc[s][t] = __builtin_amdgcn_mfma_f32_32x32x16_bf16(fr[s].v, fr[4 + t].v,
                                                              acc[s][t], 0, 0, 0);
    }
  };

  load_chunk(0);
  write_chunk(0, 0);
  __syncthreads();
  int cur = 0;
  for (int c = 0; c < nch; c++) {
    if (c + 1 < nch) load_chunk(c + 1);
    compute(cur);
    if (c + 1 < nch) write_chunk(c + 1, cur ^ 1);
    __syncthreads();
    cur ^= 1;
  }

  // non-atomic bf16 partial-G slab write
  ushort* Gs = Gslab + (size_t)b * 65536;
#pragma unroll
  for (int s = 0; s < 4; s++)
#pragma unroll
    for (int t = 0; t < 2; t++) {
      const int n0c = wcol + 32 * t + l31;
#pragma unroll
      for (int r = 0; r < 16; r++) {
        const int row = wrow + 32 * s + (r & 3) + 8 * (r >> 2) + 4 * lhi;
        Gs[row * 256 + n0c] = f2bf(acc[s][t][r]);
      }
    }

  // column-sum slab (non-atomic)
  __syncthreads();
  float* fl = (float*)sbT;  // scratch
#pragma unroll
  for (int i = 0; i < 8; i++) fl[rp * 256 + fg * 8 + i] = cs[i];
  __syncthreads();
  if (tid < 256) {
    float v = 0.0f;
    for (int j = 0; j < 16; j++) v += fl[j * 256 + tid];
    csl[(size_t)b * 256 + tid] = v;
  }
}

// reduce bf16 slabs -> fp32 G; also vsum and <G,Q>/<G,K2> partials (non-atomic)
__global__ void k_Gr(const ushort* __restrict__ Gslab, const float* __restrict__ csl,
                     const float* __restrict__ Q, const float* __restrict__ K2,
                     float* __restrict__ G, float* __restrict__ vsum,
                     float2* __restrict__ spart, int nslab) {
  __shared__ float red[4];
  const int b = blockIdx.x, t = threadIdx.x;
  const int i = b * 256 + t;
  float s0 = 0, s1 = 0, s2 = 0, s3 = 0;
  int j = 0;
  for (; j + 3 < nslab; j += 4) {
    s0 += bf2f(Gslab[(size_t)j * 65536 + i]);
    s1 += bf2f(Gslab[(size_t)(j + 1) * 65536 + i]);
    s2 += bf2f(Gslab[(size_t)(j + 2) * 65536 + i]);
    s3 += bf2f(Gslab[(size_t)(j + 3) * 65536 + i]);
  }
  float s = s0 + s1 + s2 + s3;
  for (; j < nslab; j++) s += bf2f(Gslab[(size_t)j * 65536 + i]);
  G[i] = s;
  float dq = block_sum(s * Q[i], red);
  float dk = block_sum(s * K2[i], red);
  if (t == 0) spart[b] = make_float2(dq, dk);
  float v = 0.0f;
  for (int u = t; u < nslab; u += 256) v += csl[(size_t)u * 256 + b];
  v = block_sum(v, red);
  if (t == 0) vsum[b] = v;
}

// per-iteration small products; block 258 finalizes scal
__global__ void k_small(const float* __restrict__ G, const float* __restrict__ vsum,
                        const float* __restrict__ P, const float* __restrict__ pb,
                        const float* __restrict__ wb, const float* __restrict__ sconst,
                        const float* __restrict__ qb, const float* __restrict__ kbv,
                        const float2* __restrict__ spart,
                        ushort* __restrict__ Mt, float* __restrict__ cvec,
                        float* __restrict__ dvec, float* __restrict__ scal, int N) {
  __shared__ float red[4];
  const int b = blockIdx.x, tid = threadIdx.x;
  if (b < 256) {
    float acc = 0.0f;
    for (int m = 0; m < H; m++) acc = fmaf(P[b * H + m], G[m * H + tid], acc);
    Mt[(size_t)tid * H + b] = f2bf(acc + pb[b] * vsum[tid]);
  } else if (b == 256) {
    float acc = 0.0f;
    for (int f = 0; f < H; f++) acc = fmaf(wb[f], G[f * H + tid], acc);
    cvec[tid] = acc + sconst[0] * vsum[tid];
  } else if (b == 257) {
    float acc = 0.0f;
    for (int m = 0; m < H; m++) acc = fmaf(P[tid * H + m], vsum[m], acc);
    dvec[tid] = acc + (float)N * pb[tid];
  } else {
    float2 sp = spart[tid];
    float dq = block_sum(sp.x, red);
    float dk = block_sum(sp.y, red);
    float s1 = block_sum(qb[tid] * vsum[tid], red);
    float s2 = block_sum(kbv[tid] * vsum[tid], red);
    float s3 = block_sum(wb[tid] * vsum[tid], red);
    if (tid == 0) {
      float sq = dq + 2.0f * s1 + (float)N * sconst[1];
      float sk = dk + 2.0f * s2 + (float)N * sconst[2];
      scal[2] = 1.0f / (sqrtf(sq) * sqrtf(sk));
      scal[3] = s3 + (float)N * sconst[0];
    }
  }
}

// fused k_C: phase 1 computes num = R*M via MFMA into LDS (kills k_N + numb
// round trip); phase 2 = den, fp8 gather, blend, LN, readout.
__global__ __launch_bounds__(256) void k_C(
    const ushort* __restrict__ Rb, ushort* __restrict__ Rnext,
    const ushort* __restrict__ Mt, const unsigned* __restrict__ Rf8,
    const int* __restrict__ eb, const float* __restrict__ invs,
    const float* __restrict__ cvec, const float* __restrict__ dvec,
    const float* __restrict__ vsum, const float* __restrict__ scal,
    const int* __restrict__ offs16, const int* __restrict__ deg,
    const float* __restrict__ alphap, const float* __restrict__ gamma,
    const float* __restrict__ beta, const float* __restrict__ Wr,
    const float* __restrict__ br, const float* __restrict__ wgt,
    float* __restrict__ out, int N, int layer, int last) {
  __shared__ __align__(16) float lnum[32 * 256];  // 32 KB
  const int tid = threadIdx.x, lane = tid & 63, wv = tid >> 6;
  const int half = lane >> 5, hl = lane & 31;
  const int d0 = hl * 8;
  const int nb0 = blockIdx.x * 32;

  // ---- phase 1: num tile via MFMA (A rows from Rb, B cols from Mt[n][k]) ----
  {
    f32x16 a0, a1;
#pragma unroll
    for (int e = 0; e < 16; e++) { a0[e] = 0.0f; a1[e] = 0.0f; }
    const int wcol = wv * 64;
    const ushort* aptr = Rb + (size_t)(nb0 + hl) * H;       // rows beyond N: garbage ok (unread)
    const ushort* bptr0 = Mt + (size_t)(wcol + hl) * H;
    const ushort* bptr1 = Mt + (size_t)(wcol + 32 + hl) * H;
    for (int kc = 0; kc < 16; kc++) {
      const int kb = kc * 16 + half * 8;
      FragU fa, fb0, fb1;
      *(int4*)fa.u = *(const int4*)(aptr + kb);
      *(int4*)fb0.u = *(const int4*)(bptr0 + kb);
      *(int4*)fb1.u = *(const int4*)(bptr1 + kb);
      a0 = __builtin_amdgcn_mfma_f32_32x32x16_bf16(fa.v, fb0.v, a0, 0, 0, 0);
      a1 = __builtin_amdgcn_mfma_f32_32x32x16_bf16(fa.v, fb1.v, a1, 0, 0, 0);
    }
#pragma unroll
    for (int r = 0; r < 16; r++) {
      const int row = (r & 3) + 8 * (r >> 2) + 4 * half;
      lnum[row * 256 + wcol + hl] = a0[r];
      lnum[row * 256 + wcol + 32 + hl] = a1[r];
    }
  }
  __syncthreads();

  const float invn = scal[2], denc = scal[3];
  const float al = alphap[0], om = 1.0f - al;
  const float4 dvA = *(const float4*)&dvec[d0];
  const float4 dvB = *(const float4*)&dvec[d0 + 4];
  const float4 cvA = *(const float4*)&cvec[d0];
  const float4 cvB = *(const float4*)&cvec[d0 + 4];
  const float4 vsA = *(const float4*)&vsum[d0];
  const float4 vsB = *(const float4*)&vsum[d0 + 4];
  const float4 gmA = *(const float4*)&gamma[d0];
  const float4 gmB = *(const float4*)&gamma[d0 + 4];
  const float4 btA = *(const float4*)&beta[d0];
  const float4 btB = *(const float4*)&beta[d0 + 4];
  const float4 wrA = *(const float4*)&Wr[layer * H + d0];
  const float4 wrB = *(const float4*)&Wr[layer * H + d0 + 4];
  const float wl = wgt[layer], bl = br[layer];

  for (int r = 0; r < 4; r++) {
    const int lr = wv * 8 + r * 2 + half;
    const int n = nb0 + lr;
    const bool valid = n < N;
    const int ns = valid ? n : 0;

    const int4 rv = *(const int4*)&Rb[(size_t)ns * H + d0];
    const ushort* rp = (const ushort*)&rv;
    const float4 nvA = *(const float4*)&lnum[lr * 256 + d0];
    const float4 nvB = *(const float4*)&lnum[lr * 256 + d0 + 4];
    float old[8];
#pragma unroll
    for (int j = 0; j < 8; j++) old[j] = bf2f(rp[j]);
    const float num[8] = {nvA.x, nvA.y, nvA.z, nvA.w, nvB.x, nvB.y, nvB.z, nvB.w};

    float p = old[0] * dvA.x + old[1] * dvA.y + old[2] * dvA.z + old[3] * dvA.w +
              old[4] * dvB.x + old[5] * dvB.y + old[6] * dvB.z + old[7] * dvB.w;
    p = half_sum(p);
    const float rden = 1.0f / ((p + denc) * invn + (float)N);

    f32x2 a01 = {0.f, 0.f}, a23 = {0.f, 0.f}, a45 = {0.f, 0.f}, a67 = {0.f, 0.f};
    const int st = offs16[ns];
    const int nbch = valid ? ((deg[ns] + 15) >> 4) : 0;
    const int4* pe = (const int4*)(eb + st);
    const int woff = hl * 2;
    for (int b = 0; b < nbch; b++, pe += 4) {
      int4 q0 = pe[0], q1 = pe[1], q2 = pe[2], q3 = pe[3];
      const int srcs[16] = {q0.x, q0.y, q0.z, q0.w, q1.x, q1.y, q1.z, q1.w,
                            q2.x, q2.y, q2.z, q2.w, q3.x, q3.y, q3.z, q3.w};
      uint2 g[16];
#pragma unroll
      for (int i = 0; i < 16; i++)
        g[i] = *(const uint2*)&Rf8[((size_t)srcs[i] << 6) + woff];
#pragma unroll
      for (int i = 0; i < 16; i++) {
        unpack_fp8x2_acc(a01, a23, g[i].x);
        unpack_fp8x2_acc(a45, a67, g[i].y);
      }
    }
    const float sn = invs[ns];
    float ag[8] = {a01[0] * sn, a01[1] * sn, a23[0] * sn, a23[1] * sn,
                   a45[0] * sn, a45[1] * sn, a67[0] * sn, a67[1] * sn};

    const float cva[8] = {cvA.x, cvA.y, cvA.z, cvA.w, cvB.x, cvB.y, cvB.z, cvB.w};
    const float vsa[8] = {vsA.x, vsA.y, vsA.z, vsA.w, vsB.x, vsB.y, vsB.z, vsB.w};
    float hv[8];
#pragma unroll
    for (int j = 0; j < 8; j++)
      hv[j] = al * (((num[j] + cva[j]) * invn + vsa[j]) * rden + ag[j]) + om * old[j];

    float s = 0.0f, s2 = 0.0f;
#pragma unroll
    for (int j = 0; j < 8; j++) { s += hv[j]; s2 += hv[j] * hv[j]; }
    s = half_sum(s);
    s2 = half_sum(s2);
    const float mu = s * (1.0f / H);
    const float var = s2 * (1.0f / H) - mu * mu;
    const float rs = rsqrtf(var + LN_EPS);

    const float gma[8] = {gmA.x, gmA.y, gmA.z, gmA.w, gmB.x, gmB.y, gmB.z, gmB.w};
    const float bta[8] = {btA.x, btA.y, btA.z, btA.w, btB.x, btB.y, btB.z, btB.w};
    const float wra[8] = {wrA.x, wrA.y, wrA.z, wrA.w, wrB.x, wrB.y, wrB.z, wrB.w};
    float y[8], rp2 = 0.0f;
    ushort yo[8];
#pragma unroll
    for (int j = 0; j < 8; j++) {
      y[j] = (hv[j] - mu) * rs * gma[j] + bta[j];
      yo[j] = f2bf(y[j]);
      rp2 += y[j] * wra[j];
    }
    if (!last && valid) *(int4*)&Rnext[(size_t)n * H + d0] = *(int4*)yo;
    rp2 = half_sum(rp2);
    if (hl == 0 && valid) out[n] += wl * (rp2 + bl);
  }
}

// ---------------- host ----------------

extern "C" void kernel_launch(void* const* d_in, const int* in_sizes, int n_in,
                              void* d_out, int out_size, void* d_ws, size_t ws_size,
                              hipStream_t stream) {
  const float* x = (const float*)d_in[0];
  const int* ei = (const int*)d_in[1];
  const float* W1 = (const float*)d_in[2];
  const float* b1 = (const float*)d_in[3];
  const float* Wq = (const float*)d_in[4];
  const float* bq = (const float*)d_in[5];
  const float* Wk = (const float*)d_in[6];
  const float* bk = (const float*)d_in[7];
  const float* gamma = (const float*)d_in[8];
  const float* beta = (const float*)d_in[9];
  const float* alphap = (const float*)d_in[10];
  const float* Wr = (const float*)d_in[11];
  const float* br = (const float*)d_in[12];
  const float* wgt = (const float*)d_in[13];
  float* out = (float*)d_out;

  const int N = in_sizes[0] / FIN;
  const int E = in_sizes[1] / 2;
  const int* row = ei;
  const int* col = ei + E;

  char* w = (char*)d_ws;
  auto alloc = [&](size_t bytes) -> char* {
    char* p = w;
    w += (bytes + 255) & ~(size_t)255;
    return p;
  };
  const size_t RB = (size_t)(N + 128) * H * sizeof(ushort);
  ushort* Rb0 = (ushort*)alloc(RB);
  ushort* Rb1 = (ushort*)alloc(RB);   // aliased as super-bin record scratch in setup
  ushort* Gslab = (ushort*)alloc((size_t)256 * 65536 * sizeof(ushort));  // 32 MB
  unsigned* Rf8 = (unsigned*)alloc((size_t)(N + 1) * 64 * sizeof(unsigned));  // +1 zero row
  ushort* Mt = (ushort*)alloc(H * H * sizeof(ushort));
  float* G = (float*)alloc(H * H * sizeof(float));
  float* vsum = (float*)alloc(1024);
  float* scal = (float*)alloc(256);
  float* cvec = (float*)alloc(1024);
  float* dvec = (float*)alloc(1024);
  float* P = (float*)alloc(H * H * sizeof(float));
  float* Q = (float*)alloc(H * H * sizeof(float));
  float* K2 = (float*)alloc(H * H * sizeof(float));
  float* pb = (float*)alloc(1024);
  float* qb = (float*)alloc(1024);
  float* wb = (float*)alloc(1024);
  float* kb = (float*)alloc(1024);
  float* sconst = (float*)alloc(256);
  int* deg = (int*)alloc((size_t)N * 4);
  float* invs = (float*)alloc((size_t)N * 4);
  int* offs16 = (int*)alloc((size_t)(N + 1) * 4);
  int* bsum = (int*)alloc(1024 * 4);
  int* gcnt = (int*)alloc(64 * 4);
  const int nbG = 256;  // even chunk partition
  float* csl = (float*)alloc((size_t)nbG * 256 * sizeof(float));
  float2* spart = (float2*)alloc(256 * sizeof(float2));
  size_t EPAD = (size_t)E + 16 * (size_t)N;
  EPAD = (EPAD + 3) & ~(size_t)3;
  int* eb = (int*)alloc(EPAD * sizeof(int));

  const int NSB = (N + (1 << SBW) - 1) >> SBW;  // super-bins (<=64 for N<=131072)
  int cap2 = (E / (NSB > 0 ? NSB : 1)) * 2 + 4096;
  cap2 = (cap2 + 3) & ~3;
  unsigned* breg = (unsigned*)Rb1;  // NSB*cap2*4B <= RB

  hipMemsetAsync(gcnt, 0, 64 * 4, stream);
  hipMemsetAsync(Rf8 + (size_t)N * 64, 0, 64 * sizeof(unsigned), stream);

  const int nblk = (N + 1023) / 1024;
  const int nbB1 = (E + EPB - 1) / EPB;
  k_b1<<<nbB1, 512, 0, stream>>>(row, col, breg, gcnt, cap2, E, NSB);
  k_degB2<<<NSB, 512, 0, stream>>>(breg, gcnt, cap2, deg, invs, N);
  k_scan1<<<nblk, 1024, 0, stream>>>(deg, offs16, bsum, N);
  k_scan2<<<1, 1024, 0, stream>>>(bsum, nblk);
  k_b2<<<NSB, 512, 0, stream>>>(breg, gcnt, cap2, offs16, bsum, eb, N);
  k_prep<<<769, 256, 0, stream>>>(Wq, Wk, bq, bk, P, Q, K2, pb, qb, wb, kb, sconst);
  const int gRows16 = (N + 15) / 16;
  k_fc1<<<gRows16, 256, 0, stream>>>(x, W1, b1, Wr, br, wgt, Rb0, out, N);

  const int gRows32 = (N + 31) / 32;
  ushort* Rc = Rb0;
  ushort* Rn = Rb1;
  for (int it = 1; it <= 3; ++it) {
    k_Gm<<<nbG, 512, 0, stream>>>(Rc, invs, Gslab, Rf8, csl, N);
    k_Gr<<<256, 256, 0, stream>>>(Gslab, csl, Q, K2, G, vsum, spart, nbG);
    k_small<<<259, 256, 0, stream>>>(G, vsum, P, pb, wb, sconst, qb, kb, spart,
                                     Mt, cvec, dvec, scal, N);
    k_C<<<gRows32, 256, 0, stream>>>(Rc, Rn, Mt, Rf8, eb, invs, cvec, dvec, vsum, scal,
                                     offs16, deg, alphap, gamma, beta, Wr, br, wgt, out,
                                     N, it, (it == 3) ? 1 : 0);
    ushort* t = Rc; Rc = Rn; Rn = t;
  }
}

// Round 14
// 1029.592 us; speedup vs baseline: 5.0159x; 1.0283x over previous
//
#include <hip/hip_runtime.h>

#define H 256
#define FIN 58
#define LN_EPS 1e-5f
#define EPB 8192     // k_b1 edges per block
#define SBW 11       // super-bin width: 2048 dests

typedef __bf16 bf16x8 __attribute__((ext_vector_type(8)));
typedef float f32x16 __attribute__((ext_vector_type(16)));
typedef float f32x2 __attribute__((ext_vector_type(2)));

union FragU {
  ushort u[8];
  bf16x8 v;
};

// ---------------- utilities ----------------

__device__ __forceinline__ float wave_sum(float v) {
#pragma unroll
  for (int off = 1; off < 64; off <<= 1) v += __shfl_xor(v, off, 64);
  return v;
}

__device__ __forceinline__ float half_sum(float v) {
#pragma unroll
  for (int off = 1; off < 32; off <<= 1) v += __shfl_xor(v, off, 64);
  return v;
}

__device__ __forceinline__ float block_sum(float v, volatile float* red) {
  const int tid = threadIdx.x;
  v = wave_sum(v);
  __syncthreads();
  if ((tid & 63) == 0) red[tid >> 6] = v;
  __syncthreads();
  return red[0] + red[1] + red[2] + red[3];
}

__device__ __forceinline__ ushort f2bf(float f) {
  unsigned u = __float_as_uint(f);
  unsigned r = (u + 0x7FFFu + ((u >> 16) & 1u)) >> 16;
  return (ushort)r;
}

__device__ __forceinline__ float bf2f(ushort u) {
  return __uint_as_float((unsigned)u << 16);
}

// ---- fp8 e4m3 pack/unpack (HW path on gfx950, manual fallback) ----
#if __has_builtin(__builtin_amdgcn_cvt_pk_fp8_f32) && __has_builtin(__builtin_amdgcn_cvt_pk_f32_fp8)
__device__ __forceinline__ unsigned pack_fp8x4(float a, float b, float c, float d) {
  int v = 0;
  v = __builtin_amdgcn_cvt_pk_fp8_f32(a, b, v, false);
  v = __builtin_amdgcn_cvt_pk_fp8_f32(c, d, v, true);
  return (unsigned)v;
}
__device__ __forceinline__ void unpack_fp8x2_acc(f32x2& lo, f32x2& hi, unsigned v) {
  lo += __builtin_amdgcn_cvt_pk_f32_fp8((int)v, false);
  hi += __builtin_amdgcn_cvt_pk_f32_fp8((int)v, true);
}
#else
__device__ __forceinline__ unsigned char f2e4m3_1(float f) {
  unsigned u = __float_as_uint(f);
  unsigned s = (u >> 31) << 7;
  float a = fabsf(f);
  if (a >= 448.0f) return (unsigned char)(s | 0x7E);
  if (a < 0.0009765625f) return (unsigned char)s;
  int e;
  float m = frexpf(a, &e);
  int E = e - 1 + 7;
  if (E >= 1) {
    int mm = (int)rintf((m * 2.0f - 1.0f) * 8.0f);
    if (mm == 8) { mm = 0; E++; }
    return (unsigned char)(s | (E << 3) | mm);
  }
  int mm = (int)rintf(a * 512.0f);
  if (mm > 7) return (unsigned char)(s | (1 << 3));
  return (unsigned char)(s | mm);
}
__device__ __forceinline__ unsigned pack_fp8x4(float a, float b, float c, float d) {
  return (unsigned)f2e4m3_1(a) | ((unsigned)f2e4m3_1(b) << 8) |
         ((unsigned)f2e4m3_1(c) << 16) | ((unsigned)f2e4m3_1(d) << 24);
}
__device__ __forceinline__ float e4m3f_1(unsigned v) {
  int s = (v >> 7) & 1, E = (v >> 3) & 15, m = v & 7;
  float mag = E ? ldexpf(1.0f + m * 0.125f, E - 7) : ldexpf((float)m, -9);
  return s ? -mag : mag;
}
__device__ __forceinline__ void unpack_fp8x2_acc(f32x2& lo, f32x2& hi, unsigned v) {
  lo[0] += e4m3f_1(v & 255);
  lo[1] += e4m3f_1((v >> 8) & 255);
  hi[0] += e4m3f_1((v >> 16) & 255);
  hi[1] += e4m3f_1(v >> 24);
}
#endif

// ---------------- setup: radix-style CSR build ----------------

__global__ __launch_bounds__(512) void k_b1(const int* __restrict__ row,
                                            const int* __restrict__ col,
                                            unsigned* __restrict__ breg,
                                            int* __restrict__ gcnt,
                                            int cap2, int E, int nsb) {
  __shared__ unsigned stage[EPB];  // 32 KB
  __shared__ int lh[65], lbase[65], lcur[64], gclaim[64];
  const int tid = threadIdx.x;
  const int e0 = blockIdx.x * EPB;
  const int cnt = min(EPB, E - e0);
  if (tid < 64) lh[tid] = 0;
  __syncthreads();
  for (int i = tid; i < cnt; i += 512) atomicAdd(&lh[col[e0 + i] >> SBW], 1);
  __syncthreads();
  if (tid == 0) {
    int acc = 0;
    for (int b = 0; b < nsb; b++) { lbase[b] = acc; acc += lh[b]; }
    lbase[nsb] = acc;
  }
  __syncthreads();
  if (tid < nsb) {
    gclaim[tid] = atomicAdd(&gcnt[tid], lh[tid]);
    lcur[tid] = lbase[tid];
  }
  __syncthreads();
  for (int i = tid; i < cnt; i += 512) {
    int c = col[e0 + i];
    int b = c >> SBW;
    int s = atomicAdd(&lcur[b], 1);
    stage[s] = ((unsigned)row[e0 + i] << SBW) | (unsigned)(c & ((1 << SBW) - 1));
  }
  __syncthreads();
  for (int i = tid; i < cnt; i += 512) {
    int lo = 0, hi = nsb;
    while (hi - lo > 1) {
      int mid = (lo + hi) >> 1;
      if (lbase[mid] <= i) lo = mid; else hi = mid;
    }
    int off = gclaim[lo] + (i - lbase[lo]);
    if (off < cap2) breg[(size_t)lo * cap2 + off] = stage[i];
  }
}

// per-super-bin degree count + invs (fused)
__global__ __launch_bounds__(512) void k_degB2(const unsigned* __restrict__ breg,
                                               const int* __restrict__ gcnt, int cap2,
                                               int* __restrict__ deg,
                                               float* __restrict__ invs, int N) {
  __shared__ int lcnt[1 << SBW];
  const int b = blockIdx.x, tid = threadIdx.x, base = b << SBW;
  for (int i = tid; i < (1 << SBW); i += 512) lcnt[i] = 0;
  __syncthreads();
  const int cnt = min(gcnt[b], cap2);
  const unsigned* p = breg + (size_t)b * cap2;
  for (int i = tid; i < cnt; i += 512) atomicAdd(&lcnt[p[i] & ((1 << SBW) - 1)], 1);
  __syncthreads();
  for (int i = tid; i < (1 << SBW); i += 512) {
    int d = base + i;
    if (d < N) {
      int c = lcnt[i];
      deg[d] = c;
      invs[d] = (c > 0) ? (1.0f / sqrtf((float)c)) : 0.0f;
    }
  }
}

// level 2: place into final CSR; applies bsum fix-up and writes final offs16 back
__global__ __launch_bounds__(512) void k_b2(const unsigned* __restrict__ breg,
                                            const int* __restrict__ gcnt, int cap2,
                                            int* __restrict__ offs16,
                                            const int* __restrict__ bsum,
                                            int* __restrict__ eb, int N) {
  __shared__ int loffs[1 << SBW];
  __shared__ int lcur[1 << SBW];
  const int b = blockIdx.x, tid = threadIdx.x, base = b << SBW;
  for (int i = tid; i < (1 << SBW); i += 512) {
    int d = base + i;
    if (d < N) {
      int o = offs16[d] + bsum[d >> 10];
      loffs[i] = o;
      offs16[d] = o;  // final value for k_C
    } else {
      loffs[i] = 0;
    }
    lcur[i] = 0;
  }
  __syncthreads();
  const int cnt = min(gcnt[b], cap2);
  const unsigned* p = breg + (size_t)b * cap2;
  for (int i = tid; i < cnt; i += 512) {
    unsigned rc = p[i];
    int lc = rc & ((1 << SBW) - 1);
    int slot = atomicAdd(&lcur[lc], 1);
    eb[loffs[lc] + slot] = (int)(rc >> SBW);
  }
  __syncthreads();
  for (int i = tid; i < (1 << SBW); i += 512) {
    int d = base + i;
    if (d < N) {
      int c = lcur[i];
      int pad = (c + 15) & ~15;
      int o = loffs[i];
      for (int j = c; j < pad; j++) eb[o + j] = N;
    }
  }
}

__global__ __launch_bounds__(1024) void k_scan1(const int* __restrict__ deg,
                                                int* __restrict__ offs16,
                                                int* __restrict__ bsum, int N) {
  __shared__ int buf[1024];
  const int tid = threadIdx.x;
  const int gid = blockIdx.x * 1024 + tid;
  int v = (gid < N) ? ((deg[gid] + 15) & ~15) : 0;
  buf[tid] = v;
  __syncthreads();
  for (int off = 1; off < 1024; off <<= 1) {
    int x = (tid >= off) ? buf[tid - off] : 0;
    __syncthreads();
    buf[tid] += x;
    __syncthreads();
  }
  if (gid < N) offs16[gid] = buf[tid] - v;
  if (tid == 1023) bsum[blockIdx.x] = buf[1023];
}

__global__ __launch_bounds__(1024) void k_scan2(int* __restrict__ bsum, int nb) {
  __shared__ int buf[1024];
  const int tid = threadIdx.x;
  int v = (tid < nb) ? bsum[tid] : 0;
  buf[tid] = v;
  __syncthreads();
  for (int off = 1; off < 1024; off <<= 1) {
    int x = (tid >= off) ? buf[tid - off] : 0;
    __syncthreads();
    buf[tid] += x;
    __syncthreads();
  }
  if (tid < nb) bsum[tid] = buf[tid] - v;
}

// iteration-independent weight products
__global__ void k_prep(const float* __restrict__ Wq, const float* __restrict__ Wk,
                       const float* __restrict__ bq, const float* __restrict__ bk,
                       float* __restrict__ P, float* __restrict__ Q, float* __restrict__ K2,
                       float* __restrict__ pb, float* __restrict__ qb,
                       float* __restrict__ wb, float* __restrict__ kb,
                       float* __restrict__ sconst) {
  __shared__ float red[4];
  const int b = blockIdx.x, tid = threadIdx.x;
  if (b < 768) {
    const int f = b & 255, which = b >> 8;
    const float* A = (which == 2) ? Wk : Wq;
    const float* Bm = (which == 1) ? Wq : Wk;
    float acc = 0.0f;
    for (int m = 0; m < H; m++) acc = fmaf(A[f * H + m], Bm[tid * H + m], acc);
    float* D = (which == 0) ? P : ((which == 1) ? Q : K2);
    D[f * H + tid] = acc;
  } else {
    float a1 = 0, a2 = 0, a3 = 0, a4 = 0;
    for (int m = 0; m < H; m++) {
      float wqv = Wq[tid * H + m], wkv = Wk[tid * H + m];
      a1 = fmaf(wqv, bk[m], a1);
      a2 = fmaf(wqv, bq[m], a2);
      a3 = fmaf(wkv, bq[m], a3);
      a4 = fmaf(wkv, bk[m], a4);
    }
    pb[tid] = a1; qb[tid] = a2; wb[tid] = a3; kb[tid] = a4;
    float c0 = block_sum(bq[tid] * bk[tid], red);
    float c1 = block_sum(bq[tid] * bq[tid], red);
    float c2 = block_sum(bk[tid] * bk[tid], red);
    if (tid == 0) { sconst[0] = c0; sconst[1] = c1; sconst[2] = c2; }
  }
}

// R0 = relu(x@W1 + b1) -> bf16, plus layer-0 readout
__global__ void k_fc1(const float* __restrict__ x, const float* __restrict__ W1,
                      const float* __restrict__ b1, const float* __restrict__ Wr,
                      const float* __restrict__ br, const float* __restrict__ wgt,
                      ushort* __restrict__ R0, float* __restrict__ out, int N) {
  __shared__ __align__(16) float lx[16 * FIN];
  __shared__ float red2[4][16];
  const int tid = threadIdx.x;
  const int n0 = blockIdx.x * 16;
  for (int idx = tid; idx < 16 * FIN / 4; idx += 256)
    ((float4*)lx)[idx] = ((const float4*)(x + (size_t)n0 * FIN))[idx];
  __syncthreads();
  float acc[16];
  const float bias = b1[tid];
#pragma unroll
  for (int r = 0; r < 16; r++) acc[r] = bias;
  for (int f = 0; f < FIN; f++) {
    float wv = W1[f * H + tid];
#pragma unroll
    for (int r = 0; r < 16; r++) acc[r] = fmaf(lx[r * FIN + f], wv, acc[r]);
  }
  const float wr0 = Wr[tid];
#pragma unroll
  for (int r = 0; r < 16; r++) {
    acc[r] = fmaxf(acc[r], 0.0f);
    int n = n0 + r;
    if (n < N) R0[(size_t)n * H + tid] = f2bf(acc[r]);
  }
#pragma unroll
  for (int r = 0; r < 16; r++) {
    float s = wave_sum(acc[r] * wr0);
    if ((tid & 63) == 0) red2[tid >> 6][r] = s;
  }
  __syncthreads();
  if (tid < 16) {
    int n = n0 + tid;
    if (n < N)
      out[n] = wgt[0] * (red2[0][tid] + red2[1][tid] + red2[2][tid] + red2[3][tid] + br[0]);
  }
}

// ---------------- MFMA G = R^T R (transposed-LDS, b128 frags) ----------------
// Even 256-block chunk partition (critical path = ceil(TC/256) chunks).
__global__ __launch_bounds__(512, 2) void k_Gm(const ushort* __restrict__ Rb,
                                               const float* __restrict__ invs,
                                               ushort* __restrict__ Gslab,
                                               unsigned* __restrict__ Rf8,
                                               float* __restrict__ csl, int N) {
  __shared__ ushort sbT[2][256 * 32];  // 2 x 16 KB
  const int tid = threadIdx.x;
  const int lane = tid & 63;
  const int wid = tid >> 6;
  const int wrow = (wid & 1) * 128;
  const int wcol = (wid >> 1) * 64;
  const int l31 = lane & 31;
  const int lhi = lane >> 5;

  const int TC = (N + 31) >> 5;
  const int cbase = TC >> 8;
  const int crem = TC & 255;
  const int b = blockIdx.x;
  const int startc = b * cbase + min(b, crem);
  const int nch = cbase + (b < crem ? 1 : 0);
  const int rowbase = startc * 32;

  const int rp = tid >> 5;   // node pair (nodes 2rp, 2rp+1)
  const int fg = tid & 31;   // feature group (feats fg*8..fg*8+7)
  const int k2 = rp * 2;

  f32x16 acc[4][2];
#pragma unroll
  for (int s = 0; s < 4; s++)
#pragma unroll
    for (int t = 0; t < 2; t++)
#pragma unroll
      for (int e = 0; e < 16; e++) acc[s][t][e] = 0.0f;

  float cs[8];
#pragma unroll
  for (int i = 0; i < 8; i++) cs[i] = 0.0f;

  int4 la, lb;
  float sc0, sc1;

  auto load_chunk = [&](int ch) {
    int g0 = rowbase + ch * 32 + k2;
    const int4* s0 = (const int4*)(Rb + (size_t)g0 * H + fg * 8);
    const int4* s1 = (const int4*)(Rb + (size_t)(g0 + 1) * H + fg * 8);
    la = (g0 < N) ? s0[0] : make_int4(0, 0, 0, 0);
    lb = (g0 + 1 < N) ? s1[0] : make_int4(0, 0, 0, 0);
    sc0 = (g0 < N) ? invs[g0] : 0.0f;
    sc1 = (g0 + 1 < N) ? invs[g0 + 1] : 0.0f;
  };

  auto write_chunk = [&](int ch, int buf) {
    int g0 = rowbase + ch * 32 + k2;
    const ushort* pa = (const ushort*)&la;
    const ushort* pbu = (const ushort*)&lb;
    const int blk = (k2 & 24) ^ ((fg & 3) << 3);
    uint* dst = (uint*)sbT[buf];
#pragma unroll
    for (int i = 0; i < 8; i++) {
      float av = bf2f(pa[i]), bv = bf2f(pbu[i]);
      cs[i] += av + bv;
      unsigned val = (unsigned)pa[i] | ((unsigned)pbu[i] << 16);
      int f = fg * 8 + i;
      dst[f * 16 + ((blk + (k2 & 7)) >> 1)] = val;
    }
    if (g0 < N) {
      unsigned w0 = pack_fp8x4(bf2f(pa[0]) * sc0, bf2f(pa[1]) * sc0,
                               bf2f(pa[2]) * sc0, bf2f(pa[3]) * sc0);
      unsigned w1 = pack_fp8x4(bf2f(pa[4]) * sc0, bf2f(pa[5]) * sc0,
                               bf2f(pa[6]) * sc0, bf2f(pa[7]) * sc0);
      *(uint2*)&Rf8[(size_t)g0 * 64 + fg * 2] = make_uint2(w0, w1);
    }
    if (g0 + 1 < N) {
      unsigned w0 = pack_fp8x4(bf2f(pbu[0]) * sc1, bf2f(pbu[1]) * sc1,
                               bf2f(pbu[2]) * sc1, bf2f(pbu[3]) * sc1);
      unsigned w1 = pack_fp8x4(bf2f(pbu[4]) * sc1, bf2f(pbu[5]) * sc1,
                               bf2f(pbu[6]) * sc1, bf2f(pbu[7]) * sc1);
      *(uint2*)&Rf8[(size_t)(g0 + 1) * 64 + fg * 2] = make_uint2(w0, w1);
    }
  };

  auto compute = [&](int buf) {
    const ushort* bp = sbT[buf];
#pragma unroll
    for (int ks = 0; ks < 2; ks++) {
      const int kb = ks * 16 + lhi * 8;
      FragU fr[6];
#pragma unroll
      for (int s = 0; s < 6; s++) {
        const int cb = (s < 4) ? (wrow + 32 * s + l31) : (wcol + 32 * (s - 4) + l31);
        const int off = cb * 32 + (kb ^ (((cb >> 3) & 3) << 3));
        *(int4*)fr[s].u = *(const int4*)(bp + off);
      }
#pragma unroll
      for (int s = 0; s < 4; s++)
#pragma unroll
        for (int t = 0; t < 2; t++)
          acc[s][t] = __builtin_amdgcn_mfma_f32_32x32x16_bf16(fr[s].v, fr[4 + t].v,
                                                              acc[s][t], 0, 0, 0);
    }
  };

  load_chunk(0);
  write_chunk(0, 0);
  __syncthreads();
  int cur = 0;
  for (int c = 0; c < nch; c++) {
    if (c + 1 < nch) load_chunk(c + 1);
    compute(cur);
    if (c + 1 < nch) write_chunk(c + 1, cur ^ 1);
    __syncthreads();
    cur ^= 1;
  }

  // non-atomic bf16 partial-G slab write
  ushort* Gs = Gslab + (size_t)b * 65536;
#pragma unroll
  for (int s = 0; s < 4; s++)
#pragma unroll
    for (int t = 0; t < 2; t++) {
      const int n0c = wcol + 32 * t + l31;
#pragma unroll
      for (int r = 0; r < 16; r++) {
        const int row = wrow + 32 * s + (r & 3) + 8 * (r >> 2) + 4 * lhi;
        Gs[row * 256 + n0c] = f2bf(acc[s][t][r]);
      }
    }

  // column-sum slab (non-atomic)
  __syncthreads();
  float* fl = (float*)sbT;  // scratch
#pragma unroll
  for (int i = 0; i < 8; i++) fl[rp * 256 + fg * 8 + i] = cs[i];
  __syncthreads();
  if (tid < 256) {
    float v = 0.0f;
    for (int j = 0; j < 16; j++) v += fl[j * 256 + tid];
    csl[(size_t)b * 256 + tid] = v;
  }
}

// reduce bf16 slabs -> fp32 G; also vsum and <G,Q>/<G,K2> partials (non-atomic)
__global__ void k_Gr(const ushort* __restrict__ Gslab, const float* __restrict__ csl,
                     const float* __restrict__ Q, const float* __restrict__ K2,
                     float* __restrict__ G, float* __restrict__ vsum,
                     float2* __restrict__ spart, int nslab) {
  __shared__ float red[4];
  const int b = blockIdx.x, t = threadIdx.x;
  const int i = b * 256 + t;
  float s0 = 0, s1 = 0, s2 = 0, s3 = 0;
  int j = 0;
  for (; j + 3 < nslab; j += 4) {
    s0 += bf2f(Gslab[(size_t)j * 65536 + i]);
    s1 += bf2f(Gslab[(size_t)(j + 1) * 65536 + i]);
    s2 += bf2f(Gslab[(size_t)(j + 2) * 65536 + i]);
    s3 += bf2f(Gslab[(size_t)(j + 3) * 65536 + i]);
  }
  float s = s0 + s1 + s2 + s3;
  for (; j < nslab; j++) s += bf2f(Gslab[(size_t)j * 65536 + i]);
  G[i] = s;
  float dq = block_sum(s * Q[i], red);
  float dk = block_sum(s * K2[i], red);
  if (t == 0) spart[b] = make_float2(dq, dk);
  float v = 0.0f;
  for (int u = t; u < nslab; u += 256) v += csl[(size_t)u * 256 + b];
  v = block_sum(v, red);
  if (t == 0) vsum[b] = v;
}

// per-iteration small products; block 258 finalizes scal
__global__ void k_small(const float* __restrict__ G, const float* __restrict__ vsum,
                        const float* __restrict__ P, const float* __restrict__ pb,
                        const float* __restrict__ wb, const float* __restrict__ sconst,
                        const float* __restrict__ qb, const float* __restrict__ kbv,
                        const float2* __restrict__ spart,
                        ushort* __restrict__ Mt, float* __restrict__ cvec,
                        float* __restrict__ dvec, float* __restrict__ scal, int N) {
  __shared__ float red[4];
  const int b = blockIdx.x, tid = threadIdx.x;
  if (b < 256) {
    float acc = 0.0f;
    for (int m = 0; m < H; m++) acc = fmaf(P[b * H + m], G[m * H + tid], acc);
    Mt[(size_t)tid * H + b] = f2bf(acc + pb[b] * vsum[tid]);
  } else if (b == 256) {
    float acc = 0.0f;
    for (int f = 0; f < H; f++) acc = fmaf(wb[f], G[f * H + tid], acc);
    cvec[tid] = acc + sconst[0] * vsum[tid];
  } else if (b == 257) {
    float acc = 0.0f;
    for (int m = 0; m < H; m++) acc = fmaf(P[tid * H + m], vsum[m], acc);
    dvec[tid] = acc + (float)N * pb[tid];
  } else {
    float2 sp = spart[tid];
    float dq = block_sum(sp.x, red);
    float dk = block_sum(sp.y, red);
    float s1 = block_sum(qb[tid] * vsum[tid], red);
    float s2 = block_sum(kbv[tid] * vsum[tid], red);
    float s3 = block_sum(wb[tid] * vsum[tid], red);
    if (tid == 0) {
      float sq = dq + 2.0f * s1 + (float)N * sconst[1];
      float sk = dk + 2.0f * s2 + (float)N * sconst[2];
      scal[2] = 1.0f / (sqrtf(sq) * sqrtf(sk));
      scal[3] = s3 + (float)N * sconst[0];
    }
  }
}

// fused k_C: phase 1 computes num = R*M via MFMA into bf16 LDS; phase 2 = den,
// fp8 gather, blend, LN, readout. 16KB LDS + min-4-waves/EU for occupancy.
__global__ __launch_bounds__(256, 4) void k_C(
    const ushort* __restrict__ Rb, ushort* __restrict__ Rnext,
    const ushort* __restrict__ Mt, const unsigned* __restrict__ Rf8,
    const int* __restrict__ eb, const float* __restrict__ invs,
    const float* __restrict__ cvec, const float* __restrict__ dvec,
    const float* __restrict__ vsum, const float* __restrict__ scal,
    const int* __restrict__ offs16, const int* __restrict__ deg,
    const float* __restrict__ alphap, const float* __restrict__ gamma,
    const float* __restrict__ beta, const float* __restrict__ Wr,
    const float* __restrict__ br, const float* __restrict__ wgt,
    float* __restrict__ out, int N, int layer, int last) {
  __shared__ __align__(16) ushort lnum[32 * 256];  // 16 KB (bf16)
  const int tid = threadIdx.x, lane = tid & 63, wv = tid >> 6;
  const int half = lane >> 5, hl = lane & 31;
  const int d0 = hl * 8;
  const int nb0 = blockIdx.x * 32;

  // ---- phase 1: num tile via MFMA (A rows from Rb, B cols from Mt[n][k]) ----
  {
    f32x16 a0, a1;
#pragma unroll
    for (int e = 0; e < 16; e++) { a0[e] = 0.0f; a1[e] = 0.0f; }
    const int wcol = wv * 64;
    const ushort* aptr = Rb + (size_t)(nb0 + hl) * H;  // rows beyond N: garbage ok (unread)
    const ushort* bptr0 = Mt + (size_t)(wcol + hl) * H;
    const ushort* bptr1 = Mt + (size_t)(wcol + 32 + hl) * H;
    for (int kc = 0; kc < 16; kc++) {
      const int kb = kc * 16 + half * 8;
      FragU fa, fb0, fb1;
      *(int4*)fa.u = *(const int4*)(aptr + kb);
      *(int4*)fb0.u = *(const int4*)(bptr0 + kb);
      *(int4*)fb1.u = *(const int4*)(bptr1 + kb);
      a0 = __builtin_amdgcn_mfma_f32_32x32x16_bf16(fa.v, fb0.v, a0, 0, 0, 0);
      a1 = __builtin_amdgcn_mfma_f32_32x32x16_bf16(fa.v, fb1.v, a1, 0, 0, 0);
    }
#pragma unroll
    for (int r = 0; r < 16; r++) {
      const int row = (r & 3) + 8 * (r >> 2) + 4 * half;
      lnum[row * 256 + wcol + hl] = f2bf(a0[r]);
      lnum[row * 256 + wcol + 32 + hl] = f2bf(a1[r]);
    }
  }
  __syncthreads();

  const float invn = scal[2], denc = scal[3];
  const float al = alphap[0], om = 1.0f - al;
  const float4 dvA = *(const float4*)&dvec[d0];
  const float4 dvB = *(const float4*)&dvec[d0 + 4];
  const float4 cvA = *(const float4*)&cvec[d0];
  const float4 cvB = *(const float4*)&cvec[d0 + 4];
  const float4 vsA = *(const float4*)&vsum[d0];
  const float4 vsB = *(const float4*)&vsum[d0 + 4];
  const float4 gmA = *(const float4*)&gamma[d0];
  const float4 gmB = *(const float4*)&gamma[d0 + 4];
  const float4 btA = *(const float4*)&beta[d0];
  const float4 btB = *(const float4*)&beta[d0 + 4];
  const float4 wrA = *(const float4*)&Wr[layer * H + d0];
  const float4 wrB = *(const float4*)&Wr[layer * H + d0 + 4];
  const float wl = wgt[layer], bl = br[layer];

  for (int r = 0; r < 4; r++) {
    const int lr = wv * 8 + r * 2 + half;
    const int n = nb0 + lr;
    const bool valid = n < N;
    const int ns = valid ? n : 0;

    const int4 rv = *(const int4*)&Rb[(size_t)ns * H + d0];
    const ushort* rp = (const ushort*)&rv;
    const int4 nv = *(const int4*)&lnum[lr * 256 + d0];
    const ushort* np = (const ushort*)&nv;
    float old[8], num[8];
#pragma unroll
    for (int j = 0; j < 8; j++) { old[j] = bf2f(rp[j]); num[j] = bf2f(np[j]); }

    float p = old[0] * dvA.x + old[1] * dvA.y + old[2] * dvA.z + old[3] * dvA.w +
              old[4] * dvB.x + old[5] * dvB.y + old[6] * dvB.z + old[7] * dvB.w;
    p = half_sum(p);
    const float rden = 1.0f / ((p + denc) * invn + (float)N);

    f32x2 a01 = {0.f, 0.f}, a23 = {0.f, 0.f}, a45 = {0.f, 0.f}, a67 = {0.f, 0.f};
    const int st = offs16[ns];
    const int nbch = valid ? ((deg[ns] + 15) >> 4) : 0;
    const int4* pe = (const int4*)(eb + st);
    const int woff = hl * 2;
    for (int b = 0; b < nbch; b++, pe += 4) {
      int4 q0 = pe[0], q1 = pe[1], q2 = pe[2], q3 = pe[3];
      const int srcs[16] = {q0.x, q0.y, q0.z, q0.w, q1.x, q1.y, q1.z, q1.w,
                            q2.x, q2.y, q2.z, q2.w, q3.x, q3.y, q3.z, q3.w};
      uint2 g[16];
#pragma unroll
      for (int i = 0; i < 16; i++)
        g[i] = *(const uint2*)&Rf8[((size_t)srcs[i] << 6) + woff];
#pragma unroll
      for (int i = 0; i < 16; i++) {
        unpack_fp8x2_acc(a01, a23, g[i].x);
        unpack_fp8x2_acc(a45, a67, g[i].y);
      }
    }
    const float sn = invs[ns];
    float ag[8] = {a01[0] * sn, a01[1] * sn, a23[0] * sn, a23[1] * sn,
                   a45[0] * sn, a45[1] * sn, a67[0] * sn, a67[1] * sn};

    const float cva[8] = {cvA.x, cvA.y, cvA.z, cvA.w, cvB.x, cvB.y, cvB.z, cvB.w};
    const float vsa[8] = {vsA.x, vsA.y, vsA.z, vsA.w, vsB.x, vsB.y, vsB.z, vsB.w};
    float hv[8];
#pragma unroll
    for (int j = 0; j < 8; j++)
      hv[j] = al * (((num[j] + cva[j]) * invn + vsa[j]) * rden + ag[j]) + om * old[j];

    float s = 0.0f, s2 = 0.0f;
#pragma unroll
    for (int j = 0; j < 8; j++) { s += hv[j]; s2 += hv[j] * hv[j]; }
    s = half_sum(s);
    s2 = half_sum(s2);
    const float mu = s * (1.0f / H);
    const float var = s2 * (1.0f / H) - mu * mu;
    const float rs = rsqrtf(var + LN_EPS);

    const float gma[8] = {gmA.x, gmA.y, gmA.z, gmA.w, gmB.x, gmB.y, gmB.z, gmB.w};
    const float bta[8] = {btA.x, btA.y, btA.z, btA.w, btB.x, btB.y, btB.z, btB.w};
    const float wra[8] = {wrA.x, wrA.y, wrA.z, wrA.w, wrB.x, wrB.y, wrB.z, wrB.w};
    float y[8], rp2 = 0.0f;
    ushort yo[8];
#pragma unroll
    for (int j = 0; j < 8; j++) {
      y[j] = (hv[j] - mu) * rs * gma[j] + bta[j];
      yo[j] = f2bf(y[j]);
      rp2 += y[j] * wra[j];
    }
    if (!last && valid) *(int4*)&Rnext[(size_t)n * H + d0] = *(int4*)yo;
    rp2 = half_sum(rp2);
    if (hl == 0 && valid) out[n] += wl * (rp2 + bl);
  }
}

// ---------------- host ----------------

extern "C" void kernel_launch(void* const* d_in, const int* in_sizes, int n_in,
                              void* d_out, int out_size, void* d_ws, size_t ws_size,
                              hipStream_t stream) {
  const float* x = (const float*)d_in[0];
  const int* ei = (const int*)d_in[1];
  const float* W1 = (const float*)d_in[2];
  const float* b1 = (const float*)d_in[3];
  const float* Wq = (const float*)d_in[4];
  const float* bq = (const float*)d_in[5];
  const float* Wk = (const float*)d_in[6];
  const float* bk = (const float*)d_in[7];
  const float* gamma = (const float*)d_in[8];
  const float* beta = (const float*)d_in[9];
  const float* alphap = (const float*)d_in[10];
  const float* Wr = (const float*)d_in[11];
  const float* br = (const float*)d_in[12];
  const float* wgt = (const float*)d_in[13];
  float* out = (float*)d_out;

  const int N = in_sizes[0] / FIN;
  const int E = in_sizes[1] / 2;
  const int* row = ei;
  const int* col = ei + E;

  char* w = (char*)d_ws;
  auto alloc = [&](size_t bytes) -> char* {
    char* p = w;
    w += (bytes + 255) & ~(size_t)255;
    return p;
  };
  const size_t RB = (size_t)(N + 128) * H * sizeof(ushort);
  ushort* Rb0 = (ushort*)alloc(RB);
  ushort* Rb1 = (ushort*)alloc(RB);   // aliased as super-bin record scratch in setup
  ushort* Gslab = (ushort*)alloc((size_t)256 * 65536 * sizeof(ushort));  // 32 MB
  unsigned* Rf8 = (unsigned*)alloc((size_t)(N + 1) * 64 * sizeof(unsigned));  // +1 zero row
  ushort* Mt = (ushort*)alloc(H * H * sizeof(ushort));
  float* G = (float*)alloc(H * H * sizeof(float));
  float* vsum = (float*)alloc(1024);
  float* scal = (float*)alloc(256);
  float* cvec = (float*)alloc(1024);
  float* dvec = (float*)alloc(1024);
  float* P = (float*)alloc(H * H * sizeof(float));
  float* Q = (float*)alloc(H * H * sizeof(float));
  float* K2 = (float*)alloc(H * H * sizeof(float));
  float* pb = (float*)alloc(1024);
  float* qb = (float*)alloc(1024);
  float* wb = (float*)alloc(1024);
  float* kb = (float*)alloc(1024);
  float* sconst = (float*)alloc(256);
  int* deg = (int*)alloc((size_t)N * 4);
  float* invs = (float*)alloc((size_t)N * 4);
  int* offs16 = (int*)alloc((size_t)(N + 1) * 4);
  int* bsum = (int*)alloc(1024 * 4);
  int* gcnt = (int*)alloc(64 * 4);
  const int nbG = 256;  // even chunk partition
  float* csl = (float*)alloc((size_t)nbG * 256 * sizeof(float));
  float2* spart = (float2*)alloc(256 * sizeof(float2));
  size_t EPAD = (size_t)E + 16 * (size_t)N;
  EPAD = (EPAD + 3) & ~(size_t)3;
  int* eb = (int*)alloc(EPAD * sizeof(int));

  const int NSB = (N + (1 << SBW) - 1) >> SBW;  // super-bins (<=64 for N<=131072)
  int cap2 = (E / (NSB > 0 ? NSB : 1)) * 2 + 4096;
  cap2 = (cap2 + 3) & ~3;
  unsigned* breg = (unsigned*)Rb1;  // NSB*cap2*4B <= RB

  hipMemsetAsync(gcnt, 0, 64 * 4, stream);
  hipMemsetAsync(Rf8 + (size_t)N * 64, 0, 64 * sizeof(unsigned), stream);

  const int nblk = (N + 1023) / 1024;
  const int nbB1 = (E + EPB - 1) / EPB;
  k_b1<<<nbB1, 512, 0, stream>>>(row, col, breg, gcnt, cap2, E, NSB);
  k_degB2<<<NSB, 512, 0, stream>>>(breg, gcnt, cap2, deg, invs, N);
  k_scan1<<<nblk, 1024, 0, stream>>>(deg, offs16, bsum, N);
  k_scan2<<<1, 1024, 0, stream>>>(bsum, nblk);
  k_b2<<<NSB, 512, 0, stream>>>(breg, gcnt, cap2, offs16, bsum, eb, N);
  k_prep<<<769, 256, 0, stream>>>(Wq, Wk, bq, bk, P, Q, K2, pb, qb, wb, kb, sconst);
  const int gRows16 = (N + 15) / 16;
  k_fc1<<<gRows16, 256, 0, stream>>>(x, W1, b1, Wr, br, wgt, Rb0, out, N);

  const int gRows32 = (N + 31) / 32;
  ushort* Rc = Rb0;
  ushort* Rn = Rb1;
  for (int it = 1; it <= 3; ++it) {
    k_Gm<<<nbG, 512, 0, stream>>>(Rc, invs, Gslab, Rf8, csl, N);
    k_Gr<<<256, 256, 0, stream>>>(Gslab, csl, Q, K2, G, vsum, spart, nbG);
    k_small<<<259, 256, 0, stream>>>(G, vsum, P, pb, wb, sconst, qb, kb, spart,
                                     Mt, cvec, dvec, scal, N);
    k_C<<<gRows32, 256, 0, stream>>>(Rc, Rn, Mt, Rf8, eb, invs, cvec, dvec, vsum, scal,
                                     offs16, deg, alphap, gamma, beta, Wr, br, wgt, out,
                                     N, it, (it == 3) ? 1 : 0);
    ushort* t = Rc; Rc = Rn; Rn = t;
  }
}